// Round 5
// baseline (1055.105 us; speedup 1.0000x reference)
//
#include <hip/hip_runtime.h>
#include <math.h>

#define NL 3
#define NB 32
#define NC 256
#define NC2 128
#define HZ 15
#define ZZ 225
#define XX 961
#define HMD 127

__device__ __forceinline__ float hat_int(float u){
  if (u <= -1.f) return 0.f;
  if (u <= 0.f){ float t = u + 1.f; return 0.5f*t*t; }
  if (u <= 1.f){ float t = 1.f - u; return 1.f - 0.5f*t*t; }
  return 1.f;
}
__device__ __forceinline__ float dot4(float4 a, float4 b){
  return a.x*b.x + a.y*b.y + a.z*b.z + a.w*b.w;
}

// ---------------- mask branch (batched over l) ----------------
__global__ __launch_bounds__(256) void k_mconv1(const float* __restrict__ mask,
    const float* __restrict__ wbase, const float* __restrict__ bbase, float* __restrict__ out){
  int idx = blockIdx.x*256 + threadIdx.x;
  const int OH=125, OW=125;
  if (idx >= NL*NB*4*OH*OW) return;
  int x = idx % OW, y = (idx/OW) % OH;
  int o = (idx/(OW*OH)) % 4; int lb = idx/(4*OW*OH);
  int l = lb/NB, b = lb%NB;
  const float* mb = mask + (size_t)b*HMD*HMD;
  const float* w = wbase + (size_t)l*4*2*9;
  float acc = bbase[l*4+o];
  #pragma unroll
  for (int ky=0;ky<3;ky++)
    #pragma unroll
    for (int kx=0;kx<3;kx++){
      float mv = mb[(y+ky)*HMD + (x+kx)];
      acc += w[((o*2+0)*3+ky)*3+kx]*mv;
      acc += w[((o*2+1)*3+ky)*3+kx]*(1.f-mv);
    }
  out[idx] = fmaxf(acc, 0.f);
}

__global__ __launch_bounds__(256) void k_mconv2(const float* __restrict__ in,
    const float* __restrict__ wbase, const float* __restrict__ bbase, float* __restrict__ out){
  int idx = blockIdx.x*256 + threadIdx.x;
  const int OH=123, OW=123, IH=125, IW=125;
  if (idx >= NL*NB*8*OH*OW) return;
  int x = idx % OW, y = (idx/OW) % OH;
  int o = (idx/(OW*OH)) % 8; int lb = idx/(8*OW*OH);
  int l = lb/NB;
  const float* w = wbase + (size_t)l*8*4*9;
  float acc = bbase[l*8+o];
  for (int ic=0; ic<4; ic++){
    const float* ib = in + (size_t)(lb*4+ic)*IH*IW;
    #pragma unroll
    for (int ky=0;ky<3;ky++)
      #pragma unroll
      for (int kx=0;kx<3;kx++)
        acc += w[((o*4+ic)*3+ky)*3+kx]*ib[(y+ky)*IW + (x+kx)];
  }
  out[idx] = fmaxf(acc, 0.f);
}

__global__ __launch_bounds__(256) void k_resize(const float* __restrict__ in, float* __restrict__ out,
    int total, int IH, int IW, int OH, int OW){
  int idx = blockIdx.x*256 + threadIdx.x;
  if (idx >= total) return;
  int ox = idx % OW, oy = (idx/OW) % OH;
  int bc = idx/(OW*OH);
  float sy = (float)((double)(IH-1)/(double)(OH-1));
  float sx = (float)((double)(IW-1)/(double)(OW-1));
  float yf = (float)oy * sy, xfv = (float)ox * sx;
  int y0 = (int)floorf(yf); y0 = min(max(y0,0), IH-2);
  int x0 = (int)floorf(xfv); x0 = min(max(x0,0), IW-2);
  float wy = yf - (float)y0, wx = xfv - (float)x0;
  const float* p = in + (size_t)bc*IH*IW;
  float v00=p[y0*IW+x0], v01=p[y0*IW+x0+1], v10=p[(y0+1)*IW+x0], v11=p[(y0+1)*IW+x0+1];
  out[idx] = (v00*(1.f-wy)+v10*wy)*(1.f-wx) + (v01*(1.f-wy)+v11*wy)*wx;
}

__global__ __launch_bounds__(256) void k_conv3x3_same(const float* __restrict__ in,
    const float* __restrict__ wbase, const float* __restrict__ bbase, float* __restrict__ out,
    int IC, int OC, int H, int W){
  int idx = blockIdx.x*256 + threadIdx.x;
  if (idx >= NL*NB*OC*H*W) return;
  int x = idx % W, y = (idx/W) % H;
  int o = (idx/(W*H)) % OC; int lb = idx/(OC*W*H);
  int l = lb/NB;
  const float* w = wbase + (size_t)l*OC*IC*9;
  float acc = bbase[l*OC+o];
  for (int ic=0; ic<IC; ic++){
    const float* ib = in + (size_t)(lb*IC+ic)*H*W;
    for (int ky=-1;ky<=1;ky++){
      int yy = y+ky; if (yy<0||yy>=H) continue;
      for (int kx=-1;kx<=1;kx++){
        int xx = x+kx; if (xx<0||xx>=W) continue;
        acc += w[((o*IC+ic)*3+(ky+1))*3+(kx+1)]*ib[yy*W+xx];
      }
    }
  }
  out[idx] = acc;
}

// ---------------- 64x64-tile fp32 GEMM, 4x4 per thread ----------------
// AMODE 0: A is [K][M] (stride M). AMODE 1: A is [M][K] (stride K).
// BMODE 0: B is [N][K] (stride K). BMODE 1: B is [K][N] (stride N).
template<int AMODE, int BMODE, bool BPERL, bool HASBIAS>
__global__ __launch_bounds__(256) void k_gemm64(
    const float* __restrict__ Abase, const float* __restrict__ Bbase,
    const float* __restrict__ biasbase, float* __restrict__ Obase,
    int M, int N, int K, int ntn)
{
  int lb = blockIdx.y; int l = lb / NB;
  const float* A = Abase + (size_t)lb*M*K;
  const float* B = Bbase + (BPERL ? (size_t)l : (size_t)lb)*N*K;
  float* out = Obase + (size_t)lb*M*N;
  int tm = blockIdx.x / ntn, tn = blockIdx.x % ntn;
  int m0 = tm*64, n0 = tn*64;
  __shared__ float As[32][68];
  __shared__ float Bs[32][68];
  int t = threadIdx.x;
  int tx = t & 15, ty = t >> 4;
  float acc[4][4] = {};
  for (int kc=0; kc<K; kc+=32){
    #pragma unroll
    for (int r=0;r<8;r++){
      int e = r*256 + t;
      int mm, kk;
      if (AMODE==0){ mm = e & 63; kk = e >> 6; }
      else { kk = e & 31; mm = e >> 5; }
      float va = 0.f;
      { int m = m0+mm, k = kc+kk;
        if (m < M && k < K)
          va = (AMODE==0) ? A[(size_t)k*M + m] : A[(size_t)m*K + k]; }
      As[kk][mm] = va;
      int nn, kk2;
      if (BMODE==0){ kk2 = e & 31; nn = e >> 5; }
      else { nn = e & 63; kk2 = e >> 6; }
      float vb = 0.f;
      { int n = n0+nn, k = kc+kk2;
        if (n < N && k < K)
          vb = (BMODE==0) ? B[(size_t)n*K + k] : B[(size_t)k*N + n]; }
      Bs[kk2][nn] = vb;
    }
    __syncthreads();
    #pragma unroll
    for (int kk=0; kk<32; kk++){
      float4 av = *(const float4*)&As[kk][ty*4];
      float4 bv = *(const float4*)&Bs[kk][tx*4];
      float aa[4] = {av.x, av.y, av.z, av.w};
      float bb[4] = {bv.x, bv.y, bv.z, bv.w};
      #pragma unroll
      for (int i=0;i<4;i++)
        #pragma unroll
        for (int j=0;j<4;j++)
          acc[i][j] += aa[i]*bb[j];
    }
    __syncthreads();
  }
  const float* bias = HASBIAS ? (biasbase + (size_t)l*N) : nullptr;
  #pragma unroll
  for (int i=0;i<4;i++){
    int m = m0 + ty*4 + i;
    if (m >= M) continue;
    #pragma unroll
    for (int j=0;j<4;j++){
      int n = n0 + tx*4 + j;
      if (n < N) out[(size_t)m*N + n] = acc[i][j] + (HASBIAS ? bias[n] : 0.f);
    }
  }
}

// ---------------- softmax rows of S (in place), fold 1/sqrt(C) ----------------
__global__ __launch_bounds__(256) void k_softmax(float* __restrict__ S){
  int row = blockIdx.x*4 + (threadIdx.x >> 6);
  int lane = threadIdx.x & 63;
  float* r = S + (size_t)row*ZZ;
  float v[4]; float mx = -1e30f;
  #pragma unroll
  for (int q=0;q<4;q++){
    int j = lane + q*64;
    v[q] = (j<ZZ) ? r[j] : -1e30f;
    mx = fmaxf(mx, v[q]);
  }
  #pragma unroll
  for (int off=32; off>0; off>>=1) mx = fmaxf(mx, __shfl_xor(mx, off));
  float sum = 0.f;
  #pragma unroll
  for (int q=0;q<4;q++){
    v[q] = __expf(v[q]-mx);
    if (lane + q*64 < ZZ) sum += v[q];
  }
  #pragma unroll
  for (int off=32; off>0; off>>=1) sum += __shfl_xor(sum, off);
  float inv = 1.f/(16.f*sum);
  #pragma unroll
  for (int q=0;q<4;q++){
    int j = lane + q*64;
    if (j<ZZ) r[j] = v[q]*inv;
  }
}

// ---------------- outconv: 64x64 GEMM + BN/cues/residual epilogue ----------------
__global__ __launch_bounds__(256) void k_outconv(const float* __restrict__ Y,
    const float* __restrict__ outw, const float* __restrict__ bng, const float* __restrict__ bnb,
    const float* __restrict__ bnm, const float* __restrict__ bnv,
    const float* __restrict__ cues, const float* __restrict__ zf,
    float* __restrict__ dzfout, float* __restrict__ dzffull){
  int lb = blockIdx.y; int l = lb/NB;
  const float* A = outw + (size_t)l*NC*NC2;  // [c][k] stride NC2
  const float* B = Y + (size_t)lb*ZZ*NC2;    // [z][k] stride NC2
  int tm = blockIdx.x >> 2, tn = blockIdx.x & 3;
  int m0 = tm*64, n0 = tn*64;
  __shared__ float As[32][68];
  __shared__ float Bs[32][68];
  int t = threadIdx.x;
  int tx = t & 15, ty = t >> 4;
  float acc[4][4] = {};
  for (int kc=0; kc<NC2; kc+=32){
    #pragma unroll
    for (int r=0;r<8;r++){
      int e = r*256 + t;
      int kk = e & 31, mm = e >> 5;
      As[kk][mm] = A[(size_t)(m0+mm)*NC2 + kc+kk];
      float vb = 0.f;
      int n = n0+mm;
      if (n < ZZ) vb = B[(size_t)n*NC2 + kc+kk];
      Bs[kk][mm] = vb;
    }
    __syncthreads();
    #pragma unroll
    for (int kk=0; kk<32; kk++){
      float4 av = *(const float4*)&As[kk][ty*4];
      float4 bv = *(const float4*)&Bs[kk][tx*4];
      float aa[4] = {av.x, av.y, av.z, av.w};
      float bb[4] = {bv.x, bv.y, bv.z, bv.w};
      #pragma unroll
      for (int i=0;i<4;i++)
        #pragma unroll
        for (int j=0;j<4;j++)
          acc[i][j] += aa[i]*bb[j];
    }
    __syncthreads();
  }
  #pragma unroll
  for (int i=0;i<4;i++){
    int c = m0 + ty*4 + i;
    float scale = bng[l*NC+c] * rsqrtf(bnv[l*NC+c] + 1e-5f);
    float bm = bnm[l*NC+c], bb2 = bnb[l*NC+c];
    float cu = cues[(size_t)lb*NC + c];
    #pragma unroll
    for (int j=0;j<4;j++){
      int z = n0 + tx*4 + j;
      if (z >= ZZ) continue;
      float val = (acc[i][j] - bm)*scale + bb2;
      float zv = zf[((size_t)lb*NC + c)*ZZ + z];
      float rr = cu*zv + zv + val;
      dzffull[((size_t)lb*NC + c)*ZZ + z] = rr;
      int h = z/15, wv2 = z%15;
      if (h>=4 && h<11 && wv2>=4 && wv2<11)
        dzfout[((size_t)lb*NC + c)*49 + (h-4)*7 + (wv2-4)] = rr;
    }
  }
}

// ---------------- PrRoI pooling: block = (lb, 16-channel group) ----------------
__global__ __launch_bounds__(256) void k_rois(const float* __restrict__ zf,
    const float* __restrict__ box, float* __restrict__ rois){
  int lb = blockIdx.x; int b = lb % NB; int c0 = blockIdx.y*16;
  __shared__ float Wy[7][15], Wx[7][15];
  __shared__ float fld[16*ZZ];
  __shared__ float tmp[16][7][16];
  __shared__ float area_s;
  int t = threadIdx.x;
  const float* bx = box + b*4;
  const float SC = 15.0f/127.0f;
  float x1 = bx[0]*SC, y1 = bx[1]*SC, x2 = bx[2]*SC, y2 = bx[3]*SC;
  float bh = (y2-y1)/7.f, bw = (x2-x1)/7.f;
  if (t < 105){ int p=t/15, i=t%15;
    Wy[p][i] = hat_int(y1+(float)(p+1)*bh - (float)i) - hat_int(y1+(float)p*bh - (float)i); }
  else if (t < 210){ int q=(t-105)/15, i=(t-105)%15;
    Wx[q][i] = hat_int(x1+(float)(q+1)*bw - (float)i) - hat_int(x1+(float)q*bw - (float)i); }
  if (t == 255) area_s = fmaxf(bh*bw, 1e-6f);
  const float* src = zf + ((size_t)lb*NC + c0)*ZZ;
  for (int e=t; e<16*ZZ; e+=256) fld[e] = src[e];
  __syncthreads();
  float inv_area = 1.f/area_s;
  for (int e=t; e<16*105; e+=256){
    int w = e%15; int pc = e/15; int p = pc%7; int cc = pc/7;
    float s = 0.f;
    #pragma unroll
    for (int h=0;h<15;h++) s += Wy[p][h]*fld[cc*ZZ + h*15 + w];
    tmp[cc][p][w] = s;
  }
  __syncthreads();
  float* out = rois + ((size_t)lb*NC + c0)*49;
  for (int e=t; e<16*49; e+=256){
    int q = e%7; int pc = e/7; int p = pc%7; int cc = pc/7;
    float s = 0.f;
    #pragma unroll
    for (int w=0;w<15;w++) s += tmp[cc][p][w]*Wx[q][w];
    out[(size_t)cc*49 + p*7 + q] = s*inv_area;
  }
}

__global__ __launch_bounds__(256) void k_pool(const float* __restrict__ rois,
    float* __restrict__ pavg, float* __restrict__ pmax){
  int idx = blockIdx.x*256 + threadIdx.x;
  if (idx >= NL*NB*NC) return;
  const float* r = rois + (size_t)idx*49;
  float s = 0.f, m = -1e30f;
  #pragma unroll
  for (int i=0;i<49;i++){ float v = r[i]; s += v; m = fmaxf(m,v); }
  pavg[idx] = s/49.f;
  pmax[idx] = m;
}

// ---------------- MLP heads: wave-per-row, coalesced ----------------
__global__ __launch_bounds__(256) void k_mlp(const float* __restrict__ pavg, const float* __restrict__ pmax,
    const float* __restrict__ aw1, const float* __restrict__ ab1, const float* __restrict__ aw2, const float* __restrict__ ab2,
    const float* __restrict__ mw1, const float* __restrict__ mb1, const float* __restrict__ mw2, const float* __restrict__ mb2,
    float* __restrict__ zavg, float* __restrict__ zmax){
  int lb = blockIdx.x; int l = lb/NB;
  __shared__ __align__(16) float pin[NC];
  __shared__ __align__(16) float hid[NC2];
  int t = threadIdx.x, wid = t>>6, lane = t&63;
  for (int pass=0; pass<2; pass++){
    const float* pv  = pass ? pmax : pavg;
    const float* w1  = pass ? mw1 : aw1;
    const float* b1  = pass ? mb1 : ab1;
    const float* w2  = pass ? mw2 : aw2;
    const float* b2  = pass ? mb2 : ab2;
    float* zo        = pass ? zmax : zavg;
    pin[t] = pv[(size_t)lb*NC + t];
    __syncthreads();
    for (int r=wid; r<NC2; r+=4){
      const float* wr = w1 + (size_t)(l*NC2+r)*NC;
      float s = dot4(((const float4*)wr)[lane], ((const float4*)pin)[lane]);
      #pragma unroll
      for (int off=32; off>0; off>>=1) s += __shfl_xor(s, off);
      if (lane==0) hid[r] = fmaxf(s + b1[l*NC2+r], 0.f);
    }
    __syncthreads();
    for (int r=wid; r<NC; r+=4){
      const float* wr = w2 + (size_t)(l*NC+r)*NC2;
      float2 wv = ((const float2*)wr)[lane];
      float2 hv = ((const float2*)hid)[lane];
      float s = wv.x*hv.x + wv.y*hv.y;
      #pragma unroll
      for (int off=32; off>0; off>>=1) s += __shfl_xor(s, off);
      if (lane==0) zo[(size_t)lb*NC+r] = s + b2[l*NC+r];
    }
    __syncthreads();
  }
}

// ---------------- chan_z tail: rel = relu(gw·F + gb); z2n = aw·rel + ab ----------------
__global__ __launch_bounds__(256) void k_z2n2(const float* __restrict__ F,
    const float* __restrict__ gw, const float* __restrict__ gb,
    const float* __restrict__ aw, const float* __restrict__ ab,
    float* __restrict__ z2n){
  int lb = blockIdx.x; int l = lb/NB;
  __shared__ __align__(16) float rel[2*NC];
  int t = threadIdx.x, wid = t>>6, lane = t&63;
  const float* Fb  = F  + (size_t)lb*NC*NC;
  const float* gwl = gw + (size_t)l*2*NC*NC;
  for (int r=wid; r<2*NC; r+=4){
    int g = r >> 1;
    const float* frow = Fb + (size_t)g*NC;
    const float* wrow = gwl + (size_t)r*NC;
    float s = dot4(((const float4*)wrow)[lane], ((const float4*)frow)[lane]);
    #pragma unroll
    for (int off=32; off>0; off>>=1) s += __shfl_xor(s, off);
    if (lane==0) rel[r] = fmaxf(s + gb[l*2*NC+r], 0.f);
  }
  __syncthreads();
  const float* awl = aw + (size_t)l*NC*2*NC;
  for (int c=wid; c<NC; c+=4){
    const float* arow = awl + (size_t)c*2*NC;
    float s = dot4(((const float4*)arow)[lane],    ((const float4*)rel)[lane])
            + dot4(((const float4*)arow)[lane+64], ((const float4*)rel)[lane+64]);
    #pragma unroll
    for (int off=32; off>0; off>>=1) s += __shfl_xor(s, off);
    if (lane==0) z2n[(size_t)lb*NC+c] = s + ab[l*NC+c];
  }
}

__global__ __launch_bounds__(256) void k_cues(const float* __restrict__ zavg, const float* __restrict__ zmax,
    const float* __restrict__ z2n, const float* __restrict__ drw, const float* __restrict__ drb,
    float* __restrict__ cues){
  int idx = blockIdx.x*256 + threadIdx.x;
  if (idx >= NL*NB*NC) return;
  int c = idx & 255; int lb = idx >> 8; int l = lb/NB;
  const float* dw = drw + (size_t)(l*NC + c)*3;
  float x = dw[0]*zavg[idx] + dw[1]*zmax[idx] + dw[2]*z2n[idx] + drb[l*NC+c];
  cues[idx] = 1.f/(1.f + __expf(-x));
}

// ---------------- collapsed sc branch ----------------
__global__ __launch_bounds__(256) void k_zm(const float* __restrict__ zf, const float* __restrict__ m3,
    float* __restrict__ zm, float* __restrict__ sm){
  int lb = blockIdx.x; int cg = blockIdx.y;
  __shared__ float ms[ZZ];
  int t = threadIdx.x;
  if (t < ZZ) ms[t] = m3[(size_t)lb*ZZ + t];
  __syncthreads();
  int c = cg*32 + (t >> 3);
  int sub = t & 7;
  const float* zr = zf + ((size_t)lb*NC + c)*ZZ;
  float s = 0.f;
  for (int z=sub; z<ZZ; z+=8) s += zr[z]*ms[z];
  s += __shfl_down(s, 4, 8);
  s += __shfl_down(s, 2, 8);
  s += __shfl_down(s, 1, 8);
  if (sub == 0) zm[(size_t)lb*NC + c] = s;
  if (cg == 0 && t < 64){
    float ss = 0.f;
    for (int z=t; z<ZZ; z+=64) ss += ms[z];
    #pragma unroll
    for (int off=32; off>0; off>>=1) ss += __shfl_xor(ss, off);
    if (t == 0) sm[lb] = ss;
  }
}

__global__ __launch_bounds__(256) void k_zphi(const float* __restrict__ zm, const float* __restrict__ sm,
    const float* __restrict__ phiw, const float* __restrict__ phib, float* __restrict__ zphi){
  int lb = blockIdx.x; int l = lb/NB;
  __shared__ __align__(16) float zms[NC];
  int t = threadIdx.x, wid = t>>6, lane = t&63;
  zms[t] = zm[(size_t)lb*NC + t];
  __syncthreads();
  float smv = sm[lb];
  for (int r=wid; r<NC; r+=4){
    const float* wr = phiw + (size_t)(l*NC + r)*NC;
    float s = dot4(((const float4*)wr)[lane], ((const float4*)zms)[lane]);
    #pragma unroll
    for (int off=32; off>0; off>>=1) s += __shfl_xor(s, off);
    if (lane==0) zphi[(size_t)lb*NC + r] = s + phib[l*NC + r]*smv;
  }
}

__global__ __launch_bounds__(256) void k_wvec(const float* __restrict__ zphi, const float* __restrict__ dw,
    const float* __restrict__ db, float* __restrict__ wvec, float* __restrict__ cb){
  int lb = blockIdx.x; int l = lb/NB;
  __shared__ float zp[NC];
  __shared__ float red[NC];
  int t = threadIdx.x;
  zp[t] = zphi[(size_t)lb*NC + t];
  __syncthreads();
  float s = 0.f;
  const float* dwl = dw + (size_t)l*NC*NC;
  for (int c=0;c<NC;c++) s += zp[c]*dwl[(size_t)c*NC + t];
  wvec[(size_t)lb*NC + t] = s;
  red[t] = zp[t]*db[l*NC + t];
  __syncthreads();
  for (int off2=128; off2>0; off2>>=1){
    if (t < off2) red[t] += red[t+off2];
    __syncthreads();
  }
  if (t==0) cb[lb] = red[0];
}

__global__ __launch_bounds__(256) void k_sc(const float* __restrict__ xf, const float* __restrict__ wvec,
    const float* __restrict__ cb, float* __restrict__ sc){
  int lb = blockIdx.x;
  __shared__ float wv[NC];
  int t = threadIdx.x;
  wv[t] = wvec[(size_t)lb*NC + t];
  __syncthreads();
  float cbv = cb[lb];
  int x = blockIdx.y*256 + t;
  if (x >= XX) return;
  const float* xb = xf + (size_t)lb*NC*XX;
  float s = 0.f;
  for (int c=0;c<NC;c++) s += wv[c]*xb[(size_t)c*XX + x];
  float v = (s + cbv)*0.0625f;
  sc[(size_t)lb*XX + x] = fminf(fmaxf(v, 0.f), 1.f);
}

__global__ __launch_bounds__(256) void k_xfout(const float* __restrict__ xf, const float* __restrict__ cues,
    const float* __restrict__ sc, float* __restrict__ out){
  int bc = blockIdx.y;
  int x = blockIdx.x*256 + threadIdx.x;
  if (x >= XX) return;
  int lb = bc >> 8;
  float cu = cues[bc];
  out[(size_t)bc*XX + x] = (1.f+cu)*xf[(size_t)bc*XX + x] - sc[(size_t)lb*XX + x];
}

extern "C" void kernel_launch(void* const* d_in, const int* in_sizes, int n_in,
                              void* d_out, int out_size, void* d_ws, size_t ws_size,
                              hipStream_t stream){
  const float* zf      = (const float*)d_in[0];
  const float* xf      = (const float*)d_in[1];
  const float* maskp   = (const float*)d_in[2];
  const float* box     = (const float*)d_in[3];
  const float* nl_g_w  = (const float*)d_in[4];
  const float* nl_g_b  = (const float*)d_in[5];
  const float* nl_th_w = (const float*)d_in[6];
  const float* nl_th_b = (const float*)d_in[7];
  const float* nl_ph_w = (const float*)d_in[8];
  const float* nl_ph_b = (const float*)d_in[9];
  const float* nl_out_w= (const float*)d_in[10];
  const float* bn_g    = (const float*)d_in[11];
  const float* bn_b    = (const float*)d_in[12];
  const float* bn_m    = (const float*)d_in[13];
  const float* bn_v    = (const float*)d_in[14];
  const float* cz_th_w = (const float*)d_in[15];
  const float* cz_th_b = (const float*)d_in[16];
  const float* cz_ph_w = (const float*)d_in[17];
  const float* cz_ph_b = (const float*)d_in[18];
  const float* cz_gw   = (const float*)d_in[19];
  const float* cz_gb   = (const float*)d_in[20];
  const float* cz_aw   = (const float*)d_in[21];
  const float* cz_ab   = (const float*)d_in[22];
  const float* ap_w1   = (const float*)d_in[23];
  const float* ap_b1   = (const float*)d_in[24];
  const float* ap_w2   = (const float*)d_in[25];
  const float* ap_b2   = (const float*)d_in[26];
  const float* mp_w1   = (const float*)d_in[27];
  const float* mp_b1   = (const float*)d_in[28];
  const float* mp_w2   = (const float*)d_in[29];
  const float* mp_b2   = (const float*)d_in[30];
  const float* dr_w    = (const float*)d_in[31];
  const float* dr_b    = (const float*)d_in[32];
  const float* ac1_w   = (const float*)d_in[33];
  const float* ac1_b   = (const float*)d_in[34];
  const float* ac2_w   = (const float*)d_in[35];
  const float* ac2_b   = (const float*)d_in[36];
  const float* ac3_w   = (const float*)d_in[37];
  const float* ac3_b   = (const float*)d_in[38];
  const float* ac4_w   = (const float*)d_in[39];
  const float* ac4_b   = (const float*)d_in[40];
  const float* phi_w   = (const float*)d_in[41];
  const float* phi_b   = (const float*)d_in[42];
  const float* delta_w = (const float*)d_in[43];
  const float* delta_b = (const float*)d_in[44];
  (void)in_sizes; (void)n_in; (void)out_size; (void)ws_size;

  float* ws = (float*)d_ws;
  // sizes (floats)
  const size_t SZ_C1 = (size_t)NL*NB*4*125*125;   // 6.000M
  const size_t SZ_C2 = (size_t)NL*NB*8*123*123;   // 11.619M
  const size_t SZ_R1 = (size_t)NL*NB*8*14*14;
  const size_t SZ_C3 = (size_t)NL*NB*4*14*14;
  const size_t SZ_R2 = (size_t)NL*NB*4*15*15;
  const size_t SZ_P  = (size_t)NL*NB*ZZ*NC2;      // 2.7648M each (TH/PHt/GX/Yb)
  const size_t SZ_S  = (size_t)NL*NB*ZZ*ZZ;       // 4.860M

  // Region A: mask temps (phase 1) -> reused by GEMM buffers (phase 2+)
  size_t offA = 0;
  auto allocA = [&](size_t n){ size_t o = offA; offA += (n + 15) & ~(size_t)15; return o; };
  size_t oC1 = allocA(SZ_C1);
  size_t oC2 = allocA(SZ_C2);
  size_t oR1 = allocA(SZ_R1);
  size_t oC3 = allocA(SZ_C3);
  size_t oR2 = allocA(SZ_R2);
  size_t regionA = offA;               // ~17.94M floats
  // second-life sub-allocations inside region A (mask temps dead by then)
  size_t oTH = 0, oPH = oTH + SZ_P, oGX = oPH + SZ_P, oS = oGX + SZ_P, oYb = oS + SZ_S;
  // oYb + SZ_P = 15.92M <= regionA ✓

  float* c1  = ws + oC1;  float* c2 = ws + oC2;  float* r1 = ws + oR1;
  float* c3  = ws + oC3;  float* r2 = ws + oR2;
  float* TH  = ws + oTH;  float* PHt = ws + oPH; float* GX = ws + oGX;
  float* S   = ws + oS;   float* Yb  = ws + oYb;

  // Region B: persistent smalls + F
  size_t off = regionA;
  auto alloc = [&](size_t n){ size_t o = off; off += (n + 15) & ~(size_t)15; return o; };
  float* m3   = ws + alloc((size_t)NL*NB*ZZ);
  float* rois = ws + alloc((size_t)NL*NB*NC*49);
  float* pavg = ws + alloc((size_t)NL*NB*NC);
  float* pmax = ws + alloc((size_t)NL*NB*NC);
  float* zavg = ws + alloc((size_t)NL*NB*NC);
  float* zmax = ws + alloc((size_t)NL*NB*NC);
  float* z2n  = ws + alloc((size_t)NL*NB*NC);
  float* cues = ws + alloc((size_t)NL*NB*NC);
  float* zm   = ws + alloc((size_t)NL*NB*NC);
  float* zphi = ws + alloc((size_t)NL*NB*NC);
  float* wvec = ws + alloc((size_t)NL*NB*NC);
  float* czth = ws + alloc((size_t)NL*NB*49*NC);
  float* czph = ws + alloc((size_t)NL*NB*49*NC);
  float* sm   = ws + alloc((size_t)NL*NB);
  float* cbuf = ws + alloc((size_t)NL*NB);
  float* scb  = ws + alloc((size_t)NL*NB*XX);
  float* Fbuf = ws + alloc((size_t)NL*NB*NC*NC);  // 6.29M

  float* outp    = (float*)d_out;
  float* o_zfout = outp;
  float* o_zffull= outp + (size_t)NL*NB*NC*49;
  float* o_xfout = o_zffull + (size_t)NL*NB*NC*ZZ;

  // ---- mask branch (batched over l) ----
  k_mconv1<<<(int)((SZ_C1+255)/256), 256, 0, stream>>>(maskp, ac1_w, ac1_b, c1);
  k_mconv2<<<(int)((SZ_C2+255)/256), 256, 0, stream>>>(c1, ac2_w, ac2_b, c2);
  k_resize<<<(int)((SZ_R1+255)/256), 256, 0, stream>>>(c2, r1, (int)SZ_R1, 123, 123, 14, 14);
  k_conv3x3_same<<<(int)((SZ_C3+255)/256), 256, 0, stream>>>(r1, ac3_w, ac3_b, c3, 8, 4, 14, 14);
  k_resize<<<(int)((SZ_R2+255)/256), 256, 0, stream>>>(c3, r2, (int)SZ_R2, 14, 14, 15, 15);
  k_conv3x3_same<<<(int)(((size_t)NL*NB*ZZ+255)/256), 256, 0, stream>>>(r2, ac4_w, ac4_b, m3, 4, 1, 15, 15);

  // ---- non-local projections (A = zf [K=256][M=225], W per-l [N][K]) ----
  dim3 gLB(8, NL*NB);
  k_gemm64<0,0,true,true><<<gLB, 256, 0, stream>>>(zf, nl_th_w, nl_th_b, TH,  ZZ, NC2, NC, 2);
  k_gemm64<0,0,true,true><<<gLB, 256, 0, stream>>>(zf, nl_ph_w, nl_ph_b, PHt, ZZ, NC2, NC, 2);
  k_gemm64<0,0,true,true><<<gLB, 256, 0, stream>>>(zf, nl_g_w,  nl_g_b,  GX,  ZZ, NC2, NC, 2);
  // S = TH[225][128] @ PHt[225][128]^T
  k_gemm64<1,0,false,false><<<dim3(16, NL*NB), 256, 0, stream>>>(TH, PHt, nullptr, S, ZZ, ZZ, NC2, 4);
  k_softmax<<<(NL*NB*ZZ)/4, 256, 0, stream>>>(S);
  // Y = P[225][225] @ GX[225][128]
  k_gemm64<1,1,false,false><<<dim3(8, NL*NB), 256, 0, stream>>>(S, GX, nullptr, Yb, ZZ, NC2, ZZ, 2);

  // ---- rois / cues ----
  k_rois<<<dim3(NL*NB, 16), 256, 0, stream>>>(zf, box, rois);
  k_pool<<<(NL*NB*NC+255)/256, 256, 0, stream>>>(rois, pavg, pmax);
  k_mlp<<<NL*NB, 256, 0, stream>>>(pavg, pmax, ap_w1, ap_b1, ap_w2, ap_b2,
                                    mp_w1, mp_b1, mp_w2, mp_b2, zavg, zmax);
  k_gemm64<0,0,true,true><<<dim3(4, NL*NB), 256, 0, stream>>>(rois, cz_th_w, cz_th_b, czth, 49, NC, NC, 4);
  k_gemm64<0,0,true,true><<<dim3(4, NL*NB), 256, 0, stream>>>(rois, cz_ph_w, cz_ph_b, czph, 49, NC, NC, 4);
  // F = czth^T @ czph : A [K=49][M=256] stride 256; B [K=49][N=256] stride 256
  k_gemm64<0,1,false,false><<<dim3(16, NL*NB), 256, 0, stream>>>(czth, czph, nullptr, Fbuf, NC, NC, 49, 4);
  k_z2n2<<<NL*NB, 256, 0, stream>>>(Fbuf, cz_gw, cz_gb, cz_aw, cz_ab, z2n);
  k_cues<<<(NL*NB*NC+255)/256, 256, 0, stream>>>(zavg, zmax, z2n, dr_w, dr_b, cues);

  // ---- zf_full (+7x7 slice) ----
  k_outconv<<<dim3(16, NL*NB), 256, 0, stream>>>(Yb, nl_out_w, bn_g, bn_b, bn_m, bn_v,
                                                  cues, zf, o_zfout, o_zffull);

  // ---- collapsed sc branch + xf_out ----
  k_zm<<<dim3(NL*NB, 8), 256, 0, stream>>>(zf, m3, zm, sm);
  k_zphi<<<NL*NB, 256, 0, stream>>>(zm, sm, phi_w, phi_b, zphi);
  k_wvec<<<NL*NB, 256, 0, stream>>>(zphi, delta_w, delta_b, wvec, cbuf);
  k_sc<<<dim3(NL*NB, 4), 256, 0, stream>>>(xf, wvec, cbuf, scb);
  k_xfout<<<dim3(4, NL*NB*NC), 256, 0, stream>>>(xf, cues, scb, o_xfout);
}

// Round 6
// 785.377 us; speedup vs baseline: 1.3434x; 1.3434x over previous
//
#include <hip/hip_runtime.h>
#include <math.h>

#define NL 3
#define NB 32
#define NC 256
#define NC2 128
#define HZ 15
#define ZZ 225
#define XX 961
#define HMD 127

__device__ __forceinline__ float hat_int(float u){
  if (u <= -1.f) return 0.f;
  if (u <= 0.f){ float t = u + 1.f; return 0.5f*t*t; }
  if (u <= 1.f){ float t = 1.f - u; return 1.f - 0.5f*t*t; }
  return 1.f;
}
__device__ __forceinline__ float dot4(float4 a, float4 b){
  return a.x*b.x + a.y*b.y + a.z*b.z + a.w*b.w;
}
__device__ __forceinline__ float wave_red(float s){
  #pragma unroll
  for (int off=32; off>0; off>>=1) s += __shfl_xor(s, off);
  return s;
}

// ---------------- mask branch (batched over l) ----------------
__global__ __launch_bounds__(256) void k_mconv1(const float* __restrict__ mask,
    const float* __restrict__ wbase, const float* __restrict__ bbase, float* __restrict__ out){
  int idx = blockIdx.x*256 + threadIdx.x;
  const int OH=125, OW=125;
  if (idx >= NL*NB*4*OH*OW) return;
  int x = idx % OW, y = (idx/OW) % OH;
  int o = (idx/(OW*OH)) % 4; int lb = idx/(4*OW*OH);
  int l = lb/NB, b = lb%NB;
  const float* mb = mask + (size_t)b*HMD*HMD;
  const float* w = wbase + (size_t)l*4*2*9;
  float acc = bbase[l*4+o];
  #pragma unroll
  for (int ky=0;ky<3;ky++)
    #pragma unroll
    for (int kx=0;kx<3;kx++){
      float mv = mb[(y+ky)*HMD + (x+kx)];
      acc += w[((o*2+0)*3+ky)*3+kx]*mv;
      acc += w[((o*2+1)*3+ky)*3+kx]*(1.f-mv);
    }
  out[idx] = fmaxf(acc, 0.f);
}

__global__ __launch_bounds__(256) void k_mconv2(const float* __restrict__ in,
    const float* __restrict__ wbase, const float* __restrict__ bbase, float* __restrict__ out){
  int idx = blockIdx.x*256 + threadIdx.x;
  const int OH=123, OW=123, IH=125, IW=125;
  if (idx >= NL*NB*8*OH*OW) return;
  int x = idx % OW, y = (idx/OW) % OH;
  int o = (idx/(OW*OH)) % 8; int lb = idx/(8*OW*OH);
  int l = lb/NB;
  const float* w = wbase + (size_t)l*8*4*9;
  float acc = bbase[l*8+o];
  for (int ic=0; ic<4; ic++){
    const float* ib = in + (size_t)(lb*4+ic)*IH*IW;
    #pragma unroll
    for (int ky=0;ky<3;ky++)
      #pragma unroll
      for (int kx=0;kx<3;kx++)
        acc += w[((o*4+ic)*3+ky)*3+kx]*ib[(y+ky)*IW + (x+kx)];
  }
  out[idx] = fmaxf(acc, 0.f);
}

__global__ __launch_bounds__(256) void k_resize(const float* __restrict__ in, float* __restrict__ out,
    int total, int IH, int IW, int OH, int OW){
  int idx = blockIdx.x*256 + threadIdx.x;
  if (idx >= total) return;
  int ox = idx % OW, oy = (idx/OW) % OH;
  int bc = idx/(OW*OH);
  float sy = (float)((double)(IH-1)/(double)(OH-1));
  float sx = (float)((double)(IW-1)/(double)(OW-1));
  float yf = (float)oy * sy, xfv = (float)ox * sx;
  int y0 = (int)floorf(yf); y0 = min(max(y0,0), IH-2);
  int x0 = (int)floorf(xfv); x0 = min(max(x0,0), IW-2);
  float wy = yf - (float)y0, wx = xfv - (float)x0;
  const float* p = in + (size_t)bc*IH*IW;
  float v00=p[y0*IW+x0], v01=p[y0*IW+x0+1], v10=p[(y0+1)*IW+x0], v11=p[(y0+1)*IW+x0+1];
  out[idx] = (v00*(1.f-wy)+v10*wy)*(1.f-wx) + (v01*(1.f-wy)+v11*wy)*wx;
}

__global__ __launch_bounds__(256) void k_conv3x3_same(const float* __restrict__ in,
    const float* __restrict__ wbase, const float* __restrict__ bbase, float* __restrict__ out,
    int IC, int OC, int H, int W){
  int idx = blockIdx.x*256 + threadIdx.x;
  if (idx >= NL*NB*OC*H*W) return;
  int x = idx % W, y = (idx/W) % H;
  int o = (idx/(W*H)) % OC; int lb = idx/(OC*W*H);
  int l = lb/NB;
  const float* w = wbase + (size_t)l*OC*IC*9;
  float acc = bbase[l*OC+o];
  for (int ic=0; ic<IC; ic++){
    const float* ib = in + (size_t)(lb*IC+ic)*H*W;
    for (int ky=-1;ky<=1;ky++){
      int yy = y+ky; if (yy<0||yy>=H) continue;
      for (int kx=-1;kx<=1;kx++){
        int xx = x+kx; if (xx<0||xx>=W) continue;
        acc += w[((o*IC+ic)*3+(ky+1))*3+(kx+1)]*ib[yy*W+xx];
      }
    }
  }
  out[idx] = acc;
}

// ---------------- 64x64-tile fp32 GEMM, 4x4 per thread ----------------
template<int AMODE, int BMODE, bool BPERL, bool HASBIAS>
__global__ __launch_bounds__(256) void k_gemm64(
    const float* __restrict__ Abase, const float* __restrict__ Bbase,
    const float* __restrict__ biasbase, float* __restrict__ Obase,
    int M, int N, int K, int ntn)
{
  int lb = blockIdx.y; int l = lb / NB;
  const float* A = Abase + (size_t)lb*M*K;
  const float* B = Bbase + (BPERL ? (size_t)l : (size_t)lb)*N*K;
  float* out = Obase + (size_t)lb*M*N;
  int tm = blockIdx.x / ntn, tn = blockIdx.x % ntn;
  int m0 = tm*64, n0 = tn*64;
  __shared__ float As[32][68];
  __shared__ float Bs[32][68];
  int t = threadIdx.x;
  int tx = t & 15, ty = t >> 4;
  float acc[4][4] = {};
  for (int kc=0; kc<K; kc+=32){
    #pragma unroll
    for (int r=0;r<8;r++){
      int e = r*256 + t;
      int mm, kk;
      if (AMODE==0){ mm = e & 63; kk = e >> 6; }
      else { kk = e & 31; mm = e >> 5; }
      float va = 0.f;
      { int m = m0+mm, k = kc+kk;
        if (m < M && k < K)
          va = (AMODE==0) ? A[(size_t)k*M + m] : A[(size_t)m*K + k]; }
      As[kk][mm] = va;
      int nn, kk2;
      if (BMODE==0){ kk2 = e & 31; nn = e >> 5; }
      else { nn = e & 63; kk2 = e >> 6; }
      float vb = 0.f;
      { int n = n0+nn, k = kc+kk2;
        if (n < N && k < K)
          vb = (BMODE==0) ? B[(size_t)n*K + k] : B[(size_t)k*N + n]; }
      Bs[kk2][nn] = vb;
    }
    __syncthreads();
    #pragma unroll
    for (int kk=0; kk<32; kk++){
      float4 av = *(const float4*)&As[kk][ty*4];
      float4 bv = *(const float4*)&Bs[kk][tx*4];
      float aa[4] = {av.x, av.y, av.z, av.w};
      float bb[4] = {bv.x, bv.y, bv.z, bv.w};
      #pragma unroll
      for (int i=0;i<4;i++)
        #pragma unroll
        for (int j=0;j<4;j++)
          acc[i][j] += aa[i]*bb[j];
    }
    __syncthreads();
  }
  const float* bias = HASBIAS ? (biasbase + (size_t)l*N) : nullptr;
  #pragma unroll
  for (int i=0;i<4;i++){
    int m = m0 + ty*4 + i;
    if (m >= M) continue;
    #pragma unroll
    for (int j=0;j<4;j++){
      int n = n0 + tx*4 + j;
      if (n < N) out[(size_t)m*N + n] = acc[i][j] + (HASBIAS ? bias[n] : 0.f);
    }
  }
}

// ---------------- softmax rows of S (in place), fold 1/sqrt(C) ----------------
__global__ __launch_bounds__(256) void k_softmax(float* __restrict__ S){
  int row = blockIdx.x*4 + (threadIdx.x >> 6);
  int lane = threadIdx.x & 63;
  float* r = S + (size_t)row*ZZ;
  float v[4]; float mx = -1e30f;
  #pragma unroll
  for (int q=0;q<4;q++){
    int j = lane + q*64;
    v[q] = (j<ZZ) ? r[j] : -1e30f;
    mx = fmaxf(mx, v[q]);
  }
  #pragma unroll
  for (int off=32; off>0; off>>=1) mx = fmaxf(mx, __shfl_xor(mx, off));
  float sum = 0.f;
  #pragma unroll
  for (int q=0;q<4;q++){
    v[q] = __expf(v[q]-mx);
    if (lane + q*64 < ZZ) sum += v[q];
  }
  #pragma unroll
  for (int off=32; off>0; off>>=1) sum += __shfl_xor(sum, off);
  float inv = 1.f/(16.f*sum);
  #pragma unroll
  for (int q=0;q<4;q++){
    int j = lane + q*64;
    if (j<ZZ) r[j] = v[q]*inv;
  }
}

// ---------------- outconv: 64x64 GEMM + BN/cues/residual epilogue ----------------
__global__ __launch_bounds__(256) void k_outconv(const float* __restrict__ Y,
    const float* __restrict__ outw, const float* __restrict__ bng, const float* __restrict__ bnb,
    const float* __restrict__ bnm, const float* __restrict__ bnv,
    const float* __restrict__ cues, const float* __restrict__ zf,
    float* __restrict__ dzfout, float* __restrict__ dzffull){
  int lb = blockIdx.y; int l = lb/NB;
  const float* A = outw + (size_t)l*NC*NC2;  // [c][k] stride NC2
  const float* B = Y + (size_t)lb*ZZ*NC2;    // [z][k] stride NC2
  int tm = blockIdx.x >> 2, tn = blockIdx.x & 3;
  int m0 = tm*64, n0 = tn*64;
  __shared__ float As[32][68];
  __shared__ float Bs[32][68];
  int t = threadIdx.x;
  int tx = t & 15, ty = t >> 4;
  float acc[4][4] = {};
  for (int kc=0; kc<NC2; kc+=32){
    #pragma unroll
    for (int r=0;r<8;r++){
      int e = r*256 + t;
      int kk = e & 31, mm = e >> 5;
      As[kk][mm] = A[(size_t)(m0+mm)*NC2 + kc+kk];
      float vb = 0.f;
      int n = n0+mm;
      if (n < ZZ) vb = B[(size_t)n*NC2 + kc+kk];
      Bs[kk][mm] = vb;
    }
    __syncthreads();
    #pragma unroll
    for (int kk=0; kk<32; kk++){
      float4 av = *(const float4*)&As[kk][ty*4];
      float4 bv = *(const float4*)&Bs[kk][tx*4];
      float aa[4] = {av.x, av.y, av.z, av.w};
      float bb[4] = {bv.x, bv.y, bv.z, bv.w};
      #pragma unroll
      for (int i=0;i<4;i++)
        #pragma unroll
        for (int j=0;j<4;j++)
          acc[i][j] += aa[i]*bb[j];
    }
    __syncthreads();
  }
  #pragma unroll
  for (int i=0;i<4;i++){
    int c = m0 + ty*4 + i;
    float scale = bng[l*NC+c] * rsqrtf(bnv[l*NC+c] + 1e-5f);
    float bm = bnm[l*NC+c], bb2 = bnb[l*NC+c];
    float cu = cues[(size_t)lb*NC + c];
    #pragma unroll
    for (int j=0;j<4;j++){
      int z = n0 + tx*4 + j;
      if (z >= ZZ) continue;
      float val = (acc[i][j] - bm)*scale + bb2;
      float zv = zf[((size_t)lb*NC + c)*ZZ + z];
      float rr = cu*zv + zv + val;
      dzffull[((size_t)lb*NC + c)*ZZ + z] = rr;
      int h = z/15, wv2 = z%15;
      if (h>=4 && h<11 && wv2>=4 && wv2<11)
        dzfout[((size_t)lb*NC + c)*49 + (h-4)*7 + (wv2-4)] = rr;
    }
  }
}

// ---------------- PrRoI pooling: block = (lb, 16-channel group) ----------------
__global__ __launch_bounds__(256) void k_rois(const float* __restrict__ zf,
    const float* __restrict__ box, float* __restrict__ rois){
  int lb = blockIdx.x; int b = lb % NB; int c0 = blockIdx.y*16;
  __shared__ float Wy[7][15], Wx[7][15];
  __shared__ float fld[16*ZZ];
  __shared__ float tmp[16][7][16];
  __shared__ float area_s;
  int t = threadIdx.x;
  const float* bx = box + b*4;
  const float SC = 15.0f/127.0f;
  float x1 = bx[0]*SC, y1 = bx[1]*SC, x2 = bx[2]*SC, y2 = bx[3]*SC;
  float bh = (y2-y1)/7.f, bw = (x2-x1)/7.f;
  if (t < 105){ int p=t/15, i=t%15;
    Wy[p][i] = hat_int(y1+(float)(p+1)*bh - (float)i) - hat_int(y1+(float)p*bh - (float)i); }
  else if (t < 210){ int q=(t-105)/15, i=(t-105)%15;
    Wx[q][i] = hat_int(x1+(float)(q+1)*bw - (float)i) - hat_int(x1+(float)q*bw - (float)i); }
  if (t == 255) area_s = fmaxf(bh*bw, 1e-6f);
  const float* src = zf + ((size_t)lb*NC + c0)*ZZ;
  for (int e=t; e<16*ZZ; e+=256) fld[e] = src[e];
  __syncthreads();
  float inv_area = 1.f/area_s;
  for (int e=t; e<16*105; e+=256){
    int w = e%15; int pc = e/15; int p = pc%7; int cc = pc/7;
    float s = 0.f;
    #pragma unroll
    for (int h=0;h<15;h++) s += Wy[p][h]*fld[cc*ZZ + h*15 + w];
    tmp[cc][p][w] = s;
  }
  __syncthreads();
  float* out = rois + ((size_t)lb*NC + c0)*49;
  for (int e=t; e<16*49; e+=256){
    int q = e%7; int pc = e/7; int p = pc%7; int cc = pc/7;
    float s = 0.f;
    #pragma unroll
    for (int w=0;w<15;w++) s += tmp[cc][p][w]*Wx[q][w];
    out[(size_t)cc*49 + p*7 + q] = s*inv_area;
  }
}

__global__ __launch_bounds__(256) void k_pool(const float* __restrict__ rois,
    float* __restrict__ pavg, float* __restrict__ pmax){
  int idx = blockIdx.x*256 + threadIdx.x;
  if (idx >= NL*NB*NC) return;
  const float* r = rois + (size_t)idx*49;
  float s = 0.f, m = -1e30f;
  #pragma unroll
  for (int i=0;i<49;i++){ float v = r[i]; s += v; m = fmaxf(m,v); }
  pavg[idx] = s/49.f;
  pmax[idx] = m;
}

// ---------------- MLP heads: one wave per output row, huge grid ----------------
// grid (NL*NB, 2, 32); wave w handles row r = blockIdx.z*4 + w of hidden (128)
__global__ __launch_bounds__(256) void k_mlp1(const float* __restrict__ pavg, const float* __restrict__ pmax,
    const float* __restrict__ aw1, const float* __restrict__ ab1,
    const float* __restrict__ mw1, const float* __restrict__ mb1,
    float* __restrict__ hid){
  int lb = blockIdx.x; int l = lb/NB; int pass = blockIdx.y;
  int t = threadIdx.x, wid = t>>6, lane = t&63;
  int r = blockIdx.z*4 + wid;
  const float* pv = pass ? pmax : pavg;
  const float* w1 = pass ? mw1 : aw1;
  const float* b1 = pass ? mb1 : ab1;
  const float* wr = w1 + (size_t)(l*NC2+r)*NC;
  const float* pr = pv + (size_t)lb*NC;
  float s = dot4(((const float4*)wr)[lane], ((const float4*)pr)[lane]);
  s = wave_red(s);
  if (lane==0) hid[((size_t)lb*2 + pass)*NC2 + r] = fmaxf(s + b1[l*NC2+r], 0.f);
}

// grid (NL*NB, 2, 64); wave per output c (256)
__global__ __launch_bounds__(256) void k_mlp2(const float* __restrict__ hid,
    const float* __restrict__ aw2, const float* __restrict__ ab2,
    const float* __restrict__ mw2, const float* __restrict__ mb2,
    float* __restrict__ zavg, float* __restrict__ zmax){
  int lb = blockIdx.x; int l = lb/NB; int pass = blockIdx.y;
  int t = threadIdx.x, wid = t>>6, lane = t&63;
  int c = blockIdx.z*4 + wid;
  const float* w2 = pass ? mw2 : aw2;
  const float* b2 = pass ? mb2 : ab2;
  const float* wr = w2 + (size_t)(l*NC+c)*NC2;
  const float* hr = hid + ((size_t)lb*2 + pass)*NC2;
  float2 wv = ((const float2*)wr)[lane];
  float2 hv = ((const float2*)hr)[lane];
  float s = wave_red(wv.x*hv.x + wv.y*hv.y);
  if (lane==0){
    float* zo = pass ? zmax : zavg;
    zo[(size_t)lb*NC + c] = s + b2[l*NC+c];
  }
}

// ---------------- chan_z tail ----------------
// rel[lb][r] = relu(gb + gw[r,:]·F[lb, r>>1, :])   grid (NL*NB, 128), wave per r
__global__ __launch_bounds__(256) void k_relw(const float* __restrict__ F,
    const float* __restrict__ gw, const float* __restrict__ gb,
    float* __restrict__ rel){
  int lb = blockIdx.x; int l = lb/NB;
  int t = threadIdx.x, wid = t>>6, lane = t&63;
  int r = blockIdx.y*4 + wid;
  const float* wrow = gw + ((size_t)l*2*NC + r)*NC;
  const float* frow = F + ((size_t)lb*NC + (r>>1))*NC;
  float s = dot4(((const float4*)wrow)[lane], ((const float4*)frow)[lane]);
  s = wave_red(s);
  if (lane==0) rel[(size_t)lb*2*NC + r] = fmaxf(s + gb[l*2*NC+r], 0.f);
}

// z2n[lb][c] = ab + aw[c,:]·rel[lb,:]   grid (NL*NB, 64), wave per c, K=512
__global__ __launch_bounds__(256) void k_z2naw(const float* __restrict__ rel,
    const float* __restrict__ aw, const float* __restrict__ ab,
    float* __restrict__ z2n){
  int lb = blockIdx.x; int l = lb/NB;
  int t = threadIdx.x, wid = t>>6, lane = t&63;
  int c = blockIdx.z*4 + blockIdx.y*4 + wid; // only y used; z unused
  c = blockIdx.y*4 + wid;
  const float* arow = aw + ((size_t)l*NC + c)*2*NC;
  const float* rrow = rel + (size_t)lb*2*NC;
  float s = dot4(((const float4*)arow)[lane],    ((const float4*)rrow)[lane])
          + dot4(((const float4*)arow)[lane+64], ((const float4*)rrow)[lane+64]);
  s = wave_red(s);
  if (lane==0) z2n[(size_t)lb*NC + c] = s + ab[l*NC+c];
}

__global__ __launch_bounds__(256) void k_cues(const float* __restrict__ zavg, const float* __restrict__ zmax,
    const float* __restrict__ z2n, const float* __restrict__ drw, const float* __restrict__ drb,
    float* __restrict__ cues){
  int idx = blockIdx.x*256 + threadIdx.x;
  if (idx >= NL*NB*NC) return;
  int c = idx & 255; int lb = idx >> 8; int l = lb/NB;
  const float* dw = drw + (size_t)(l*NC + c)*3;
  float x = dw[0]*zavg[idx] + dw[1]*zmax[idx] + dw[2]*z2n[idx] + drb[l*NC+c];
  cues[idx] = 1.f/(1.f + __expf(-x));
}

// ---------------- collapsed sc branch ----------------
__global__ __launch_bounds__(256) void k_zm(const float* __restrict__ zf, const float* __restrict__ m3,
    float* __restrict__ zm, float* __restrict__ sm){
  int lb = blockIdx.x; int cg = blockIdx.y;
  __shared__ float ms[ZZ];
  int t = threadIdx.x;
  if (t < ZZ) ms[t] = m3[(size_t)lb*ZZ + t];
  __syncthreads();
  int c = cg*32 + (t >> 3);
  int sub = t & 7;
  const float* zr = zf + ((size_t)lb*NC + c)*ZZ;
  float s = 0.f;
  for (int z=sub; z<ZZ; z+=8) s += zr[z]*ms[z];
  s += __shfl_down(s, 4, 8);
  s += __shfl_down(s, 2, 8);
  s += __shfl_down(s, 1, 8);
  if (sub == 0) zm[(size_t)lb*NC + c] = s;
  if (cg == 0 && t < 64){
    float ss = 0.f;
    for (int z=t; z<ZZ; z+=64) ss += ms[z];
    ss = wave_red(ss);
    if (t == 0) sm[lb] = ss;
  }
}

// zphi[lb][r] = phib*sm + phiw[r,:]·zm[lb,:]   grid (NL*NB, 64), wave per r
__global__ __launch_bounds__(256) void k_zphi(const float* __restrict__ zm, const float* __restrict__ sm,
    const float* __restrict__ phiw, const float* __restrict__ phib, float* __restrict__ zphi){
  int lb = blockIdx.x; int l = lb/NB;
  int t = threadIdx.x, wid = t>>6, lane = t&63;
  int r = blockIdx.y*4 + wid;
  const float* wr = phiw + (size_t)(l*NC + r)*NC;
  const float* zr = zm + (size_t)lb*NC;
  float s = dot4(((const float4*)wr)[lane], ((const float4*)zr)[lane]);
  s = wave_red(s);
  if (lane==0) zphi[(size_t)lb*NC + r] = s + phib[l*NC + r]*sm[lb];
}

__global__ __launch_bounds__(256) void k_wvec(const float* __restrict__ zphi, const float* __restrict__ dw,
    const float* __restrict__ db, float* __restrict__ wvec, float* __restrict__ cb){
  int lb = blockIdx.x; int l = lb/NB;
  __shared__ float zp[NC];
  __shared__ float red[NC];
  int t = threadIdx.x;
  zp[t] = zphi[(size_t)lb*NC + t];
  __syncthreads();
  float s = 0.f;
  const float* dwl = dw + (size_t)l*NC*NC;
  for (int c=0;c<NC;c++) s += zp[c]*dwl[(size_t)c*NC + t];
  wvec[(size_t)lb*NC + t] = s;
  red[t] = zp[t]*db[l*NC + t];
  __syncthreads();
  for (int off2=128; off2>0; off2>>=1){
    if (t < off2) red[t] += red[t+off2];
    __syncthreads();
  }
  if (t==0) cb[lb] = red[0];
}

__global__ __launch_bounds__(256) void k_sc(const float* __restrict__ xf, const float* __restrict__ wvec,
    const float* __restrict__ cb, float* __restrict__ sc){
  int lb = blockIdx.x;
  __shared__ float wv[NC];
  int t = threadIdx.x;
  wv[t] = wvec[(size_t)lb*NC + t];
  __syncthreads();
  float cbv = cb[lb];
  int x = blockIdx.y*256 + t;
  if (x >= XX) return;
  const float* xb = xf + (size_t)lb*NC*XX;
  float s = 0.f;
  for (int c=0;c<NC;c++) s += wv[c]*xb[(size_t)c*XX + x];
  float v = (s + cbv)*0.0625f;
  sc[(size_t)lb*XX + x] = fminf(fmaxf(v, 0.f), 1.f);
}

__global__ __launch_bounds__(256) void k_xfout(const float* __restrict__ xf, const float* __restrict__ cues,
    const float* __restrict__ sc, float* __restrict__ out){
  int bc = blockIdx.y;
  int x = blockIdx.x*256 + threadIdx.x;
  if (x >= XX) return;
  int lb = bc >> 8;
  float cu = cues[bc];
  out[(size_t)bc*XX + x] = (1.f+cu)*xf[(size_t)bc*XX + x] - sc[(size_t)lb*XX + x];
}

extern "C" void kernel_launch(void* const* d_in, const int* in_sizes, int n_in,
                              void* d_out, int out_size, void* d_ws, size_t ws_size,
                              hipStream_t stream){
  const float* zf      = (const float*)d_in[0];
  const float* xf      = (const float*)d_in[1];
  const float* maskp   = (const float*)d_in[2];
  const float* box     = (const float*)d_in[3];
  const float* nl_g_w  = (const float*)d_in[4];
  const float* nl_g_b  = (const float*)d_in[5];
  const float* nl_th_w = (const float*)d_in[6];
  const float* nl_th_b = (const float*)d_in[7];
  const float* nl_ph_w = (const float*)d_in[8];
  const float* nl_ph_b = (const float*)d_in[9];
  const float* nl_out_w= (const float*)d_in[10];
  const float* bn_g    = (const float*)d_in[11];
  const float* bn_b    = (const float*)d_in[12];
  const float* bn_m    = (const float*)d_in[13];
  const float* bn_v    = (const float*)d_in[14];
  const float* cz_th_w = (const float*)d_in[15];
  const float* cz_th_b = (const float*)d_in[16];
  const float* cz_ph_w = (const float*)d_in[17];
  const float* cz_ph_b = (const float*)d_in[18];
  const float* cz_gw   = (const float*)d_in[19];
  const float* cz_gb   = (const float*)d_in[20];
  const float* cz_aw   = (const float*)d_in[21];
  const float* cz_ab   = (const float*)d_in[22];
  const float* ap_w1   = (const float*)d_in[23];
  const float* ap_b1   = (const float*)d_in[24];
  const float* ap_w2   = (const float*)d_in[25];
  const float* ap_b2   = (const float*)d_in[26];
  const float* mp_w1   = (const float*)d_in[27];
  const float* mp_b1   = (const float*)d_in[28];
  const float* mp_w2   = (const float*)d_in[29];
  const float* mp_b2   = (const float*)d_in[30];
  const float* dr_w    = (const float*)d_in[31];
  const float* dr_b    = (const float*)d_in[32];
  const float* ac1_w   = (const float*)d_in[33];
  const float* ac1_b   = (const float*)d_in[34];
  const float* ac2_w   = (const float*)d_in[35];
  const float* ac2_b   = (const float*)d_in[36];
  const float* ac3_w   = (const float*)d_in[37];
  const float* ac3_b   = (const float*)d_in[38];
  const float* ac4_w   = (const float*)d_in[39];
  const float* ac4_b   = (const float*)d_in[40];
  const float* phi_w   = (const float*)d_in[41];
  const float* phi_b   = (const float*)d_in[42];
  const float* delta_w = (const float*)d_in[43];
  const float* delta_b = (const float*)d_in[44];
  (void)in_sizes; (void)n_in; (void)out_size; (void)ws_size;

  float* ws = (float*)d_ws;
  const size_t SZ_C1 = (size_t)NL*NB*4*125*125;
  const size_t SZ_C2 = (size_t)NL*NB*8*123*123;
  const size_t SZ_R1 = (size_t)NL*NB*8*14*14;
  const size_t SZ_C3 = (size_t)NL*NB*4*14*14;
  const size_t SZ_R2 = (size_t)NL*NB*4*15*15;
  const size_t SZ_P  = (size_t)NL*NB*ZZ*NC2;
  const size_t SZ_S  = (size_t)NL*NB*ZZ*ZZ;

  size_t offA = 0;
  auto allocA = [&](size_t n){ size_t o = offA; offA += (n + 15) & ~(size_t)15; return o; };
  size_t oC1 = allocA(SZ_C1);
  size_t oC2 = allocA(SZ_C2);
  size_t oR1 = allocA(SZ_R1);
  size_t oC3 = allocA(SZ_C3);
  size_t oR2 = allocA(SZ_R2);
  size_t regionA = offA;
  size_t oTH = 0, oPH = oTH + SZ_P, oGX = oPH + SZ_P, oS = oGX + SZ_P, oYb = oS + SZ_S;

  float* c1  = ws + oC1;  float* c2 = ws + oC2;  float* r1 = ws + oR1;
  float* c3  = ws + oC3;  float* r2 = ws + oR2;
  float* TH  = ws + oTH;  float* PHt = ws + oPH; float* GX = ws + oGX;
  float* S   = ws + oS;   float* Yb  = ws + oYb;

  size_t off = regionA;
  auto alloc = [&](size_t n){ size_t o = off; off += (n + 15) & ~(size_t)15; return o; };
  float* m3   = ws + alloc((size_t)NL*NB*ZZ);
  float* rois = ws + alloc((size_t)NL*NB*NC*49);
  float* pavg = ws + alloc((size_t)NL*NB*NC);
  float* pmax = ws + alloc((size_t)NL*NB*NC);
  float* zavg = ws + alloc((size_t)NL*NB*NC);
  float* zmax = ws + alloc((size_t)NL*NB*NC);
  float* z2n  = ws + alloc((size_t)NL*NB*NC);
  float* cues = ws + alloc((size_t)NL*NB*NC);
  float* zm   = ws + alloc((size_t)NL*NB*NC);
  float* zphi = ws + alloc((size_t)NL*NB*NC);
  float* wvec = ws + alloc((size_t)NL*NB*NC);
  float* czth = ws + alloc((size_t)NL*NB*49*NC);
  float* czph = ws + alloc((size_t)NL*NB*49*NC);
  float* sm   = ws + alloc((size_t)NL*NB);
  float* cbuf = ws + alloc((size_t)NL*NB);
  float* scb  = ws + alloc((size_t)NL*NB*XX);
  float* Fbuf = ws + alloc((size_t)NL*NB*NC*NC);
  float* relb = ws + alloc((size_t)NL*NB*2*NC);
  float* hidb = ws + alloc((size_t)NL*NB*2*NC2);

  float* outp    = (float*)d_out;
  float* o_zfout = outp;
  float* o_zffull= outp + (size_t)NL*NB*NC*49;
  float* o_xfout = o_zffull + (size_t)NL*NB*NC*ZZ;

  // ---- mask branch (batched over l) ----
  k_mconv1<<<(int)((SZ_C1+255)/256), 256, 0, stream>>>(maskp, ac1_w, ac1_b, c1);
  k_mconv2<<<(int)((SZ_C2+255)/256), 256, 0, stream>>>(c1, ac2_w, ac2_b, c2);
  k_resize<<<(int)((SZ_R1+255)/256), 256, 0, stream>>>(c2, r1, (int)SZ_R1, 123, 123, 14, 14);
  k_conv3x3_same<<<(int)((SZ_C3+255)/256), 256, 0, stream>>>(r1, ac3_w, ac3_b, c3, 8, 4, 14, 14);
  k_resize<<<(int)((SZ_R2+255)/256), 256, 0, stream>>>(c3, r2, (int)SZ_R2, 14, 14, 15, 15);
  k_conv3x3_same<<<(int)(((size_t)NL*NB*ZZ+255)/256), 256, 0, stream>>>(r2, ac4_w, ac4_b, m3, 4, 1, 15, 15);

  // ---- non-local projections ----
  dim3 gLB(8, NL*NB);
  k_gemm64<0,0,true,true><<<gLB, 256, 0, stream>>>(zf, nl_th_w, nl_th_b, TH,  ZZ, NC2, NC, 2);
  k_gemm64<0,0,true,true><<<gLB, 256, 0, stream>>>(zf, nl_ph_w, nl_ph_b, PHt, ZZ, NC2, NC, 2);
  k_gemm64<0,0,true,true><<<gLB, 256, 0, stream>>>(zf, nl_g_w,  nl_g_b,  GX,  ZZ, NC2, NC, 2);
  k_gemm64<1,0,false,false><<<dim3(16, NL*NB), 256, 0, stream>>>(TH, PHt, nullptr, S, ZZ, ZZ, NC2, 4);
  k_softmax<<<(NL*NB*ZZ)/4, 256, 0, stream>>>(S);
  k_gemm64<1,1,false,false><<<dim3(8, NL*NB), 256, 0, stream>>>(S, GX, nullptr, Yb, ZZ, NC2, ZZ, 2);

  // ---- rois / cues ----
  k_rois<<<dim3(NL*NB, 16), 256, 0, stream>>>(zf, box, rois);
  k_pool<<<(NL*NB*NC+255)/256, 256, 0, stream>>>(rois, pavg, pmax);
  k_mlp1<<<dim3(NL*NB, 2, 32), 256, 0, stream>>>(pavg, pmax, ap_w1, ap_b1, mp_w1, mp_b1, hidb);
  k_mlp2<<<dim3(NL*NB, 2, 64), 256, 0, stream>>>(hidb, ap_w2, ap_b2, mp_w2, mp_b2, zavg, zmax);
  k_gemm64<0,0,true,true><<<dim3(4, NL*NB), 256, 0, stream>>>(rois, cz_th_w, cz_th_b, czth, 49, NC, NC, 4);
  k_gemm64<0,0,true,true><<<dim3(4, NL*NB), 256, 0, stream>>>(rois, cz_ph_w, cz_ph_b, czph, 49, NC, NC, 4);
  k_gemm64<0,1,false,false><<<dim3(16, NL*NB), 256, 0, stream>>>(czth, czph, nullptr, Fbuf, NC, NC, 49, 4);
  k_relw<<<dim3(NL*NB, 128), 256, 0, stream>>>(Fbuf, cz_gw, cz_gb, relb);
  k_z2naw<<<dim3(NL*NB, 64), 256, 0, stream>>>(relb, cz_aw, cz_ab, z2n);
  k_cues<<<(NL*NB*NC+255)/256, 256, 0, stream>>>(zavg, zmax, z2n, dr_w, dr_b, cues);

  // ---- zf_full (+7x7 slice) ----
  k_outconv<<<dim3(16, NL*NB), 256, 0, stream>>>(Yb, nl_out_w, bn_g, bn_b, bn_m, bn_v,
                                                  cues, zf, o_zfout, o_zffull);

  // ---- collapsed sc branch + xf_out ----
  k_zm<<<dim3(NL*NB, 8), 256, 0, stream>>>(zf, m3, zm, sm);
  k_zphi<<<dim3(NL*NB, 64), 256, 0, stream>>>(zm, sm, phi_w, phi_b, zphi);
  k_wvec<<<NL*NB, 256, 0, stream>>>(zphi, delta_w, delta_b, wvec, cbuf);
  k_sc<<<dim3(NL*NB, 4), 256, 0, stream>>>(xf, wvec, cbuf, scb);
  k_xfout<<<dim3(4, NL*NB*NC), 256, 0, stream>>>(xf, cues, scb, o_xfout);
}

// Round 7
// 686.596 us; speedup vs baseline: 1.5367x; 1.1439x over previous
//
#include <hip/hip_runtime.h>
#include <math.h>

#define NL 3
#define NB 32
#define NC 256
#define NC2 128
#define HZ 15
#define ZZ 225
#define XX 961
#define HMD 127

__device__ __forceinline__ float hat_int(float u){
  if (u <= -1.f) return 0.f;
  if (u <= 0.f){ float t = u + 1.f; return 0.5f*t*t; }
  if (u <= 1.f){ float t = 1.f - u; return 1.f - 0.5f*t*t; }
  return 1.f;
}
__device__ __forceinline__ float dot4(float4 a, float4 b){
  return a.x*b.x + a.y*b.y + a.z*b.z + a.w*b.w;
}
__device__ __forceinline__ float wave_red(float s){
  #pragma unroll
  for (int off=32; off>0; off>>=1) s += __shfl_xor(s, off);
  return s;
}

// ================= fused mask branch: one block per (l,b) =================
// chain: mask(127x127) -> c1 VALID conv 2->4 (125x125, sampled 56x56 grid)
//        -> c2 VALID conv 4->8 (123x123, sampled 28x28 pts) -> resize to 14x14
//        -> c3 SAME conv 8->4 -> resize to 15x15 -> m3 SAME conv 4->1
__global__ __launch_bounds__(256) void k_mask(const float* __restrict__ mask,
    const float* __restrict__ w1, const float* __restrict__ b1,
    const float* __restrict__ w2, const float* __restrict__ b2,
    const float* __restrict__ w3, const float* __restrict__ b3,
    const float* __restrict__ w4, const float* __restrict__ b4,
    float* __restrict__ m3out){
  int lb = blockIdx.x; int l = lb/NB, b = lb%NB;
  int t = threadIdx.x;
  __shared__ float c1s[4][56][56];
  __shared__ float c2s[8][28][28];
  __shared__ float r1s[8][14][14];
  __shared__ float c3s[4][14][14];
  __shared__ float r2s[4][15][15];
  __shared__ int   y0t[14];
  __shared__ float wyt[14];
  __shared__ int   y0t15[15];
  __shared__ float wyt15[15];
  if (t < 14){
    float sy = 122.0f/13.0f;
    float yf = (float)t * sy;
    int y0 = (int)floorf(yf); y0 = min(max(y0,0), 121);
    y0t[t] = y0; wyt[t] = yf - (float)y0;
  } else if (t < 29){
    int q = t-14;
    float sy = 13.0f/14.0f;
    float yf = (float)q * sy;
    int y0 = (int)floorf(yf); y0 = min(max(y0,0), 12);
    y0t15[q] = y0; wyt15[q] = yf - (float)y0;
  }
  __syncthreads();
  const float* mb = mask + (size_t)b*HMD*HMD;
  const float* wc1 = w1 + (size_t)l*4*2*9;
  // stage 1: c1 on 56x56 gather grid (rows y0t[g]+k, k=0..3)
  for (int e=t; e<4*56*56; e+=256){
    int ci = e % 56, ri = (e/56) % 56, oc = e/(56*56);
    int row = y0t[ri>>2] + (ri&3);
    int col = y0t[ci>>2] + (ci&3);
    float acc = b1[l*4+oc];
    #pragma unroll
    for (int ky=0;ky<3;ky++)
      #pragma unroll
      for (int kx=0;kx<3;kx++){
        float mv = mb[(row+ky)*HMD + (col+kx)];
        acc += wc1[((oc*2+0)*3+ky)*3+kx]*mv;
        acc += wc1[((oc*2+1)*3+ky)*3+kx]*(1.f-mv);
      }
    c1s[oc][ri][ci] = fmaxf(acc, 0.f);
  }
  __syncthreads();
  // stage 2: c2 at 28x28 sampled conv positions
  const float* wc2 = w2 + (size_t)l*8*4*9;
  for (int e=t; e<8*28*28; e+=256){
    int j = e % 28, i = (e/28) % 28, oc = e/(28*28);
    int g = i>>1, dy = i&1, gc = j>>1, dx = j&1;
    float acc = b2[l*8+oc];
    #pragma unroll
    for (int ic=0; ic<4; ic++)
      #pragma unroll
      for (int ky=0;ky<3;ky++)
        #pragma unroll
        for (int kx=0;kx<3;kx++)
          acc += wc2[((oc*4+ic)*3+ky)*3+kx]*c1s[ic][g*4+dy+ky][gc*4+dx+kx];
    c2s[oc][i][j] = fmaxf(acc, 0.f);
  }
  __syncthreads();
  // stage 3: bilerp 123x123(sampled) -> 14x14
  for (int e=t; e<8*14*14; e+=256){
    int ox = e % 14, oy = (e/14) % 14, oc = e/(14*14);
    float wy = wyt[oy], wx = wyt[ox];
    float v00 = c2s[oc][2*oy][2*ox],   v01 = c2s[oc][2*oy][2*ox+1];
    float v10 = c2s[oc][2*oy+1][2*ox], v11 = c2s[oc][2*oy+1][2*ox+1];
    r1s[oc][oy][ox] = (v00*(1.f-wy)+v10*wy)*(1.f-wx) + (v01*(1.f-wy)+v11*wy)*wx;
  }
  __syncthreads();
  // stage 4: c3 = SAME conv 8->4 at 14x14 (no relu)
  const float* wc3 = w3 + (size_t)l*4*8*9;
  for (int e=t; e<4*14*14; e+=256){
    int x = e % 14, y = (e/14) % 14, oc = e/(14*14);
    float acc = b3[l*4+oc];
    for (int ic=0; ic<8; ic++)
      #pragma unroll
      for (int ky=-1;ky<=1;ky++){
        int yy = y+ky; if (yy<0||yy>=14) continue;
        #pragma unroll
        for (int kx=-1;kx<=1;kx++){
          int xx = x+kx; if (xx<0||xx>=14) continue;
          acc += wc3[((oc*8+ic)*3+(ky+1))*3+(kx+1)]*r1s[ic][yy][xx];
        }
      }
    c3s[oc][y][x] = acc;
  }
  __syncthreads();
  // stage 5: resize 14->15
  for (int e=t; e<4*15*15; e+=256){
    int ox = e % 15, oy = (e/15) % 15, oc = e/(15*15);
    int y0 = y0t15[oy], x0 = y0t15[ox];
    float wy = wyt15[oy], wx = wyt15[ox];
    float v00 = c3s[oc][y0][x0],   v01 = c3s[oc][y0][x0+1];
    float v10 = c3s[oc][y0+1][x0], v11 = c3s[oc][y0+1][x0+1];
    r2s[oc][oy][ox] = (v00*(1.f-wy)+v10*wy)*(1.f-wx) + (v01*(1.f-wy)+v11*wy)*wx;
  }
  __syncthreads();
  // stage 6: m3 = SAME conv 4->1 at 15x15 (no relu)
  const float* wc4 = w4 + (size_t)l*1*4*9;
  for (int e=t; e<15*15; e+=256){
    int x = e % 15, y = e/15;
    float acc = b4[l];
    #pragma unroll
    for (int ic=0; ic<4; ic++)
      #pragma unroll
      for (int ky=-1;ky<=1;ky++){
        int yy = y+ky; if (yy<0||yy>=15) continue;
        #pragma unroll
        for (int kx=-1;kx<=1;kx++){
          int xx = x+kx; if (xx<0||xx>=15) continue;
          acc += wc4[(ic*3+(ky+1))*3+(kx+1)]*r2s[ic][yy][xx];
        }
      }
    m3out[(size_t)lb*ZZ + y*15 + x] = acc;
  }
}

// ---------------- 64x64-tile fp32 GEMM, 4x4 per thread ----------------
template<int AMODE, int BMODE, bool BPERL, bool HASBIAS>
__global__ __launch_bounds__(256) void k_gemm64(
    const float* __restrict__ Abase, const float* __restrict__ Bbase,
    const float* __restrict__ biasbase, float* __restrict__ Obase,
    int M, int N, int K, int ntn)
{
  int lb = blockIdx.y; int l = lb / NB;
  const float* A = Abase + (size_t)lb*M*K;
  const float* B = Bbase + (BPERL ? (size_t)l : (size_t)lb)*N*K;
  float* out = Obase + (size_t)lb*M*N;
  int tm = blockIdx.x / ntn, tn = blockIdx.x % ntn;
  int m0 = tm*64, n0 = tn*64;
  __shared__ float As[32][68];
  __shared__ float Bs[32][68];
  int t = threadIdx.x;
  int tx = t & 15, ty = t >> 4;
  float acc[4][4] = {};
  for (int kc=0; kc<K; kc+=32){
    #pragma unroll
    for (int r=0;r<8;r++){
      int e = r*256 + t;
      int mm, kk;
      if (AMODE==0){ mm = e & 63; kk = e >> 6; }
      else { kk = e & 31; mm = e >> 5; }
      float va = 0.f;
      { int m = m0+mm, k = kc+kk;
        if (m < M && k < K)
          va = (AMODE==0) ? A[(size_t)k*M + m] : A[(size_t)m*K + k]; }
      As[kk][mm] = va;
      int nn, kk2;
      if (BMODE==0){ kk2 = e & 31; nn = e >> 5; }
      else { nn = e & 63; kk2 = e >> 6; }
      float vb = 0.f;
      { int n = n0+nn, k = kc+kk2;
        if (n < N && k < K)
          vb = (BMODE==0) ? B[(size_t)n*K + k] : B[(size_t)k*N + n]; }
      Bs[kk2][nn] = vb;
    }
    __syncthreads();
    #pragma unroll
    for (int kk=0; kk<32; kk++){
      float4 av = *(const float4*)&As[kk][ty*4];
      float4 bv = *(const float4*)&Bs[kk][tx*4];
      float aa[4] = {av.x, av.y, av.z, av.w};
      float bb[4] = {bv.x, bv.y, bv.z, bv.w};
      #pragma unroll
      for (int i=0;i<4;i++)
        #pragma unroll
        for (int j=0;j<4;j++)
          acc[i][j] += aa[i]*bb[j];
    }
    __syncthreads();
  }
  const float* bias = HASBIAS ? (biasbase + (size_t)l*N) : nullptr;
  #pragma unroll
  for (int i=0;i<4;i++){
    int m = m0 + ty*4 + i;
    if (m >= M) continue;
    #pragma unroll
    for (int j=0;j<4;j++){
      int n = n0 + tx*4 + j;
      if (n < N) out[(size_t)m*N + n] = acc[i][j] + (HASBIAS ? bias[n] : 0.f);
    }
  }
}

// ---------------- softmax rows of S (in place), fold 1/sqrt(C) ----------------
__global__ __launch_bounds__(256) void k_softmax(float* __restrict__ S){
  int row = blockIdx.x*4 + (threadIdx.x >> 6);
  int lane = threadIdx.x & 63;
  float* r = S + (size_t)row*ZZ;
  float v[4]; float mx = -1e30f;
  #pragma unroll
  for (int q=0;q<4;q++){
    int j = lane + q*64;
    v[q] = (j<ZZ) ? r[j] : -1e30f;
    mx = fmaxf(mx, v[q]);
  }
  #pragma unroll
  for (int off=32; off>0; off>>=1) mx = fmaxf(mx, __shfl_xor(mx, off));
  float sum = 0.f;
  #pragma unroll
  for (int q=0;q<4;q++){
    v[q] = __expf(v[q]-mx);
    if (lane + q*64 < ZZ) sum += v[q];
  }
  #pragma unroll
  for (int off=32; off>0; off>>=1) sum += __shfl_xor(sum, off);
  float inv = 1.f/(16.f*sum);
  #pragma unroll
  for (int q=0;q<4;q++){
    int j = lane + q*64;
    if (j<ZZ) r[j] = v[q]*inv;
  }
}

// ---------------- outconv: 64x64 GEMM + BN/cues/residual epilogue ----------------
__global__ __launch_bounds__(256) void k_outconv(const float* __restrict__ Y,
    const float* __restrict__ outw, const float* __restrict__ bng, const float* __restrict__ bnb,
    const float* __restrict__ bnm, const float* __restrict__ bnv,
    const float* __restrict__ cues, const float* __restrict__ zf,
    float* __restrict__ dzfout, float* __restrict__ dzffull){
  int lb = blockIdx.y; int l = lb/NB;
  const float* A = outw + (size_t)l*NC*NC2;  // [c][k] stride NC2
  const float* B = Y + (size_t)lb*ZZ*NC2;    // [z][k] stride NC2
  int tm = blockIdx.x >> 2, tn = blockIdx.x & 3;
  int m0 = tm*64, n0 = tn*64;
  __shared__ float As[32][68];
  __shared__ float Bs[32][68];
  int t = threadIdx.x;
  int tx = t & 15, ty = t >> 4;
  float acc[4][4] = {};
  for (int kc=0; kc<NC2; kc+=32){
    #pragma unroll
    for (int r=0;r<8;r++){
      int e = r*256 + t;
      int kk = e & 31, mm = e >> 5;
      As[kk][mm] = A[(size_t)(m0+mm)*NC2 + kc+kk];
      float vb = 0.f;
      int n = n0+mm;
      if (n < ZZ) vb = B[(size_t)n*NC2 + kc+kk];
      Bs[kk][mm] = vb;
    }
    __syncthreads();
    #pragma unroll
    for (int kk=0; kk<32; kk++){
      float4 av = *(const float4*)&As[kk][ty*4];
      float4 bv = *(const float4*)&Bs[kk][tx*4];
      float aa[4] = {av.x, av.y, av.z, av.w};
      float bb[4] = {bv.x, bv.y, bv.z, bv.w};
      #pragma unroll
      for (int i=0;i<4;i++)
        #pragma unroll
        for (int j=0;j<4;j++)
          acc[i][j] += aa[i]*bb[j];
    }
    __syncthreads();
  }
  #pragma unroll
  for (int i=0;i<4;i++){
    int c = m0 + ty*4 + i;
    float scale = bng[l*NC+c] * rsqrtf(bnv[l*NC+c] + 1e-5f);
    float bm = bnm[l*NC+c], bb2 = bnb[l*NC+c];
    float cu = cues[(size_t)lb*NC + c];
    #pragma unroll
    for (int j=0;j<4;j++){
      int z = n0 + tx*4 + j;
      if (z >= ZZ) continue;
      float val = (acc[i][j] - bm)*scale + bb2;
      float zv = zf[((size_t)lb*NC + c)*ZZ + z];
      float rr = cu*zv + zv + val;
      dzffull[((size_t)lb*NC + c)*ZZ + z] = rr;
      int h = z/15, wv2 = z%15;
      if (h>=4 && h<11 && wv2>=4 && wv2<11)
        dzfout[((size_t)lb*NC + c)*49 + (h-4)*7 + (wv2-4)] = rr;
    }
  }
}

// ---------------- PrRoI pooling: block = (lb, 16-channel group) ----------------
__global__ __launch_bounds__(256) void k_rois(const float* __restrict__ zf,
    const float* __restrict__ box, float* __restrict__ rois){
  int lb = blockIdx.x; int b = lb % NB; int c0 = blockIdx.y*16;
  __shared__ float Wy[7][15], Wx[7][15];
  __shared__ float fld[16*ZZ];
  __shared__ float tmp[16][7][16];
  __shared__ float area_s;
  int t = threadIdx.x;
  const float* bx = box + b*4;
  const float SC = 15.0f/127.0f;
  float x1 = bx[0]*SC, y1 = bx[1]*SC, x2 = bx[2]*SC, y2 = bx[3]*SC;
  float bh = (y2-y1)/7.f, bw = (x2-x1)/7.f;
  if (t < 105){ int p=t/15, i=t%15;
    Wy[p][i] = hat_int(y1+(float)(p+1)*bh - (float)i) - hat_int(y1+(float)p*bh - (float)i); }
  else if (t < 210){ int q=(t-105)/15, i=(t-105)%15;
    Wx[q][i] = hat_int(x1+(float)(q+1)*bw - (float)i) - hat_int(x1+(float)q*bw - (float)i); }
  if (t == 255) area_s = fmaxf(bh*bw, 1e-6f);
  const float* src = zf + ((size_t)lb*NC + c0)*ZZ;
  for (int e=t; e<16*ZZ; e+=256) fld[e] = src[e];
  __syncthreads();
  float inv_area = 1.f/area_s;
  for (int e=t; e<16*105; e+=256){
    int w = e%15; int pc = e/15; int p = pc%7; int cc = pc/7;
    float s = 0.f;
    #pragma unroll
    for (int h=0;h<15;h++) s += Wy[p][h]*fld[cc*ZZ + h*15 + w];
    tmp[cc][p][w] = s;
  }
  __syncthreads();
  float* out = rois + ((size_t)lb*NC + c0)*49;
  for (int e=t; e<16*49; e+=256){
    int q = e%7; int pc = e/7; int p = pc%7; int cc = pc/7;
    float s = 0.f;
    #pragma unroll
    for (int w=0;w<15;w++) s += tmp[cc][p][w]*Wx[q][w];
    out[(size_t)cc*49 + p*7 + q] = s*inv_area;
  }
}

__global__ __launch_bounds__(256) void k_pool(const float* __restrict__ rois,
    float* __restrict__ pavg, float* __restrict__ pmax){
  int idx = blockIdx.x*256 + threadIdx.x;
  if (idx >= NL*NB*NC) return;
  const float* r = rois + (size_t)idx*49;
  float s = 0.f, m = -1e30f;
  #pragma unroll
  for (int i=0;i<49;i++){ float v = r[i]; s += v; m = fmaxf(m,v); }
  pavg[idx] = s/49.f;
  pmax[idx] = m;
}

// ---------------- MLP heads: one wave per output row ----------------
__global__ __launch_bounds__(256) void k_mlp1(const float* __restrict__ pavg, const float* __restrict__ pmax,
    const float* __restrict__ aw1, const float* __restrict__ ab1,
    const float* __restrict__ mw1, const float* __restrict__ mb1,
    float* __restrict__ hid){
  int lb = blockIdx.x; int l = lb/NB; int pass = blockIdx.y;
  int t = threadIdx.x, wid = t>>6, lane = t&63;
  int r = blockIdx.z*4 + wid;
  const float* pv = pass ? pmax : pavg;
  const float* w1 = pass ? mw1 : aw1;
  const float* b1 = pass ? mb1 : ab1;
  const float* wr = w1 + (size_t)(l*NC2+r)*NC;
  const float* pr = pv + (size_t)lb*NC;
  float s = dot4(((const float4*)wr)[lane], ((const float4*)pr)[lane]);
  s = wave_red(s);
  if (lane==0) hid[((size_t)lb*2 + pass)*NC2 + r] = fmaxf(s + b1[l*NC2+r], 0.f);
}

__global__ __launch_bounds__(256) void k_mlp2(const float* __restrict__ hid,
    const float* __restrict__ aw2, const float* __restrict__ ab2,
    const float* __restrict__ mw2, const float* __restrict__ mb2,
    float* __restrict__ zavg, float* __restrict__ zmax){
  int lb = blockIdx.x; int l = lb/NB; int pass = blockIdx.y;
  int t = threadIdx.x, wid = t>>6, lane = t&63;
  int c = blockIdx.z*4 + wid;
  const float* w2 = pass ? mw2 : aw2;
  const float* b2 = pass ? mb2 : ab2;
  const float* wr = w2 + (size_t)(l*NC+c)*NC2;
  const float* hr = hid + ((size_t)lb*2 + pass)*NC2;
  float2 wv = ((const float2*)wr)[lane];
  float2 hv = ((const float2*)hr)[lane];
  float s = wave_red(wv.x*hv.x + wv.y*hv.y);
  if (lane==0){
    float* zo = pass ? zmax : zavg;
    zo[(size_t)lb*NC + c] = s + b2[l*NC+c];
  }
}

// ---------------- chan_z tail ----------------
__global__ __launch_bounds__(256) void k_relw(const float* __restrict__ F,
    const float* __restrict__ gw, const float* __restrict__ gb,
    float* __restrict__ rel){
  int lb = blockIdx.x; int l = lb/NB;
  int t = threadIdx.x, wid = t>>6, lane = t&63;
  int r = blockIdx.y*4 + wid;
  const float* wrow = gw + ((size_t)l*2*NC + r)*NC;
  const float* frow = F + ((size_t)lb*NC + (r>>1))*NC;
  float s = dot4(((const float4*)wrow)[lane], ((const float4*)frow)[lane]);
  s = wave_red(s);
  if (lane==0) rel[(size_t)lb*2*NC + r] = fmaxf(s + gb[l*2*NC+r], 0.f);
}

__global__ __launch_bounds__(256) void k_z2naw(const float* __restrict__ rel,
    const float* __restrict__ aw, const float* __restrict__ ab,
    float* __restrict__ z2n){
  int lb = blockIdx.x; int l = lb/NB;
  int t = threadIdx.x, wid = t>>6, lane = t&63;
  int c = blockIdx.y*4 + wid;
  const float* arow = aw + ((size_t)l*NC + c)*2*NC;
  const float* rrow = rel + (size_t)lb*2*NC;
  float s = dot4(((const float4*)arow)[lane],    ((const float4*)rrow)[lane])
          + dot4(((const float4*)arow)[lane+64], ((const float4*)rrow)[lane+64]);
  s = wave_red(s);
  if (lane==0) z2n[(size_t)lb*NC + c] = s + ab[l*NC+c];
}

__global__ __launch_bounds__(256) void k_cues(const float* __restrict__ zavg, const float* __restrict__ zmax,
    const float* __restrict__ z2n, const float* __restrict__ drw, const float* __restrict__ drb,
    float* __restrict__ cues){
  int idx = blockIdx.x*256 + threadIdx.x;
  if (idx >= NL*NB*NC) return;
  int c = idx & 255; int lb = idx >> 8; int l = lb/NB;
  const float* dw = drw + (size_t)(l*NC + c)*3;
  float x = dw[0]*zavg[idx] + dw[1]*zmax[idx] + dw[2]*z2n[idx] + drb[l*NC+c];
  cues[idx] = 1.f/(1.f + __expf(-x));
}

// ---------------- collapsed sc branch ----------------
__global__ __launch_bounds__(256) void k_zm(const float* __restrict__ zf, const float* __restrict__ m3,
    float* __restrict__ zm, float* __restrict__ sm){
  int lb = blockIdx.x; int cg = blockIdx.y;
  __shared__ float ms[ZZ];
  int t = threadIdx.x;
  if (t < ZZ) ms[t] = m3[(size_t)lb*ZZ + t];
  __syncthreads();
  int c = cg*32 + (t >> 3);
  int sub = t & 7;
  const float* zr = zf + ((size_t)lb*NC + c)*ZZ;
  float s = 0.f;
  for (int z=sub; z<ZZ; z+=8) s += zr[z]*ms[z];
  s += __shfl_down(s, 4, 8);
  s += __shfl_down(s, 2, 8);
  s += __shfl_down(s, 1, 8);
  if (sub == 0) zm[(size_t)lb*NC + c] = s;
  if (cg == 0 && t < 64){
    float ss = 0.f;
    for (int z=t; z<ZZ; z+=64) ss += ms[z];
    ss = wave_red(ss);
    if (t == 0) sm[lb] = ss;
  }
}

__global__ __launch_bounds__(256) void k_zphi(const float* __restrict__ zm, const float* __restrict__ sm,
    const float* __restrict__ phiw, const float* __restrict__ phib, float* __restrict__ zphi){
  int lb = blockIdx.x; int l = lb/NB;
  int t = threadIdx.x, wid = t>>6, lane = t&63;
  int r = blockIdx.y*4 + wid;
  const float* wr = phiw + (size_t)(l*NC + r)*NC;
  const float* zr = zm + (size_t)lb*NC;
  float s = dot4(((const float4*)wr)[lane], ((const float4*)zr)[lane]);
  s = wave_red(s);
  if (lane==0) zphi[(size_t)lb*NC + r] = s + phib[l*NC + r]*sm[lb];
}

__global__ __launch_bounds__(256) void k_wvec(const float* __restrict__ zphi, const float* __restrict__ dw,
    const float* __restrict__ db, float* __restrict__ wvec, float* __restrict__ cb){
  int lb = blockIdx.x; int l = lb/NB;
  __shared__ float zp[NC];
  __shared__ float red[NC];
  int t = threadIdx.x;
  zp[t] = zphi[(size_t)lb*NC + t];
  __syncthreads();
  float s = 0.f;
  const float* dwl = dw + (size_t)l*NC*NC;
  for (int c=0;c<NC;c++) s += zp[c]*dwl[(size_t)c*NC + t];
  wvec[(size_t)lb*NC + t] = s;
  red[t] = zp[t]*db[l*NC + t];
  __syncthreads();
  for (int off2=128; off2>0; off2>>=1){
    if (t < off2) red[t] += red[t+off2];
    __syncthreads();
  }
  if (t==0) cb[lb] = red[0];
}

// ---------------- fused sc + xf_out: block = (lb, x-tile of 256) ----------------
__global__ __launch_bounds__(256) void k_scxf(const float* __restrict__ xf,
    const float* __restrict__ wvec, const float* __restrict__ cb,
    const float* __restrict__ cues, float* __restrict__ out){
  int lb = blockIdx.x;
  __shared__ float wv[NC];
  __shared__ float cu[NC];
  int t = threadIdx.x;
  wv[t] = wvec[(size_t)lb*NC + t];
  cu[t] = cues[(size_t)lb*NC + t];
  __syncthreads();
  int x = blockIdx.y*256 + t;
  if (x >= XX) return;
  float cbv = cb[lb];
  const float* xb = xf + (size_t)lb*NC*XX + x;
  float s = 0.f;
  #pragma unroll 4
  for (int c=0;c<NC;c++) s += wv[c]*xb[(size_t)c*XX];
  float scv = fminf(fmaxf((s + cbv)*0.0625f, 0.f), 1.f);
  float* ob = out + (size_t)lb*NC*XX + x;
  #pragma unroll 4
  for (int c=0;c<NC;c++)
    ob[(size_t)c*XX] = (1.f+cu[c])*xb[(size_t)c*XX] - scv;
}

extern "C" void kernel_launch(void* const* d_in, const int* in_sizes, int n_in,
                              void* d_out, int out_size, void* d_ws, size_t ws_size,
                              hipStream_t stream){
  const float* zf      = (const float*)d_in[0];
  const float* xf      = (const float*)d_in[1];
  const float* maskp   = (const float*)d_in[2];
  const float* box     = (const float*)d_in[3];
  const float* nl_g_w  = (const float*)d_in[4];
  const float* nl_g_b  = (const float*)d_in[5];
  const float* nl_th_w = (const float*)d_in[6];
  const float* nl_th_b = (const float*)d_in[7];
  const float* nl_ph_w = (const float*)d_in[8];
  const float* nl_ph_b = (const float*)d_in[9];
  const float* nl_out_w= (const float*)d_in[10];
  const float* bn_g    = (const float*)d_in[11];
  const float* bn_b    = (const float*)d_in[12];
  const float* bn_m    = (const float*)d_in[13];
  const float* bn_v    = (const float*)d_in[14];
  const float* cz_th_w = (const float*)d_in[15];
  const float* cz_th_b = (const float*)d_in[16];
  const float* cz_ph_w = (const float*)d_in[17];
  const float* cz_ph_b = (const float*)d_in[18];
  const float* cz_gw   = (const float*)d_in[19];
  const float* cz_gb   = (const float*)d_in[20];
  const float* cz_aw   = (const float*)d_in[21];
  const float* cz_ab   = (const float*)d_in[22];
  const float* ap_w1   = (const float*)d_in[23];
  const float* ap_b1   = (const float*)d_in[24];
  const float* ap_w2   = (const float*)d_in[25];
  const float* ap_b2   = (const float*)d_in[26];
  const float* mp_w1   = (const float*)d_in[27];
  const float* mp_b1   = (const float*)d_in[28];
  const float* mp_w2   = (const float*)d_in[29];
  const float* mp_b2   = (const float*)d_in[30];
  const float* dr_w    = (const float*)d_in[31];
  const float* dr_b    = (const float*)d_in[32];
  const float* ac1_w   = (const float*)d_in[33];
  const float* ac1_b   = (const float*)d_in[34];
  const float* ac2_w   = (const float*)d_in[35];
  const float* ac2_b   = (const float*)d_in[36];
  const float* ac3_w   = (const float*)d_in[37];
  const float* ac3_b   = (const float*)d_in[38];
  const float* ac4_w   = (const float*)d_in[39];
  const float* ac4_b   = (const float*)d_in[40];
  const float* phi_w   = (const float*)d_in[41];
  const float* phi_b   = (const float*)d_in[42];
  const float* delta_w = (const float*)d_in[43];
  const float* delta_b = (const float*)d_in[44];
  (void)in_sizes; (void)n_in; (void)out_size; (void)ws_size;

  float* ws = (float*)d_ws;
  const size_t SZ_P  = (size_t)NL*NB*ZZ*NC2;
  const size_t SZ_S  = (size_t)NL*NB*ZZ*ZZ;

  size_t off = 0;
  auto alloc = [&](size_t n){ size_t o = off; off += (n + 15) & ~(size_t)15; return o; };
  float* TH  = ws + alloc(SZ_P);
  float* PHt = ws + alloc(SZ_P);
  float* GX  = ws + alloc(SZ_P);
  float* S   = ws + alloc(SZ_S);
  float* Yb  = ws + alloc(SZ_P);
  float* m3   = ws + alloc((size_t)NL*NB*ZZ);
  float* rois = ws + alloc((size_t)NL*NB*NC*49);
  float* pavg = ws + alloc((size_t)NL*NB*NC);
  float* pmax = ws + alloc((size_t)NL*NB*NC);
  float* zavg = ws + alloc((size_t)NL*NB*NC);
  float* zmax = ws + alloc((size_t)NL*NB*NC);
  float* z2n  = ws + alloc((size_t)NL*NB*NC);
  float* cues = ws + alloc((size_t)NL*NB*NC);
  float* zm   = ws + alloc((size_t)NL*NB*NC);
  float* zphi = ws + alloc((size_t)NL*NB*NC);
  float* wvec = ws + alloc((size_t)NL*NB*NC);
  float* czth = ws + alloc((size_t)NL*NB*49*NC);
  float* czph = ws + alloc((size_t)NL*NB*49*NC);
  float* sm   = ws + alloc((size_t)NL*NB);
  float* cbuf = ws + alloc((size_t)NL*NB);
  float* Fbuf = ws + alloc((size_t)NL*NB*NC*NC);
  float* relb = ws + alloc((size_t)NL*NB*2*NC);
  float* hidb = ws + alloc((size_t)NL*NB*2*NC2);

  float* outp    = (float*)d_out;
  float* o_zfout = outp;
  float* o_zffull= outp + (size_t)NL*NB*NC*49;
  float* o_xfout = o_zffull + (size_t)NL*NB*NC*ZZ;

  // ---- fused mask branch ----
  k_mask<<<NL*NB, 256, 0, stream>>>(maskp, ac1_w, ac1_b, ac2_w, ac2_b,
                                     ac3_w, ac3_b, ac4_w, ac4_b, m3);

  // ---- non-local projections ----
  dim3 gLB(8, NL*NB);
  k_gemm64<0,0,true,true><<<gLB, 256, 0, stream>>>(zf, nl_th_w, nl_th_b, TH,  ZZ, NC2, NC, 2);
  k_gemm64<0,0,true,true><<<gLB, 256, 0, stream>>>(zf, nl_ph_w, nl_ph_b, PHt, ZZ, NC2, NC, 2);
  k_gemm64<0,0,true,true><<<gLB, 256, 0, stream>>>(zf, nl_g_w,  nl_g_b,  GX,  ZZ, NC2, NC, 2);
  k_gemm64<1,0,false,false><<<dim3(16, NL*NB), 256, 0, stream>>>(TH, PHt, nullptr, S, ZZ, ZZ, NC2, 4);
  k_softmax<<<(NL*NB*ZZ)/4, 256, 0, stream>>>(S);
  k_gemm64<1,1,false,false><<<dim3(8, NL*NB), 256, 0, stream>>>(S, GX, nullptr, Yb, ZZ, NC2, ZZ, 2);

  // ---- rois / cues ----
  k_rois<<<dim3(NL*NB, 16), 256, 0, stream>>>(zf, box, rois);
  k_pool<<<(NL*NB*NC+255)/256, 256, 0, stream>>>(rois, pavg, pmax);
  k_mlp1<<<dim3(NL*NB, 2, 32), 256, 0, stream>>>(pavg, pmax, ap_w1, ap_b1, mp_w1, mp_b1, hidb);
  k_mlp2<<<dim3(NL*NB, 2, 64), 256, 0, stream>>>(hidb, ap_w2, ap_b2, mp_w2, mp_b2, zavg, zmax);
  k_gemm64<0,0,true,true><<<dim3(4, NL*NB), 256, 0, stream>>>(rois, cz_th_w, cz_th_b, czth, 49, NC, NC, 4);
  k_gemm64<0,0,true,true><<<dim3(4, NL*NB), 256, 0, stream>>>(rois, cz_ph_w, cz_ph_b, czph, 49, NC, NC, 4);
  k_gemm64<0,1,false,false><<<dim3(16, NL*NB), 256, 0, stream>>>(czth, czph, nullptr, Fbuf, NC, NC, 49, 4);
  k_relw<<<dim3(NL*NB, 128), 256, 0, stream>>>(Fbuf, cz_gw, cz_gb, relb);
  k_z2naw<<<dim3(NL*NB, 64), 256, 0, stream>>>(relb, cz_aw, cz_ab, z2n);
  k_cues<<<(NL*NB*NC+255)/256, 256, 0, stream>>>(zavg, zmax, z2n, dr_w, dr_b, cues);

  // ---- zf_full (+7x7 slice) ----
  k_outconv<<<dim3(16, NL*NB), 256, 0, stream>>>(Yb, nl_out_w, bn_g, bn_b, bn_m, bn_v,
                                                  cues, zf, o_zfout, o_zffull);

  // ---- collapsed sc branch + fused xf_out ----
  k_zm<<<dim3(NL*NB, 8), 256, 0, stream>>>(zf, m3, zm, sm);
  k_zphi<<<dim3(NL*NB, 64), 256, 0, stream>>>(zm, sm, phi_w, phi_b, zphi);
  k_wvec<<<NL*NB, 256, 0, stream>>>(zphi, delta_w, delta_b, wvec, cbuf);
  k_scxf<<<dim3(NL*NB, 4), 256, 0, stream>>>(xf, wvec, cbuf, cues, o_xfout);
}

// Round 8
// 592.097 us; speedup vs baseline: 1.7820x; 1.1596x over previous
//
#include <hip/hip_runtime.h>
#include <math.h>

#define NL 3
#define NB 32
#define NC 256
#define NC2 128
#define HZ 15
#define ZZ 225
#define XX 961
#define HMD 127

__device__ __forceinline__ float hat_int(float u){
  if (u <= -1.f) return 0.f;
  if (u <= 0.f){ float t = u + 1.f; return 0.5f*t*t; }
  if (u <= 1.f){ float t = 1.f - u; return 1.f - 0.5f*t*t; }
  return 1.f;
}
__device__ __forceinline__ float dot4(float4 a, float4 b){
  return a.x*b.x + a.y*b.y + a.z*b.z + a.w*b.w;
}
__device__ __forceinline__ float wave_red(float s){
  #pragma unroll
  for (int off=32; off>0; off>>=1) s += __shfl_xor(s, off);
  return s;
}

// ================= fused mask branch: one block per (l,b) =================
__global__ __launch_bounds__(256) void k_mask(const float* __restrict__ mask,
    const float* __restrict__ w1, const float* __restrict__ b1,
    const float* __restrict__ w2, const float* __restrict__ b2,
    const float* __restrict__ w3, const float* __restrict__ b3,
    const float* __restrict__ w4, const float* __restrict__ b4,
    float* __restrict__ m3out){
  int lb = blockIdx.x; int l = lb/NB, b = lb%NB;
  int t = threadIdx.x;
  __shared__ float c1s[4][56][56];
  __shared__ float c2s[8][28][28];
  __shared__ float r1s[8][14][14];
  __shared__ float c3s[4][14][14];
  __shared__ float r2s[4][15][15];
  __shared__ int   y0t[14];
  __shared__ float wyt[14];
  __shared__ int   y0t15[15];
  __shared__ float wyt15[15];
  if (t < 14){
    float sy = 122.0f/13.0f;
    float yf = (float)t * sy;
    int y0 = (int)floorf(yf); y0 = min(max(y0,0), 121);
    y0t[t] = y0; wyt[t] = yf - (float)y0;
  } else if (t < 29){
    int q = t-14;
    float sy = 13.0f/14.0f;
    float yf = (float)q * sy;
    int y0 = (int)floorf(yf); y0 = min(max(y0,0), 12);
    y0t15[q] = y0; wyt15[q] = yf - (float)y0;
  }
  __syncthreads();
  const float* mb = mask + (size_t)b*HMD*HMD;
  const float* wc1 = w1 + (size_t)l*4*2*9;
  for (int e=t; e<4*56*56; e+=256){
    int ci = e % 56, ri = (e/56) % 56, oc = e/(56*56);
    int row = y0t[ri>>2] + (ri&3);
    int col = y0t[ci>>2] + (ci&3);
    float acc = b1[l*4+oc];
    #pragma unroll
    for (int ky=0;ky<3;ky++)
      #pragma unroll
      for (int kx=0;kx<3;kx++){
        float mv = mb[(row+ky)*HMD + (col+kx)];
        acc += wc1[((oc*2+0)*3+ky)*3+kx]*mv;
        acc += wc1[((oc*2+1)*3+ky)*3+kx]*(1.f-mv);
      }
    c1s[oc][ri][ci] = fmaxf(acc, 0.f);
  }
  __syncthreads();
  const float* wc2 = w2 + (size_t)l*8*4*9;
  for (int e=t; e<8*28*28; e+=256){
    int j = e % 28, i = (e/28) % 28, oc = e/(28*28);
    int g = i>>1, dy = i&1, gc = j>>1, dx = j&1;
    float acc = b2[l*8+oc];
    #pragma unroll
    for (int ic=0; ic<4; ic++)
      #pragma unroll
      for (int ky=0;ky<3;ky++)
        #pragma unroll
        for (int kx=0;kx<3;kx++)
          acc += wc2[((oc*4+ic)*3+ky)*3+kx]*c1s[ic][g*4+dy+ky][gc*4+dx+kx];
    c2s[oc][i][j] = fmaxf(acc, 0.f);
  }
  __syncthreads();
  for (int e=t; e<8*14*14; e+=256){
    int ox = e % 14, oy = (e/14) % 14, oc = e/(14*14);
    float wy = wyt[oy], wx = wyt[ox];
    float v00 = c2s[oc][2*oy][2*ox],   v01 = c2s[oc][2*oy][2*ox+1];
    float v10 = c2s[oc][2*oy+1][2*ox], v11 = c2s[oc][2*oy+1][2*ox+1];
    r1s[oc][oy][ox] = (v00*(1.f-wy)+v10*wy)*(1.f-wx) + (v01*(1.f-wy)+v11*wy)*wx;
  }
  __syncthreads();
  const float* wc3 = w3 + (size_t)l*4*8*9;
  for (int e=t; e<4*14*14; e+=256){
    int x = e % 14, y = (e/14) % 14, oc = e/(14*14);
    float acc = b3[l*4+oc];
    for (int ic=0; ic<8; ic++)
      #pragma unroll
      for (int ky=-1;ky<=1;ky++){
        int yy = y+ky; if (yy<0||yy>=14) continue;
        #pragma unroll
        for (int kx=-1;kx<=1;kx++){
          int xx = x+kx; if (xx<0||xx>=14) continue;
          acc += wc3[((oc*8+ic)*3+(ky+1))*3+(kx+1)]*r1s[ic][yy][xx];
        }
      }
    c3s[oc][y][x] = acc;
  }
  __syncthreads();
  for (int e=t; e<4*15*15; e+=256){
    int ox = e % 15, oy = (e/15) % 15, oc = e/(15*15);
    int y0 = y0t15[oy], x0 = y0t15[ox];
    float wy = wyt15[oy], wx = wyt15[ox];
    float v00 = c3s[oc][y0][x0],   v01 = c3s[oc][y0][x0+1];
    float v10 = c3s[oc][y0+1][x0], v11 = c3s[oc][y0+1][x0+1];
    r2s[oc][oy][ox] = (v00*(1.f-wy)+v10*wy)*(1.f-wx) + (v01*(1.f-wy)+v11*wy)*wx;
  }
  __syncthreads();
  const float* wc4 = w4 + (size_t)l*1*4*9;
  for (int e=t; e<15*15; e+=256){
    int x = e % 15, y = e/15;
    float acc = b4[l];
    #pragma unroll
    for (int ic=0; ic<4; ic++)
      #pragma unroll
      for (int ky=-1;ky<=1;ky++){
        int yy = y+ky; if (yy<0||yy>=15) continue;
        #pragma unroll
        for (int kx=-1;kx<=1;kx++){
          int xx = x+kx; if (xx<0||xx>=15) continue;
          acc += wc4[(ic*3+(ky+1))*3+(kx+1)]*r2s[ic][yy][xx];
        }
      }
    m3out[(size_t)lb*ZZ + y*15 + x] = acc;
  }
}

// ---------------- weight pack kernels ----------------
__global__ __launch_bounds__(256) void k_pack_proj(
    const float* __restrict__ thw, const float* __restrict__ thb,
    const float* __restrict__ phw, const float* __restrict__ phb,
    const float* __restrict__ gw,  const float* __restrict__ gb,
    float* __restrict__ Wcat, float* __restrict__ bcat){
  int idx = blockIdx.x*256 + threadIdx.x;
  if (idx < NL*384*256){
    int k = idx & 255; int r = (idx >> 8) % 384; int l = idx/(384*256);
    float v;
    if (r < 128)      v = thw[((size_t)l*128 + r)*256 + k];
    else if (r < 256) v = phw[((size_t)l*128 + (r-128))*256 + k];
    else              v = gw [((size_t)l*128 + (r-256))*256 + k];
    Wcat[idx] = v;
  }
  if (idx < NL*384){
    int r = idx % 384, l = idx/384;
    bcat[idx] = (r<128) ? thb[l*128+r] : (r<256) ? phb[l*128+r-128] : gb[l*128+r-256];
  }
}

__global__ __launch_bounds__(256) void k_pack_cz(
    const float* __restrict__ thw, const float* __restrict__ thb,
    const float* __restrict__ phw, const float* __restrict__ phb,
    float* __restrict__ Wcz, float* __restrict__ bcz){
  int idx = blockIdx.x*256 + threadIdx.x;
  if (idx < NL*512*256){
    int k = idx & 255; int r = (idx >> 8) % 512; int l = idx/(512*256);
    float v;
    if (r < 256) v = thw[((size_t)l*256 + r)*256 + k];
    else         v = phw[((size_t)l*256 + (r-256))*256 + k];
    Wcz[idx] = v;
  }
  if (idx < NL*512){
    int r = idx % 512, l = idx/512;
    bcz[idx] = (r<256) ? thb[l*256+r] : phb[l*256+r-256];
  }
}

// ---------------- generalized 64x64-tile fp32 GEMM, 4x4 per thread ----------------
// AMODE 0: va=A[k*lda+m]. AMODE 1: va=A[m*lda+k].
// BMODE 0: vb=B[n*ldb+k]. BMODE 1: vb=B[k*ldb+n].
template<int AMODE, int BMODE, bool BPERL, bool HASBIAS>
__global__ __launch_bounds__(256) void k_gemmG(
    const float* __restrict__ A0, const float* __restrict__ B0,
    const float* __restrict__ bias0, float* __restrict__ O0,
    int M, int N, int K, int lda, int ldb, int ldo,
    long Abatch, long Bbatch, long Obatch, int ntn)
{
  int lb = blockIdx.y; int l = lb / NB;
  const float* A = A0 + (size_t)lb*Abatch;
  const float* B = B0 + (BPERL ? (size_t)l : (size_t)lb)*Bbatch;
  float* out = O0 + (size_t)lb*Obatch;
  int tm = blockIdx.x / ntn, tn = blockIdx.x % ntn;
  int m0 = tm*64, n0 = tn*64;
  __shared__ float As[32][68];
  __shared__ float Bs[32][68];
  int t = threadIdx.x;
  int tx = t & 15, ty = t >> 4;
  float acc[4][4] = {};
  for (int kc=0; kc<K; kc+=32){
    #pragma unroll
    for (int r=0;r<8;r++){
      int e = r*256 + t;
      int mm, kk;
      if (AMODE==0){ mm = e & 63; kk = e >> 6; }
      else { kk = e & 31; mm = e >> 5; }
      float va = 0.f;
      { int m = m0+mm, k = kc+kk;
        if (m < M && k < K)
          va = (AMODE==0) ? A[(size_t)k*lda + m] : A[(size_t)m*lda + k]; }
      As[kk][mm] = va;
      int nn, kk2;
      if (BMODE==0){ kk2 = e & 31; nn = e >> 5; }
      else { nn = e & 63; kk2 = e >> 6; }
      float vb = 0.f;
      { int n = n0+nn, k = kc+kk2;
        if (n < N && k < K)
          vb = (BMODE==0) ? B[(size_t)n*ldb + k] : B[(size_t)k*ldb + n]; }
      Bs[kk2][nn] = vb;
    }
    __syncthreads();
    #pragma unroll
    for (int kk=0; kk<32; kk++){
      float4 av = *(const float4*)&As[kk][ty*4];
      float4 bv = *(const float4*)&Bs[kk][tx*4];
      float aa[4] = {av.x, av.y, av.z, av.w};
      float bb[4] = {bv.x, bv.y, bv.z, bv.w};
      #pragma unroll
      for (int i=0;i<4;i++)
        #pragma unroll
        for (int j=0;j<4;j++)
          acc[i][j] += aa[i]*bb[j];
    }
    __syncthreads();
  }
  const float* bias = HASBIAS ? (bias0 + (size_t)l*N) : nullptr;
  #pragma unroll
  for (int i=0;i<4;i++){
    int m = m0 + ty*4 + i;
    if (m >= M) continue;
    #pragma unroll
    for (int j=0;j<4;j++){
      int n = n0 + tx*4 + j;
      if (n < N) out[(size_t)m*ldo + n] = acc[i][j] + (HASBIAS ? bias[n] : 0.f);
    }
  }
}

// ---------------- softmax rows of S (in place), fold 1/sqrt(C) ----------------
__global__ __launch_bounds__(256) void k_softmax(float* __restrict__ S){
  int row = blockIdx.x*4 + (threadIdx.x >> 6);
  int lane = threadIdx.x & 63;
  float* r = S + (size_t)row*ZZ;
  float v[4]; float mx = -1e30f;
  #pragma unroll
  for (int q=0;q<4;q++){
    int j = lane + q*64;
    v[q] = (j<ZZ) ? r[j] : -1e30f;
    mx = fmaxf(mx, v[q]);
  }
  #pragma unroll
  for (int off=32; off>0; off>>=1) mx = fmaxf(mx, __shfl_xor(mx, off));
  float sum = 0.f;
  #pragma unroll
  for (int q=0;q<4;q++){
    v[q] = __expf(v[q]-mx);
    if (lane + q*64 < ZZ) sum += v[q];
  }
  #pragma unroll
  for (int off=32; off>0; off>>=1) sum += __shfl_xor(sum, off);
  float inv = 1.f/(16.f*sum);
  #pragma unroll
  for (int q=0;q<4;q++){
    int j = lane + q*64;
    if (j<ZZ) r[j] = v[q]*inv;
  }
}

// ---------------- outconv: 64x64 GEMM + BN/cues/residual epilogue ----------------
__global__ __launch_bounds__(256) void k_outconv(const float* __restrict__ Y,
    const float* __restrict__ outw, const float* __restrict__ bng, const float* __restrict__ bnb,
    const float* __restrict__ bnm, const float* __restrict__ bnv,
    const float* __restrict__ cues, const float* __restrict__ zf,
    float* __restrict__ dzfout, float* __restrict__ dzffull){
  int lb = blockIdx.y; int l = lb/NB;
  const float* A = outw + (size_t)l*NC*NC2;
  const float* B = Y + (size_t)lb*ZZ*NC2;
  int tm = blockIdx.x >> 2, tn = blockIdx.x & 3;
  int m0 = tm*64, n0 = tn*64;
  __shared__ float As[32][68];
  __shared__ float Bs[32][68];
  int t = threadIdx.x;
  int tx = t & 15, ty = t >> 4;
  float acc[4][4] = {};
  for (int kc=0; kc<NC2; kc+=32){
    #pragma unroll
    for (int r=0;r<8;r++){
      int e = r*256 + t;
      int kk = e & 31, mm = e >> 5;
      As[kk][mm] = A[(size_t)(m0+mm)*NC2 + kc+kk];
      float vb = 0.f;
      int n = n0+mm;
      if (n < ZZ) vb = B[(size_t)n*NC2 + kc+kk];
      Bs[kk][mm] = vb;
    }
    __syncthreads();
    #pragma unroll
    for (int kk=0; kk<32; kk++){
      float4 av = *(const float4*)&As[kk][ty*4];
      float4 bv = *(const float4*)&Bs[kk][tx*4];
      float aa[4] = {av.x, av.y, av.z, av.w};
      float bb[4] = {bv.x, bv.y, bv.z, bv.w};
      #pragma unroll
      for (int i=0;i<4;i++)
        #pragma unroll
        for (int j=0;j<4;j++)
          acc[i][j] += aa[i]*bb[j];
    }
    __syncthreads();
  }
  #pragma unroll
  for (int i=0;i<4;i++){
    int c = m0 + ty*4 + i;
    float scale = bng[l*NC+c] * rsqrtf(bnv[l*NC+c] + 1e-5f);
    float bm = bnm[l*NC+c], bb2 = bnb[l*NC+c];
    float cu = cues[(size_t)lb*NC + c];
    #pragma unroll
    for (int j=0;j<4;j++){
      int z = n0 + tx*4 + j;
      if (z >= ZZ) continue;
      float val = (acc[i][j] - bm)*scale + bb2;
      float zv = zf[((size_t)lb*NC + c)*ZZ + z];
      float rr = cu*zv + zv + val;
      dzffull[((size_t)lb*NC + c)*ZZ + z] = rr;
      int h = z/15, wv2 = z%15;
      if (h>=4 && h<11 && wv2>=4 && wv2<11)
        dzfout[((size_t)lb*NC + c)*49 + (h-4)*7 + (wv2-4)] = rr;
    }
  }
}

// ---------------- PrRoI pooling ----------------
__global__ __launch_bounds__(256) void k_rois(const float* __restrict__ zf,
    const float* __restrict__ box, float* __restrict__ rois){
  int lb = blockIdx.x; int b = lb % NB; int c0 = blockIdx.y*16;
  __shared__ float Wy[7][15], Wx[7][15];
  __shared__ float fld[16*ZZ];
  __shared__ float tmp[16][7][16];
  __shared__ float area_s;
  int t = threadIdx.x;
  const float* bx = box + b*4;
  const float SC = 15.0f/127.0f;
  float x1 = bx[0]*SC, y1 = bx[1]*SC, x2 = bx[2]*SC, y2 = bx[3]*SC;
  float bh = (y2-y1)/7.f, bw = (x2-x1)/7.f;
  if (t < 105){ int p=t/15, i=t%15;
    Wy[p][i] = hat_int(y1+(float)(p+1)*bh - (float)i) - hat_int(y1+(float)p*bh - (float)i); }
  else if (t < 210){ int q=(t-105)/15, i=(t-105)%15;
    Wx[q][i] = hat_int(x1+(float)(q+1)*bw - (float)i) - hat_int(x1+(float)q*bw - (float)i); }
  if (t == 255) area_s = fmaxf(bh*bw, 1e-6f);
  const float* src = zf + ((size_t)lb*NC + c0)*ZZ;
  for (int e=t; e<16*ZZ; e+=256) fld[e] = src[e];
  __syncthreads();
  float inv_area = 1.f/area_s;
  for (int e=t; e<16*105; e+=256){
    int w = e%15; int pc = e/15; int p = pc%7; int cc = pc/7;
    float s = 0.f;
    #pragma unroll
    for (int h=0;h<15;h++) s += Wy[p][h]*fld[cc*ZZ + h*15 + w];
    tmp[cc][p][w] = s;
  }
  __syncthreads();
  float* out = rois + ((size_t)lb*NC + c0)*49;
  for (int e=t; e<16*49; e+=256){
    int q = e%7; int pc = e/7; int p = pc%7; int cc = pc/7;
    float s = 0.f;
    #pragma unroll
    for (int w=0;w<15;w++) s += tmp[cc][p][w]*Wx[q][w];
    out[(size_t)cc*49 + p*7 + q] = s*inv_area;
  }
}

__global__ __launch_bounds__(256) void k_pool(const float* __restrict__ rois,
    float* __restrict__ pavg, float* __restrict__ pmax){
  int idx = blockIdx.x*256 + threadIdx.x;
  if (idx >= NL*NB*NC) return;
  const float* r = rois + (size_t)idx*49;
  float s = 0.f, m = -1e30f;
  #pragma unroll
  for (int i=0;i<49;i++){ float v = r[i]; s += v; m = fmaxf(m,v); }
  pavg[idx] = s/49.f;
  pmax[idx] = m;
}

// ---------------- MLP heads ----------------
__global__ __launch_bounds__(256) void k_mlp1(const float* __restrict__ pavg, const float* __restrict__ pmax,
    const float* __restrict__ aw1, const float* __restrict__ ab1,
    const float* __restrict__ mw1, const float* __restrict__ mb1,
    float* __restrict__ hid){
  int lb = blockIdx.x; int l = lb/NB; int pass = blockIdx.y;
  int t = threadIdx.x, wid = t>>6, lane = t&63;
  int r = blockIdx.z*4 + wid;
  const float* pv = pass ? pmax : pavg;
  const float* w1 = pass ? mw1 : aw1;
  const float* b1 = pass ? mb1 : ab1;
  const float* wr = w1 + (size_t)(l*NC2+r)*NC;
  const float* pr = pv + (size_t)lb*NC;
  float s = dot4(((const float4*)wr)[lane], ((const float4*)pr)[lane]);
  s = wave_red(s);
  if (lane==0) hid[((size_t)lb*2 + pass)*NC2 + r] = fmaxf(s + b1[l*NC2+r], 0.f);
}

__global__ __launch_bounds__(256) void k_mlp2(const float* __restrict__ hid,
    const float* __restrict__ aw2, const float* __restrict__ ab2,
    const float* __restrict__ mw2, const float* __restrict__ mb2,
    float* __restrict__ zavg, float* __restrict__ zmax){
  int lb = blockIdx.x; int l = lb/NB; int pass = blockIdx.y;
  int t = threadIdx.x, wid = t>>6, lane = t&63;
  int c = blockIdx.z*4 + wid;
  const float* w2 = pass ? mw2 : aw2;
  const float* b2 = pass ? mb2 : ab2;
  const float* wr = w2 + (size_t)(l*NC+c)*NC2;
  const float* hr = hid + ((size_t)lb*2 + pass)*NC2;
  float2 wv = ((const float2*)wr)[lane];
  float2 hv = ((const float2*)hr)[lane];
  float s = wave_red(wv.x*hv.x + wv.y*hv.y);
  if (lane==0){
    float* zo = pass ? zmax : zavg;
    zo[(size_t)lb*NC + c] = s + b2[l*NC+c];
  }
}

// ---------------- chan_z tail ----------------
__global__ __launch_bounds__(256) void k_relw(const float* __restrict__ F,
    const float* __restrict__ gw, const float* __restrict__ gb,
    float* __restrict__ rel){
  int lb = blockIdx.x; int l = lb/NB;
  int t = threadIdx.x, wid = t>>6, lane = t&63;
  int r = blockIdx.y*4 + wid;
  const float* wrow = gw + ((size_t)l*2*NC + r)*NC;
  const float* frow = F + (size_t)lb*NC*NC + (size_t)(r>>1)*NC;
  float s = dot4(((const float4*)wrow)[lane], ((const float4*)frow)[lane]);
  s = wave_red(s);
  if (lane==0) rel[(size_t)lb*2*NC + r] = fmaxf(s + gb[l*2*NC+r], 0.f);
}

__global__ __launch_bounds__(256) void k_z2naw(const float* __restrict__ rel,
    const float* __restrict__ aw, const float* __restrict__ ab,
    float* __restrict__ z2n){
  int lb = blockIdx.x; int l = lb/NB;
  int t = threadIdx.x, wid = t>>6, lane = t&63;
  int c = blockIdx.y*4 + wid;
  const float* arow = aw + ((size_t)l*NC + c)*2*NC;
  const float* rrow = rel + (size_t)lb*2*NC;
  float s = dot4(((const float4*)arow)[lane],    ((const float4*)rrow)[lane])
          + dot4(((const float4*)arow)[lane+64], ((const float4*)rrow)[lane+64]);
  s = wave_red(s);
  if (lane==0) z2n[(size_t)lb*NC + c] = s + ab[l*NC+c];
}

__global__ __launch_bounds__(256) void k_cues(const float* __restrict__ zavg, const float* __restrict__ zmax,
    const float* __restrict__ z2n, const float* __restrict__ drw, const float* __restrict__ drb,
    float* __restrict__ cues){
  int idx = blockIdx.x*256 + threadIdx.x;
  if (idx >= NL*NB*NC) return;
  int c = idx & 255; int lb = idx >> 8; int l = lb/NB;
  const float* dw = drw + (size_t)(l*NC + c)*3;
  float x = dw[0]*zavg[idx] + dw[1]*zmax[idx] + dw[2]*z2n[idx] + drb[l*NC+c];
  cues[idx] = 1.f/(1.f + __expf(-x));
}

// ---------------- collapsed sc branch ----------------
__global__ __launch_bounds__(256) void k_zm(const float* __restrict__ zf, const float* __restrict__ m3,
    float* __restrict__ zm, float* __restrict__ sm){
  int lb = blockIdx.x; int cg = blockIdx.y;
  __shared__ float ms[ZZ];
  int t = threadIdx.x;
  if (t < ZZ) ms[t] = m3[(size_t)lb*ZZ + t];
  __syncthreads();
  int c = cg*32 + (t >> 3);
  int sub = t & 7;
  const float* zr = zf + ((size_t)lb*NC + c)*ZZ;
  float s = 0.f;
  for (int z=sub; z<ZZ; z+=8) s += zr[z]*ms[z];
  s += __shfl_down(s, 4, 8);
  s += __shfl_down(s, 2, 8);
  s += __shfl_down(s, 1, 8);
  if (sub == 0) zm[(size_t)lb*NC + c] = s;
  if (cg == 0 && t < 64){
    float ss = 0.f;
    for (int z=t; z<ZZ; z+=64) ss += ms[z];
    ss = wave_red(ss);
    if (t == 0) sm[lb] = ss;
  }
}

__global__ __launch_bounds__(256) void k_zphi(const float* __restrict__ zm, const float* __restrict__ sm,
    const float* __restrict__ phiw, const float* __restrict__ phib, float* __restrict__ zphi){
  int lb = blockIdx.x; int l = lb/NB;
  int t = threadIdx.x, wid = t>>6, lane = t&63;
  int r = blockIdx.y*4 + wid;
  const float* wr = phiw + (size_t)(l*NC + r)*NC;
  const float* zr = zm + (size_t)lb*NC;
  float s = dot4(((const float4*)wr)[lane], ((const float4*)zr)[lane]);
  s = wave_red(s);
  if (lane==0) zphi[(size_t)lb*NC + r] = s + phib[l*NC + r]*sm[lb];
}

__global__ __launch_bounds__(256) void k_wvec(const float* __restrict__ zphi, const float* __restrict__ dw,
    const float* __restrict__ db, float* __restrict__ wvec, float* __restrict__ cb){
  int lb = blockIdx.x; int l = lb/NB;
  __shared__ float zp[NC];
  __shared__ float red[NC];
  int t = threadIdx.x;
  zp[t] = zphi[(size_t)lb*NC + t];
  __syncthreads();
  float s = 0.f;
  const float* dwl = dw + (size_t)l*NC*NC;
  for (int c=0;c<NC;c++) s += zp[c]*dwl[(size_t)c*NC + t];
  wvec[(size_t)lb*NC + t] = s;
  red[t] = zp[t]*db[l*NC + t];
  __syncthreads();
  for (int off2=128; off2>0; off2>>=1){
    if (t < off2) red[t] += red[t+off2];
    __syncthreads();
  }
  if (t==0) cb[lb] = red[0];
}

// ---------------- sc partial sums: grid (lb, 4 xtiles, 4 csplit) ----------------
__global__ __launch_bounds__(256) void k_sc_part(const float* __restrict__ xf,
    const float* __restrict__ wvec, float* __restrict__ part){
  int lb = blockIdx.x, xt = blockIdx.y, cs = blockIdx.z;
  __shared__ float wv[64];
  int t = threadIdx.x;
  if (t < 64) wv[t] = wvec[(size_t)lb*NC + cs*64 + t];
  __syncthreads();
  int x = xt*256 + t;
  if (x >= XX) return;
  const float* xb = xf + ((size_t)lb*NC + cs*64)*XX + x;
  float s = 0.f;
  #pragma unroll 8
  for (int c=0;c<64;c++) s += wv[c]*xb[(size_t)c*XX];
  part[((size_t)lb*4 + cs)*XX + x] = s;
}

// ---------------- xf_out: grid (4, lb*NC) ----------------
__global__ __launch_bounds__(256) void k_xfout2(const float* __restrict__ xf,
    const float* __restrict__ part, const float* __restrict__ cb,
    const float* __restrict__ cues, float* __restrict__ out){
  int bc = blockIdx.y;
  int x = blockIdx.x*256 + threadIdx.x;
  if (x >= XX) return;
  int lb = bc >> 8;
  const float* pp = part + (size_t)lb*4*XX + x;
  float scv = pp[0] + pp[XX] + pp[2*XX] + pp[3*XX];
  scv = fminf(fmaxf((scv + cb[lb])*0.0625f, 0.f), 1.f);
  float cu = cues[bc];
  out[(size_t)bc*XX + x] = (1.f+cu)*xf[(size_t)bc*XX + x] - scv;
}

extern "C" void kernel_launch(void* const* d_in, const int* in_sizes, int n_in,
                              void* d_out, int out_size, void* d_ws, size_t ws_size,
                              hipStream_t stream){
  const float* zf      = (const float*)d_in[0];
  const float* xf      = (const float*)d_in[1];
  const float* maskp   = (const float*)d_in[2];
  const float* box     = (const float*)d_in[3];
  const float* nl_g_w  = (const float*)d_in[4];
  const float* nl_g_b  = (const float*)d_in[5];
  const float* nl_th_w = (const float*)d_in[6];
  const float* nl_th_b = (const float*)d_in[7];
  const float* nl_ph_w = (const float*)d_in[8];
  const float* nl_ph_b = (const float*)d_in[9];
  const float* nl_out_w= (const float*)d_in[10];
  const float* bn_g    = (const float*)d_in[11];
  const float* bn_b    = (const float*)d_in[12];
  const float* bn_m    = (const float*)d_in[13];
  const float* bn_v    = (const float*)d_in[14];
  const float* cz_th_w = (const float*)d_in[15];
  const float* cz_th_b = (const float*)d_in[16];
  const float* cz_ph_w = (const float*)d_in[17];
  const float* cz_ph_b = (const float*)d_in[18];
  const float* cz_gw   = (const float*)d_in[19];
  const float* cz_gb   = (const float*)d_in[20];
  const float* cz_aw   = (const float*)d_in[21];
  const float* cz_ab   = (const float*)d_in[22];
  const float* ap_w1   = (const float*)d_in[23];
  const float* ap_b1   = (const float*)d_in[24];
  const float* ap_w2   = (const float*)d_in[25];
  const float* ap_b2   = (const float*)d_in[26];
  const float* mp_w1   = (const float*)d_in[27];
  const float* mp_b1   = (const float*)d_in[28];
  const float* mp_w2   = (const float*)d_in[29];
  const float* mp_b2   = (const float*)d_in[30];
  const float* dr_w    = (const float*)d_in[31];
  const float* dr_b    = (const float*)d_in[32];
  const float* ac1_w   = (const float*)d_in[33];
  const float* ac1_b   = (const float*)d_in[34];
  const float* ac2_w   = (const float*)d_in[35];
  const float* ac2_b   = (const float*)d_in[36];
  const float* ac3_w   = (const float*)d_in[37];
  const float* ac3_b   = (const float*)d_in[38];
  const float* ac4_w   = (const float*)d_in[39];
  const float* ac4_b   = (const float*)d_in[40];
  const float* phi_w   = (const float*)d_in[41];
  const float* phi_b   = (const float*)d_in[42];
  const float* delta_w = (const float*)d_in[43];
  const float* delta_b = (const float*)d_in[44];
  (void)in_sizes; (void)n_in; (void)out_size; (void)ws_size;

  float* ws = (float*)d_ws;
  size_t off = 0;
  auto alloc = [&](size_t n){ size_t o = off; off += (n + 15) & ~(size_t)15; return o; };
  float* TH3  = ws + alloc((size_t)NL*NB*ZZ*384);      // 8.294M; F aliases this later
  float* S    = ws + alloc((size_t)NL*NB*ZZ*ZZ);       // 4.860M
  float* Yb   = ws + alloc((size_t)NL*NB*ZZ*NC2);      // 2.765M
  float* CZ3  = ws + alloc((size_t)NL*NB*49*512);      // 2.408M
  float* m3   = ws + alloc((size_t)NL*NB*ZZ);
  float* rois = ws + alloc((size_t)NL*NB*NC*49);
  float* pavg = ws + alloc((size_t)NL*NB*NC);
  float* pmax = ws + alloc((size_t)NL*NB*NC);
  float* zavg = ws + alloc((size_t)NL*NB*NC);
  float* zmax = ws + alloc((size_t)NL*NB*NC);
  float* z2n  = ws + alloc((size_t)NL*NB*NC);
  float* cues = ws + alloc((size_t)NL*NB*NC);
  float* zm   = ws + alloc((size_t)NL*NB*NC);
  float* zphi = ws + alloc((size_t)NL*NB*NC);
  float* wvec = ws + alloc((size_t)NL*NB*NC);
  float* sm   = ws + alloc((size_t)NL*NB);
  float* cbuf = ws + alloc((size_t)NL*NB);
  float* part = ws + alloc((size_t)NL*NB*4*XX);
  float* Wcat = ws + alloc((size_t)NL*384*256);
  float* bcat = ws + alloc((size_t)NL*384);
  float* Wcz  = ws + alloc((size_t)NL*512*256);
  float* bcz  = ws + alloc((size_t)NL*512);
  float* hidb = ws + alloc((size_t)NL*NB*2*NC2);
  float* relb = ws + alloc((size_t)NL*NB*2*NC);
  float* Freg = TH3;  // alias: TH3 dead after PV

  float* outp    = (float*)d_out;
  float* o_zfout = outp;
  float* o_zffull= outp + (size_t)NL*NB*NC*49;
  float* o_xfout = o_zffull + (size_t)NL*NB*NC*ZZ;

  // ---- fused mask branch + weight packs ----
  k_mask<<<NL*NB, 256, 0, stream>>>(maskp, ac1_w, ac1_b, ac2_w, ac2_b,
                                     ac3_w, ac3_b, ac4_w, ac4_b, m3);
  k_pack_proj<<<(NL*384*256+255)/256, 256, 0, stream>>>(nl_th_w, nl_th_b, nl_ph_w, nl_ph_b,
                                                         nl_g_w, nl_g_b, Wcat, bcat);
  k_pack_cz<<<(NL*512*256+255)/256, 256, 0, stream>>>(cz_th_w, cz_th_b, cz_ph_w, cz_ph_b, Wcz, bcz);

  // ---- merged non-local projections: TH3[lb][225][384] = {th, ph, g} ----
  k_gemmG<0,0,true,true><<<dim3(24, NL*NB), 256, 0, stream>>>(
      zf, Wcat, bcat, TH3, ZZ, 384, NC, ZZ, NC, 384,
      (long)NC*ZZ, (long)384*NC, (long)ZZ*384, 6);
  // S = TH · PH^T
  k_gemmG<1,0,false,false><<<dim3(16, NL*NB), 256, 0, stream>>>(
      TH3, TH3+128, nullptr, S, ZZ, ZZ, NC2, 384, 384, ZZ,
      (long)ZZ*384, (long)ZZ*384, (long)ZZ*ZZ, 4);
  k_softmax<<<(NL*NB*ZZ)/4, 256, 0, stream>>>(S);
  // Y = P · G
  k_gemmG<1,1,false,false><<<dim3(8, NL*NB), 256, 0, stream>>>(
      S, TH3+256, nullptr, Yb, ZZ, NC2, ZZ, ZZ, 384, NC2,
      (long)ZZ*ZZ, (long)ZZ*384, (long)ZZ*NC2, 2);

  // ---- rois / cues ----
  k_rois<<<dim3(NL*NB, 16), 256, 0, stream>>>(zf, box, rois);
  k_pool<<<(NL*NB*NC+255)/256, 256, 0, stream>>>(rois, pavg, pmax);
  k_mlp1<<<dim3(NL*NB, 2, 32), 256, 0, stream>>>(pavg, pmax, ap_w1, ap_b1, mp_w1, mp_b1, hidb);
  k_mlp2<<<dim3(NL*NB, 2, 64), 256, 0, stream>>>(hidb, ap_w2, ap_b2, mp_w2, mp_b2, zavg, zmax);
  // CZ3[lb][49][512] = {czth, czph}
  k_gemmG<0,0,true,true><<<dim3(8, NL*NB), 256, 0, stream>>>(
      rois, Wcz, bcz, CZ3, 49, 512, NC, 49, NC, 512,
      (long)NC*49, (long)512*NC, (long)49*512, 8);
  // F = czth^T · czph  (writes into dead TH3 region)
  k_gemmG<0,1,false,false><<<dim3(16, NL*NB), 256, 0, stream>>>(
      CZ3, CZ3+256, nullptr, Freg, NC, NC, 49, 512, 512, NC,
      (long)49*512, (long)49*512, (long)NC*NC, 4);
  k_relw<<<dim3(NL*NB, 128), 256, 0, stream>>>(Freg, cz_gw, cz_gb, relb);
  k_z2naw<<<dim3(NL*NB, 64), 256, 0, stream>>>(relb, cz_aw, cz_ab, z2n);
  k_cues<<<(NL*NB*NC+255)/256, 256, 0, stream>>>(zavg, zmax, z2n, dr_w, dr_b, cues);

  // ---- zf_full (+7x7 slice) ----
  k_outconv<<<dim3(16, NL*NB), 256, 0, stream>>>(Yb, nl_out_w, bn_g, bn_b, bn_m, bn_v,
                                                  cues, zf, o_zfout, o_zffull);

  // ---- collapsed sc branch + xf_out ----
  k_zm<<<dim3(NL*NB, 8), 256, 0, stream>>>(zf, m3, zm, sm);
  k_zphi<<<dim3(NL*NB, 64), 256, 0, stream>>>(zm, sm, phi_w, phi_b, zphi);
  k_wvec<<<NL*NB, 256, 0, stream>>>(zphi, delta_w, delta_b, wvec, cbuf);
  k_sc_part<<<dim3(NL*NB, 4, 4), 256, 0, stream>>>(xf, wvec, part);
  k_xfout2<<<dim3(4, NL*NB*NC), 256, 0, stream>>>(xf, part, cbuf, cues, o_xfout);
}

// Round 10
// 336.439 us; speedup vs baseline: 3.1361x; 1.7599x over previous
//
#include <hip/hip_runtime.h>
#include <math.h>

#define NL 3
#define NB 32
#define NC 256
#define NC2 128
#define HZ 15
#define ZZ 225
#define XX 961
#define HMD 127

typedef unsigned short u16;
typedef __attribute__((ext_vector_type(8))) unsigned short us8;
typedef __attribute__((ext_vector_type(8))) short bf8v;
typedef __attribute__((ext_vector_type(4))) float f4v;

__device__ __forceinline__ u16 f2bf(float f){
  unsigned int u = __float_as_uint(f);
  unsigned int r = (u + 0x7fffu + ((u>>16)&1u)) >> 16;
  return (u16)r;
}
__device__ __forceinline__ float hat_int(float u){
  if (u <= -1.f) return 0.f;
  if (u <= 0.f){ float t = u + 1.f; return 0.5f*t*t; }
  if (u <= 1.f){ float t = 1.f - u; return 1.f - 0.5f*t*t; }
  return 1.f;
}
__device__ __forceinline__ float dot4(float4 a, float4 b){
  return a.x*b.x + a.y*b.y + a.z*b.z + a.w*b.w;
}
__device__ __forceinline__ float wave_red(float s){
  #pragma unroll
  for (int off=32; off>0; off>>=1) s += __shfl_xor(s, off);
  return s;
}

// ================= fused mask branch =================
__global__ __launch_bounds__(256) void k_mask(const float* __restrict__ mask,
    const float* __restrict__ w1, const float* __restrict__ b1,
    const float* __restrict__ w2, const float* __restrict__ b2,
    const float* __restrict__ w3, const float* __restrict__ b3,
    const float* __restrict__ w4, const float* __restrict__ b4,
    float* __restrict__ m3out){
  int lb = blockIdx.x; int l = lb/NB, b = lb%NB;
  int t = threadIdx.x;
  __shared__ float c1s[4][56][56];
  __shared__ float c2s[8][28][28];
  __shared__ float r1s[8][14][14];
  __shared__ float c3s[4][14][14];
  __shared__ float r2s[4][15][15];
  __shared__ int   y0t[14];
  __shared__ float wyt[14];
  __shared__ int   y0t15[15];
  __shared__ float wyt15[15];
  if (t < 14){
    float sy = 122.0f/13.0f;
    float yf = (float)t * sy;
    int y0 = (int)floorf(yf); y0 = min(max(y0,0), 121);
    y0t[t] = y0; wyt[t] = yf - (float)y0;
  } else if (t < 29){
    int q = t-14;
    float sy = 13.0f/14.0f;
    float yf = (float)q * sy;
    int y0 = (int)floorf(yf); y0 = min(max(y0,0), 12);
    y0t15[q] = y0; wyt15[q] = yf - (float)y0;
  }
  __syncthreads();
  const float* mb = mask + (size_t)b*HMD*HMD;
  const float* wc1 = w1 + (size_t)l*4*2*9;
  for (int e=t; e<4*56*56; e+=256){
    int ci = e % 56, ri = (e/56) % 56, oc = e/(56*56);
    int row = y0t[ri>>2] + (ri&3);
    int col = y0t[ci>>2] + (ci&3);
    float acc = b1[l*4+oc];
    #pragma unroll
    for (int ky=0;ky<3;ky++)
      #pragma unroll
      for (int kx=0;kx<3;kx++){
        float mv = mb[(row+ky)*HMD + (col+kx)];
        acc += wc1[((oc*2+0)*3+ky)*3+kx]*mv;
        acc += wc1[((oc*2+1)*3+ky)*3+kx]*(1.f-mv);
      }
    c1s[oc][ri][ci] = fmaxf(acc, 0.f);
  }
  __syncthreads();
  const float* wc2 = w2 + (size_t)l*8*4*9;
  for (int e=t; e<8*28*28; e+=256){
    int j = e % 28, i = (e/28) % 28, oc = e/(28*28);
    int g = i>>1, dy = i&1, gc = j>>1, dx = j&1;
    float acc = b2[l*8+oc];
    #pragma unroll
    for (int ic=0; ic<4; ic++)
      #pragma unroll
      for (int ky=0;ky<3;ky++)
        #pragma unroll
        for (int kx=0;kx<3;kx++)
          acc += wc2[((oc*4+ic)*3+ky)*3+kx]*c1s[ic][g*4+dy+ky][gc*4+dx+kx];
    c2s[oc][i][j] = fmaxf(acc, 0.f);
  }
  __syncthreads();
  for (int e=t; e<8*14*14; e+=256){
    int ox = e % 14, oy = (e/14) % 14, oc = e/(14*14);
    float wy = wyt[oy], wx = wyt[ox];
    float v00 = c2s[oc][2*oy][2*ox],   v01 = c2s[oc][2*oy][2*ox+1];
    float v10 = c2s[oc][2*oy+1][2*ox], v11 = c2s[oc][2*oy+1][2*ox+1];
    r1s[oc][oy][ox] = (v00*(1.f-wy)+v10*wy)*(1.f-wx) + (v01*(1.f-wy)+v11*wy)*wx;
  }
  __syncthreads();
  const float* wc3 = w3 + (size_t)l*4*8*9;
  for (int e=t; e<4*14*14; e+=256){
    int x = e % 14, y = (e/14) % 14, oc = e/(14*14);
    float acc = b3[l*4+oc];
    for (int ic=0; ic<8; ic++)
      #pragma unroll
      for (int ky=-1;ky<=1;ky++){
        int yy = y+ky; if (yy<0||yy>=14) continue;
        #pragma unroll
        for (int kx=-1;kx<=1;kx++){
          int xx = x+kx; if (xx<0||xx>=14) continue;
          acc += wc3[((oc*8+ic)*3+(ky+1))*3+(kx+1)]*r1s[ic][yy][xx];
        }
      }
    c3s[oc][y][x] = acc;
  }
  __syncthreads();
  for (int e=t; e<4*15*15; e+=256){
    int ox = e % 15, oy = (e/15) % 15, oc = e/(15*15);
    int y0 = y0t15[oy], x0 = y0t15[ox];
    float wy = wyt15[oy], wx = wyt15[ox];
    float v00 = c3s[oc][y0][x0],   v01 = c3s[oc][y0][x0+1];
    float v10 = c3s[oc][y0+1][x0], v11 = c3s[oc][y0+1][x0+1];
    r2s[oc][oy][ox] = (v00*(1.f-wy)+v10*wy)*(1.f-wx) + (v01*(1.f-wy)+v11*wy)*wx;
  }
  __syncthreads();
  const float* wc4 = w4 + (size_t)l*1*4*9;
  for (int e=t; e<15*15; e+=256){
    int x = e % 15, y = e/15;
    float acc = b4[l];
    #pragma unroll
    for (int ic=0; ic<4; ic++)
      #pragma unroll
      for (int ky=-1;ky<=1;ky++){
        int yy = y+ky; if (yy<0||yy>=15) continue;
        #pragma unroll
        for (int kx=-1;kx<=1;kx++){
          int xx = x+kx; if (xx<0||xx>=15) continue;
          acc += wc4[(ic*3+(ky+1))*3+(kx+1)]*r2s[ic][yy][xx];
        }
      }
    m3out[(size_t)lb*ZZ + y*15 + x] = acc;
  }
}

// ---------------- converts / packs ----------------
// zf [lb][256][225] f32 -> zfT [lb][225][256] bf16
__global__ __launch_bounds__(256) void k_zft(const float* __restrict__ zf, u16* __restrict__ zfT){
  int lb = blockIdx.x;
  int z0 = blockIdx.y*32, c0 = blockIdx.z*32;
  __shared__ float tile[32][33];
  int t = threadIdx.x;
  int zi = t & 31, ci = t >> 5;
  const float* src = zf + (size_t)lb*NC*ZZ;
  #pragma unroll
  for (int p=0;p<4;p++){
    int c = c0 + ci + p*8;
    int z = z0 + zi;
    tile[ci+p*8][zi] = (z < ZZ) ? src[(size_t)c*ZZ + z] : 0.f;
  }
  __syncthreads();
  u16* dst = zfT + (size_t)lb*ZZ*NC;
  int ci2 = t & 31, zi2 = t >> 5;
  #pragma unroll
  for (int p=0;p<4;p++){
    int z = z0 + zi2 + p*8;
    if (z < ZZ) dst[(size_t)z*NC + c0 + ci2] = f2bf(tile[ci2][zi2+p*8]);
  }
}

__global__ __launch_bounds__(256) void k_pack_proj(
    const float* __restrict__ thw, const float* __restrict__ thb,
    const float* __restrict__ phw, const float* __restrict__ phb,
    const float* __restrict__ gw,  const float* __restrict__ gb,
    u16* __restrict__ Wcat, float* __restrict__ bcat){
  int idx = blockIdx.x*256 + threadIdx.x;
  if (idx < NL*384*256){
    int k = idx & 255; int r = (idx >> 8) % 384; int l = idx/(384*256);
    float v;
    if (r < 128)      v = thw[((size_t)l*128 + r)*256 + k];
    else if (r < 256) v = phw[((size_t)l*128 + (r-128))*256 + k];
    else              v = gw [((size_t)l*128 + (r-256))*256 + k];
    Wcat[idx] = f2bf(v);
  }
  if (idx < NL*384){
    int r = idx % 384, l = idx/384;
    bcat[idx] = (r<128) ? thb[l*128+r] : (r<256) ? phb[l*128+r-128] : gb[l*128+r-256];
  }
}

__global__ __launch_bounds__(256) void k_pack_cz(
    const float* __restrict__ thw, const float* __restrict__ thb,
    const float* __restrict__ phw, const float* __restrict__ phb,
    u16* __restrict__ Wcz, float* __restrict__ bcz){
  int idx = blockIdx.x*256 + threadIdx.x;
  if (idx < NL*512*256){
    int k = idx & 255; int r = (idx >> 8) % 512; int l = idx/(512*256);
    float v;
    if (r < 256) v = thw[((size_t)l*256 + r)*256 + k];
    else         v = phw[((size_t)l*256 + (r-256))*256 + k];
    Wcz[idx] = f2bf(v);
  }
  if (idx < NL*512){
    int r = idx % 512, l = idx/512;
    bcz[idx] = (r<256) ? thb[l*256+r] : phb[l*256+r-256];
  }
}

__global__ __launch_bounds__(256) void k_cvt_outw(const float* __restrict__ w, u16* __restrict__ o){
  int idx = blockIdx.x*256 + threadIdx.x;
  if (idx < NL*NC*NC2) o[idx] = f2bf(w[idx]);
}

// rois [lb][256][49] f32 -> roisT [lb][49][256] bf16
__global__ __launch_bounds__(256) void k_roisT(const float* __restrict__ rois, u16* __restrict__ roisT){
  int lb = blockIdx.x;
  int t = threadIdx.x;
  const float* src = rois + (size_t)lb*NC*49;
  u16* dst = roisT + (size_t)lb*49*NC;
  for (int s=0;s<49;s++)
    dst[(size_t)s*NC + t] = f2bf(src[(size_t)t*49 + s]);
}

// GX slice of TH3 [225][384](cols 256..383) bf16 -> GXT [128][256] bf16 (z pad 0)
__global__ __launch_bounds__(256) void k_gxt(const u16* __restrict__ TH3, u16* __restrict__ GXT){
  int lb = blockIdx.x; int z0 = blockIdx.y*32;
  __shared__ u16 lds[32][130];
  int t = threadIdx.x;
  int n = t & 127, zi = t >> 7;
  const u16* src = TH3 + (size_t)lb*ZZ*384 + 256;
  #pragma unroll
  for (int p=0;p<16;p++){
    int z = z0 + zi + p*2;
    lds[zi+p*2][n] = (z < ZZ) ? src[(size_t)z*384 + n] : (u16)0;
  }
  __syncthreads();
  u16* dst = GXT + (size_t)lb*128*256;
  int zi2 = t & 31, ni = t >> 5;
  #pragma unroll
  for (int p=0;p<16;p++){
    int nn = ni + p*8;
    dst[(size_t)nn*256 + z0 + zi2] = lds[zi2][nn];
  }
}

// ---------------- bf16 MFMA GEMM: out[m][n] = sum_k A[m][k]*B[n][k] (+bias[n]) ----------------
// A bf16 [.][lda], B bf16 [.][ldb]. 64x64 tile, 4 waves, 16x16x32 MFMA.
template<bool BPERL, bool HASBIAS, bool OUTBF, bool TROUT>
__global__ __launch_bounds__(256) void k_mg(
    const u16* __restrict__ A0, const u16* __restrict__ B0,
    const float* __restrict__ bias0, void* __restrict__ O0,
    int M, int N, int K, int lda, int ldb, int ldo,
    long Ab, long Bb, long Ob, int ntn)
{
  int lb = blockIdx.y; int l = lb / NB;
  const u16* A = A0 + (size_t)lb*Ab;
  const u16* B = B0 + (BPERL ? (size_t)l : (size_t)lb)*Bb;
  int tm = blockIdx.x / ntn, tn = blockIdx.x % ntn;
  int m0 = tm*64, n0 = tn*64;
  __shared__ u16 Asl[64][40];
  __shared__ u16 Bsl[64][40];
  int t = threadIdx.x;
  int w = t>>6, l6 = t&63;
  int fr = l6&15, kg = (l6>>4)*8;
  int srow = t>>2, sseg = (t&3)*8;
  f4v ac0={0,0,0,0}, ac1={0,0,0,0}, ac2={0,0,0,0}, ac3={0,0,0,0};
  for (int kc=0; kc<K; kc+=32){
    us8 va = {0,0,0,0,0,0,0,0};
    int am = m0 + srow;
    if (am < M) va = *(const us8*)&A[(size_t)am*lda + kc + sseg];
    *(us8*)&Asl[srow][sseg] = va;
    us8 vb = {0,0,0,0,0,0,0,0};
    int bn = n0 + srow;
    if (bn < N) vb = *(const us8*)&B[(size_t)bn*ldb + kc + sseg];
    *(us8*)&Bsl[srow][sseg] = vb;
    __syncthreads();
    bf8v af = *(const bf8v*)&Asl[w*16 + fr][kg];
    bf8v b0 = *(const bf8v*)&Bsl[fr][kg];
    bf8v b1 = *(const bf8v*)&Bsl[16+fr][kg];
    bf8v b2 = *(const bf8v*)&Bsl[32+fr][kg];
    bf8v b3 = *(const bf8v*)&Bsl[48+fr][kg];
    ac0 = __builtin_amdgcn_mfma_f32_16x16x32_bf16(af, b0, ac0, 0,0,0);
    ac1 = __builtin_amdgcn_mfma_f32_16x16x32_bf16(af, b1, ac1, 0,0,0);
    ac2 = __builtin_amdgcn_mfma_f32_16x16x32_bf16(af, b2, ac2, 0,0,0);
    ac3 = __builtin_amdgcn_mfma_f32_16x16x32_bf16(af, b3, ac3, 0,0,0);
    __syncthreads();
  }
  int mb = m0 + w*16 + ((l6>>4)<<2);
  #pragma unroll
  for (int j=0;j<4;j++){
    int n = n0 + j*16 + fr;
    if (n >= N) continue;
    float bv = HASBIAS ? bias0[(size_t)l*N + n] : 0.f;
    f4v a = (j==0)?ac0:(j==1)?ac1:(j==2)?ac2:ac3;
    #pragma unroll
    for (int r=0;r<4;r++){
      int m = mb + r;
      if (TROUT){
        u16* out = (u16*)O0 + (size_t)lb*Ob;
        out[(size_t)n*ldo + m] = f2bf((m<M) ? (a[r]+bv) : 0.f);
      } else if (m < M){
        if (OUTBF){
          u16* out = (u16*)O0 + (size_t)lb*Ob;
          out[(size_t)m*ldo + n] = f2bf(a[r]+bv);
        } else {
          float* out = (float*)O0 + (size_t)lb*Ob;
          out[(size_t)m*ldo + n] = a[r]+bv;
        }
      }
    }
  }
}

// ---------------- softmax: fp32 S rows -> bf16 P [225][256] zero-padded ----------------
__global__ __launch_bounds__(256) void k_softmax(const float* __restrict__ S, u16* __restrict__ P){
  int row = blockIdx.x*4 + (threadIdx.x >> 6);
  int lane = threadIdx.x & 63;
  const float* r = S + (size_t)row*ZZ;
  float v[4]; float mx = -1e30f;
  #pragma unroll
  for (int q=0;q<4;q++){
    int j = lane + q*64;
    v[q] = (j<ZZ) ? r[j] : -1e30f;
    mx = fmaxf(mx, v[q]);
  }
  #pragma unroll
  for (int off=32; off>0; off>>=1) mx = fmaxf(mx, __shfl_xor(mx, off));
  float sum = 0.f;
  #pragma unroll
  for (int q=0;q<4;q++){
    v[q] = __expf(v[q]-mx);
    if (lane + q*64 < ZZ) sum += v[q];
  }
  #pragma unroll
  for (int off=32; off>0; off>>=1) sum += __shfl_xor(sum, off);
  float inv = 1.f/(16.f*sum);
  u16* pr = P + (size_t)row*256;
  #pragma unroll
  for (int q=0;q<4;q++){
    int j = lane + q*64;
    pr[j] = (j<ZZ) ? f2bf(v[q]*inv) : (u16)0;
  }
}

// ---------------- outconv MFMA: self_attn GEMM + BN/cues/residual/slice ----------------
__global__ __launch_bounds__(256) void k_outconv_m(const u16* __restrict__ outwb,
    const u16* __restrict__ Ybb,
    const float* __restrict__ bng, const float* __restrict__ bnb,
    const float* __restrict__ bnm, const float* __restrict__ bnv,
    const float* __restrict__ cues, const float* __restrict__ zf,
    float* __restrict__ dzfout, float* __restrict__ dzffull){
  int lb = blockIdx.y; int l = lb/NB;
  const u16* A = outwb + (size_t)l*NC*NC2;   // [c][k]
  const u16* B = Ybb + (size_t)lb*ZZ*NC2;    // [z][k]
  int tm = blockIdx.x >> 2, tn = blockIdx.x & 3;
  int m0 = tm*64, n0 = tn*64;
  __shared__ u16 Asl[64][40];
  __shared__ u16 Bsl[64][40];
  int t = threadIdx.x;
  int w = t>>6, l6 = t&63;
  int fr = l6&15, kg = (l6>>4)*8;
  int srow = t>>2, sseg = (t&3)*8;
  f4v ac0={0,0,0,0}, ac1={0,0,0,0}, ac2={0,0,0,0}, ac3={0,0,0,0};
  for (int kc=0; kc<NC2; kc+=32){
    us8 va = *(const us8*)&A[(size_t)(m0+srow)*NC2 + kc + sseg];
    *(us8*)&Asl[srow][sseg] = va;
    us8 vb = {0,0,0,0,0,0,0,0};
    int bn = n0 + srow;
    if (bn < ZZ) vb = *(const us8*)&B[(size_t)bn*NC2 + kc + sseg];
    *(us8*)&Bsl[srow][sseg] = vb;
    __syncthreads();
    bf8v af = *(const bf8v*)&Asl[w*16 + fr][kg];
    bf8v b0 = *(const bf8v*)&Bsl[fr][kg];
    bf8v b1 = *(const bf8v*)&Bsl[16+fr][kg];
    bf8v b2 = *(const bf8v*)&Bsl[32+fr][kg];
    bf8v b3 = *(const bf8v*)&Bsl[48+fr][kg];
    ac0 = __builtin_amdgcn_mfma_f32_16x16x32_bf16(af, b0, ac0, 0,0,0);
    ac1 = __builtin_amdgcn_mfma_f32_16x16x32_bf16(af, b1, ac1, 0,0,0);
    ac2 = __builtin_amdgcn_mfma_f32_16x16x32_bf16(af, b2, ac2, 0,0,0);
    ac3 = __builtin_amdgcn_mfma_f32_16x16x32_bf16(af, b3, ac3, 0,0,0);
    __syncthreads();
  }
  int mb = m0 + w*16 + ((l6>>4)<<2);
  #pragma unroll
  for (int j=0;j<4;j++){
    int z = n0 + j*16 + fr;
    if (z >= ZZ) continue;
    int h = z/15, wv2 = z%15;
    f4v a = (j==0)?ac0:(j==1)?ac1:(j==2)?ac2:ac3;
    #pragma unroll
    for (int r=0;r<4;r++){
      int c = mb + r;
      float scale = bng[l*NC+c] * rsqrtf(bnv[l*NC+c] + 1e-5f);
      float val = (a[r] - bnm[l*NC+c])*scale + bnb[l*NC+c];
      float cu = cues[(size_t)lb*NC + c];
      float zv = zf[((size_t)lb*NC + c)*ZZ + z];
      float rr = cu*zv + zv + val;
      dzffull[((size_t)lb*NC + c)*ZZ + z] = rr;
      if (h>=4 && h<11 && wv2>=4 && wv2<11)
        dzfout[((size_t)lb*NC + c)*49 + (h-4)*7 + (wv2-4)] = rr;
    }
  }
}

// ---------------- PrRoI pooling ----------------
__global__ __launch_bounds__(256) void k_rois(const float* __restrict__ zf,
    const float* __restrict__ box, float* __restrict__ rois){
  int lb = blockIdx.x; int b = lb % NB; int c0 = blockIdx.y*16;
  __shared__ float Wy[7][15], Wx[7][15];
  __shared__ float fld[16*ZZ];
  __shared__ float tmp[16][7][16];
  __shared__ float area_s;
  int t = threadIdx.x;
  const float* bx = box + b*4;
  const float SC = 15.0f/127.0f;
  float x1 = bx[0]*SC, y1 = bx[1]*SC, x2 = bx[2]*SC, y2 = bx[3]*SC;
  float bh = (y2-y1)/7.f, bw = (x2-x1)/7.f;
  if (t < 105){ int p=t/15, i=t%15;
    Wy[p][i] = hat_int(y1+(float)(p+1)*bh - (float)i) - hat_int(y1+(float)p*bh - (float)i); }
  else if (t < 210){ int q=(t-105)/15, i=(t-105)%15;
    Wx[q][i] = hat_int(x1+(float)(q+1)*bw - (float)i) - hat_int(x1+(float)q*bw - (float)i); }
  if (t == 255) area_s = fmaxf(bh*bw, 1e-6f);
  const float* src = zf + ((size_t)lb*NC + c0)*ZZ;
  for (int e=t; e<16*ZZ; e+=256) fld[e] = src[e];
  __syncthreads();
  float inv_area = 1.f/area_s;
  for (int e=t; e<16*105; e+=256){
    int w = e%15; int pc = e/15; int p = pc%7; int cc = pc/7;
    float s = 0.f;
    #pragma unroll
    for (int h=0;h<15;h++) s += Wy[p][h]*fld[cc*ZZ + h*15 + w];
    tmp[cc][p][w] = s;
  }
  __syncthreads();
  float* out = rois + ((size_t)lb*NC + c0)*49;
  for (int e=t; e<16*49; e+=256){
    int q = e%7; int pc = e/7; int p = pc%7; int cc = pc/7;
    float s = 0.f;
    #pragma unroll
    for (int w=0;w<15;w++) s += tmp[cc][p][w]*Wx[q][w];
    out[(size_t)cc*49 + p*7 + q] = s*inv_area;
  }
}

__global__ __launch_bounds__(256) void k_pool(const float* __restrict__ rois,
    float* __restrict__ pavg, float* __restrict__ pmax){
  int idx = blockIdx.x*256 + threadIdx.x;
  if (idx >= NL*NB*NC) return;
  const float* r = rois + (size_t)idx*49;
  float s = 0.f, m = -1e30f;
  #pragma unroll
  for (int i=0;i<49;i++){ float v = r[i]; s += v; m = fmaxf(m,v); }
  pavg[idx] = s/49.f;
  pmax[idx] = m;
}

// ---------------- MLP heads ----------------
__global__ __launch_bounds__(256) void k_mlp1(const float* __restrict__ pavg, const float* __restrict__ pmax,
    const float* __restrict__ aw1, const float* __restrict__ ab1,
    const float* __restrict__ mw1, const float* __restrict__ mb1,
    float* __restrict__ hid){
  int lb = blockIdx.x; int l = lb/NB; int pass = blockIdx.y;
  int t = threadIdx.x, wid = t>>6, lane = t&63;
  int r = blockIdx.z*4 + wid;
  const float* pv = pass ? pmax : pavg;
  const float* w1 = pass ? mw1 : aw1;
  const float* b1 = pass ? mb1 : ab1;
  const float* wr = w1 + (size_t)(l*NC2+r)*NC;
  const float* pr = pv + (size_t)lb*NC;
  float s = dot4(((const float4*)wr)[lane], ((const float4*)pr)[lane]);
  s = wave_red(s);
  if (lane==0) hid[((size_t)lb*2 + pass)*NC2 + r] = fmaxf(s + b1[l*NC2+r], 0.f);
}

__global__ __launch_bounds__(256) void k_mlp2(const float* __restrict__ hid,
    const float* __restrict__ aw2, const float* __restrict__ ab2,
    const float* __restrict__ mw2, const float* __restrict__ mb2,
    float* __restrict__ zavg, float* __restrict__ zmax){
  int lb = blockIdx.x; int l = lb/NB; int pass = blockIdx.y;
  int t = threadIdx.x, wid = t>>6, lane = t&63;
  int c = blockIdx.z*4 + wid;
  const float* w2 = pass ? mw2 : aw2;
  const float* b2 = pass ? mb2 : ab2;
  const float* wr = w2 + (size_t)(l*NC+c)*NC2;
  const float* hr = hid + ((size_t)lb*2 + pass)*NC2;
  float2 wv = ((const float2*)wr)[lane];
  float2 hv = ((const float2*)hr)[lane];
  float s = wave_red(wv.x*hv.x + wv.y*hv.y);
  if (lane==0){
    float* zo = pass ? zmax : zavg;
    zo[(size_t)lb*NC + c] = s + b2[l*NC+c];
  }
}

// ---------------- chan_z tail ----------------
__global__ __launch_bounds__(256) void k_relw(const float* __restrict__ F,
    const float* __restrict__ gw, const float* __restrict__ gb,
    float* __restrict__ rel){
  int lb = blockIdx.x; int l = lb/NB;
  int t = threadIdx.x, wid = t>>6, lane = t&63;
  int r = blockIdx.y*4 + wid;
  const float* wrow = gw + ((size_t)l*2*NC + r)*NC;
  const float* frow = F + (size_t)lb*NC*NC + (size_t)(r>>1)*NC;
  float s = dot4(((const float4*)wrow)[lane], ((const float4*)frow)[lane]);
  s = wave_red(s);
  if (lane==0) rel[(size_t)lb*2*NC + r] = fmaxf(s + gb[l*2*NC+r], 0.f);
}

__global__ __launch_bounds__(256) void k_z2naw(const float* __restrict__ rel,
    const float* __restrict__ aw, const float* __restrict__ ab,
    float* __restrict__ z2n){
  int lb = blockIdx.x; int l = lb/NB;
  int t = threadIdx.x, wid = t>>6, lane = t&63;
  int c = blockIdx.y*4 + wid;
  const float* arow = aw + ((size_t)l*NC + c)*2*NC;
  const float* rrow = rel + (size_t)lb*2*NC;
  float s = dot4(((const float4*)arow)[lane],    ((const float4*)rrow)[lane])
          + dot4(((const float4*)arow)[lane+64], ((const float4*)rrow)[lane+64]);
  s = wave_red(s);
  if (lane==0) z2n[(size_t)lb*NC + c] = s + ab[l*NC+c];
}

__global__ __launch_bounds__(256) void k_cues(const float* __restrict__ zavg, const float* __restrict__ zmax,
    const float* __restrict__ z2n, const float* __restrict__ drw, const float* __restrict__ drb,
    float* __restrict__ cues){
  int idx = blockIdx.x*256 + threadIdx.x;
  if (idx >= NL*NB*NC) return;
  int c = idx & 255; int lb = idx >> 8; int l = lb/NB;
  const float* dw = drw + (size_t)(l*NC + c)*3;
  float x = dw[0]*zavg[idx] + dw[1]*zmax[idx] + dw[2]*z2n[idx] + drb[l*NC+c];
  cues[idx] = 1.f/(1.f + __expf(-x));
}

// ---------------- collapsed sc branch ----------------
__global__ __launch_bounds__(256) void k_zm(const float* __restrict__ zf, const float* __restrict__ m3,
    float* __restrict__ zm, float* __restrict__ sm){
  int lb = blockIdx.x; int cg = blockIdx.y;
  __shared__ float ms[ZZ];
  int t = threadIdx.x;
  if (t < ZZ) ms[t] = m3[(size_t)lb*ZZ + t];
  __syncthreads();
  int c = cg*32 + (t >> 3);
  int sub = t & 7;
  const float* zr = zf + ((size_t)lb*NC + c)*ZZ;
  float s = 0.f;
  for (int z=sub; z<ZZ; z+=8) s += zr[z]*ms[z];
  s += __shfl_down(s, 4, 8);
  s += __shfl_down(s, 2, 8);
  s += __shfl_down(s, 1, 8);
  if (sub == 0) zm[(size_t)lb*NC + c] = s;
  if (cg == 0 && t < 64){
    float ss = 0.f;
    for (int z=t; z<ZZ; z+=64) ss += ms[z];
    ss = wave_red(ss);
    if (t == 0) sm[lb] = ss;
  }
}

__global__ __launch_bounds__(256) void k_zphi(const float* __restrict__ zm, const float* __restrict__ sm,
    const float* __restrict__ phiw, const float* __restrict__ phib, float* __restrict__ zphi){
  int lb = blockIdx.x; int l = lb/NB;
  int t = threadIdx.x, wid = t>>6, lane = t&63;
  int r = blockIdx.y*4 + wid;
  const float* wr = phiw + (size_t)(l*NC + r)*NC;
  const float* zr = zm + (size_t)lb*NC;
  float s = dot4(((const float4*)wr)[lane], ((const float4*)zr)[lane]);
  s = wave_red(s);
  if (lane==0) zphi[(size_t)lb*NC + r] = s + phib[l*NC + r]*sm[lb];
}

__global__ __launch_bounds__(256) void k_wvec(const float* __restrict__ zphi, const float* __restrict__ dw,
    const float* __restrict__ db, float* __restrict__ wvec, float* __restrict__ cb){
  int lb = blockIdx.x; int l = lb/NB;
  __shared__ float zp[NC];
  __shared__ float red[NC];
  int t = threadIdx.x;
  zp[t] = zphi[(size_t)lb*NC + t];
  __syncthreads();
  float s = 0.f;
  const float* dwl = dw + (size_t)l*NC*NC;
  for (int c=0;c<NC;c++) s += zp[c]*dwl[(size_t)c*NC + t];
  wvec[(size_t)lb*NC + t] = s;
  red[t] = zp[t]*db[l*NC + t];
  __syncthreads();
  for (int off2=128; off2>0; off2>>=1){
    if (t < off2) red[t] += red[t+off2];
    __syncthreads();
  }
  if (t==0) cb[lb] = red[0];
}

__global__ __launch_bounds__(256) void k_sc_part(const float* __restrict__ xf,
    const float* __restrict__ wvec, float* __restrict__ part){
  int lb = blockIdx.x, xt = blockIdx.y, cs = blockIdx.z;
  __shared__ float wv[64];
  int t = threadIdx.x;
  if (t < 64) wv[t] = wvec[(size_t)lb*NC + cs*64 + t];
  __syncthreads();
  int x = xt*256 + t;
  if (x >= XX) return;
  const float* xb = xf + ((size_t)lb*NC + cs*64)*XX + x;
  float s = 0.f;
  #pragma unroll 8
  for (int c=0;c<64;c++) s += wv[c]*xb[(size_t)c*XX];
  part[((size_t)lb*4 + cs)*XX + x] = s;
}

__global__ __launch_bounds__(256) void k_xfout2(const float* __restrict__ xf,
    const float* __restrict__ part, const float* __restrict__ cb,
    const float* __restrict__ cues, float* __restrict__ out){
  int bc = blockIdx.y;
  int x = blockIdx.x*256 + threadIdx.x;
  if (x >= XX) return;
  int lb = bc >> 8;
  const float* pp = part + (size_t)lb*4*XX + x;
  float scv = pp[0] + pp[XX] + pp[2*XX] + pp[3*XX];
  scv = fminf(fmaxf((scv + cb[lb])*0.0625f, 0.f), 1.f);
  float cu = cues[bc];
  out[(size_t)bc*XX + x] = (1.f+cu)*xf[(size_t)bc*XX + x] - scv;
}

extern "C" void kernel_launch(void* const* d_in, const int* in_sizes, int n_in,
                              void* d_out, int out_size, void* d_ws, size_t ws_size,
                              hipStream_t stream){
  const float* zf      = (const float*)d_in[0];
  const float* xf      = (const float*)d_in[1];
  const float* maskp   = (const float*)d_in[2];
  const float* box     = (const float*)d_in[3];
  const float* nl_g_w  = (const float*)d_in[4];
  const float* nl_g_b  = (const float*)d_in[5];
  const float* nl_th_w = (const float*)d_in[6];
  const float* nl_th_b = (const float*)d_in[7];
  const float* nl_ph_w = (const float*)d_in[8];
  const float* nl_ph_b = (const float*)d_in[9];
  const float* nl_out_w= (const float*)d_in[10];
  const float* bn_g    = (const float*)d_in[11];
  const float* bn_b    = (const float*)d_in[12];
  const float* bn_m    = (const float*)d_in[13];
  const float* bn_v    = (const float*)d_in[14];
  const float* cz_th_w = (const float*)d_in[15];
  const float* cz_th_b = (const float*)d_in[16];
  const float* cz_ph_w = (const float*)d_in[17];
  const float* cz_ph_b = (const float*)d_in[18];
  const float* cz_gw   = (const float*)d_in[19];
  const float* cz_gb   = (const float*)d_in[20];
  const float* cz_aw   = (const float*)d_in[21];
  const float* cz_ab   = (const float*)d_in[22];
  const float* ap_w1   = (const float*)d_in[23];
  const float* ap_b1   = (const float*)d_in[24];
  const float* ap_w2   = (const float*)d_in[25];
  const float* ap_b2   = (const float*)d_in[26];
  const float* mp_w1   = (const float*)d_in[27];
  const float* mp_b1   = (const float*)d_in[28];
  const float* mp_w2   = (const float*)d_in[29];
  const float* mp_b2   = (const float*)d_in[30];
  const float* dr_w    = (const float*)d_in[31];
  const float* dr_b    = (const float*)d_in[32];
  const float* ac1_w   = (const float*)d_in[33];
  const float* ac1_b   = (const float*)d_in[34];
  const float* ac2_w   = (const float*)d_in[35];
  const float* ac2_b   = (const float*)d_in[36];
  const float* ac3_w   = (const float*)d_in[37];
  const float* ac3_b   = (const float*)d_in[38];
  const float* ac4_w   = (const float*)d_in[39];
  const float* ac4_b   = (const float*)d_in[40];
  const float* phi_w   = (const float*)d_in[41];
  const float* phi_b   = (const float*)d_in[42];
  const float* delta_w = (const float*)d_in[43];
  const float* delta_b = (const float*)d_in[44];
  (void)in_sizes; (void)n_in; (void)out_size; (void)ws_size;

  float* ws = (float*)d_ws;
  size_t off = 0;
  auto alloc = [&](size_t n){ size_t o = off; off += (n + 15) & ~(size_t)15; return o; };
  // bf16 buffers sized in floats (2 u16 per float)
  float* TH3f  = ws + alloc((size_t)NL*NB*ZZ*384/2);   // bf16 [225][384]
  float* Sb    = ws + alloc((size_t)NL*NB*ZZ*ZZ);      // fp32 scores
  u16* TH3  = (u16*)TH3f;
  // F fp32 [256][256]/lb = 65536 floats/lb; spans TH3f (43200/lb) + into Sb —
  // both dead after softmax/PV; combined region 9.0M floats >= 6.3M needed.
  float* Freg  = TH3f;
  float* zfTf  = ws + alloc((size_t)NL*NB*ZZ*NC/2);
  float* Pbf   = ws + alloc((size_t)NL*NB*ZZ*256/2);
  float* GXTf  = ws + alloc((size_t)NL*NB*128*256/2);
  float* Ybbf  = ws + alloc((size_t)NL*NB*ZZ*NC2/2);
  float* CZ3Tf = ws + alloc((size_t)NL*NB*512*64/2);
  float* roisTf= ws + alloc((size_t)NL*NB*49*NC/2);
  float* Wcatf = ws + alloc((size_t)NL*384*256/2);
  float* Wczf  = ws + alloc((size_t)NL*512*256/2);
  float* outwbf= ws + alloc((size_t)NL*NC*NC2/2);
  u16 *zfT=(u16*)zfTf, *Pb=(u16*)Pbf, *GXT=(u16*)GXTf, *Ybb=(u16*)Ybbf,
      *CZ3T=(u16*)CZ3Tf, *roisT=(u16*)roisTf, *Wcat=(u16*)Wcatf,
      *Wcz=(u16*)Wczf, *outwb=(u16*)outwbf;
  float* bcat = ws + alloc((size_t)NL*384);
  float* bcz  = ws + alloc((size_t)NL*512);
  float* m3   = ws + alloc((size_t)NL*NB*ZZ);
  float* rois = ws + alloc((size_t)NL*NB*NC*49);
  float* pavg = ws + alloc((size_t)NL*NB*NC);
  float* pmax = ws + alloc((size_t)NL*NB*NC);
  float* zavg = ws + alloc((size_t)NL*NB*NC);
  float* zmax = ws + alloc((size_t)NL*NB*NC);
  float* z2n  = ws + alloc((size_t)NL*NB*NC);
  float* cues = ws + alloc((size_t)NL*NB*NC);
  float* zm   = ws + alloc((size_t)NL*NB*NC);
  float* zphi = ws + alloc((size_t)NL*NB*NC);
  float* wvec = ws + alloc((size_t)NL*NB*NC);
  float* sm   = ws + alloc((size_t)NL*NB);
  float* cbuf = ws + alloc((size_t)NL*NB);
  float* part = ws + alloc((size_t)NL*NB*4*XX);
  float* hidb = ws + alloc((size_t)NL*NB*2*NC2);
  float* relb = ws + alloc((size_t)NL*NB*2*NC);

  float* outp    = (float*)d_out;
  float* o_zfout = outp;
  float* o_zffull= outp + (size_t)NL*NB*NC*49;
  float* o_xfout = o_zffull + (size_t)NL*NB*NC*ZZ;

  // ---- mask branch + converts/packs ----
  k_mask<<<NL*NB, 256, 0, stream>>>(maskp, ac1_w, ac1_b, ac2_w, ac2_b,
                                     ac3_w, ac3_b, ac4_w, ac4_b, m3);
  k_zft<<<dim3(NL*NB, 8, 8), 256, 0, stream>>>(zf, zfT);
  k_pack_proj<<<(NL*384*256+255)/256, 256, 0, stream>>>(nl_th_w, nl_th_b, nl_ph_w, nl_ph_b,
                                                         nl_g_w, nl_g_b, Wcat, bcat);
  k_pack_cz<<<(NL*512*256+255)/256, 256, 0, stream>>>(cz_th_w, cz_th_b, cz_ph_w, cz_ph_b, Wcz, bcz);
  k_cvt_outw<<<(NL*NC*NC2+255)/256, 256, 0, stream>>>(nl_out_w, outwb);

  // ---- projections: TH3 = zfT @ Wcat^T  (bf16 out, [225][384]) ----
  k_mg<true,true,true,false><<<dim3(24, NL*NB), 256, 0, stream>>>(
      zfT, Wcat, bcat, TH3, ZZ, 384, NC, 256, 256, 384,
      (long)ZZ*256, (long)384*256, (long)ZZ*384, 6);
  // S = TH @ PH^T (fp32)
  k_mg<false,false,false,false><<<dim3(16, NL*NB), 256, 0, stream>>>(
      TH3, TH3+128, nullptr, Sb, ZZ, ZZ, NC2, 384, 384, ZZ,
      (long)ZZ*384, (long)ZZ*384, (long)ZZ*ZZ, 4);
  k_softmax<<<(NL*NB*ZZ)/4, 256, 0, stream>>>(Sb, Pb);
  k_gxt<<<dim3(NL*NB, 8), 256, 0, stream>>>(TH3, GXT);
  // Y = P @ GX (bf16 out [225][128])
  k_mg<false,false,true,false><<<dim3(8, NL*NB), 256, 0, stream>>>(
      Pb, GXT, nullptr, Ybb, ZZ, NC2, 256, 256, 256, NC2,
      (long)ZZ*256, (long)128*256, (long)ZZ*NC2, 2);

  // ---- rois / cues ----
  k_rois<<<dim3(NL*NB, 16), 256, 0, stream>>>(zf, box, rois);
  k_pool<<<(NL*NB*NC+255)/256, 256, 0, stream>>>(rois, pavg, pmax);
  k_mlp1<<<dim3(NL*NB, 2, 32), 256, 0, stream>>>(pavg, pmax, ap_w1, ap_b1, mp_w1, mp_b1, hidb);
  k_mlp2<<<dim3(NL*NB, 2, 64), 256, 0, stream>>>(hidb, ap_w2, ap_b2, mp_w2, mp_b2, zavg, zmax);
  k_roisT<<<NL*NB, 256, 0, stream>>>(rois, roisT);
  // CZ3T[n][s] (bf16, transposed out, [512][64] zero-padded)
  k_mg<true,true,true,true><<<dim3(8, NL*NB), 256, 0, stream>>>(
      roisT, Wcz, bcz, CZ3T, 49, 512, NC, 256, 256, 64,
      (long)49*256, (long)512*256, (long)512*64, 8);
  // F = czth^T @ czph (fp32 [256][256])
  k_mg<false,false,false,false><<<dim3(16, NL*NB), 256, 0, stream>>>(
      CZ3T, CZ3T+256*64, nullptr, Freg, NC, NC, 64, 64, 64, NC,
      (long)512*64, (long)512*64, (long)NC*NC, 4);
  k_relw<<<dim3(NL*NB, 128), 256, 0, stream>>>(Freg, cz_gw, cz_gb, relb);
  k_z2naw<<<dim3(NL*NB, 64), 256, 0, stream>>>(relb, cz_aw, cz_ab, z2n);
  k_cues<<<(NL*NB*NC+255)/256, 256, 0, stream>>>(zavg, zmax, z2n, dr_w, dr_b, cues);

  // ---- zf_full (+7x7 slice) ----
  k_outconv_m<<<dim3(16, NL*NB), 256, 0, stream>>>(outwb, Ybb, bn_g, bn_b, bn_m, bn_v,
                                                    cues, zf, o_zfout, o_zffull);

  // ---- collapsed sc branch + xf_out ----
  k_zm<<<dim3(NL*NB, 8), 256, 0, stream>>>(zf, m3, zm, sm);
  k_zphi<<<dim3(NL*NB, 64), 256, 0, stream>>>(zm, sm, phi_w, phi_b, zphi);
  k_wvec<<<NL*NB, 256, 0, stream>>>(zphi, delta_w, delta_b, wvec, cbuf);
  k_sc_part<<<dim3(NL*NB, 4, 4), 256, 0, stream>>>(xf, wvec, part);
  k_xfout2<<<dim3(4, NL*NB*NC), 256, 0, stream>>>(xf, part, cbuf, cues, o_xfout);
}

// Round 11
// 329.242 us; speedup vs baseline: 3.2046x; 1.0219x over previous
//
#include <hip/hip_runtime.h>
#include <math.h>

#define NL 3
#define NB 32
#define NC 256
#define NC2 128
#define HZ 15
#define ZZ 225
#define XX 961
#define HMD 127

typedef unsigned short u16;
typedef __attribute__((ext_vector_type(8))) unsigned short us8;
typedef __attribute__((ext_vector_type(8))) short bf8v;
typedef __attribute__((ext_vector_type(4))) float f4v;

__device__ __forceinline__ u16 f2bf(float f){
  unsigned int u = __float_as_uint(f);
  unsigned int r = (u + 0x7fffu + ((u>>16)&1u)) >> 16;
  return (u16)r;
}
__device__ __forceinline__ float hat_int(float u){
  if (u <= -1.f) return 0.f;
  if (u <= 0.f){ float t = u + 1.f; return 0.5f*t*t; }
  if (u <= 1.f){ float t = 1.f - u; return 1.f - 0.5f*t*t; }
  return 1.f;
}
__device__ __forceinline__ float dot4(float4 a, float4 b){
  return a.x*b.x + a.y*b.y + a.z*b.z + a.w*b.w;
}
__device__ __forceinline__ float wave_red(float s){
  #pragma unroll
  for (int off=32; off>0; off>>=1) s += __shfl_xor(s, off);
  return s;
}

// ================= fused mask branch =================
__global__ __launch_bounds__(256) void k_mask(const float* __restrict__ mask,
    const float* __restrict__ w1, const float* __restrict__ b1,
    const float* __restrict__ w2, const float* __restrict__ b2,
    const float* __restrict__ w3, const float* __restrict__ b3,
    const float* __restrict__ w4, const float* __restrict__ b4,
    float* __restrict__ m3out){
  int lb = blockIdx.x; int l = lb/NB, b = lb%NB;
  int t = threadIdx.x;
  __shared__ float c1s[4][56][56];
  __shared__ float c2s[8][28][28];
  __shared__ float r1s[8][14][14];
  __shared__ float c3s[4][14][14];
  __shared__ float r2s[4][15][15];
  __shared__ int   y0t[14];
  __shared__ float wyt[14];
  __shared__ int   y0t15[15];
  __shared__ float wyt15[15];
  if (t < 14){
    float sy = 122.0f/13.0f;
    float yf = (float)t * sy;
    int y0 = (int)floorf(yf); y0 = min(max(y0,0), 121);
    y0t[t] = y0; wyt[t] = yf - (float)y0;
  } else if (t < 29){
    int q = t-14;
    float sy = 13.0f/14.0f;
    float yf = (float)q * sy;
    int y0 = (int)floorf(yf); y0 = min(max(y0,0), 12);
    y0t15[q] = y0; wyt15[q] = yf - (float)y0;
  }
  __syncthreads();
  const float* mb = mask + (size_t)b*HMD*HMD;
  const float* wc1 = w1 + (size_t)l*4*2*9;
  for (int e=t; e<4*56*56; e+=256){
    int ci = e % 56, ri = (e/56) % 56, oc = e/(56*56);
    int row = y0t[ri>>2] + (ri&3);
    int col = y0t[ci>>2] + (ci&3);
    float acc = b1[l*4+oc];
    #pragma unroll
    for (int ky=0;ky<3;ky++)
      #pragma unroll
      for (int kx=0;kx<3;kx++){
        float mv = mb[(row+ky)*HMD + (col+kx)];
        acc += wc1[((oc*2+0)*3+ky)*3+kx]*mv;
        acc += wc1[((oc*2+1)*3+ky)*3+kx]*(1.f-mv);
      }
    c1s[oc][ri][ci] = fmaxf(acc, 0.f);
  }
  __syncthreads();
  const float* wc2 = w2 + (size_t)l*8*4*9;
  for (int e=t; e<8*28*28; e+=256){
    int j = e % 28, i = (e/28) % 28, oc = e/(28*28);
    int g = i>>1, dy = i&1, gc = j>>1, dx = j&1;
    float acc = b2[l*8+oc];
    #pragma unroll
    for (int ic=0; ic<4; ic++)
      #pragma unroll
      for (int ky=0;ky<3;ky++)
        #pragma unroll
        for (int kx=0;kx<3;kx++)
          acc += wc2[((oc*4+ic)*3+ky)*3+kx]*c1s[ic][g*4+dy+ky][gc*4+dx+kx];
    c2s[oc][i][j] = fmaxf(acc, 0.f);
  }
  __syncthreads();
  for (int e=t; e<8*14*14; e+=256){
    int ox = e % 14, oy = (e/14) % 14, oc = e/(14*14);
    float wy = wyt[oy], wx = wyt[ox];
    float v00 = c2s[oc][2*oy][2*ox],   v01 = c2s[oc][2*oy][2*ox+1];
    float v10 = c2s[oc][2*oy+1][2*ox], v11 = c2s[oc][2*oy+1][2*ox+1];
    r1s[oc][oy][ox] = (v00*(1.f-wy)+v10*wy)*(1.f-wx) + (v01*(1.f-wy)+v11*wy)*wx;
  }
  __syncthreads();
  const float* wc3 = w3 + (size_t)l*4*8*9;
  for (int e=t; e<4*14*14; e+=256){
    int x = e % 14, y = (e/14) % 14, oc = e/(14*14);
    float acc = b3[l*4+oc];
    for (int ic=0; ic<8; ic++)
      #pragma unroll
      for (int ky=-1;ky<=1;ky++){
        int yy = y+ky; if (yy<0||yy>=14) continue;
        #pragma unroll
        for (int kx=-1;kx<=1;kx++){
          int xx = x+kx; if (xx<0||xx>=14) continue;
          acc += wc3[((oc*8+ic)*3+(ky+1))*3+(kx+1)]*r1s[ic][yy][xx];
        }
      }
    c3s[oc][y][x] = acc;
  }
  __syncthreads();
  for (int e=t; e<4*15*15; e+=256){
    int ox = e % 15, oy = (e/15) % 15, oc = e/(15*15);
    int y0 = y0t15[oy], x0 = y0t15[ox];
    float wy = wyt15[oy], wx = wyt15[ox];
    float v00 = c3s[oc][y0][x0],   v01 = c3s[oc][y0][x0+1];
    float v10 = c3s[oc][y0+1][x0], v11 = c3s[oc][y0+1][x0+1];
    r2s[oc][oy][ox] = (v00*(1.f-wy)+v10*wy)*(1.f-wx) + (v01*(1.f-wy)+v11*wy)*wx;
  }
  __syncthreads();
  const float* wc4 = w4 + (size_t)l*1*4*9;
  for (int e=t; e<15*15; e+=256){
    int x = e % 15, y = e/15;
    float acc = b4[l];
    #pragma unroll
    for (int ic=0; ic<4; ic++)
      #pragma unroll
      for (int ky=-1;ky<=1;ky++){
        int yy = y+ky; if (yy<0||yy>=15) continue;
        #pragma unroll
        for (int kx=-1;kx<=1;kx++){
          int xx = x+kx; if (xx<0||xx>=15) continue;
          acc += wc4[(ic*3+(ky+1))*3+(kx+1)]*r2s[ic][yy][xx];
        }
      }
    m3out[(size_t)lb*ZZ + y*15 + x] = acc;
  }
}

// ---------------- converts / packs ----------------
// zf [lb][256][225] f32 -> zfT [lb][225][256] bf16
__global__ __launch_bounds__(256) void k_zft(const float* __restrict__ zf, u16* __restrict__ zfT){
  int lb = blockIdx.x;
  int z0 = blockIdx.y*32, c0 = blockIdx.z*32;
  __shared__ float tile[32][33];
  int t = threadIdx.x;
  int zi = t & 31, ci = t >> 5;
  const float* src = zf + (size_t)lb*NC*ZZ;
  #pragma unroll
  for (int p=0;p<4;p++){
    int c = c0 + ci + p*8;
    int z = z0 + zi;
    tile[ci+p*8][zi] = (z < ZZ) ? src[(size_t)c*ZZ + z] : 0.f;
  }
  __syncthreads();
  u16* dst = zfT + (size_t)lb*ZZ*NC;
  int ci2 = t & 31, zi2 = t >> 5;
  #pragma unroll
  for (int p=0;p<4;p++){
    int z = z0 + zi2 + p*8;
    if (z < ZZ) dst[(size_t)z*NC + c0 + ci2] = f2bf(tile[ci2][zi2+p*8]);
  }
}

// all weight packs in one kernel
__global__ __launch_bounds__(256) void k_packs(
    const float* __restrict__ thw, const float* __restrict__ thb,
    const float* __restrict__ phw, const float* __restrict__ phb,
    const float* __restrict__ gw,  const float* __restrict__ gb,
    const float* __restrict__ czthw, const float* __restrict__ czthb,
    const float* __restrict__ czphw, const float* __restrict__ czphb,
    const float* __restrict__ outw,
    u16* __restrict__ Wcat, float* __restrict__ bcat,
    u16* __restrict__ Wcz, float* __restrict__ bcz,
    u16* __restrict__ outwb){
  int idx = blockIdx.x*256 + threadIdx.x;
  if (idx < NL*384*256){
    int k = idx & 255; int r = (idx >> 8) % 384; int l = idx/(384*256);
    float v;
    if (r < 128)      v = thw[((size_t)l*128 + r)*256 + k];
    else if (r < 256) v = phw[((size_t)l*128 + (r-128))*256 + k];
    else              v = gw [((size_t)l*128 + (r-256))*256 + k];
    Wcat[idx] = f2bf(v);
  }
  if (idx < NL*512*256){
    int k = idx & 255; int r = (idx >> 8) % 512; int l = idx/(512*256);
    float v;
    if (r < 256) v = czthw[((size_t)l*256 + r)*256 + k];
    else         v = czphw[((size_t)l*256 + (r-256))*256 + k];
    Wcz[idx] = f2bf(v);
  }
  if (idx < NL*NC*NC2) outwb[idx] = f2bf(outw[idx]);
  if (idx < NL*384){
    int r = idx % 384, l = idx/384;
    bcat[idx] = (r<128) ? thb[l*128+r] : (r<256) ? phb[l*128+r-128] : gb[l*128+r-256];
  }
  if (idx < NL*512){
    int r = idx % 512, l = idx/512;
    bcz[idx] = (r<256) ? czthb[l*256+r] : czphb[l*256+r-256];
  }
}

// GX slice of TH3 [225][384](cols 256..383) bf16 -> GXT [128][256] bf16 (z pad 0)
__global__ __launch_bounds__(256) void k_gxt(const u16* __restrict__ TH3, u16* __restrict__ GXT){
  int lb = blockIdx.x; int z0 = blockIdx.y*32;
  __shared__ u16 lds[32][130];
  int t = threadIdx.x;
  int n = t & 127, zi = t >> 7;
  const u16* src = TH3 + (size_t)lb*ZZ*384 + 256;
  #pragma unroll
  for (int p=0;p<16;p++){
    int z = z0 + zi + p*2;
    lds[zi+p*2][n] = (z < ZZ) ? src[(size_t)z*384 + n] : (u16)0;
  }
  __syncthreads();
  u16* dst = GXT + (size_t)lb*128*256;
  int zi2 = t & 31, ni = t >> 5;
  #pragma unroll
  for (int p=0;p<16;p++){
    int nn = ni + p*8;
    dst[(size_t)nn*256 + z0 + zi2] = lds[zi2][nn];
  }
}

// ---------------- bf16 MFMA GEMM: out[m][n] = sum_k A[m][k]*B[n][k] (+bias[n]) ----------------
template<bool BPERL, bool HASBIAS, bool OUTBF, bool TROUT>
__global__ __launch_bounds__(256) void k_mg(
    const u16* __restrict__ A0, const u16* __restrict__ B0,
    const float* __restrict__ bias0, void* __restrict__ O0,
    int M, int N, int K, int lda, int ldb, int ldo,
    long Ab, long Bb, long Ob, int ntn)
{
  int lb = blockIdx.y; int l = lb / NB;
  const u16* A = A0 + (size_t)lb*Ab;
  const u16* B = B0 + (BPERL ? (size_t)l : (size_t)lb)*Bb;
  int tm = blockIdx.x / ntn, tn = blockIdx.x % ntn;
  int m0 = tm*64, n0 = tn*64;
  __shared__ u16 Asl[64][40];
  __shared__ u16 Bsl[64][40];
  int t = threadIdx.x;
  int w = t>>6, l6 = t&63;
  int fr = l6&15, kg = (l6>>4)*8;
  int srow = t>>2, sseg = (t&3)*8;
  f4v ac0={0,0,0,0}, ac1={0,0,0,0}, ac2={0,0,0,0}, ac3={0,0,0,0};
  for (int kc=0; kc<K; kc+=32){
    us8 va = {0,0,0,0,0,0,0,0};
    int am = m0 + srow;
    if (am < M) va = *(const us8*)&A[(size_t)am*lda + kc + sseg];
    *(us8*)&Asl[srow][sseg] = va;
    us8 vb = {0,0,0,0,0,0,0,0};
    int bn = n0 + srow;
    if (bn < N) vb = *(const us8*)&B[(size_t)bn*ldb + kc + sseg];
    *(us8*)&Bsl[srow][sseg] = vb;
    __syncthreads();
    bf8v af = *(const bf8v*)&Asl[w*16 + fr][kg];
    bf8v b0 = *(const bf8v*)&Bsl[fr][kg];
    bf8v b1 = *(const bf8v*)&Bsl[16+fr][kg];
    bf8v b2 = *(const bf8v*)&Bsl[32+fr][kg];
    bf8v b3 = *(const bf8v*)&Bsl[48+fr][kg];
    ac0 = __builtin_amdgcn_mfma_f32_16x16x32_bf16(af, b0, ac0, 0,0,0);
    ac1 = __builtin_amdgcn_mfma_f32_16x16x32_bf16(af, b1, ac1, 0,0,0);
    ac2 = __builtin_amdgcn_mfma_f32_16x16x32_bf16(af, b2, ac2, 0,0,0);
    ac3 = __builtin_amdgcn_mfma_f32_16x16x32_bf16(af, b3, ac3, 0,0,0);
    __syncthreads();
  }
  int mb = m0 + w*16 + ((l6>>4)<<2);
  #pragma unroll
  for (int j=0;j<4;j++){
    int n = n0 + j*16 + fr;
    if (n >= N) continue;
    float bv = HASBIAS ? bias0[(size_t)l*N + n] : 0.f;
    f4v a = (j==0)?ac0:(j==1)?ac1:(j==2)?ac2:ac3;
    #pragma unroll
    for (int r=0;r<4;r++){
      int m = mb + r;
      if (TROUT){
        u16* out = (u16*)O0 + (size_t)lb*Ob;
        out[(size_t)n*ldo + m] = f2bf((m<M) ? (a[r]+bv) : 0.f);
      } else if (m < M){
        if (OUTBF){
          u16* out = (u16*)O0 + (size_t)lb*Ob;
          out[(size_t)m*ldo + n] = f2bf(a[r]+bv);
        } else {
          float* out = (float*)O0 + (size_t)lb*Ob;
          out[(size_t)m*ldo + n] = a[r]+bv;
        }
      }
    }
  }
}

// ---------------- softmax: fp32 S rows -> bf16 P [225][256] zero-padded ----------------
__global__ __launch_bounds__(256) void k_softmax(const float* __restrict__ S, u16* __restrict__ P){
  int row = blockIdx.x*4 + (threadIdx.x >> 6);
  int lane = threadIdx.x & 63;
  const float* r = S + (size_t)row*ZZ;
  float v[4]; float mx = -1e30f;
  #pragma unroll
  for (int q=0;q<4;q++){
    int j = lane + q*64;
    v[q] = (j<ZZ) ? r[j] : -1e30f;
    mx = fmaxf(mx, v[q]);
  }
  #pragma unroll
  for (int off=32; off>0; off>>=1) mx = fmaxf(mx, __shfl_xor(mx, off));
  float sum = 0.f;
  #pragma unroll
  for (int q=0;q<4;q++){
    v[q] = __expf(v[q]-mx);
    if (lane + q*64 < ZZ) sum += v[q];
  }
  #pragma unroll
  for (int off=32; off>0; off>>=1) sum += __shfl_xor(sum, off);
  float inv = 1.f/(16.f*sum);
  u16* pr = P + (size_t)row*256;
  #pragma unroll
  for (int q=0;q<4;q++){
    int j = lane + q*64;
    pr[j] = (j<ZZ) ? f2bf(v[q]*inv) : (u16)0;
  }
}

// ---------------- outconv MFMA: self_attn GEMM + BN/cues/residual/slice ----------------
__global__ __launch_bounds__(256) void k_outconv_m(const u16* __restrict__ outwb,
    const u16* __restrict__ Ybb,
    const float* __restrict__ bng, const float* __restrict__ bnb,
    const float* __restrict__ bnm, const float* __restrict__ bnv,
    const float* __restrict__ cues, const float* __restrict__ zf,
    float* __restrict__ dzfout, float* __restrict__ dzffull){
  int lb = blockIdx.y; int l = lb/NB;
  const u16* A = outwb + (size_t)l*NC*NC2;   // [c][k]
  const u16* B = Ybb + (size_t)lb*ZZ*NC2;    // [z][k]
  int tm = blockIdx.x >> 2, tn = blockIdx.x & 3;
  int m0 = tm*64, n0 = tn*64;
  __shared__ u16 Asl[64][40];
  __shared__ u16 Bsl[64][40];
  int t = threadIdx.x;
  int w = t>>6, l6 = t&63;
  int fr = l6&15, kg = (l6>>4)*8;
  int srow = t>>2, sseg = (t&3)*8;
  f4v ac0={0,0,0,0}, ac1={0,0,0,0}, ac2={0,0,0,0}, ac3={0,0,0,0};
  for (int kc=0; kc<NC2; kc+=32){
    us8 va = *(const us8*)&A[(size_t)(m0+srow)*NC2 + kc + sseg];
    *(us8*)&Asl[srow][sseg] = va;
    us8 vb = {0,0,0,0,0,0,0,0};
    int bn = n0 + srow;
    if (bn < ZZ) vb = *(const us8*)&B[(size_t)bn*NC2 + kc + sseg];
    *(us8*)&Bsl[srow][sseg] = vb;
    __syncthreads();
    bf8v af = *(const bf8v*)&Asl[w*16 + fr][kg];
    bf8v b0 = *(const bf8v*)&Bsl[fr][kg];
    bf8v b1 = *(const bf8v*)&Bsl[16+fr][kg];
    bf8v b2 = *(const bf8v*)&Bsl[32+fr][kg];
    bf8v b3 = *(const bf8v*)&Bsl[48+fr][kg];
    ac0 = __builtin_amdgcn_mfma_f32_16x16x32_bf16(af, b0, ac0, 0,0,0);
    ac1 = __builtin_amdgcn_mfma_f32_16x16x32_bf16(af, b1, ac1, 0,0,0);
    ac2 = __builtin_amdgcn_mfma_f32_16x16x32_bf16(af, b2, ac2, 0,0,0);
    ac3 = __builtin_amdgcn_mfma_f32_16x16x32_bf16(af, b3, ac3, 0,0,0);
    __syncthreads();
  }
  int mb = m0 + w*16 + ((l6>>4)<<2);
  #pragma unroll
  for (int j=0;j<4;j++){
    int z = n0 + j*16 + fr;
    if (z >= ZZ) continue;
    int h = z/15, wv2 = z%15;
    f4v a = (j==0)?ac0:(j==1)?ac1:(j==2)?ac2:ac3;
    #pragma unroll
    for (int r=0;r<4;r++){
      int c = mb + r;
      float scale = bng[l*NC+c] * rsqrtf(bnv[l*NC+c] + 1e-5f);
      float val = (a[r] - bnm[l*NC+c])*scale + bnb[l*NC+c];
      float cu = cues[(size_t)lb*NC + c];
      float zv = zf[((size_t)lb*NC + c)*ZZ + z];
      float rr = cu*zv + zv + val;
      dzffull[((size_t)lb*NC + c)*ZZ + z] = rr;
      if (h>=4 && h<11 && wv2>=4 && wv2<11)
        dzfout[((size_t)lb*NC + c)*49 + (h-4)*7 + (wv2-4)] = rr;
    }
  }
}

// ---------------- PrRoI pooling ----------------
__global__ __launch_bounds__(256) void k_rois(const float* __restrict__ zf,
    const float* __restrict__ box, float* __restrict__ rois){
  int lb = blockIdx.x; int b = lb % NB; int c0 = blockIdx.y*16;
  __shared__ float Wy[7][15], Wx[7][15];
  __shared__ float fld[16*ZZ];
  __shared__ float tmp[16][7][16];
  __shared__ float area_s;
  int t = threadIdx.x;
  const float* bx = box + b*4;
  const float SC = 15.0f/127.0f;
  float x1 = bx[0]*SC, y1 = bx[1]*SC, x2 = bx[2]*SC, y2 = bx[3]*SC;
  float bh = (y2-y1)/7.f, bw = (x2-x1)/7.f;
  if (t < 105){ int p=t/15, i=t%15;
    Wy[p][i] = hat_int(y1+(float)(p+1)*bh - (float)i) - hat_int(y1+(float)p*bh - (float)i); }
  else if (t < 210){ int q=(t-105)/15, i=(t-105)%15;
    Wx[q][i] = hat_int(x1+(float)(q+1)*bw - (float)i) - hat_int(x1+(float)q*bw - (float)i); }
  if (t == 255) area_s = fmaxf(bh*bw, 1e-6f);
  const float* src = zf + ((size_t)lb*NC + c0)*ZZ;
  for (int e=t; e<16*ZZ; e+=256) fld[e] = src[e];
  __syncthreads();
  float inv_area = 1.f/area_s;
  for (int e=t; e<16*105; e+=256){
    int w = e%15; int pc = e/15; int p = pc%7; int cc = pc/7;
    float s = 0.f;
    #pragma unroll
    for (int h=0;h<15;h++) s += Wy[p][h]*fld[cc*ZZ + h*15 + w];
    tmp[cc][p][w] = s;
  }
  __syncthreads();
  float* out = rois + ((size_t)lb*NC + c0)*49;
  for (int e=t; e<16*49; e+=256){
    int q = e%7; int pc = e/7; int p = pc%7; int cc = pc/7;
    float s = 0.f;
    #pragma unroll
    for (int w=0;w<15;w++) s += tmp[cc][p][w]*Wx[q][w];
    out[(size_t)cc*49 + p*7 + q] = s*inv_area;
  }
}

// pool + transpose-to-bf16 fused: thread per channel
__global__ __launch_bounds__(256) void k_poolT(const float* __restrict__ rois,
    float* __restrict__ pavg, float* __restrict__ pmax, u16* __restrict__ roisT){
  int lb = blockIdx.x;
  int t = threadIdx.x;
  const float* r = rois + ((size_t)lb*NC + t)*49;
  u16* dst = roisT + (size_t)lb*49*NC;
  float v[49];
  float s = 0.f, m = -1e30f;
  #pragma unroll
  for (int i=0;i<49;i++){ v[i] = r[i]; s += v[i]; m = fmaxf(m,v[i]); }
  pavg[(size_t)lb*NC + t] = s/49.f;
  pmax[(size_t)lb*NC + t] = m;
  #pragma unroll
  for (int i=0;i<49;i++) dst[(size_t)i*NC + t] = f2bf(v[i]);
}

// ---------------- MLP heads ----------------
__global__ __launch_bounds__(256) void k_mlp1(const float* __restrict__ pavg, const float* __restrict__ pmax,
    const float* __restrict__ aw1, const float* __restrict__ ab1,
    const float* __restrict__ mw1, const float* __restrict__ mb1,
    float* __restrict__ hid){
  int lb = blockIdx.x; int l = lb/NB; int pass = blockIdx.y;
  int t = threadIdx.x, wid = t>>6, lane = t&63;
  int r = blockIdx.z*4 + wid;
  const float* pv = pass ? pmax : pavg;
  const float* w1 = pass ? mw1 : aw1;
  const float* b1 = pass ? mb1 : ab1;
  const float* wr = w1 + (size_t)(l*NC2+r)*NC;
  const float* pr = pv + (size_t)lb*NC;
  float s = dot4(((const float4*)wr)[lane], ((const float4*)pr)[lane]);
  s = wave_red(s);
  if (lane==0) hid[((size_t)lb*2 + pass)*NC2 + r] = fmaxf(s + b1[l*NC2+r], 0.f);
}

__global__ __launch_bounds__(256) void k_mlp2(const float* __restrict__ hid,
    const float* __restrict__ aw2, const float* __restrict__ ab2,
    const float* __restrict__ mw2, const float* __restrict__ mb2,
    float* __restrict__ zavg, float* __restrict__ zmax){
  int lb = blockIdx.x; int l = lb/NB; int pass = blockIdx.y;
  int t = threadIdx.x, wid = t>>6, lane = t&63;
  int c = blockIdx.z*4 + wid;
  const float* w2 = pass ? mw2 : aw2;
  const float* b2 = pass ? mb2 : ab2;
  const float* wr = w2 + (size_t)(l*NC+c)*NC2;
  const float* hr = hid + ((size_t)lb*2 + pass)*NC2;
  float2 wv = ((const float2*)wr)[lane];
  float2 hv = ((const float2*)hr)[lane];
  float s = wave_red(wv.x*hv.x + wv.y*hv.y);
  if (lane==0){
    float* zo = pass ? zmax : zavg;
    zo[(size_t)lb*NC + c] = s + b2[l*NC+c];
  }
}

// ---------------- chan_z tail ----------------
__global__ __launch_bounds__(256) void k_relw(const float* __restrict__ F,
    const float* __restrict__ gw, const float* __restrict__ gb,
    float* __restrict__ rel){
  int lb = blockIdx.x; int l = lb/NB;
  int t = threadIdx.x, wid = t>>6, lane = t&63;
  int r = blockIdx.y*4 + wid;
  const float* wrow = gw + ((size_t)l*2*NC + r)*NC;
  const float* frow = F + (size_t)lb*NC*NC + (size_t)(r>>1)*NC;
  float s = dot4(((const float4*)wrow)[lane], ((const float4*)frow)[lane]);
  s = wave_red(s);
  if (lane==0) rel[(size_t)lb*2*NC + r] = fmaxf(s + gb[l*2*NC+r], 0.f);
}

// z2n + cues fused: wave per c; lane0 applies dr/sigmoid
__global__ __launch_bounds__(256) void k_z2ncue(const float* __restrict__ rel,
    const float* __restrict__ aw, const float* __restrict__ ab,
    const float* __restrict__ zavg, const float* __restrict__ zmax,
    const float* __restrict__ drw, const float* __restrict__ drb,
    float* __restrict__ cues){
  int lb = blockIdx.x; int l = lb/NB;
  int t = threadIdx.x, wid = t>>6, lane = t&63;
  int c = blockIdx.y*4 + wid;
  const float* arow = aw + ((size_t)l*NC + c)*2*NC;
  const float* rrow = rel + (size_t)lb*2*NC;
  float s = dot4(((const float4*)arow)[lane],    ((const float4*)rrow)[lane])
          + dot4(((const float4*)arow)[lane+64], ((const float4*)rrow)[lane+64]);
  s = wave_red(s);
  if (lane==0){
    float z2 = s + ab[l*NC+c];
    size_t idx = (size_t)lb*NC + c;
    const float* dw = drw + (size_t)(l*NC + c)*3;
    float x = dw[0]*zavg[idx] + dw[1]*zmax[idx] + dw[2]*z2 + drb[l*NC+c];
    cues[idx] = 1.f/(1.f + __expf(-x));
  }
}

// ---------------- collapsed sc branch ----------------
__global__ __launch_bounds__(256) void k_zm(const float* __restrict__ zf, const float* __restrict__ m3,
    float* __restrict__ zm, float* __restrict__ sm){
  int lb = blockIdx.x; int cg = blockIdx.y;
  __shared__ float ms[ZZ];
  int t = threadIdx.x;
  if (t < ZZ) ms[t] = m3[(size_t)lb*ZZ + t];
  __syncthreads();
  int c = cg*32 + (t >> 3);
  int sub = t & 7;
  const float* zr = zf + ((size_t)lb*NC + c)*ZZ;
  float s = 0.f;
  for (int z=sub; z<ZZ; z+=8) s += zr[z]*ms[z];
  s += __shfl_down(s, 4, 8);
  s += __shfl_down(s, 2, 8);
  s += __shfl_down(s, 1, 8);
  if (sub == 0) zm[(size_t)lb*NC + c] = s;
  if (cg == 0 && t < 64){
    float ss = 0.f;
    for (int z=t; z<ZZ; z+=64) ss += ms[z];
    ss = wave_red(ss);
    if (t == 0) sm[lb] = ss;
  }
}

__global__ __launch_bounds__(256) void k_zphi(const float* __restrict__ zm, const float* __restrict__ sm,
    const float* __restrict__ phiw, const float* __restrict__ phib, float* __restrict__ zphi){
  int lb = blockIdx.x; int l = lb/NB;
  int t = threadIdx.x, wid = t>>6, lane = t&63;
  int r = blockIdx.y*4 + wid;
  const float* wr = phiw + (size_t)(l*NC + r)*NC;
  const float* zr = zm + (size_t)lb*NC;
  float s = dot4(((const float4*)wr)[lane], ((const float4*)zr)[lane]);
  s = wave_red(s);
  if (lane==0) zphi[(size_t)lb*NC + r] = s + phib[l*NC + r]*sm[lb];
}

__global__ __launch_bounds__(256) void k_wvec(const float* __restrict__ zphi, const float* __restrict__ dw,
    const float* __restrict__ db, float* __restrict__ wvec, float* __restrict__ cb){
  int lb = blockIdx.x; int l = lb/NB;
  __shared__ float zp[NC];
  __shared__ float red[NC];
  int t = threadIdx.x;
  zp[t] = zphi[(size_t)lb*NC + t];
  __syncthreads();
  float s = 0.f;
  const float* dwl = dw + (size_t)l*NC*NC;
  for (int c=0;c<NC;c++) s += zp[c]*dwl[(size_t)c*NC + t];
  wvec[(size_t)lb*NC + t] = s;
  red[t] = zp[t]*db[l*NC + t];
  __syncthreads();
  for (int off2=128; off2>0; off2>>=1){
    if (t < off2) red[t] += red[t+off2];
    __syncthreads();
  }
  if (t==0) cb[lb] = red[0];
}

__global__ __launch_bounds__(256) void k_sc_part(const float* __restrict__ xf,
    const float* __restrict__ wvec, float* __restrict__ part){
  int lb = blockIdx.x, xt = blockIdx.y, cs = blockIdx.z;
  __shared__ float wv[64];
  int t = threadIdx.x;
  if (t < 64) wv[t] = wvec[(size_t)lb*NC + cs*64 + t];
  __syncthreads();
  int x = xt*256 + t;
  if (x >= XX) return;
  const float* xb = xf + ((size_t)lb*NC + cs*64)*XX + x;
  float s = 0.f;
  #pragma unroll 8
  for (int c=0;c<64;c++) s += wv[c]*xb[(size_t)c*XX];
  part[((size_t)lb*4 + cs)*XX + x] = s;
}

__global__ __launch_bounds__(256) void k_xfout2(const float* __restrict__ xf,
    const float* __restrict__ part, const float* __restrict__ cb,
    const float* __restrict__ cues, float* __restrict__ out){
  int bc = blockIdx.y;
  int x = blockIdx.x*256 + threadIdx.x;
  if (x >= XX) return;
  int lb = bc >> 8;
  const float* pp = part + (size_t)lb*4*XX + x;
  float scv = pp[0] + pp[XX] + pp[2*XX] + pp[3*XX];
  scv = fminf(fmaxf((scv + cb[lb])*0.0625f, 0.f), 1.f);
  float cu = cues[bc];
  out[(size_t)bc*XX + x] = (1.f+cu)*xf[(size_t)bc*XX + x] - scv;
}

extern "C" void kernel_launch(void* const* d_in, const int* in_sizes, int n_in,
                              void* d_out, int out_size, void* d_ws, size_t ws_size,
                              hipStream_t stream){
  const float* zf      = (const float*)d_in[0];
  const float* xf      = (const float*)d_in[1];
  const float* maskp   = (const float*)d_in[2];
  const float* box     = (const float*)d_in[3];
  const float* nl_g_w  = (const float*)d_in[4];
  const float* nl_g_b  = (const float*)d_in[5];
  const float* nl_th_w = (const float*)d_in[6];
  const float* nl_th_b = (const float*)d_in[7];
  const float* nl_ph_w = (const float*)d_in[8];
  const float* nl_ph_b = (const float*)d_in[9];
  const float* nl_out_w= (const float*)d_in[10];
  const float* bn_g    = (const float*)d_in[11];
  const float* bn_b    = (const float*)d_in[12];
  const float* bn_m    = (const float*)d_in[13];
  const float* bn_v    = (const float*)d_in[14];
  const float* cz_th_w = (const float*)d_in[15];
  const float* cz_th_b = (const float*)d_in[16];
  const float* cz_ph_w = (const float*)d_in[17];
  const float* cz_ph_b = (const float*)d_in[18];
  const float* cz_gw   = (const float*)d_in[19];
  const float* cz_gb   = (const float*)d_in[20];
  const float* cz_aw   = (const float*)d_in[21];
  const float* cz_ab   = (const float*)d_in[22];
  const float* ap_w1   = (const float*)d_in[23];
  const float* ap_b1   = (const float*)d_in[24];
  const float* ap_w2   = (const float*)d_in[25];
  const float* ap_b2   = (const float*)d_in[26];
  const float* mp_w1   = (const float*)d_in[27];
  const float* mp_b1   = (const float*)d_in[28];
  const float* mp_w2   = (const float*)d_in[29];
  const float* mp_b2   = (const float*)d_in[30];
  const float* dr_w    = (const float*)d_in[31];
  const float* dr_b    = (const float*)d_in[32];
  const float* ac1_w   = (const float*)d_in[33];
  const float* ac1_b   = (const float*)d_in[34];
  const float* ac2_w   = (const float*)d_in[35];
  const float* ac2_b   = (const float*)d_in[36];
  const float* ac3_w   = (const float*)d_in[37];
  const float* ac3_b   = (const float*)d_in[38];
  const float* ac4_w   = (const float*)d_in[39];
  const float* ac4_b   = (const float*)d_in[40];
  const float* phi_w   = (const float*)d_in[41];
  const float* phi_b   = (const float*)d_in[42];
  const float* delta_w = (const float*)d_in[43];
  const float* delta_b = (const float*)d_in[44];
  (void)in_sizes; (void)n_in; (void)out_size; (void)ws_size;

  float* ws = (float*)d_ws;
  size_t off = 0;
  auto alloc = [&](size_t n){ size_t o = off; off += (n + 15) & ~(size_t)15; return o; };
  float* TH3f  = ws + alloc((size_t)NL*NB*ZZ*384/2);   // bf16 [225][384]
  float* Sb    = ws + alloc((size_t)NL*NB*ZZ*ZZ);      // fp32 scores
  u16* TH3  = (u16*)TH3f;
  // F fp32 [256][256]/lb = 65536 floats/lb; spans TH3f (43200/lb) + into Sb —
  // both dead after softmax/PV; combined region 9.0M floats >= 6.3M needed.
  float* Freg  = TH3f;
  float* zfTf  = ws + alloc((size_t)NL*NB*ZZ*NC/2);
  float* Pbf   = ws + alloc((size_t)NL*NB*ZZ*256/2);
  float* GXTf  = ws + alloc((size_t)NL*NB*128*256/2);
  float* Ybbf  = ws + alloc((size_t)NL*NB*ZZ*NC2/2);
  float* CZ3Tf = ws + alloc((size_t)NL*NB*512*64/2);
  float* roisTf= ws + alloc((size_t)NL*NB*49*NC/2);
  float* Wcatf = ws + alloc((size_t)NL*384*256/2);
  float* Wczf  = ws + alloc((size_t)NL*512*256/2);
  float* outwbf= ws + alloc((size_t)NL*NC*NC2/2);
  u16 *zfT=(u16*)zfTf, *Pb=(u16*)Pbf, *GXT=(u16*)GXTf, *Ybb=(u16*)Ybbf,
      *CZ3T=(u16*)CZ3Tf, *roisT=(u16*)roisTf, *Wcat=(u16*)Wcatf,
      *Wcz=(u16*)Wczf, *outwb=(u16*)outwbf;
  float* bcat = ws + alloc((size_t)NL*384);
  float* bcz  = ws + alloc((size_t)NL*512);
  float* m3   = ws + alloc((size_t)NL*NB*ZZ);
  float* rois = ws + alloc((size_t)NL*NB*NC*49);
  float* pavg = ws + alloc((size_t)NL*NB*NC);
  float* pmax = ws + alloc((size_t)NL*NB*NC);
  float* zavg = ws + alloc((size_t)NL*NB*NC);
  float* zmax = ws + alloc((size_t)NL*NB*NC);
  float* cues = ws + alloc((size_t)NL*NB*NC);
  float* zm   = ws + alloc((size_t)NL*NB*NC);
  float* zphi = ws + alloc((size_t)NL*NB*NC);
  float* wvec = ws + alloc((size_t)NL*NB*NC);
  float* sm   = ws + alloc((size_t)NL*NB);
  float* cbuf = ws + alloc((size_t)NL*NB);
  float* part = ws + alloc((size_t)NL*NB*4*XX);
  float* hidb = ws + alloc((size_t)NL*NB*2*NC2);
  float* relb = ws + alloc((size_t)NL*NB*2*NC);

  float* outp    = (float*)d_out;
  float* o_zfout = outp;
  float* o_zffull= outp + (size_t)NL*NB*NC*49;
  float* o_xfout = o_zffull + (size_t)NL*NB*NC*ZZ;

  // ---- mask branch + converts/packs ----
  k_mask<<<NL*NB, 256, 0, stream>>>(maskp, ac1_w, ac1_b, ac2_w, ac2_b,
                                     ac3_w, ac3_b, ac4_w, ac4_b, m3);
  k_zft<<<dim3(NL*NB, 8, 8), 256, 0, stream>>>(zf, zfT);
  k_packs<<<(NL*512*256+255)/256, 256, 0, stream>>>(
      nl_th_w, nl_th_b, nl_ph_w, nl_ph_b, nl_g_w, nl_g_b,
      cz_th_w, cz_th_b, cz_ph_w, cz_ph_b, nl_out_w,
      Wcat, bcat, Wcz, bcz, outwb);

  // ---- projections: TH3 = zfT @ Wcat^T  (bf16 out, [225][384]) ----
  k_mg<true,true,true,false><<<dim3(24, NL*NB), 256, 0, stream>>>(
      zfT, Wcat, bcat, TH3, ZZ, 384, NC, 256, 256, 384,
      (long)ZZ*256, (long)384*256, (long)ZZ*384, 6);
  // S = TH @ PH^T (fp32)
  k_mg<false,false,false,false><<<dim3(16, NL*NB), 256, 0, stream>>>(
      TH3, TH3+128, nullptr, Sb, ZZ, ZZ, NC2, 384, 384, ZZ,
      (long)ZZ*384, (long)ZZ*384, (long)ZZ*ZZ, 4);
  k_softmax<<<(NL*NB*ZZ)/4, 256, 0, stream>>>(Sb, Pb);
  k_gxt<<<dim3(NL*NB, 8), 256, 0, stream>>>(TH3, GXT);
  // Y = P @ GX (bf16 out [225][128])
  k_mg<false,false,true,false><<<dim3(8, NL*NB), 256, 0, stream>>>(
      Pb, GXT, nullptr, Ybb, ZZ, NC2, 256, 256, 256, NC2,
      (long)ZZ*256, (long)128*256, (long)ZZ*NC2, 2);

  // ---- rois / cues ----
  k_rois<<<dim3(NL*NB, 16), 256, 0, stream>>>(zf, box, rois);
  k_poolT<<<NL*NB, 256, 0, stream>>>(rois, pavg, pmax, roisT);
  k_mlp1<<<dim3(NL*NB, 2, 32), 256, 0, stream>>>(pavg, pmax, ap_w1, ap_b1, mp_w1, mp_b1, hidb);
  k_mlp2<<<dim3(NL*NB, 2, 64), 256, 0, stream>>>(hidb, ap_w2, ap_b2, mp_w2, mp_b2, zavg, zmax);
  // CZ3T[n][s] (bf16, transposed out, [512][64] zero-padded)
  k_mg<true,true,true,true><<<dim3(8, NL*NB), 256, 0, stream>>>(
      roisT, Wcz, bcz, CZ3T, 49, 512, NC, 256, 256, 64,
      (long)49*256, (long)512*256, (long)512*64, 8);
  // F = czth^T @ czph (fp32 [256][256])
  k_mg<false,false,false,false><<<dim3(16, NL*NB), 256, 0, stream>>>(
      CZ3T, CZ3T+256*64, nullptr, Freg, NC, NC, 64, 64, 64, NC,
      (long)512*64, (long)512*64, (long)NC*NC, 4);
  k_relw<<<dim3(NL*NB, 128), 256, 0, stream>>>(Freg, cz_gw, cz_gb, relb);
  k_z2ncue<<<dim3(NL*NB, 64), 256, 0, stream>>>(relb, cz_aw, cz_ab,
                                                 zavg, zmax, dr_w, dr_b, cues);

  // ---- zf_full (+7x7 slice) ----
  k_outconv_m<<<dim3(16, NL*NB), 256, 0, stream>>>(outwb, Ybb, bn_g, bn_b, bn_m, bn_v,
                                                    cues, zf, o_zfout, o_zffull);

  // ---- collapsed sc branch + xf_out ----
  k_zm<<<dim3(NL*NB, 8), 256, 0, stream>>>(zf, m3, zm, sm);
  k_zphi<<<dim3(NL*NB, 64), 256, 0, stream>>>(zm, sm, phi_w, phi_b, zphi);
  k_wvec<<<NL*NB, 256, 0, stream>>>(zphi, delta_w, delta_b, wvec, cbuf);
  k_sc_part<<<dim3(NL*NB, 4, 4), 256, 0, stream>>>(xf, wvec, part);
  k_xfout2<<<dim3(4, NL*NB*NC), 256, 0, stream>>>(xf, part, cbuf, cues, o_xfout);
}

// Round 12
// 312.847 us; speedup vs baseline: 3.3726x; 1.0524x over previous
//
#include <hip/hip_runtime.h>
#include <math.h>

#define NL 3
#define NB 32
#define NC 256
#define NC2 128
#define HZ 15
#define ZZ 225
#define XX 961
#define HMD 127

typedef unsigned short u16;
typedef __attribute__((ext_vector_type(8))) unsigned short us8;
typedef __attribute__((ext_vector_type(8))) short bf8v;
typedef __attribute__((ext_vector_type(4))) float f4v;

__device__ __forceinline__ u16 f2bf(float f){
  unsigned int u = __float_as_uint(f);
  unsigned int r = (u + 0x7fffu + ((u>>16)&1u)) >> 16;
  return (u16)r;
}
__device__ __forceinline__ float hat_int(float u){
  if (u <= -1.f) return 0.f;
  if (u <= 0.f){ float t = u + 1.f; return 0.5f*t*t; }
  if (u <= 1.f){ float t = 1.f - u; return 1.f - 0.5f*t*t; }
  return 1.f;
}
__device__ __forceinline__ float dot4(float4 a, float4 b){
  return a.x*b.x + a.y*b.y + a.z*b.z + a.w*b.w;
}
__device__ __forceinline__ float wave_red(float s){
  #pragma unroll
  for (int off=32; off>0; off>>=1) s += __shfl_xor(s, off);
  return s;
}

// ================= fused mask branch =================
__global__ __launch_bounds__(256) void k_mask(const float* __restrict__ mask,
    const float* __restrict__ w1, const float* __restrict__ b1,
    const float* __restrict__ w2, const float* __restrict__ b2,
    const float* __restrict__ w3, const float* __restrict__ b3,
    const float* __restrict__ w4, const float* __restrict__ b4,
    float* __restrict__ m3out){
  int lb = blockIdx.x; int l = lb/NB, b = lb%NB;
  int t = threadIdx.x;
  __shared__ float c1s[4][56][56];
  __shared__ float c2s[8][28][28];
  __shared__ float r1s[8][14][14];
  __shared__ float c3s[4][14][14];
  __shared__ float r2s[4][15][15];
  __shared__ int   y0t[14];
  __shared__ float wyt[14];
  __shared__ int   y0t15[15];
  __shared__ float wyt15[15];
  if (t < 14){
    float sy = 122.0f/13.0f;
    float yf = (float)t * sy;
    int y0 = (int)floorf(yf); y0 = min(max(y0,0), 121);
    y0t[t] = y0; wyt[t] = yf - (float)y0;
  } else if (t < 29){
    int q = t-14;
    float sy = 13.0f/14.0f;
    float yf = (float)q * sy;
    int y0 = (int)floorf(yf); y0 = min(max(y0,0), 12);
    y0t15[q] = y0; wyt15[q] = yf - (float)y0;
  }
  __syncthreads();
  const float* mb = mask + (size_t)b*HMD*HMD;
  const float* wc1 = w1 + (size_t)l*4*2*9;
  for (int e=t; e<4*56*56; e+=256){
    int ci = e % 56, ri = (e/56) % 56, oc = e/(56*56);
    int row = y0t[ri>>2] + (ri&3);
    int col = y0t[ci>>2] + (ci&3);
    float acc = b1[l*4+oc];
    #pragma unroll
    for (int ky=0;ky<3;ky++)
      #pragma unroll
      for (int kx=0;kx<3;kx++){
        float mv = mb[(row+ky)*HMD + (col+kx)];
        acc += wc1[((oc*2+0)*3+ky)*3+kx]*mv;
        acc += wc1[((oc*2+1)*3+ky)*3+kx]*(1.f-mv);
      }
    c1s[oc][ri][ci] = fmaxf(acc, 0.f);
  }
  __syncthreads();
  const float* wc2 = w2 + (size_t)l*8*4*9;
  for (int e=t; e<8*28*28; e+=256){
    int j = e % 28, i = (e/28) % 28, oc = e/(28*28);
    int g = i>>1, dy = i&1, gc = j>>1, dx = j&1;
    float acc = b2[l*8+oc];
    #pragma unroll
    for (int ic=0; ic<4; ic++)
      #pragma unroll
      for (int ky=0;ky<3;ky++)
        #pragma unroll
        for (int kx=0;kx<3;kx++)
          acc += wc2[((oc*4+ic)*3+ky)*3+kx]*c1s[ic][g*4+dy+ky][gc*4+dx+kx];
    c2s[oc][i][j] = fmaxf(acc, 0.f);
  }
  __syncthreads();
  for (int e=t; e<8*14*14; e+=256){
    int ox = e % 14, oy = (e/14) % 14, oc = e/(14*14);
    float wy = wyt[oy], wx = wyt[ox];
    float v00 = c2s[oc][2*oy][2*ox],   v01 = c2s[oc][2*oy][2*ox+1];
    float v10 = c2s[oc][2*oy+1][2*ox], v11 = c2s[oc][2*oy+1][2*ox+1];
    r1s[oc][oy][ox] = (v00*(1.f-wy)+v10*wy)*(1.f-wx) + (v01*(1.f-wy)+v11*wy)*wx;
  }
  __syncthreads();
  const float* wc3 = w3 + (size_t)l*4*8*9;
  for (int e=t; e<4*14*14; e+=256){
    int x = e % 14, y = (e/14) % 14, oc = e/(14*14);
    float acc = b3[l*4+oc];
    for (int ic=0; ic<8; ic++)
      #pragma unroll
      for (int ky=-1;ky<=1;ky++){
        int yy = y+ky; if (yy<0||yy>=14) continue;
        #pragma unroll
        for (int kx=-1;kx<=1;kx++){
          int xx = x+kx; if (xx<0||xx>=14) continue;
          acc += wc3[((oc*8+ic)*3+(ky+1))*3+(kx+1)]*r1s[ic][yy][xx];
        }
      }
    c3s[oc][y][x] = acc;
  }
  __syncthreads();
  for (int e=t; e<4*15*15; e+=256){
    int ox = e % 15, oy = (e/15) % 15, oc = e/(15*15);
    int y0 = y0t15[oy], x0 = y0t15[ox];
    float wy = wyt15[oy], wx = wyt15[ox];
    float v00 = c3s[oc][y0][x0],   v01 = c3s[oc][y0][x0+1];
    float v10 = c3s[oc][y0+1][x0], v11 = c3s[oc][y0+1][x0+1];
    r2s[oc][oy][ox] = (v00*(1.f-wy)+v10*wy)*(1.f-wx) + (v01*(1.f-wy)+v11*wy)*wx;
  }
  __syncthreads();
  const float* wc4 = w4 + (size_t)l*1*4*9;
  for (int e=t; e<15*15; e+=256){
    int x = e % 15, y = e/15;
    float acc = b4[l];
    #pragma unroll
    for (int ic=0; ic<4; ic++)
      #pragma unroll
      for (int ky=-1;ky<=1;ky++){
        int yy = y+ky; if (yy<0||yy>=15) continue;
        #pragma unroll
        for (int kx=-1;kx<=1;kx++){
          int xx = x+kx; if (xx<0||xx>=15) continue;
          acc += wc4[(ic*3+(ky+1))*3+(kx+1)]*r2s[ic][yy][xx];
        }
      }
    m3out[(size_t)lb*ZZ + y*15 + x] = acc;
  }
}

// all weight packs in one kernel
__global__ __launch_bounds__(256) void k_packs(
    const float* __restrict__ thw, const float* __restrict__ thb,
    const float* __restrict__ phw, const float* __restrict__ phb,
    const float* __restrict__ gw,  const float* __restrict__ gb,
    const float* __restrict__ czthw, const float* __restrict__ czthb,
    const float* __restrict__ czphw, const float* __restrict__ czphb,
    const float* __restrict__ outw,
    u16* __restrict__ Wcat, float* __restrict__ bcat,
    u16* __restrict__ Wcz, float* __restrict__ bcz,
    u16* __restrict__ outwb){
  int idx = blockIdx.x*256 + threadIdx.x;
  if (idx < NL*384*256){
    int k = idx & 255; int r = (idx >> 8) % 384; int l = idx/(384*256);
    float v;
    if (r < 128)      v = thw[((size_t)l*128 + r)*256 + k];
    else if (r < 256) v = phw[((size_t)l*128 + (r-128))*256 + k];
    else              v = gw [((size_t)l*128 + (r-256))*256 + k];
    Wcat[idx] = f2bf(v);
  }
  if (idx < NL*512*256){
    int k = idx & 255; int r = (idx >> 8) % 512; int l = idx/(512*256);
    float v;
    if (r < 256) v = czthw[((size_t)l*256 + r)*256 + k];
    else         v = czphw[((size_t)l*256 + (r-256))*256 + k];
    Wcz[idx] = f2bf(v);
  }
  if (idx < NL*NC*NC2) outwb[idx] = f2bf(outw[idx]);
  if (idx < NL*384){
    int r = idx % 384, l = idx/384;
    bcat[idx] = (r<128) ? thb[l*128+r] : (r<256) ? phb[l*128+r-128] : gb[l*128+r-256];
  }
  if (idx < NL*512){
    int r = idx % 512, l = idx/512;
    bcz[idx] = (r<256) ? czthb[l*256+r] : czphb[l*256+r-256];
  }
}

// ============ fused zf pass: zfT transpose + PrRoI(+pool+roisT) + zm/sm ============
// grid (NL*NB, 8): block handles 32 channels c0..c0+31 of one (l,b)
__global__ __launch_bounds__(256) void k_zfall(const float* __restrict__ zf,
    const float* __restrict__ box, const float* __restrict__ m3,
    u16* __restrict__ zfT, float* __restrict__ pavg, float* __restrict__ pmax,
    u16* __restrict__ roisT, float* __restrict__ zm, float* __restrict__ sm){
  int lb = blockIdx.x; int b = lb % NB; int c0 = blockIdx.y*32;
  __shared__ float fld[32*ZZ];
  __shared__ float Wy[7][15], Wx[7][15];
  __shared__ float tmp[32][7][16];
  __shared__ float roi[32][49];
  __shared__ float ms[ZZ];
  __shared__ float area_s;
  int t = threadIdx.x;
  const float* bx = box + b*4;
  const float SC = 15.0f/127.0f;
  float x1 = bx[0]*SC, y1 = bx[1]*SC, x2 = bx[2]*SC, y2 = bx[3]*SC;
  float bh = (y2-y1)/7.f, bw = (x2-x1)/7.f;
  if (t < 105){ int p=t/15, i=t%15;
    Wy[p][i] = hat_int(y1+(float)(p+1)*bh - (float)i) - hat_int(y1+(float)p*bh - (float)i); }
  else if (t < 210){ int q=(t-105)/15, i=(t-105)%15;
    Wx[q][i] = hat_int(x1+(float)(q+1)*bw - (float)i) - hat_int(x1+(float)q*bw - (float)i); }
  if (t == 255) area_s = fmaxf(bh*bw, 1e-6f);
  if (t < ZZ) ms[t] = m3[(size_t)lb*ZZ + t];
  const float* src = zf + ((size_t)lb*NC + c0)*ZZ;
  for (int e=t; e<32*ZZ; e+=256) fld[e] = src[e];
  __syncthreads();
  // 1. zfT write (bf16 transpose)
  u16* dstT = zfT + (size_t)lb*ZZ*NC + c0;
  for (int e=t; e<ZZ*32; e+=256){
    int ci = e & 31, z = e >> 5;
    dstT[(size_t)z*NC + ci] = f2bf(fld[ci*ZZ + z]);
  }
  // 2. PrRoI stage 1
  float inv_area = 1.f/area_s;
  for (int e=t; e<32*105; e+=256){
    int w = e%15; int pc = e/15; int p = pc%7; int cc = pc/7;
    float s = 0.f;
    #pragma unroll
    for (int h=0;h<15;h++) s += Wy[p][h]*fld[cc*ZZ + h*15 + w];
    tmp[cc][p][w] = s;
  }
  // 3. zm partial (fld + ms only; independent of tmp)
  {
    int cc = t>>3, sub = t&7;
    const float* fr = &fld[cc*ZZ];
    float s = 0.f;
    for (int z=sub; z<ZZ; z+=8) s += fr[z]*ms[z];
    s += __shfl_down(s, 4, 8);
    s += __shfl_down(s, 2, 8);
    s += __shfl_down(s, 1, 8);
    if (sub == 0) zm[(size_t)lb*NC + c0 + cc] = s;
  }
  // 4. sm (once per lb)
  if (blockIdx.y == 0 && t < 64){
    float ss = 0.f;
    for (int z=t; z<ZZ; z+=64) ss += ms[z];
    ss = wave_red(ss);
    if (t == 0) sm[lb] = ss;
  }
  __syncthreads();
  // 5. PrRoI stage 2 -> roi
  for (int e=t; e<32*49; e+=256){
    int q = e%7; int pc = e/7; int p = pc%7; int cc = pc/7;
    float s = 0.f;
    #pragma unroll
    for (int w=0;w<15;w++) s += tmp[cc][p][w]*Wx[q][w];
    roi[cc][p*7+q] = s*inv_area;
  }
  __syncthreads();
  // 6. roisT (bf16) + pool
  u16* dR = roisT + (size_t)lb*49*NC + c0;
  for (int e=t; e<49*32; e+=256){
    int ci = e & 31, s = e >> 5;
    dR[(size_t)s*NC + ci] = f2bf(roi[ci][s]);
  }
  if (t < 32){
    float s = 0.f, m = -1e30f;
    #pragma unroll
    for (int i=0;i<49;i++){ float v = roi[t][i]; s += v; m = fmaxf(m,v); }
    pavg[(size_t)lb*NC + c0 + t] = s/49.f;
    pmax[(size_t)lb*NC + c0 + t] = m;
  }
}

// GX slice of TH3 [225][384](cols 256..383) bf16 -> GXT [128][256] bf16 (z pad 0)
__global__ __launch_bounds__(256) void k_gxt(const u16* __restrict__ TH3, u16* __restrict__ GXT){
  int lb = blockIdx.x; int z0 = blockIdx.y*32;
  __shared__ u16 lds[32][130];
  int t = threadIdx.x;
  int n = t & 127, zi = t >> 7;
  const u16* src = TH3 + (size_t)lb*ZZ*384 + 256;
  #pragma unroll
  for (int p=0;p<16;p++){
    int z = z0 + zi + p*2;
    lds[zi+p*2][n] = (z < ZZ) ? src[(size_t)z*384 + n] : (u16)0;
  }
  __syncthreads();
  u16* dst = GXT + (size_t)lb*128*256;
  int zi2 = t & 31, ni = t >> 5;
  #pragma unroll
  for (int p=0;p<16;p++){
    int nn = ni + p*8;
    dst[(size_t)nn*256 + z0 + zi2] = lds[zi2][nn];
  }
}

// ---------------- bf16 MFMA GEMM ----------------
template<bool BPERL, bool HASBIAS, bool OUTBF, bool TROUT>
__global__ __launch_bounds__(256) void k_mg(
    const u16* __restrict__ A0, const u16* __restrict__ B0,
    const float* __restrict__ bias0, void* __restrict__ O0,
    int M, int N, int K, int lda, int ldb, int ldo,
    long Ab, long Bb, long Ob, int ntn)
{
  int lb = blockIdx.y; int l = lb / NB;
  const u16* A = A0 + (size_t)lb*Ab;
  const u16* B = B0 + (BPERL ? (size_t)l : (size_t)lb)*Bb;
  int tm = blockIdx.x / ntn, tn = blockIdx.x % ntn;
  int m0 = tm*64, n0 = tn*64;
  __shared__ u16 Asl[64][40];
  __shared__ u16 Bsl[64][40];
  int t = threadIdx.x;
  int w = t>>6, l6 = t&63;
  int fr = l6&15, kg = (l6>>4)*8;
  int srow = t>>2, sseg = (t&3)*8;
  f4v ac0={0,0,0,0}, ac1={0,0,0,0}, ac2={0,0,0,0}, ac3={0,0,0,0};
  for (int kc=0; kc<K; kc+=32){
    us8 va = {0,0,0,0,0,0,0,0};
    int am = m0 + srow;
    if (am < M) va = *(const us8*)&A[(size_t)am*lda + kc + sseg];
    *(us8*)&Asl[srow][sseg] = va;
    us8 vb = {0,0,0,0,0,0,0,0};
    int bn = n0 + srow;
    if (bn < N) vb = *(const us8*)&B[(size_t)bn*ldb + kc + sseg];
    *(us8*)&Bsl[srow][sseg] = vb;
    __syncthreads();
    bf8v af = *(const bf8v*)&Asl[w*16 + fr][kg];
    bf8v b0 = *(const bf8v*)&Bsl[fr][kg];
    bf8v b1 = *(const bf8v*)&Bsl[16+fr][kg];
    bf8v b2 = *(const bf8v*)&Bsl[32+fr][kg];
    bf8v b3 = *(const bf8v*)&Bsl[48+fr][kg];
    ac0 = __builtin_amdgcn_mfma_f32_16x16x32_bf16(af, b0, ac0, 0,0,0);
    ac1 = __builtin_amdgcn_mfma_f32_16x16x32_bf16(af, b1, ac1, 0,0,0);
    ac2 = __builtin_amdgcn_mfma_f32_16x16x32_bf16(af, b2, ac2, 0,0,0);
    ac3 = __builtin_amdgcn_mfma_f32_16x16x32_bf16(af, b3, ac3, 0,0,0);
    __syncthreads();
  }
  int mb = m0 + w*16 + ((l6>>4)<<2);
  #pragma unroll
  for (int j=0;j<4;j++){
    int n = n0 + j*16 + fr;
    if (n >= N) continue;
    float bv = HASBIAS ? bias0[(size_t)l*N + n] : 0.f;
    f4v a = (j==0)?ac0:(j==1)?ac1:(j==2)?ac2:ac3;
    #pragma unroll
    for (int r=0;r<4;r++){
      int m = mb + r;
      if (TROUT){
        u16* out = (u16*)O0 + (size_t)lb*Ob;
        out[(size_t)n*ldo + m] = f2bf((m<M) ? (a[r]+bv) : 0.f);
      } else if (m < M){
        if (OUTBF){
          u16* out = (u16*)O0 + (size_t)lb*Ob;
          out[(size_t)m*ldo + n] = f2bf(a[r]+bv);
        } else {
          float* out = (float*)O0 + (size_t)lb*Ob;
          out[(size_t)m*ldo + n] = a[r]+bv;
        }
      }
    }
  }
}

// ---------------- softmax: fp32 S rows -> bf16 P [225][256] zero-padded ----------------
__global__ __launch_bounds__(256) void k_softmax(const float* __restrict__ S, u16* __restrict__ P){
  int row = blockIdx.x*4 + (threadIdx.x >> 6);
  int lane = threadIdx.x & 63;
  const float* r = S + (size_t)row*ZZ;
  float v[4]; float mx = -1e30f;
  #pragma unroll
  for (int q=0;q<4;q++){
    int j = lane + q*64;
    v[q] = (j<ZZ) ? r[j] : -1e30f;
    mx = fmaxf(mx, v[q]);
  }
  #pragma unroll
  for (int off=32; off>0; off>>=1) mx = fmaxf(mx, __shfl_xor(mx, off));
  float sum = 0.f;
  #pragma unroll
  for (int q=0;q<4;q++){
    v[q] = __expf(v[q]-mx);
    if (lane + q*64 < ZZ) sum += v[q];
  }
  #pragma unroll
  for (int off=32; off>0; off>>=1) sum += __shfl_xor(sum, off);
  float inv = 1.f/(16.f*sum);
  u16* pr = P + (size_t)row*256;
  #pragma unroll
  for (int q=0;q<4;q++){
    int j = lane + q*64;
    pr[j] = (j<ZZ) ? f2bf(v[q]*inv) : (u16)0;
  }
}

// ---------------- outconv MFMA + BN/cues/residual/slice ----------------
__global__ __launch_bounds__(256) void k_outconv_m(const u16* __restrict__ outwb,
    const u16* __restrict__ Ybb,
    const float* __restrict__ bng, const float* __restrict__ bnb,
    const float* __restrict__ bnm, const float* __restrict__ bnv,
    const float* __restrict__ cues, const float* __restrict__ zf,
    float* __restrict__ dzfout, float* __restrict__ dzffull){
  int lb = blockIdx.y; int l = lb/NB;
  const u16* A = outwb + (size_t)l*NC*NC2;
  const u16* B = Ybb + (size_t)lb*ZZ*NC2;
  int tm = blockIdx.x >> 2, tn = blockIdx.x & 3;
  int m0 = tm*64, n0 = tn*64;
  __shared__ u16 Asl[64][40];
  __shared__ u16 Bsl[64][40];
  int t = threadIdx.x;
  int w = t>>6, l6 = t&63;
  int fr = l6&15, kg = (l6>>4)*8;
  int srow = t>>2, sseg = (t&3)*8;
  f4v ac0={0,0,0,0}, ac1={0,0,0,0}, ac2={0,0,0,0}, ac3={0,0,0,0};
  for (int kc=0; kc<NC2; kc+=32){
    us8 va = *(const us8*)&A[(size_t)(m0+srow)*NC2 + kc + sseg];
    *(us8*)&Asl[srow][sseg] = va;
    us8 vb = {0,0,0,0,0,0,0,0};
    int bn = n0 + srow;
    if (bn < ZZ) vb = *(const us8*)&B[(size_t)bn*NC2 + kc + sseg];
    *(us8*)&Bsl[srow][sseg] = vb;
    __syncthreads();
    bf8v af = *(const bf8v*)&Asl[w*16 + fr][kg];
    bf8v b0 = *(const bf8v*)&Bsl[fr][kg];
    bf8v b1 = *(const bf8v*)&Bsl[16+fr][kg];
    bf8v b2 = *(const bf8v*)&Bsl[32+fr][kg];
    bf8v b3 = *(const bf8v*)&Bsl[48+fr][kg];
    ac0 = __builtin_amdgcn_mfma_f32_16x16x32_bf16(af, b0, ac0, 0,0,0);
    ac1 = __builtin_amdgcn_mfma_f32_16x16x32_bf16(af, b1, ac1, 0,0,0);
    ac2 = __builtin_amdgcn_mfma_f32_16x16x32_bf16(af, b2, ac2, 0,0,0);
    ac3 = __builtin_amdgcn_mfma_f32_16x16x32_bf16(af, b3, ac3, 0,0,0);
    __syncthreads();
  }
  int mb = m0 + w*16 + ((l6>>4)<<2);
  #pragma unroll
  for (int j=0;j<4;j++){
    int z = n0 + j*16 + fr;
    if (z >= ZZ) continue;
    int h = z/15, wv2 = z%15;
    f4v a = (j==0)?ac0:(j==1)?ac1:(j==2)?ac2:ac3;
    #pragma unroll
    for (int r=0;r<4;r++){
      int c = mb + r;
      float scale = bng[l*NC+c] * rsqrtf(bnv[l*NC+c] + 1e-5f);
      float val = (a[r] - bnm[l*NC+c])*scale + bnb[l*NC+c];
      float cu = cues[(size_t)lb*NC + c];
      float zv = zf[((size_t)lb*NC + c)*ZZ + z];
      float rr = cu*zv + zv + val;
      dzffull[((size_t)lb*NC + c)*ZZ + z] = rr;
      if (h>=4 && h<11 && wv2>=4 && wv2<11)
        dzfout[((size_t)lb*NC + c)*49 + (h-4)*7 + (wv2-4)] = rr;
    }
  }
}

// ---------------- MLP heads ----------------
__global__ __launch_bounds__(256) void k_mlp1(const float* __restrict__ pavg, const float* __restrict__ pmax,
    const float* __restrict__ aw1, const float* __restrict__ ab1,
    const float* __restrict__ mw1, const float* __restrict__ mb1,
    float* __restrict__ hid){
  int lb = blockIdx.x; int l = lb/NB; int pass = blockIdx.y;
  int t = threadIdx.x, wid = t>>6, lane = t&63;
  int r = blockIdx.z*4 + wid;
  const float* pv = pass ? pmax : pavg;
  const float* w1 = pass ? mw1 : aw1;
  const float* b1 = pass ? mb1 : ab1;
  const float* wr = w1 + (size_t)(l*NC2+r)*NC;
  const float* pr = pv + (size_t)lb*NC;
  float s = dot4(((const float4*)wr)[lane], ((const float4*)pr)[lane]);
  s = wave_red(s);
  if (lane==0) hid[((size_t)lb*2 + pass)*NC2 + r] = fmaxf(s + b1[l*NC2+r], 0.f);
}

__global__ __launch_bounds__(256) void k_mlp2(const float* __restrict__ hid,
    const float* __restrict__ aw2, const float* __restrict__ ab2,
    const float* __restrict__ mw2, const float* __restrict__ mb2,
    float* __restrict__ zavg, float* __restrict__ zmax){
  int lb = blockIdx.x; int l = lb/NB; int pass = blockIdx.y;
  int t = threadIdx.x, wid = t>>6, lane = t&63;
  int c = blockIdx.z*4 + wid;
  const float* w2 = pass ? mw2 : aw2;
  const float* b2 = pass ? mb2 : ab2;
  const float* wr = w2 + (size_t)(l*NC+c)*NC2;
  const float* hr = hid + ((size_t)lb*2 + pass)*NC2;
  float2 wv = ((const float2*)wr)[lane];
  float2 hv = ((const float2*)hr)[lane];
  float s = wave_red(wv.x*hv.x + wv.y*hv.y);
  if (lane==0){
    float* zo = pass ? zmax : zavg;
    zo[(size_t)lb*NC + c] = s + b2[l*NC+c];
  }
}

// ---------------- chan_z tail ----------------
__global__ __launch_bounds__(256) void k_relw(const float* __restrict__ F,
    const float* __restrict__ gw, const float* __restrict__ gb,
    float* __restrict__ rel){
  int lb = blockIdx.x; int l = lb/NB;
  int t = threadIdx.x, wid = t>>6, lane = t&63;
  int r = blockIdx.y*4 + wid;
  const float* wrow = gw + ((size_t)l*2*NC + r)*NC;
  const float* frow = F + (size_t)lb*NC*NC + (size_t)(r>>1)*NC;
  float s = dot4(((const float4*)wrow)[lane], ((const float4*)frow)[lane]);
  s = wave_red(s);
  if (lane==0) rel[(size_t)lb*2*NC + r] = fmaxf(s + gb[l*2*NC+r], 0.f);
}

__global__ __launch_bounds__(256) void k_z2ncue(const float* __restrict__ rel,
    const float* __restrict__ aw, const float* __restrict__ ab,
    const float* __restrict__ zavg, const float* __restrict__ zmax,
    const float* __restrict__ drw, const float* __restrict__ drb,
    float* __restrict__ cues){
  int lb = blockIdx.x; int l = lb/NB;
  int t = threadIdx.x, wid = t>>6, lane = t&63;
  int c = blockIdx.y*4 + wid;
  const float* arow = aw + ((size_t)l*NC + c)*2*NC;
  const float* rrow = rel + (size_t)lb*2*NC;
  float s = dot4(((const float4*)arow)[lane],    ((const float4*)rrow)[lane])
          + dot4(((const float4*)arow)[lane+64], ((const float4*)rrow)[lane+64]);
  s = wave_red(s);
  if (lane==0){
    float z2 = s + ab[l*NC+c];
    size_t idx = (size_t)lb*NC + c;
    const float* dw = drw + (size_t)(l*NC + c)*3;
    float x = dw[0]*zavg[idx] + dw[1]*zmax[idx] + dw[2]*z2 + drb[l*NC+c];
    cues[idx] = 1.f/(1.f + __expf(-x));
  }
}

// ---------------- collapsed sc branch ----------------
__global__ __launch_bounds__(256) void k_zphi(const float* __restrict__ zm, const float* __restrict__ sm,
    const float* __restrict__ phiw, const float* __restrict__ phib, float* __restrict__ zphi){
  int lb = blockIdx.x; int l = lb/NB;
  int t = threadIdx.x, wid = t>>6, lane = t&63;
  int r = blockIdx.y*4 + wid;
  const float* wr = phiw + (size_t)(l*NC + r)*NC;
  const float* zr = zm + (size_t)lb*NC;
  float s = dot4(((const float4*)wr)[lane], ((const float4*)zr)[lane]);
  s = wave_red(s);
  if (lane==0) zphi[(size_t)lb*NC + r] = s + phib[l*NC + r]*sm[lb];
}

__global__ __launch_bounds__(256) void k_wvec(const float* __restrict__ zphi, const float* __restrict__ dw,
    const float* __restrict__ db, float* __restrict__ wvec, float* __restrict__ cb){
  int lb = blockIdx.x; int l = lb/NB;
  __shared__ float zp[NC];
  __shared__ float red[NC];
  int t = threadIdx.x;
  zp[t] = zphi[(size_t)lb*NC + t];
  __syncthreads();
  float s = 0.f;
  const float* dwl = dw + (size_t)l*NC*NC;
  for (int c=0;c<NC;c++) s += zp[c]*dwl[(size_t)c*NC + t];
  wvec[(size_t)lb*NC + t] = s;
  red[t] = zp[t]*db[l*NC + t];
  __syncthreads();
  for (int off2=128; off2>0; off2>>=1){
    if (t < off2) red[t] += red[t+off2];
    __syncthreads();
  }
  if (t==0) cb[lb] = red[0];
}

__global__ __launch_bounds__(256) void k_sc_part(const float* __restrict__ xf,
    const float* __restrict__ wvec, float* __restrict__ part){
  int lb = blockIdx.x, xt = blockIdx.y, cs = blockIdx.z;
  __shared__ float wv[64];
  int t = threadIdx.x;
  if (t < 64) wv[t] = wvec[(size_t)lb*NC + cs*64 + t];
  __syncthreads();
  int x = xt*256 + t;
  if (x >= XX) return;
  const float* xb = xf + ((size_t)lb*NC + cs*64)*XX + x;
  float s = 0.f;
  #pragma unroll 8
  for (int c=0;c<64;c++) s += wv[c]*xb[(size_t)c*XX];
  part[((size_t)lb*4 + cs)*XX + x] = s;
}

__global__ __launch_bounds__(256) void k_xfout2(const float* __restrict__ xf,
    const float* __restrict__ part, const float* __restrict__ cb,
    const float* __restrict__ cues, float* __restrict__ out){
  int bc = blockIdx.y;
  int x = blockIdx.x*256 + threadIdx.x;
  if (x >= XX) return;
  int lb = bc >> 8;
  const float* pp = part + (size_t)lb*4*XX + x;
  float scv = pp[0] + pp[XX] + pp[2*XX] + pp[3*XX];
  scv = fminf(fmaxf((scv + cb[lb])*0.0625f, 0.f), 1.f);
  float cu = cues[bc];
  out[(size_t)bc*XX + x] = (1.f+cu)*xf[(size_t)bc*XX + x] - scv;
}

extern "C" void kernel_launch(void* const* d_in, const int* in_sizes, int n_in,
                              void* d_out, int out_size, void* d_ws, size_t ws_size,
                              hipStream_t stream){
  const float* zf      = (const float*)d_in[0];
  const float* xf      = (const float*)d_in[1];
  const float* maskp   = (const float*)d_in[2];
  const float* box     = (const float*)d_in[3];
  const float* nl_g_w  = (const float*)d_in[4];
  const float* nl_g_b  = (const float*)d_in[5];
  const float* nl_th_w = (const float*)d_in[6];
  const float* nl_th_b = (const float*)d_in[7];
  const float* nl_ph_w = (const float*)d_in[8];
  const float* nl_ph_b = (const float*)d_in[9];
  const float* nl_out_w= (const float*)d_in[10];
  const float* bn_g    = (const float*)d_in[11];
  const float* bn_b    = (const float*)d_in[12];
  const float* bn_m    = (const float*)d_in[13];
  const float* bn_v    = (const float*)d_in[14];
  const float* cz_th_w = (const float*)d_in[15];
  const float* cz_th_b = (const float*)d_in[16];
  const float* cz_ph_w = (const float*)d_in[17];
  const float* cz_ph_b = (const float*)d_in[18];
  const float* cz_gw   = (const float*)d_in[19];
  const float* cz_gb   = (const float*)d_in[20];
  const float* cz_aw   = (const float*)d_in[21];
  const float* cz_ab   = (const float*)d_in[22];
  const float* ap_w1   = (const float*)d_in[23];
  const float* ap_b1   = (const float*)d_in[24];
  const float* ap_w2   = (const float*)d_in[25];
  const float* ap_b2   = (const float*)d_in[26];
  const float* mp_w1   = (const float*)d_in[27];
  const float* mp_b1   = (const float*)d_in[28];
  const float* mp_w2   = (const float*)d_in[29];
  const float* mp_b2   = (const float*)d_in[30];
  const float* dr_w    = (const float*)d_in[31];
  const float* dr_b    = (const float*)d_in[32];
  const float* ac1_w   = (const float*)d_in[33];
  const float* ac1_b   = (const float*)d_in[34];
  const float* ac2_w   = (const float*)d_in[35];
  const float* ac2_b   = (const float*)d_in[36];
  const float* ac3_w   = (const float*)d_in[37];
  const float* ac3_b   = (const float*)d_in[38];
  const float* ac4_w   = (const float*)d_in[39];
  const float* ac4_b   = (const float*)d_in[40];
  const float* phi_w   = (const float*)d_in[41];
  const float* phi_b   = (const float*)d_in[42];
  const float* delta_w = (const float*)d_in[43];
  const float* delta_b = (const float*)d_in[44];
  (void)in_sizes; (void)n_in; (void)out_size; (void)ws_size;

  float* ws = (float*)d_ws;
  size_t off = 0;
  auto alloc = [&](size_t n){ size_t o = off; off += (n + 15) & ~(size_t)15; return o; };
  float* TH3f  = ws + alloc((size_t)NL*NB*ZZ*384/2);   // bf16 [225][384]
  float* Sb    = ws + alloc((size_t)NL*NB*ZZ*ZZ);      // fp32 scores
  u16* TH3  = (u16*)TH3f;
  // F fp32 [256][256]/lb spans TH3f+Sb (both dead by then); 9.0M >= 6.3M floats.
  float* Freg  = TH3f;
  float* zfTf  = ws + alloc((size_t)NL*NB*ZZ*NC/2);
  float* Pbf   = ws + alloc((size_t)NL*NB*ZZ*256/2);
  float* GXTf  = ws + alloc((size_t)NL*NB*128*256/2);
  float* Ybbf  = ws + alloc((size_t)NL*NB*ZZ*NC2/2);
  float* CZ3Tf = ws + alloc((size_t)NL*NB*512*64/2);
  float* roisTf= ws + alloc((size_t)NL*NB*49*NC/2);
  float* Wcatf = ws + alloc((size_t)NL*384*256/2);
  float* Wczf  = ws + alloc((size_t)NL*512*256/2);
  float* outwbf= ws + alloc((size_t)NL*NC*NC2/2);
  u16 *zfT=(u16*)zfTf, *Pb=(u16*)Pbf, *GXT=(u16*)GXTf, *Ybb=(u16*)Ybbf,
      *CZ3T=(u16*)CZ3Tf, *roisT=(u16*)roisTf, *Wcat=(u16*)Wcatf,
      *Wcz=(u16*)Wczf, *outwb=(u16*)outwbf;
  float* bcat = ws + alloc((size_t)NL*384);
  float* bcz  = ws + alloc((size_t)NL*512);
  float* m3   = ws + alloc((size_t)NL*NB*ZZ);
  float* pavg = ws + alloc((size_t)NL*NB*NC);
  float* pmax = ws + alloc((size_t)NL*NB*NC);
  float* zavg = ws + alloc((size_t)NL*NB*NC);
  float* zmax = ws + alloc((size_t)NL*NB*NC);
  float* cues = ws + alloc((size_t)NL*NB*NC);
  float* zm   = ws + alloc((size_t)NL*NB*NC);
  float* zphi = ws + alloc((size_t)NL*NB*NC);
  float* wvec = ws + alloc((size_t)NL*NB*NC);
  float* sm   = ws + alloc((size_t)NL*NB);
  float* cbuf = ws + alloc((size_t)NL*NB);
  float* part = ws + alloc((size_t)NL*NB*4*XX);
  float* hidb = ws + alloc((size_t)NL*NB*2*NC2);
  float* relb = ws + alloc((size_t)NL*NB*2*NC);

  float* outp    = (float*)d_out;
  float* o_zfout = outp;
  float* o_zffull= outp + (size_t)NL*NB*NC*49;
  float* o_xfout = o_zffull + (size_t)NL*NB*NC*ZZ;

  // ---- mask branch + packs + fused zf pass ----
  k_mask<<<NL*NB, 256, 0, stream>>>(maskp, ac1_w, ac1_b, ac2_w, ac2_b,
                                     ac3_w, ac3_b, ac4_w, ac4_b, m3);
  k_packs<<<(NL*512*256+255)/256, 256, 0, stream>>>(
      nl_th_w, nl_th_b, nl_ph_w, nl_ph_b, nl_g_w, nl_g_b,
      cz_th_w, cz_th_b, cz_ph_w, cz_ph_b, nl_out_w,
      Wcat, bcat, Wcz, bcz, outwb);
  k_zfall<<<dim3(NL*NB, 8), 256, 0, stream>>>(zf, box, m3, zfT, pavg, pmax,
                                               roisT, zm, sm);

  // ---- projections: TH3 = zfT @ Wcat^T ----
  k_mg<true,true,true,false><<<dim3(24, NL*NB), 256, 0, stream>>>(
      zfT, Wcat, bcat, TH3, ZZ, 384, NC, 256, 256, 384,
      (long)ZZ*256, (long)384*256, (long)ZZ*384, 6);
  // S = TH @ PH^T (fp32)
  k_mg<false,false,false,false><<<dim3(16, NL*NB), 256, 0, stream>>>(
      TH3, TH3+128, nullptr, Sb, ZZ, ZZ, NC2, 384, 384, ZZ,
      (long)ZZ*384, (long)ZZ*384, (long)ZZ*ZZ, 4);
  k_softmax<<<(NL*NB*ZZ)/4, 256, 0, stream>>>(Sb, Pb);
  k_gxt<<<dim3(NL*NB, 8), 256, 0, stream>>>(TH3, GXT);
  // Y = P @ GX (bf16 out [225][128])
  k_mg<false,false,true,false><<<dim3(8, NL*NB), 256, 0, stream>>>(
      Pb, GXT, nullptr, Ybb, ZZ, NC2, 256, 256, 256, NC2,
      (long)ZZ*256, (long)128*256, (long)ZZ*NC2, 2);

  // ---- cues chain ----
  k_mlp1<<<dim3(NL*NB, 2, 32), 256, 0, stream>>>(pavg, pmax, ap_w1, ap_b1, mp_w1, mp_b1, hidb);
  k_mlp2<<<dim3(NL*NB, 2, 64), 256, 0, stream>>>(hidb, ap_w2, ap_b2, mp_w2, mp_b2, zavg, zmax);
  k_mg<true,true,true,true><<<dim3(8, NL*NB), 256, 0, stream>>>(
      roisT, Wcz, bcz, CZ3T, 49, 512, NC, 256, 256, 64,
      (long)49*256, (long)512*256, (long)512*64, 8);
  k_mg<false,false,false,false><<<dim3(16, NL*NB), 256, 0, stream>>>(
      CZ3T, CZ3T+256*64, nullptr, Freg, NC, NC, 64, 64, 64, NC,
      (long)512*64, (long)512*64, (long)NC*NC, 4);
  k_relw<<<dim3(NL*NB, 128), 256, 0, stream>>>(Freg, cz_gw, cz_gb, relb);
  k_z2ncue<<<dim3(NL*NB, 64), 256, 0, stream>>>(relb, cz_aw, cz_ab,
                                                 zavg, zmax, dr_w, dr_b, cues);

  // ---- zf_full (+7x7 slice) ----
  k_outconv_m<<<dim3(16, NL*NB), 256, 0, stream>>>(outwb, Ybb, bn_g, bn_b, bn_m, bn_v,
                                                    cues, zf, o_zfout, o_zffull);

  // ---- collapsed sc branch + xf_out ----
  k_zphi<<<dim3(NL*NB, 64), 256, 0, stream>>>(zm, sm, phi_w, phi_b, zphi);
  k_wvec<<<NL*NB, 256, 0, stream>>>(zphi, delta_w, delta_b, wvec, cbuf);
  k_sc_part<<<dim3(NL*NB, 4, 4), 256, 0, stream>>>(xf, wvec, part);
  k_xfout2<<<dim3(4, NL*NB*NC), 256, 0, stream>>>(xf, part, cbuf, cues, o_xfout);
}

// Round 13
// 281.311 us; speedup vs baseline: 3.7507x; 1.1121x over previous
//
#include <hip/hip_runtime.h>
#include <math.h>

#define NL 3
#define NB 32
#define NC 256
#define NC2 128
#define HZ 15
#define ZZ 225
#define XX 961
#define HMD 127

typedef unsigned short u16;
typedef __attribute__((ext_vector_type(8))) unsigned short us8;
typedef __attribute__((ext_vector_type(8))) short bf8v;
typedef __attribute__((ext_vector_type(4))) float f4v;

__device__ __forceinline__ u16 f2bf(float f){
  unsigned int u = __float_as_uint(f);
  unsigned int r = (u + 0x7fffu + ((u>>16)&1u)) >> 16;
  return (u16)r;
}
__device__ __forceinline__ float hat_int(float u){
  if (u <= -1.f) return 0.f;
  if (u <= 0.f){ float t = u + 1.f; return 0.5f*t*t; }
  if (u <= 1.f){ float t = 1.f - u; return 1.f - 0.5f*t*t; }
  return 1.f;
}
__device__ __forceinline__ float dot4(float4 a, float4 b){
  return a.x*b.x + a.y*b.y + a.z*b.z + a.w*b.w;
}
__device__ __forceinline__ float wave_red(float s){
  #pragma unroll
  for (int off=32; off>0; off>>=1) s += __shfl_xor(s, off);
  return s;
}

// ================= role: fused mask branch (bid in [0,96)) =================
__device__ void d_mask(int lb, int t, const float* __restrict__ mask,
    const float* __restrict__ w1, const float* __restrict__ b1,
    const float* __restrict__ w2, const float* __restrict__ b2,
    const float* __restrict__ w3, const float* __restrict__ b3,
    const float* __restrict__ w4, const float* __restrict__ b4,
    float* __restrict__ m3out){
  int l = lb/NB, b = lb%NB;
  __shared__ float c1s[4][56][56];
  __shared__ float c2s[8][28][28];
  __shared__ float r1s[8][14][14];
  __shared__ float c3s[4][14][14];
  __shared__ float r2s[4][15][15];
  __shared__ int   y0t[14];
  __shared__ float wyt[14];
  __shared__ int   y0t15[15];
  __shared__ float wyt15[15];
  if (t < 14){
    float sy = 122.0f/13.0f;
    float yf = (float)t * sy;
    int y0 = (int)floorf(yf); y0 = min(max(y0,0), 121);
    y0t[t] = y0; wyt[t] = yf - (float)y0;
  } else if (t < 29){
    int q = t-14;
    float sy = 13.0f/14.0f;
    float yf = (float)q * sy;
    int y0 = (int)floorf(yf); y0 = min(max(y0,0), 12);
    y0t15[q] = y0; wyt15[q] = yf - (float)y0;
  }
  __syncthreads();
  const float* mb = mask + (size_t)b*HMD*HMD;
  const float* wc1 = w1 + (size_t)l*4*2*9;
  for (int e=t; e<4*56*56; e+=256){
    int ci = e % 56, ri = (e/56) % 56, oc = e/(56*56);
    int row = y0t[ri>>2] + (ri&3);
    int col = y0t[ci>>2] + (ci&3);
    float acc = b1[l*4+oc];
    #pragma unroll
    for (int ky=0;ky<3;ky++)
      #pragma unroll
      for (int kx=0;kx<3;kx++){
        float mv = mb[(row+ky)*HMD + (col+kx)];
        acc += wc1[((oc*2+0)*3+ky)*3+kx]*mv;
        acc += wc1[((oc*2+1)*3+ky)*3+kx]*(1.f-mv);
      }
    c1s[oc][ri][ci] = fmaxf(acc, 0.f);
  }
  __syncthreads();
  const float* wc2 = w2 + (size_t)l*8*4*9;
  for (int e=t; e<8*28*28; e+=256){
    int j = e % 28, i = (e/28) % 28, oc = e/(28*28);
    int g = i>>1, dy = i&1, gc = j>>1, dx = j&1;
    float acc = b2[l*8+oc];
    #pragma unroll
    for (int ic=0; ic<4; ic++)
      #pragma unroll
      for (int ky=0;ky<3;ky++)
        #pragma unroll
        for (int kx=0;kx<3;kx++)
          acc += wc2[((oc*4+ic)*3+ky)*3+kx]*c1s[ic][g*4+dy+ky][gc*4+dx+kx];
    c2s[oc][i][j] = fmaxf(acc, 0.f);
  }
  __syncthreads();
  for (int e=t; e<8*14*14; e+=256){
    int ox = e % 14, oy = (e/14) % 14, oc = e/(14*14);
    float wy = wyt[oy], wx = wyt[ox];
    float v00 = c2s[oc][2*oy][2*ox],   v01 = c2s[oc][2*oy][2*ox+1];
    float v10 = c2s[oc][2*oy+1][2*ox], v11 = c2s[oc][2*oy+1][2*ox+1];
    r1s[oc][oy][ox] = (v00*(1.f-wy)+v10*wy)*(1.f-wx) + (v01*(1.f-wy)+v11*wy)*wx;
  }
  __syncthreads();
  const float* wc3 = w3 + (size_t)l*4*8*9;
  for (int e=t; e<4*14*14; e+=256){
    int x = e % 14, y = (e/14) % 14, oc = e/(14*14);
    float acc = b3[l*4+oc];
    for (int ic=0; ic<8; ic++)
      #pragma unroll
      for (int ky=-1;ky<=1;ky++){
        int yy = y+ky; if (yy<0||yy>=14) continue;
        #pragma unroll
        for (int kx=-1;kx<=1;kx++){
          int xx = x+kx; if (xx<0||xx>=14) continue;
          acc += wc3[((oc*8+ic)*3+(ky+1))*3+(kx+1)]*r1s[ic][yy][xx];
        }
      }
    c3s[oc][y][x] = acc;
  }
  __syncthreads();
  for (int e=t; e<4*15*15; e+=256){
    int ox = e % 15, oy = (e/15) % 15, oc = e/(15*15);
    int y0 = y0t15[oy], x0 = y0t15[ox];
    float wy = wyt15[oy], wx = wyt15[ox];
    float v00 = c3s[oc][y0][x0],   v01 = c3s[oc][y0][x0+1];
    float v10 = c3s[oc][y0+1][x0], v11 = c3s[oc][y0+1][x0+1];
    r2s[oc][oy][ox] = (v00*(1.f-wy)+v10*wy)*(1.f-wx) + (v01*(1.f-wy)+v11*wy)*wx;
  }
  __syncthreads();
  const float* wc4 = w4 + (size_t)l*1*4*9;
  for (int e=t; e<15*15; e+=256){
    int x = e % 15, y = e/15;
    float acc = b4[l];
    #pragma unroll
    for (int ic=0; ic<4; ic++)
      #pragma unroll
      for (int ky=-1;ky<=1;ky++){
        int yy = y+ky; if (yy<0||yy>=15) continue;
        #pragma unroll
        for (int kx=-1;kx<=1;kx++){
          int xx = x+kx; if (xx<0||xx>=15) continue;
          acc += wc4[(ic*3+(ky+1))*3+(kx+1)]*r2s[ic][yy][xx];
        }
      }
    m3out[(size_t)lb*ZZ + y*15 + x] = acc;
  }
}

// ================= role: weight packs =================
__device__ void d_packs(int idx,
    const float* __restrict__ thw, const float* __restrict__ thb,
    const float* __restrict__ phw, const float* __restrict__ phb,
    const float* __restrict__ gw,  const float* __restrict__ gb,
    const float* __restrict__ czthw, const float* __restrict__ czthb,
    const float* __restrict__ czphw, const float* __restrict__ czphb,
    const float* __restrict__ outw,
    u16* __restrict__ Wcat, float* __restrict__ bcat,
    u16* __restrict__ Wcz, float* __restrict__ bcz,
    u16* __restrict__ outwb){
  if (idx < NL*384*256){
    int k = idx & 255; int r = (idx >> 8) % 384; int l = idx/(384*256);
    float v;
    if (r < 128)      v = thw[((size_t)l*128 + r)*256 + k];
    else if (r < 256) v = phw[((size_t)l*128 + (r-128))*256 + k];
    else              v = gw [((size_t)l*128 + (r-256))*256 + k];
    Wcat[idx] = f2bf(v);
  }
  if (idx < NL*512*256){
    int k = idx & 255; int r = (idx >> 8) % 512; int l = idx/(512*256);
    float v;
    if (r < 256) v = czthw[((size_t)l*256 + r)*256 + k];
    else         v = czphw[((size_t)l*256 + (r-256))*256 + k];
    Wcz[idx] = f2bf(v);
  }
  if (idx < NL*NC*NC2) outwb[idx] = f2bf(outw[idx]);
  if (idx < NL*384){
    int r = idx % 384, l = idx/384;
    bcat[idx] = (r<128) ? thb[l*128+r] : (r<256) ? phb[l*128+r-128] : gb[l*128+r-256];
  }
  if (idx < NL*512){
    int r = idx % 512, l = idx/512;
    bcz[idx] = (r<256) ? czthb[l*256+r] : czphb[l*256+r-256];
  }
}

__global__ __launch_bounds__(256) void sk_a(const float* __restrict__ mask,
    const float* w1, const float* b1, const float* w2, const float* b2,
    const float* w3, const float* b3, const float* w4, const float* b4,
    float* m3out,
    const float* thw, const float* thb, const float* phw, const float* phb,
    const float* gw, const float* gb,
    const float* czthw, const float* czthb, const float* czphw, const float* czphb,
    const float* outw, u16* Wcat, float* bcat, u16* Wcz, float* bcz, u16* outwb){
  int bid = blockIdx.x, t = threadIdx.x;
  if (bid < NL*NB){
    d_mask(bid, t, mask, w1, b1, w2, b2, w3, b3, w4, b4, m3out);
  } else {
    d_packs((bid - NL*NB)*256 + t, thw, thb, phw, phb, gw, gb,
            czthw, czthb, czphw, czphb, outw, Wcat, bcat, Wcz, bcz, outwb);
  }
}

// ============ fused zf pass (own launch, grid (96,8)) ============
__global__ __launch_bounds__(256) void k_zfall(const float* __restrict__ zf,
    const float* __restrict__ box, const float* __restrict__ m3,
    u16* __restrict__ zfT, float* __restrict__ pavg, float* __restrict__ pmax,
    u16* __restrict__ roisT, float* __restrict__ zm, float* __restrict__ sm){
  int lb = blockIdx.x; int b = lb % NB; int c0 = blockIdx.y*32;
  __shared__ float fld[32*ZZ];
  __shared__ float Wy[7][15], Wx[7][15];
  __shared__ float tmp[32][7][16];
  __shared__ float roi[32][49];
  __shared__ float ms[ZZ];
  __shared__ float area_s;
  int t = threadIdx.x;
  const float* bx = box + b*4;
  const float SC = 15.0f/127.0f;
  float x1 = bx[0]*SC, y1 = bx[1]*SC, x2 = bx[2]*SC, y2 = bx[3]*SC;
  float bh = (y2-y1)/7.f, bw = (x2-x1)/7.f;
  if (t < 105){ int p=t/15, i=t%15;
    Wy[p][i] = hat_int(y1+(float)(p+1)*bh - (float)i) - hat_int(y1+(float)p*bh - (float)i); }
  else if (t < 210){ int q=(t-105)/15, i=(t-105)%15;
    Wx[q][i] = hat_int(x1+(float)(q+1)*bw - (float)i) - hat_int(x1+(float)q*bw - (float)i); }
  if (t == 255) area_s = fmaxf(bh*bw, 1e-6f);
  if (t < ZZ) ms[t] = m3[(size_t)lb*ZZ + t];
  const float* src = zf + ((size_t)lb*NC + c0)*ZZ;
  for (int e=t; e<32*ZZ; e+=256) fld[e] = src[e];
  __syncthreads();
  u16* dstT = zfT + (size_t)lb*ZZ*NC + c0;
  for (int e=t; e<ZZ*32; e+=256){
    int ci = e & 31, z = e >> 5;
    dstT[(size_t)z*NC + ci] = f2bf(fld[ci*ZZ + z]);
  }
  float inv_area = 1.f/area_s;
  for (int e=t; e<32*105; e+=256){
    int w = e%15; int pc = e/15; int p = pc%7; int cc = pc/7;
    float s = 0.f;
    #pragma unroll
    for (int h=0;h<15;h++) s += Wy[p][h]*fld[cc*ZZ + h*15 + w];
    tmp[cc][p][w] = s;
  }
  {
    int cc = t>>3, sub = t&7;
    const float* fr = &fld[cc*ZZ];
    float s = 0.f;
    for (int z=sub; z<ZZ; z+=8) s += fr[z]*ms[z];
    s += __shfl_down(s, 4, 8);
    s += __shfl_down(s, 2, 8);
    s += __shfl_down(s, 1, 8);
    if (sub == 0) zm[(size_t)lb*NC + c0 + cc] = s;
  }
  if (blockIdx.y == 0 && t < 64){
    float ss = 0.f;
    for (int z=t; z<ZZ; z+=64) ss += ms[z];
    ss = wave_red(ss);
    if (t == 0) sm[lb] = ss;
  }
  __syncthreads();
  for (int e=t; e<32*49; e+=256){
    int q = e%7; int pc = e/7; int p = pc%7; int cc = pc/7;
    float s = 0.f;
    #pragma unroll
    for (int w=0;w<15;w++) s += tmp[cc][p][w]*Wx[q][w];
    roi[cc][p*7+q] = s*inv_area;
  }
  __syncthreads();
  u16* dR = roisT + (size_t)lb*49*NC + c0;
  for (int e=t; e<49*32; e+=256){
    int ci = e & 31, s = e >> 5;
    dR[(size_t)s*NC + ci] = f2bf(roi[ci][s]);
  }
  if (t < 32){
    float s = 0.f, m = -1e30f;
    #pragma unroll
    for (int i=0;i<49;i++){ float v = roi[t][i]; s += v; m = fmaxf(m,v); }
    pavg[(size_t)lb*NC + c0 + t] = s/49.f;
    pmax[(size_t)lb*NC + c0 + t] = m;
  }
}

// ================= role: bf16 MFMA GEMM (flattened bid) =================
template<bool BPERL, bool HASBIAS, bool OUTBF, bool TROUT>
__device__ void d_mg(int bid, int t,
    const u16* __restrict__ A0, const u16* __restrict__ B0,
    const float* __restrict__ bias0, void* __restrict__ O0,
    int M, int N, int K, int lda, int ldb, int ldo,
    long Ab, long Bb, long Ob, int ntn, int ntiles)
{
  int lb = bid / ntiles; int tile = bid % ntiles; int l = lb / NB;
  const u16* A = A0 + (size_t)lb*Ab;
  const u16* B = B0 + (BPERL ? (size_t)l : (size_t)lb)*Bb;
  int tm = tile / ntn, tn = tile % ntn;
  int m0 = tm*64, n0 = tn*64;
  __shared__ u16 Asl[64][40];
  __shared__ u16 Bsl[64][40];
  int w = t>>6, l6 = t&63;
  int fr = l6&15, kg = (l6>>4)*8;
  int srow = t>>2, sseg = (t&3)*8;
  f4v ac0={0,0,0,0}, ac1={0,0,0,0}, ac2={0,0,0,0}, ac3={0,0,0,0};
  for (int kc=0; kc<K; kc+=32){
    us8 va = {0,0,0,0,0,0,0,0};
    int am = m0 + srow;
    if (am < M) va = *(const us8*)&A[(size_t)am*lda + kc + sseg];
    *(us8*)&Asl[srow][sseg] = va;
    us8 vb = {0,0,0,0,0,0,0,0};
    int bn = n0 + srow;
    if (bn < N) vb = *(const us8*)&B[(size_t)bn*ldb + kc + sseg];
    *(us8*)&Bsl[srow][sseg] = vb;
    __syncthreads();
    bf8v af = *(const bf8v*)&Asl[w*16 + fr][kg];
    bf8v b0 = *(const bf8v*)&Bsl[fr][kg];
    bf8v b1 = *(const bf8v*)&Bsl[16+fr][kg];
    bf8v b2 = *(const bf8v*)&Bsl[32+fr][kg];
    bf8v b3 = *(const bf8v*)&Bsl[48+fr][kg];
    ac0 = __builtin_amdgcn_mfma_f32_16x16x32_bf16(af, b0, ac0, 0,0,0);
    ac1 = __builtin_amdgcn_mfma_f32_16x16x32_bf16(af, b1, ac1, 0,0,0);
    ac2 = __builtin_amdgcn_mfma_f32_16x16x32_bf16(af, b2, ac2, 0,0,0);
    ac3 = __builtin_amdgcn_mfma_f32_16x16x32_bf16(af, b3, ac3, 0,0,0);
    __syncthreads();
  }
  int mb = m0 + w*16 + ((l6>>4)<<2);
  #pragma unroll
  for (int j=0;j<4;j++){
    int n = n0 + j*16 + fr;
    if (n >= N) continue;
    float bv = HASBIAS ? bias0[(size_t)l*N + n] : 0.f;
    f4v a = (j==0)?ac0:(j==1)?ac1:(j==2)?ac2:ac3;
    #pragma unroll
    for (int r=0;r<4;r++){
      int m = mb + r;
      if (TROUT){
        u16* out = (u16*)O0 + (size_t)lb*Ob;
        out[(size_t)n*ldo + m] = f2bf((m<M) ? (a[r]+bv) : 0.f);
      } else if (m < M){
        if (OUTBF){
          u16* out = (u16*)O0 + (size_t)lb*Ob;
          out[(size_t)m*ldo + n] = f2bf(a[r]+bv);
        } else {
          float* out = (float*)O0 + (size_t)lb*Ob;
          out[(size_t)m*ldo + n] = a[r]+bv;
        }
      }
    }
  }
}

// ================= role: mlp1 =================
__device__ void d_mlp1(int bid, int t, const float* __restrict__ pavg, const float* __restrict__ pmax,
    const float* __restrict__ aw1, const float* __restrict__ ab1,
    const float* __restrict__ mw1, const float* __restrict__ mb1,
    float* __restrict__ hid){
  int lb = bid >> 6; int rem = bid & 63; int pass = rem >> 5; int zb = rem & 31;
  int l = lb/NB;
  int wid = t>>6, lane = t&63;
  int r = zb*4 + wid;
  const float* pv = pass ? pmax : pavg;
  const float* w1 = pass ? mw1 : aw1;
  const float* b1 = pass ? mb1 : ab1;
  const float* wr = w1 + (size_t)(l*NC2+r)*NC;
  const float* pr = pv + (size_t)lb*NC;
  float s = dot4(((const float4*)wr)[lane], ((const float4*)pr)[lane]);
  s = wave_red(s);
  if (lane==0) hid[((size_t)lb*2 + pass)*NC2 + r] = fmaxf(s + b1[l*NC2+r], 0.f);
}

// ================= role: zphi =================
__device__ void d_zphi(int bid, int t, const float* __restrict__ zm, const float* __restrict__ sm,
    const float* __restrict__ phiw, const float* __restrict__ phib, float* __restrict__ zphi){
  int lb = bid >> 6; int rb = bid & 63; int l = lb/NB;
  int wid = t>>6, lane = t&63;
  int r = rb*4 + wid;
  const float* wr = phiw + (size_t)(l*NC + r)*NC;
  const float* zr = zm + (size_t)lb*NC;
  float s = dot4(((const float4*)wr)[lane], ((const float4*)zr)[lane]);
  s = wave_red(s);
  if (lane==0) zphi[(size_t)lb*NC + r] = s + phib[l*NC + r]*sm[lb];
}

__global__ __launch_bounds__(256) void sk_b(
    const u16* zfT, const u16* Wcat, const float* bcat, u16* TH3,
    const float* pavg, const float* pmax,
    const float* ap_w1, const float* ap_b1, const float* mp_w1, const float* mp_b1, float* hidb,
    const u16* roisT, const u16* Wcz, const float* bcz, u16* CZ3T,
    const float* zm, const float* sm, const float* phi_w, const float* phi_b, float* zphi){
  int bid = blockIdx.x, t = threadIdx.x;
  const int N1 = 96*24, N2 = N1 + 96*64, N3 = N2 + 96*8;
  if (bid < N1){
    d_mg<true,true,true,false>(bid, t, zfT, Wcat, bcat, TH3, ZZ, 384, NC, 256, 256, 384,
        (long)ZZ*256, (long)384*256, (long)ZZ*384, 6, 24);
  } else if (bid < N2){
    d_mlp1(bid - N1, t, pavg, pmax, ap_w1, ap_b1, mp_w1, mp_b1, hidb);
  } else if (bid < N3){
    d_mg<true,true,true,true>(bid - N2, t, roisT, Wcz, bcz, CZ3T, 49, 512, NC, 256, 256, 64,
        (long)49*256, (long)512*256, (long)512*64, 8, 8);
  } else {
    d_zphi(bid - N3, t, zm, sm, phi_w, phi_b, zphi);
  }
}

// ================= role: gxt =================
__device__ void d_gxt(int bid, int t, const u16* __restrict__ TH3, u16* __restrict__ GXT){
  int lb = bid >> 3; int z0 = (bid & 7)*32;
  __shared__ u16 lds[32][130];
  int n = t & 127, zi = t >> 7;
  const u16* src = TH3 + (size_t)lb*ZZ*384 + 256;
  #pragma unroll
  for (int p=0;p<16;p++){
    int z = z0 + zi + p*2;
    lds[zi+p*2][n] = (z < ZZ) ? src[(size_t)z*384 + n] : (u16)0;
  }
  __syncthreads();
  u16* dst = GXT + (size_t)lb*128*256;
  int zi2 = t & 31, ni = t >> 5;
  #pragma unroll
  for (int p=0;p<16;p++){
    int nn = ni + p*8;
    dst[(size_t)nn*256 + z0 + zi2] = lds[zi2][nn];
  }
}

// ================= role: mlp2 =================
__device__ void d_mlp2(int bid, int t, const float* __restrict__ hid,
    const float* __restrict__ aw2, const float* __restrict__ ab2,
    const float* __restrict__ mw2, const float* __restrict__ mb2,
    float* __restrict__ zavg, float* __restrict__ zmax){
  int lb = bid >> 7; int rem = bid & 127; int pass = rem >> 6; int cb = rem & 63;
  int l = lb/NB;
  int wid = t>>6, lane = t&63;
  int c = cb*4 + wid;
  const float* w2 = pass ? mw2 : aw2;
  const float* b2 = pass ? mb2 : ab2;
  const float* wr = w2 + (size_t)(l*NC+c)*NC2;
  const float* hr = hid + ((size_t)lb*2 + pass)*NC2;
  float2 wv = ((const float2*)wr)[lane];
  float2 hv = ((const float2*)hr)[lane];
  float s = wave_red(wv.x*hv.x + wv.y*hv.y);
  if (lane==0){
    float* zo = pass ? zmax : zavg;
    zo[(size_t)lb*NC + c] = s + b2[l*NC+c];
  }
}

// ================= role: wvec =================
__device__ void d_wvec(int lb, int t, const float* __restrict__ zphi, const float* __restrict__ dw,
    const float* __restrict__ db, float* __restrict__ wvec, float* __restrict__ cb){
  int l = lb/NB;
  __shared__ float zp[NC];
  __shared__ float red[NC];
  zp[t] = zphi[(size_t)lb*NC + t];
  __syncthreads();
  float s = 0.f;
  const float* dwl = dw + (size_t)l*NC*NC;
  for (int c=0;c<NC;c++) s += zp[c]*dwl[(size_t)c*NC + t];
  wvec[(size_t)lb*NC + t] = s;
  red[t] = zp[t]*db[l*NC + t];
  __syncthreads();
  for (int off2=128; off2>0; off2>>=1){
    if (t < off2) red[t] += red[t+off2];
    __syncthreads();
  }
  if (t==0) cb[lb] = red[0];
}

__global__ __launch_bounds__(256) void sk_c(
    const u16* TH3, float* Sb,
    u16* GXT,
    const float* hidb, const float* ap_w2, const float* ap_b2,
    const float* mp_w2, const float* mp_b2, float* zavg, float* zmax,
    const u16* CZ3T, float* Fbuf,
    const float* zphi, const float* delta_w, const float* delta_b, float* wvec, float* cbuf){
  int bid = blockIdx.x, t = threadIdx.x;
  const int N1 = 96*16, N2 = N1 + 96*8, N3 = N2 + 96*128, N4 = N3 + 96*16;
  if (bid < N1){
    d_mg<false,false,false,false>(bid, t, TH3, TH3+128, nullptr, Sb, ZZ, ZZ, NC2, 384, 384, ZZ,
        (long)ZZ*384, (long)ZZ*384, (long)ZZ*ZZ, 4, 16);
  } else if (bid < N2){
    d_gxt(bid - N1, t, TH3, GXT);
  } else if (bid < N3){
    d_mlp2(bid - N2, t, hidb, ap_w2, ap_b2, mp_w2, mp_b2, zavg, zmax);
  } else if (bid < N4){
    d_mg<false,false,false,false>(bid - N3, t, CZ3T, CZ3T+256*64, nullptr, Fbuf, NC, NC, 64, 64, 64, NC,
        (long)512*64, (long)512*64, (long)NC*NC, 4, 16);
  } else {
    d_wvec(bid - N4, t, zphi, delta_w, delta_b, wvec, cbuf);
  }
}

// ================= role: sc partial =================
__device__ void d_sc_part(int bid, int t, const float* __restrict__ xf,
    const float* __restrict__ wvec, float* __restrict__ part){
  int lb = bid >> 4; int rem = bid & 15; int xt = rem >> 2, cs = rem & 3;
  __shared__ float wv[64];
  if (t < 64) wv[t] = wvec[(size_t)lb*NC + cs*64 + t];
  __syncthreads();
  int x = xt*256 + t;
  if (x >= XX) return;
  const float* xb = xf + ((size_t)lb*NC + cs*64)*XX + x;
  float s = 0.f;
  #pragma unroll 8
  for (int c=0;c<64;c++) s += wv[c]*xb[(size_t)c*XX];
  part[((size_t)lb*4 + cs)*XX + x] = s;
}

// ================= role: softmax =================
__device__ void d_softmax(int bid, int t, const float* __restrict__ S, u16* __restrict__ P){
  int row = bid*4 + (t >> 6);
  int lane = t & 63;
  const float* r = S + (size_t)row*ZZ;
  float v[4]; float mx = -1e30f;
  #pragma unroll
  for (int q=0;q<4;q++){
    int j = lane + q*64;
    v[q] = (j<ZZ) ? r[j] : -1e30f;
    mx = fmaxf(mx, v[q]);
  }
  #pragma unroll
  for (int off=32; off>0; off>>=1) mx = fmaxf(mx, __shfl_xor(mx, off));
  float sum = 0.f;
  #pragma unroll
  for (int q=0;q<4;q++){
    v[q] = __expf(v[q]-mx);
    if (lane + q*64 < ZZ) sum += v[q];
  }
  #pragma unroll
  for (int off=32; off>0; off>>=1) sum += __shfl_xor(sum, off);
  float inv = 1.f/(16.f*sum);
  u16* pr = P + (size_t)row*256;
  #pragma unroll
  for (int q=0;q<4;q++){
    int j = lane + q*64;
    pr[j] = (j<ZZ) ? f2bf(v[q]*inv) : (u16)0;
  }
}

// ================= role: relw =================
__device__ void d_relw(int bid, int t, const float* __restrict__ F,
    const float* __restrict__ gw, const float* __restrict__ gb,
    float* __restrict__ rel){
  int lb = bid >> 7; int rb = bid & 127; int l = lb/NB;
  int wid = t>>6, lane = t&63;
  int r = rb*4 + wid;
  const float* wrow = gw + ((size_t)l*2*NC + r)*NC;
  const float* frow = F + (size_t)lb*NC*NC + (size_t)(r>>1)*NC;
  float s = dot4(((const float4*)wrow)[lane], ((const float4*)frow)[lane]);
  s = wave_red(s);
  if (lane==0) rel[(size_t)lb*2*NC + r] = fmaxf(s + gb[l*2*NC+r], 0.f);
}

__global__ __launch_bounds__(256) void sk_d(
    const float* xf, const float* wvec, float* part,
    const float* Sb, u16* Pb,
    const float* Fbuf, const float* cz_gw, const float* cz_gb, float* relb){
  int bid = blockIdx.x, t = threadIdx.x;
  const int N1 = 96*16, N2 = N1 + 5400;
  if (bid < N1){
    d_sc_part(bid, t, xf, wvec, part);
  } else if (bid < N2){
    d_softmax(bid - N1, t, Sb, Pb);
  } else {
    d_relw(bid - N2, t, Fbuf, cz_gw, cz_gb, relb);
  }
}

// ================= role: z2n+cues =================
__device__ void d_z2ncue(int bid, int t, const float* __restrict__ rel,
    const float* __restrict__ aw, const float* __restrict__ ab,
    const float* __restrict__ zavg, const float* __restrict__ zmax,
    const float* __restrict__ drw, const float* __restrict__ drb,
    float* __restrict__ cues){
  int lb = bid >> 6; int cb = bid & 63; int l = lb/NB;
  int wid = t>>6, lane = t&63;
  int c = cb*4 + wid;
  const float* arow = aw + ((size_t)l*NC + c)*2*NC;
  const float* rrow = rel + (size_t)lb*2*NC;
  float s = dot4(((const float4*)arow)[lane],    ((const float4*)rrow)[lane])
          + dot4(((const float4*)arow)[lane+64], ((const float4*)rrow)[lane+64]);
  s = wave_red(s);
  if (lane==0){
    float z2 = s + ab[l*NC+c];
    size_t idx = (size_t)lb*NC + c;
    const float* dw = drw + (size_t)(l*NC + c)*3;
    float x = dw[0]*zavg[idx] + dw[1]*zmax[idx] + dw[2]*z2 + drb[l*NC+c];
    cues[idx] = 1.f/(1.f + __expf(-x));
  }
}

__global__ __launch_bounds__(256) void sk_e(
    const u16* Pb, const u16* GXT, u16* Ybb,
    const float* relb, const float* cz_aw, const float* cz_ab,
    const float* zavg, const float* zmax, const float* dr_w, const float* dr_b, float* cues){
  int bid = blockIdx.x, t = threadIdx.x;
  const int N1 = 96*8;
  if (bid < N1){
    d_mg<false,false,true,false>(bid, t, Pb, GXT, nullptr, Ybb, ZZ, NC2, 256, 256, 256, NC2,
        (long)ZZ*256, (long)128*256, (long)ZZ*NC2, 2, 8);
  } else {
    d_z2ncue(bid - N1, t, relb, cz_aw, cz_ab, zavg, zmax, dr_w, dr_b, cues);
  }
}

// ================= role: outconv =================
__device__ void d_outconv(int bid, int t, const u16* __restrict__ outwb,
    const u16* __restrict__ Ybb,
    const float* __restrict__ bng, const float* __restrict__ bnb,
    const float* __restrict__ bnm, const float* __restrict__ bnv,
    const float* __restrict__ cues, const float* __restrict__ zf,
    float* __restrict__ dzfout, float* __restrict__ dzffull){
  int lb = bid >> 4; int tile = bid & 15; int l = lb/NB;
  const u16* A = outwb + (size_t)l*NC*NC2;
  const u16* B = Ybb + (size_t)lb*ZZ*NC2;
  int tm = tile >> 2, tn = tile & 3;
  int m0 = tm*64, n0 = tn*64;
  __shared__ u16 Asl[64][40];
  __shared__ u16 Bsl[64][40];
  int w = t>>6, l6 = t&63;
  int fr = l6&15, kg = (l6>>4)*8;
  int srow = t>>2, sseg = (t&3)*8;
  f4v ac0={0,0,0,0}, ac1={0,0,0,0}, ac2={0,0,0,0}, ac3={0,0,0,0};
  for (int kc=0; kc<NC2; kc+=32){
    us8 va = *(const us8*)&A[(size_t)(m0+srow)*NC2 + kc + sseg];
    *(us8*)&Asl[srow][sseg] = va;
    us8 vb = {0,0,0,0,0,0,0,0};
    int bn = n0 + srow;
    if (bn < ZZ) vb = *(const us8*)&B[(size_t)bn*NC2 + kc + sseg];
    *(us8*)&Bsl[srow][sseg] = vb;
    __syncthreads();
    bf8v af = *(const bf8v*)&Asl[w*16 + fr][kg];
    bf8v b0 = *(const bf8v*)&Bsl[fr][kg];
    bf8v b1 = *(const bf8v*)&Bsl[16+fr][kg];
    bf8v b2 = *(const bf8v*)&Bsl[32+fr][kg];
    bf8v b3 = *(const bf8v*)&Bsl[48+fr][kg];
    ac0 = __builtin_amdgcn_mfma_f32_16x16x32_bf16(af, b0, ac0, 0,0,0);
    ac1 = __builtin_amdgcn_mfma_f32_16x16x32_bf16(af, b1, ac1, 0,0,0);
    ac2 = __builtin_amdgcn_mfma_f32_16x16x32_bf16(af, b2, ac2, 0,0,0);
    ac3 = __builtin_amdgcn_mfma_f32_16x16x32_bf16(af, b3, ac3, 0,0,0);
    __syncthreads();
  }
  int mb = m0 + w*16 + ((l6>>4)<<2);
  #pragma unroll
  for (int j=0;j<4;j++){
    int z = n0 + j*16 + fr;
    if (z >= ZZ) continue;
    int h = z/15, wv2 = z%15;
    f4v a = (j==0)?ac0:(j==1)?ac1:(j==2)?ac2:ac3;
    #pragma unroll
    for (int r=0;r<4;r++){
      int c = mb + r;
      float scale = bng[l*NC+c] * rsqrtf(bnv[l*NC+c] + 1e-5f);
      float val = (a[r] - bnm[l*NC+c])*scale + bnb[l*NC+c];
      float cu = cues[(size_t)lb*NC + c];
      float zv = zf[((size_t)lb*NC + c)*ZZ + z];
      float rr = cu*zv + zv + val;
      dzffull[((size_t)lb*NC + c)*ZZ + z] = rr;
      if (h>=4 && h<11 && wv2>=4 && wv2<11)
        dzfout[((size_t)lb*NC + c)*49 + (h-4)*7 + (wv2-4)] = rr;
    }
  }
}

// ================= role: xfout =================
__device__ void d_xfout(int bid, int t, const float* __restrict__ xf,
    const float* __restrict__ part, const float* __restrict__ cb,
    const float* __restrict__ cues, float* __restrict__ out){
  int bc = bid >> 2; int xt = bid & 3;
  int x = xt*256 + t;
  if (x >= XX) return;
  int lb = bc >> 8;
  const float* pp = part + (size_t)lb*4*XX + x;
  float scv = pp[0] + pp[XX] + pp[2*XX] + pp[3*XX];
  scv = fminf(fmaxf((scv + cb[lb])*0.0625f, 0.f), 1.f);
  float cu = cues[bc];
  out[(size_t)bc*XX + x] = (1.f+cu)*xf[(size_t)bc*XX + x] - scv;
}

__global__ __launch_bounds__(256) void sk_f(
    const u16* outwb, const u16* Ybb,
    const float* bn_g, const float* bn_b, const float* bn_m, const float* bn_v,
    const float* cues, const float* zf, float* o_zfout, float* o_zffull,
    const float* xf, const float* part, const float* cbuf, float* o_xfout){
  int bid = blockIdx.x, t = threadIdx.x;
  const int N1 = 96*16;
  if (bid < N1){
    d_outconv(bid, t, outwb, Ybb, bn_g, bn_b, bn_m, bn_v, cues, zf, o_zfout, o_zffull);
  } else {
    d_xfout(bid - N1, t, xf, part, cbuf, cues, o_xfout);
  }
}

extern "C" void kernel_launch(void* const* d_in, const int* in_sizes, int n_in,
                              void* d_out, int out_size, void* d_ws, size_t ws_size,
                              hipStream_t stream){
  const float* zf      = (const float*)d_in[0];
  const float* xf      = (const float*)d_in[1];
  const float* maskp   = (const float*)d_in[2];
  const float* box     = (const float*)d_in[3];
  const float* nl_g_w  = (const float*)d_in[4];
  const float* nl_g_b  = (const float*)d_in[5];
  const float* nl_th_w = (const float*)d_in[6];
  const float* nl_th_b = (const float*)d_in[7];
  const float* nl_ph_w = (const float*)d_in[8];
  const float* nl_ph_b = (const float*)d_in[9];
  const float* nl_out_w= (const float*)d_in[10];
  const float* bn_g    = (const float*)d_in[11];
  const float* bn_b    = (const float*)d_in[12];
  const float* bn_m    = (const float*)d_in[13];
  const float* bn_v    = (const float*)d_in[14];
  const float* cz_th_w = (const float*)d_in[15];
  const float* cz_th_b = (const float*)d_in[16];
  const float* cz_ph_w = (const float*)d_in[17];
  const float* cz_ph_b = (const float*)d_in[18];
  const float* cz_gw   = (const float*)d_in[19];
  const float* cz_gb   = (const float*)d_in[20];
  const float* cz_aw   = (const float*)d_in[21];
  const float* cz_ab   = (const float*)d_in[22];
  const float* ap_w1   = (const float*)d_in[23];
  const float* ap_b1   = (const float*)d_in[24];
  const float* ap_w2   = (const float*)d_in[25];
  const float* ap_b2   = (const float*)d_in[26];
  const float* mp_w1   = (const float*)d_in[27];
  const float* mp_b1   = (const float*)d_in[28];
  const float* mp_w2   = (const float*)d_in[29];
  const float* mp_b2   = (const float*)d_in[30];
  const float* dr_w    = (const float*)d_in[31];
  const float* dr_b    = (const float*)d_in[32];
  const float* ac1_w   = (const float*)d_in[33];
  const float* ac1_b   = (const float*)d_in[34];
  const float* ac2_w   = (const float*)d_in[35];
  const float* ac2_b   = (const float*)d_in[36];
  const float* ac3_w   = (const float*)d_in[37];
  const float* ac3_b   = (const float*)d_in[38];
  const float* ac4_w   = (const float*)d_in[39];
  const float* ac4_b   = (const float*)d_in[40];
  const float* phi_w   = (const float*)d_in[41];
  const float* phi_b   = (const float*)d_in[42];
  const float* delta_w = (const float*)d_in[43];
  const float* delta_b = (const float*)d_in[44];
  (void)in_sizes; (void)n_in; (void)out_size; (void)ws_size;

  float* ws = (float*)d_ws;
  size_t off = 0;
  auto alloc = [&](size_t n){ size_t o = off; off += (n + 15) & ~(size_t)15; return o; };
  float* TH3f  = ws + alloc((size_t)NL*NB*ZZ*384/2);
  float* Sb    = ws + alloc((size_t)NL*NB*ZZ*ZZ);
  float* Fbuf  = ws + alloc((size_t)NL*NB*NC*NC);     // dedicated (no aliasing: written same launch as Sb/TH3 reads)
  float* zfTf  = ws + alloc((size_t)NL*NB*ZZ*NC/2);
  float* Pbf   = ws + alloc((size_t)NL*NB*ZZ*256/2);
  float* GXTf  = ws + alloc((size_t)NL*NB*128*256/2);
  float* Ybbf  = ws + alloc((size_t)NL*NB*ZZ*NC2/2);
  float* CZ3Tf = ws + alloc((size_t)NL*NB*512*64/2);
  float* roisTf= ws + alloc((size_t)NL*NB*49*NC/2);
  float* Wcatf = ws + alloc((size_t)NL*384*256/2);
  float* Wczf  = ws + alloc((size_t)NL*512*256/2);
  float* outwbf= ws + alloc((size_t)NL*NC*NC2/2);
  u16* TH3  = (u16*)TH3f;
  u16 *zfT=(u16*)zfTf, *Pb=(u16*)Pbf, *GXT=(u16*)GXTf, *Ybb=(u16*)Ybbf,
      *CZ3T=(u16*)CZ3Tf, *roisT=(u16*)roisTf, *Wcat=(u16*)Wcatf,
      *Wcz=(u16*)Wczf, *outwb=(u16*)outwbf;
  float* bcat = ws + alloc((size_t)NL*384);
  float* bcz  = ws + alloc((size_t)NL*512);
  float* m3   = ws + alloc((size_t)NL*NB*ZZ);
  float* pavg = ws + alloc((size_t)NL*NB*NC);
  float* pmax = ws + alloc((size_t)NL*NB*NC);
  float* zavg = ws + alloc((size_t)NL*NB*NC);
  float* zmax = ws + alloc((size_t)NL*NB*NC);
  float* cues = ws + alloc((size_t)NL*NB*NC);
  float* zm   = ws + alloc((size_t)NL*NB*NC);
  float* zphi = ws + alloc((size_t)NL*NB*NC);
  float* wvec = ws + alloc((size_t)NL*NB*NC);
  float* sm   = ws + alloc((size_t)NL*NB);
  float* cbuf = ws + alloc((size_t)NL*NB);
  float* part = ws + alloc((size_t)NL*NB*4*XX);
  float* hidb = ws + alloc((size_t)NL*NB*2*NC2);
  float* relb = ws + alloc((size_t)NL*NB*2*NC);

  float* outp    = (float*)d_out;
  float* o_zfout = outp;
  float* o_zffull= outp + (size_t)NL*NB*NC*49;
  float* o_xfout = o_zffull + (size_t)NL*NB*NC*ZZ;

  // L1: mask + packs
  sk_a<<<NL*NB + (NL*512*256+255)/256, 256, 0, stream>>>(
      maskp, ac1_w, ac1_b, ac2_w, ac2_b, ac3_w, ac3_b, ac4_w, ac4_b, m3,
      nl_th_w, nl_th_b, nl_ph_w, nl_ph_b, nl_g_w, nl_g_b,
      cz_th_w, cz_th_b, cz_ph_w, cz_ph_b, nl_out_w,
      Wcat, bcat, Wcz, bcz, outwb);
  // L2: fused zf pass
  k_zfall<<<dim3(NL*NB, 8), 256, 0, stream>>>(zf, box, m3, zfT, pavg, pmax,
                                               roisT, zm, sm);
  // L3: projcat + mlp1 + CZ + zphi
  sk_b<<<96*24 + 96*64 + 96*8 + 96*64, 256, 0, stream>>>(
      zfT, Wcat, bcat, TH3, pavg, pmax, ap_w1, ap_b1, mp_w1, mp_b1, hidb,
      roisT, Wcz, bcz, CZ3T, zm, sm, phi_w, phi_b, zphi);
  // L4: S + gxt + mlp2 + F + wvec
  sk_c<<<96*16 + 96*8 + 96*128 + 96*16 + 96, 256, 0, stream>>>(
      TH3, Sb, GXT, hidb, ap_w2, ap_b2, mp_w2, mp_b2, zavg, zmax,
      CZ3T, Fbuf, zphi, delta_w, delta_b, wvec, cbuf);
  // L5: sc_part + softmax + relw
  sk_d<<<96*16 + 5400 + 96*128, 256, 0, stream>>>(
      xf, wvec, part, Sb, Pb, Fbuf, cz_gw, cz_gb, relb);
  // L6: PV + z2ncue
  sk_e<<<96*8 + 96*64, 256, 0, stream>>>(
      Pb, GXT, Ybb, relb, cz_aw, cz_ab, zavg, zmax, dr_w, dr_b, cues);
  // L7: outconv + xfout
  sk_f<<<96*16 + 4*NL*NB*NC, 256, 0, stream>>>(
      outwb, Ybb, bn_g, bn_b, bn_m, bn_v, cues, zf, o_zfout, o_zffull,
      xf, part, cbuf, o_xfout);
}

// Round 15
// 270.781 us; speedup vs baseline: 3.8965x; 1.0389x over previous
//
#include <hip/hip_runtime.h>
#include <math.h>

#define NL 3
#define NB 32
#define NC 256
#define NC2 128
#define HZ 15
#define ZZ 225
#define XX 961
#define HMD 127

typedef unsigned short u16;
typedef __attribute__((ext_vector_type(8))) unsigned short us8;
typedef __attribute__((ext_vector_type(8))) short bf8v;
typedef __attribute__((ext_vector_type(4))) float f4v;

__device__ __forceinline__ u16 f2bf(float f){
  unsigned int u = __float_as_uint(f);
  unsigned int r = (u + 0x7fffu + ((u>>16)&1u)) >> 16;
  return (u16)r;
}
__device__ __forceinline__ float hat_int(float u){
  if (u <= -1.f) return 0.f;
  if (u <= 0.f){ float t = u + 1.f; return 0.5f*t*t; }
  if (u <= 1.f){ float t = 1.f - u; return 1.f - 0.5f*t*t; }
  return 1.f;
}
__device__ __forceinline__ float dot4(float4 a, float4 b){
  return a.x*b.x + a.y*b.y + a.z*b.z + a.w*b.w;
}
__device__ __forceinline__ float wave_red(float s){
  #pragma unroll
  for (int off=32; off>0; off>>=1) s += __shfl_xor(s, off);
  return s;
}

// ================= role: fused mask branch (bid in [0,96)) =================
__device__ void d_mask(int lb, int t, const float* __restrict__ mask,
    const float* __restrict__ w1, const float* __restrict__ b1,
    const float* __restrict__ w2, const float* __restrict__ b2,
    const float* __restrict__ w3, const float* __restrict__ b3,
    const float* __restrict__ w4, const float* __restrict__ b4,
    float* __restrict__ m3out){
  int l = lb/NB, b = lb%NB;
  __shared__ float c1s[4][56][56];
  __shared__ float c2s[8][28][28];
  __shared__ float r1s[8][14][14];
  __shared__ float c3s[4][14][14];
  __shared__ float r2s[4][15][15];
  __shared__ int   y0t[14];
  __shared__ float wyt[14];
  __shared__ int   y0t15[15];
  __shared__ float wyt15[15];
  if (t < 14){
    float sy = 122.0f/13.0f;
    float yf = (float)t * sy;
    int y0 = (int)floorf(yf); y0 = min(max(y0,0), 121);
    y0t[t] = y0; wyt[t] = yf - (float)y0;
  } else if (t < 29){
    int q = t-14;
    float sy = 13.0f/14.0f;
    float yf = (float)q * sy;
    int y0 = (int)floorf(yf); y0 = min(max(y0,0), 12);
    y0t15[q] = y0; wyt15[q] = yf - (float)y0;
  }
  __syncthreads();
  const float* mb = mask + (size_t)b*HMD*HMD;
  const float* wc1 = w1 + (size_t)l*4*2*9;
  for (int e=t; e<4*56*56; e+=256){
    int ci = e % 56, ri = (e/56) % 56, oc = e/(56*56);
    int row = y0t[ri>>2] + (ri&3);
    int col = y0t[ci>>2] + (ci&3);
    float acc = b1[l*4+oc];
    #pragma unroll
    for (int ky=0;ky<3;ky++)
      #pragma unroll
      for (int kx=0;kx<3;kx++){
        float mv = mb[(row+ky)*HMD + (col+kx)];
        acc += wc1[((oc*2+0)*3+ky)*3+kx]*mv;
        acc += wc1[((oc*2+1)*3+ky)*3+kx]*(1.f-mv);
      }
    c1s[oc][ri][ci] = fmaxf(acc, 0.f);
  }
  __syncthreads();
  const float* wc2 = w2 + (size_t)l*8*4*9;
  for (int e=t; e<8*28*28; e+=256){
    int j = e % 28, i = (e/28) % 28, oc = e/(28*28);
    int g = i>>1, dy = i&1, gc = j>>1, dx = j&1;
    float acc = b2[l*8+oc];
    #pragma unroll
    for (int ic=0; ic<4; ic++)
      #pragma unroll
      for (int ky=0;ky<3;ky++)
        #pragma unroll
        for (int kx=0;kx<3;kx++)
          acc += wc2[((oc*4+ic)*3+ky)*3+kx]*c1s[ic][g*4+dy+ky][gc*4+dx+kx];
    c2s[oc][i][j] = fmaxf(acc, 0.f);
  }
  __syncthreads();
  for (int e=t; e<8*14*14; e+=256){
    int ox = e % 14, oy = (e/14) % 14, oc = e/(14*14);
    float wy = wyt[oy], wx = wyt[ox];
    float v00 = c2s[oc][2*oy][2*ox],   v01 = c2s[oc][2*oy][2*ox+1];
    float v10 = c2s[oc][2*oy+1][2*ox], v11 = c2s[oc][2*oy+1][2*ox+1];
    r1s[oc][oy][ox] = (v00*(1.f-wy)+v10*wy)*(1.f-wx) + (v01*(1.f-wy)+v11*wy)*wx;
  }
  __syncthreads();
  const float* wc3 = w3 + (size_t)l*4*8*9;
  for (int e=t; e<4*14*14; e+=256){
    int x = e % 14, y = (e/14) % 14, oc = e/(14*14);
    float acc = b3[l*4+oc];
    for (int ic=0; ic<8; ic++)
      #pragma unroll
      for (int ky=-1;ky<=1;ky++){
        int yy = y+ky; if (yy<0||yy>=14) continue;
        #pragma unroll
        for (int kx=-1;kx<=1;kx++){
          int xx = x+kx; if (xx<0||xx>=14) continue;
          acc += wc3[((oc*8+ic)*3+(ky+1))*3+(kx+1)]*r1s[ic][yy][xx];
        }
      }
    c3s[oc][y][x] = acc;
  }
  __syncthreads();
  for (int e=t; e<4*15*15; e+=256){
    int ox = e % 15, oy = (e/15) % 15, oc = e/(15*15);
    int y0 = y0t15[oy], x0 = y0t15[ox];
    float wy = wyt15[oy], wx = wyt15[ox];
    float v00 = c3s[oc][y0][x0],   v01 = c3s[oc][y0][x0+1];
    float v10 = c3s[oc][y0+1][x0], v11 = c3s[oc][y0+1][x0+1];
    r2s[oc][oy][ox] = (v00*(1.f-wy)+v10*wy)*(1.f-wx) + (v01*(1.f-wy)+v11*wy)*wx;
  }
  __syncthreads();
  const float* wc4 = w4 + (size_t)l*1*4*9;
  for (int e=t; e<15*15; e+=256){
    int x = e % 15, y = e/15;
    float acc = b4[l];
    #pragma unroll
    for (int ic=0; ic<4; ic++)
      #pragma unroll
      for (int ky=-1;ky<=1;ky++){
        int yy = y+ky; if (yy<0||yy>=15) continue;
        #pragma unroll
        for (int kx=-1;kx<=1;kx++){
          int xx = x+kx; if (xx<0||xx>=15) continue;
          acc += wc4[(ic*3+(ky+1))*3+(kx+1)]*r2s[ic][yy][xx];
        }
      }
    m3out[(size_t)lb*ZZ + y*15 + x] = acc;
  }
}

// ================= role: weight packs =================
__device__ void d_packs(int idx,
    const float* __restrict__ thw, const float* __restrict__ thb,
    const float* __restrict__ phw, const float* __restrict__ phb,
    const float* __restrict__ gw,  const float* __restrict__ gb,
    const float* __restrict__ czthw, const float* __restrict__ czthb,
    const float* __restrict__ czphw, const float* __restrict__ czphb,
    const float* __restrict__ outw,
    u16* __restrict__ Wcat, float* __restrict__ bcat,
    u16* __restrict__ Wcz, float* __restrict__ bcz,
    u16* __restrict__ outwb){
  if (idx < NL*384*256){
    int k = idx & 255; int r = (idx >> 8) % 384; int l = idx/(384*256);
    float v;
    if (r < 128)      v = thw[((size_t)l*128 + r)*256 + k];
    else if (r < 256) v = phw[((size_t)l*128 + (r-128))*256 + k];
    else              v = gw [((size_t)l*128 + (r-256))*256 + k];
    Wcat[idx] = f2bf(v);
  }
  if (idx < NL*512*256){
    int k = idx & 255; int r = (idx >> 8) % 512; int l = idx/(512*256);
    float v;
    if (r < 256) v = czthw[((size_t)l*256 + r)*256 + k];
    else         v = czphw[((size_t)l*256 + (r-256))*256 + k];
    Wcz[idx] = f2bf(v);
  }
  if (idx < NL*NC*NC2) outwb[idx] = f2bf(outw[idx]);
  if (idx < NL*384){
    int r = idx % 384, l = idx/384;
    bcat[idx] = (r<128) ? thb[l*128+r] : (r<256) ? phb[l*128+r-128] : gb[l*128+r-256];
  }
  if (idx < NL*512){
    int r = idx % 512, l = idx/512;
    bcz[idx] = (r<256) ? czthb[l*256+r] : czphb[l*256+r-256];
  }
}

__global__ __launch_bounds__(256) void sk_a(const float* __restrict__ mask,
    const float* w1, const float* b1, const float* w2, const float* b2,
    const float* w3, const float* b3, const float* w4, const float* b4,
    float* m3out,
    const float* thw, const float* thb, const float* phw, const float* phb,
    const float* gw, const float* gb,
    const float* czthw, const float* czthb, const float* czphw, const float* czphb,
    const float* outw, u16* Wcat, float* bcat, u16* Wcz, float* bcz, u16* outwb){
  int bid = blockIdx.x, t = threadIdx.x;
  if (bid < NL*NB){
    d_mask(bid, t, mask, w1, b1, w2, b2, w3, b3, w4, b4, m3out);
  } else {
    d_packs((bid - NL*NB)*256 + t, thw, thb, phw, phb, gw, gb,
            czthw, czthb, czphw, czphb, outw, Wcat, bcat, Wcz, bcz, outwb);
  }
}

// ============ fused zf pass (own launch, grid (96,8)) ============
__global__ __launch_bounds__(256) void k_zfall(const float* __restrict__ zf,
    const float* __restrict__ box, const float* __restrict__ m3,
    u16* __restrict__ zfT, float* __restrict__ pavg, float* __restrict__ pmax,
    u16* __restrict__ roisT, float* __restrict__ zm, float* __restrict__ sm){
  int lb = blockIdx.x; int b = lb % NB; int c0 = blockIdx.y*32;
  __shared__ float fld[32*ZZ];
  __shared__ float Wy[7][15], Wx[7][15];
  __shared__ float tmp[32][7][16];
  __shared__ float roi[32][49];
  __shared__ float ms[ZZ];
  __shared__ float area_s;
  int t = threadIdx.x;
  const float* bx = box + b*4;
  const float SC = 15.0f/127.0f;
  float x1 = bx[0]*SC, y1 = bx[1]*SC, x2 = bx[2]*SC, y2 = bx[3]*SC;
  float bh = (y2-y1)/7.f, bw = (x2-x1)/7.f;
  if (t < 105){ int p=t/15, i=t%15;
    Wy[p][i] = hat_int(y1+(float)(p+1)*bh - (float)i) - hat_int(y1+(float)p*bh - (float)i); }
  else if (t < 210){ int q=(t-105)/15, i=(t-105)%15;
    Wx[q][i] = hat_int(x1+(float)(q+1)*bw - (float)i) - hat_int(x1+(float)q*bw - (float)i); }
  if (t == 255) area_s = fmaxf(bh*bw, 1e-6f);
  if (t < ZZ) ms[t] = m3[(size_t)lb*ZZ + t];
  const float* src = zf + ((size_t)lb*NC + c0)*ZZ;
  for (int e=t; e<32*ZZ; e+=256) fld[e] = src[e];
  __syncthreads();
  u16* dstT = zfT + (size_t)lb*ZZ*NC + c0;
  for (int e=t; e<ZZ*32; e+=256){
    int ci = e & 31, z = e >> 5;
    dstT[(size_t)z*NC + ci] = f2bf(fld[ci*ZZ + z]);
  }
  float inv_area = 1.f/area_s;
  for (int e=t; e<32*105; e+=256){
    int w = e%15; int pc = e/15; int p = pc%7; int cc = pc/7;
    float s = 0.f;
    #pragma unroll
    for (int h=0;h<15;h++) s += Wy[p][h]*fld[cc*ZZ + h*15 + w];
    tmp[cc][p][w] = s;
  }
  {
    int cc = t>>3, sub = t&7;
    const float* fr = &fld[cc*ZZ];
    float s = 0.f;
    for (int z=sub; z<ZZ; z+=8) s += fr[z]*ms[z];
    s += __shfl_down(s, 4, 8);
    s += __shfl_down(s, 2, 8);
    s += __shfl_down(s, 1, 8);
    if (sub == 0) zm[(size_t)lb*NC + c0 + cc] = s;
  }
  if (blockIdx.y == 0 && t < 64){
    float ss = 0.f;
    for (int z=t; z<ZZ; z+=64) ss += ms[z];
    ss = wave_red(ss);
    if (t == 0) sm[lb] = ss;
  }
  __syncthreads();
  for (int e=t; e<32*49; e+=256){
    int q = e%7; int pc = e/7; int p = pc%7; int cc = pc/7;
    float s = 0.f;
    #pragma unroll
    for (int w=0;w<15;w++) s += tmp[cc][p][w]*Wx[q][w];
    roi[cc][p*7+q] = s*inv_area;
  }
  __syncthreads();
  u16* dR = roisT + (size_t)lb*49*NC + c0;
  for (int e=t; e<49*32; e+=256){
    int ci = e & 31, s = e >> 5;
    dR[(size_t)s*NC + ci] = f2bf(roi[ci][s]);
  }
  if (t < 32){
    float s = 0.f, m = -1e30f;
    #pragma unroll
    for (int i=0;i<49;i++){ float v = roi[t][i]; s += v; m = fmaxf(m,v); }
    pavg[(size_t)lb*NC + c0 + t] = s/49.f;
    pmax[(size_t)lb*NC + c0 + t] = m;
  }
}

// ================= role: bf16 MFMA GEMM (flattened bid) =================
template<bool BPERL, bool HASBIAS, bool OUTBF, bool TROUT>
__device__ void d_mg(int bid, int t,
    const u16* __restrict__ A0, const u16* __restrict__ B0,
    const float* __restrict__ bias0, void* __restrict__ O0,
    int M, int N, int K, int lda, int ldb, int ldo,
    long Ab, long Bb, long Ob, int ntn, int ntiles)
{
  int lb = bid / ntiles; int tile = bid % ntiles; int l = lb / NB;
  const u16* A = A0 + (size_t)lb*Ab;
  const u16* B = B0 + (BPERL ? (size_t)l : (size_t)lb)*Bb;
  int tm = tile / ntn, tn = tile % ntn;
  int m0 = tm*64, n0 = tn*64;
  __shared__ u16 Asl[64][40];
  __shared__ u16 Bsl[64][40];
  int w = t>>6, l6 = t&63;
  int fr = l6&15, kg = (l6>>4)*8;
  int srow = t>>2, sseg = (t&3)*8;
  f4v ac0={0,0,0,0}, ac1={0,0,0,0}, ac2={0,0,0,0}, ac3={0,0,0,0};
  for (int kc=0; kc<K; kc+=32){
    us8 va = {0,0,0,0,0,0,0,0};
    int am = m0 + srow;
    if (am < M) va = *(const us8*)&A[(size_t)am*lda + kc + sseg];
    *(us8*)&Asl[srow][sseg] = va;
    us8 vb = {0,0,0,0,0,0,0,0};
    int bn = n0 + srow;
    if (bn < N) vb = *(const us8*)&B[(size_t)bn*ldb + kc + sseg];
    *(us8*)&Bsl[srow][sseg] = vb;
    __syncthreads();
    bf8v af = *(const bf8v*)&Asl[w*16 + fr][kg];
    bf8v b0 = *(const bf8v*)&Bsl[fr][kg];
    bf8v b1 = *(const bf8v*)&Bsl[16+fr][kg];
    bf8v b2 = *(const bf8v*)&Bsl[32+fr][kg];
    bf8v b3 = *(const bf8v*)&Bsl[48+fr][kg];
    ac0 = __builtin_amdgcn_mfma_f32_16x16x32_bf16(af, b0, ac0, 0,0,0);
    ac1 = __builtin_amdgcn_mfma_f32_16x16x32_bf16(af, b1, ac1, 0,0,0);
    ac2 = __builtin_amdgcn_mfma_f32_16x16x32_bf16(af, b2, ac2, 0,0,0);
    ac3 = __builtin_amdgcn_mfma_f32_16x16x32_bf16(af, b3, ac3, 0,0,0);
    __syncthreads();
  }
  int mb = m0 + w*16 + ((l6>>4)<<2);
  #pragma unroll
  for (int j=0;j<4;j++){
    int n = n0 + j*16 + fr;
    if (n >= N) continue;
    float bv = HASBIAS ? bias0[(size_t)l*N + n] : 0.f;
    f4v a = (j==0)?ac0:(j==1)?ac1:(j==2)?ac2:ac3;
    #pragma unroll
    for (int r=0;r<4;r++){
      int m = mb + r;
      if (TROUT){
        u16* out = (u16*)O0 + (size_t)lb*Ob;
        out[(size_t)n*ldo + m] = f2bf((m<M) ? (a[r]+bv) : 0.f);
      } else if (m < M){
        if (OUTBF){
          u16* out = (u16*)O0 + (size_t)lb*Ob;
          out[(size_t)m*ldo + n] = f2bf(a[r]+bv);
        } else {
          float* out = (float*)O0 + (size_t)lb*Ob;
          out[(size_t)m*ldo + n] = a[r]+bv;
        }
      }
    }
  }
}

// ================= role: mlp1 =================
__device__ void d_mlp1(int bid, int t, const float* __restrict__ pavg, const float* __restrict__ pmax,
    const float* __restrict__ aw1, const float* __restrict__ ab1,
    const float* __restrict__ mw1, const float* __restrict__ mb1,
    float* __restrict__ hid){
  int lb = bid >> 6; int rem = bid & 63; int pass = rem >> 5; int zb = rem & 31;
  int l = lb/NB;
  int wid = t>>6, lane = t&63;
  int r = zb*4 + wid;
  const float* pv = pass ? pmax : pavg;
  const float* w1 = pass ? mw1 : aw1;
  const float* b1 = pass ? mb1 : ab1;
  const float* wr = w1 + (size_t)(l*NC2+r)*NC;
  const float* pr = pv + (size_t)lb*NC;
  float s = dot4(((const float4*)wr)[lane], ((const float4*)pr)[lane]);
  s = wave_red(s);
  if (lane==0) hid[((size_t)lb*2 + pass)*NC2 + r] = fmaxf(s + b1[l*NC2+r], 0.f);
}

// ================= role: zphi =================
__device__ void d_zphi(int bid, int t, const float* __restrict__ zm, const float* __restrict__ sm,
    const float* __restrict__ phiw, const float* __restrict__ phib, float* __restrict__ zphi){
  int lb = bid >> 6; int rb = bid & 63; int l = lb/NB;
  int wid = t>>6, lane = t&63;
  int r = rb*4 + wid;
  const float* wr = phiw + (size_t)(l*NC + r)*NC;
  const float* zr = zm + (size_t)lb*NC;
  float s = dot4(((const float4*)wr)[lane], ((const float4*)zr)[lane]);
  s = wave_red(s);
  if (lane==0) zphi[(size_t)lb*NC + r] = s + phib[l*NC + r]*sm[lb];
}

__global__ __launch_bounds__(256) void sk_b(
    const u16* zfT, const u16* Wcat, const float* bcat, u16* TH3,
    const float* pavg, const float* pmax,
    const float* ap_w1, const float* ap_b1, const float* mp_w1, const float* mp_b1, float* hidb,
    const u16* roisT, const u16* Wcz, const float* bcz, u16* CZ3T,
    const float* zm, const float* sm, const float* phi_w, const float* phi_b, float* zphi){
  int bid = blockIdx.x, t = threadIdx.x;
  const int N1 = 96*24, N2 = N1 + 96*64, N3 = N2 + 96*8;
  if (bid < N1){
    d_mg<true,true,true,false>(bid, t, zfT, Wcat, bcat, TH3, ZZ, 384, NC, 256, 256, 384,
        (long)ZZ*256, (long)384*256, (long)ZZ*384, 6, 24);
  } else if (bid < N2){
    d_mlp1(bid - N1, t, pavg, pmax, ap_w1, ap_b1, mp_w1, mp_b1, hidb);
  } else if (bid < N3){
    d_mg<true,true,true,true>(bid - N2, t, roisT, Wcz, bcz, CZ3T, 49, 512, NC, 256, 256, 64,
        (long)49*256, (long)512*256, (long)512*64, 8, 8);
  } else {
    d_zphi(bid - N3, t, zm, sm, phi_w, phi_b, zphi);
  }
}

// ================= role: gxt =================
__device__ void d_gxt(int bid, int t, const u16* __restrict__ TH3, u16* __restrict__ GXT){
  int lb = bid >> 3; int z0 = (bid & 7)*32;
  __shared__ u16 lds[32][130];
  int n = t & 127, zi = t >> 7;
  const u16* src = TH3 + (size_t)lb*ZZ*384 + 256;
  #pragma unroll
  for (int p=0;p<16;p++){
    int z = z0 + zi + p*2;
    lds[zi+p*2][n] = (z < ZZ) ? src[(size_t)z*384 + n] : (u16)0;
  }
  __syncthreads();
  u16* dst = GXT + (size_t)lb*128*256;
  int zi2 = t & 31, ni = t >> 5;
  #pragma unroll
  for (int p=0;p<16;p++){
    int nn = ni + p*8;
    dst[(size_t)nn*256 + z0 + zi2] = lds[zi2][nn];
  }
}

// ================= role: mlp2 =================
__device__ void d_mlp2(int bid, int t, const float* __restrict__ hid,
    const float* __restrict__ aw2, const float* __restrict__ ab2,
    const float* __restrict__ mw2, const float* __restrict__ mb2,
    float* __restrict__ zavg, float* __restrict__ zmax){
  int lb = bid >> 7; int rem = bid & 127; int pass = rem >> 6; int cb = rem & 63;
  int l = lb/NB;
  int wid = t>>6, lane = t&63;
  int c = cb*4 + wid;
  const float* w2 = pass ? mw2 : aw2;
  const float* b2 = pass ? mb2 : ab2;
  const float* wr = w2 + (size_t)(l*NC+c)*NC2;
  const float* hr = hid + ((size_t)lb*2 + pass)*NC2;
  float2 wv = ((const float2*)wr)[lane];
  float2 hv = ((const float2*)hr)[lane];
  float s = wave_red(wv.x*hv.x + wv.y*hv.y);
  if (lane==0){
    float* zo = pass ? zmax : zavg;
    zo[(size_t)lb*NC + c] = s + b2[l*NC+c];
  }
}

// ================= role: wvec =================
__device__ void d_wvec(int lb, int t, const float* __restrict__ zphi, const float* __restrict__ dw,
    const float* __restrict__ db, float* __restrict__ wvec, float* __restrict__ cb){
  int l = lb/NB;
  __shared__ float zp[NC];
  __shared__ float red[NC];
  zp[t] = zphi[(size_t)lb*NC + t];
  __syncthreads();
  float s = 0.f;
  const float* dwl = dw + (size_t)l*NC*NC;
  for (int c=0;c<NC;c++) s += zp[c]*dwl[(size_t)c*NC + t];
  wvec[(size_t)lb*NC + t] = s;
  red[t] = zp[t]*db[l*NC + t];
  __syncthreads();
  for (int off2=128; off2>0; off2>>=1){
    if (t < off2) red[t] += red[t+off2];
    __syncthreads();
  }
  if (t==0) cb[lb] = red[0];
}

__global__ __launch_bounds__(256) void sk_c(
    const u16* TH3, float* Sb,
    u16* GXT,
    const float* hidb, const float* ap_w2, const float* ap_b2,
    const float* mp_w2, const float* mp_b2, float* zavg, float* zmax,
    const u16* CZ3T, float* Fbuf,
    const float* zphi, const float* delta_w, const float* delta_b, float* wvec, float* cbuf){
  int bid = blockIdx.x, t = threadIdx.x;
  const int N1 = 96*16, N2 = N1 + 96*8, N3 = N2 + 96*128, N4 = N3 + 96*16;
  if (bid < N1){
    d_mg<false,false,false,false>(bid, t, TH3, TH3+128, nullptr, Sb, ZZ, ZZ, NC2, 384, 384, ZZ,
        (long)ZZ*384, (long)ZZ*384, (long)ZZ*ZZ, 4, 16);
  } else if (bid < N2){
    d_gxt(bid - N1, t, TH3, GXT);
  } else if (bid < N3){
    d_mlp2(bid - N2, t, hidb, ap_w2, ap_b2, mp_w2, mp_b2, zavg, zmax);
  } else if (bid < N4){
    d_mg<false,false,false,false>(bid - N3, t, CZ3T, CZ3T+256*64, nullptr, Fbuf, NC, NC, 64, 64, 64, NC,
        (long)512*64, (long)512*64, (long)NC*NC, 4, 16);
  } else {
    d_wvec(bid - N4, t, zphi, delta_w, delta_b, wvec, cbuf);
  }
}

// ================= role: sc partial =================
__device__ void d_sc_part(int bid, int t, const float* __restrict__ xf,
    const float* __restrict__ wvec, float* __restrict__ part){
  int lb = bid >> 4; int rem = bid & 15; int xt = rem >> 2, cs = rem & 3;
  __shared__ float wv[64];
  if (t < 64) wv[t] = wvec[(size_t)lb*NC + cs*64 + t];
  __syncthreads();
  int x = xt*256 + t;
  if (x >= XX) return;
  const float* xb = xf + ((size_t)lb*NC + cs*64)*XX + x;
  float s = 0.f;
  #pragma unroll 8
  for (int c=0;c<64;c++) s += wv[c]*xb[(size_t)c*XX];
  part[((size_t)lb*4 + cs)*XX + x] = s;
}

// ================= role: softmax =================
__device__ void d_softmax(int bid, int t, const float* __restrict__ S, u16* __restrict__ P){
  int row = bid*4 + (t >> 6);
  int lane = t & 63;
  const float* r = S + (size_t)row*ZZ;
  float v[4]; float mx = -1e30f;
  #pragma unroll
  for (int q=0;q<4;q++){
    int j = lane + q*64;
    v[q] = (j<ZZ) ? r[j] : -1e30f;
    mx = fmaxf(mx, v[q]);
  }
  #pragma unroll
  for (int off=32; off>0; off>>=1) mx = fmaxf(mx, __shfl_xor(mx, off));
  float sum = 0.f;
  #pragma unroll
  for (int q=0;q<4;q++){
    v[q] = __expf(v[q]-mx);
    if (lane + q*64 < ZZ) sum += v[q];
  }
  #pragma unroll
  for (int off=32; off>0; off>>=1) sum += __shfl_xor(sum, off);
  float inv = 1.f/(16.f*sum);
  u16* pr = P + (size_t)row*256;
  #pragma unroll
  for (int q=0;q<4;q++){
    int j = lane + q*64;
    pr[j] = (j<ZZ) ? f2bf(v[q]*inv) : (u16)0;
  }
}

// ================= role: relw =================
__device__ void d_relw(int bid, int t, const float* __restrict__ F,
    const float* __restrict__ gw, const float* __restrict__ gb,
    float* __restrict__ rel){
  int lb = bid >> 7; int rb = bid & 127; int l = lb/NB;
  int wid = t>>6, lane = t&63;
  int r = rb*4 + wid;
  const float* wrow = gw + ((size_t)l*2*NC + r)*NC;
  const float* frow = F + (size_t)lb*NC*NC + (size_t)(r>>1)*NC;
  float s = dot4(((const float4*)wrow)[lane], ((const float4*)frow)[lane]);
  s = wave_red(s);
  if (lane==0) rel[(size_t)lb*2*NC + r] = fmaxf(s + gb[l*2*NC+r], 0.f);
}

__global__ __launch_bounds__(256) void sk_d(
    const float* xf, const float* wvec, float* part,
    const float* Sb, u16* Pb,
    const float* Fbuf, const float* cz_gw, const float* cz_gb, float* relb){
  int bid = blockIdx.x, t = threadIdx.x;
  const int N1 = 96*16, N2 = N1 + 5400;
  if (bid < N1){
    d_sc_part(bid, t, xf, wvec, part);
  } else if (bid < N2){
    d_softmax(bid - N1, t, Sb, Pb);
  } else {
    d_relw(bid - N2, t, Fbuf, cz_gw, cz_gb, relb);
  }
}

// ================= role: z2n+cues =================
__device__ void d_z2ncue(int bid, int t, const float* __restrict__ rel,
    const float* __restrict__ aw, const float* __restrict__ ab,
    const float* __restrict__ zavg, const float* __restrict__ zmax,
    const float* __restrict__ drw, const float* __restrict__ drb,
    float* __restrict__ cues){
  int lb = bid >> 6; int cb = bid & 63; int l = lb/NB;
  int wid = t>>6, lane = t&63;
  int c = cb*4 + wid;
  const float* arow = aw + ((size_t)l*NC + c)*2*NC;
  const float* rrow = rel + (size_t)lb*2*NC;
  float s = dot4(((const float4*)arow)[lane],    ((const float4*)rrow)[lane])
          + dot4(((const float4*)arow)[lane+64], ((const float4*)rrow)[lane+64]);
  s = wave_red(s);
  if (lane==0){
    float z2 = s + ab[l*NC+c];
    size_t idx = (size_t)lb*NC + c;
    const float* dw = drw + (size_t)(l*NC + c)*3;
    float x = dw[0]*zavg[idx] + dw[1]*zmax[idx] + dw[2]*z2 + drb[l*NC+c];
    cues[idx] = 1.f/(1.f + __expf(-x));
  }
}

// ================= role: sc finalize =================
__device__ void d_scfin(int lb, int t, const float* __restrict__ part,
    const float* __restrict__ cb, float* __restrict__ scb){
  float cbv = cb[lb];
  const float* pp = part + (size_t)lb*4*XX;
  for (int x = t; x < XX; x += 256){
    float s = pp[x] + pp[XX + x] + pp[2*XX + x] + pp[3*XX + x];
    scb[(size_t)lb*XX + x] = fminf(fmaxf((s + cbv)*0.0625f, 0.f), 1.f);
  }
}

__global__ __launch_bounds__(256) void sk_e(
    const u16* Pb, const u16* GXT, u16* Ybb,
    const float* relb, const float* cz_aw, const float* cz_ab,
    const float* zavg, const float* zmax, const float* dr_w, const float* dr_b, float* cues,
    const float* part, const float* cbuf, float* scb){
  int bid = blockIdx.x, t = threadIdx.x;
  const int N1 = 96*8, N2 = N1 + 96*64;
  if (bid < N1){
    d_mg<false,false,true,false>(bid, t, Pb, GXT, nullptr, Ybb, ZZ, NC2, 256, 256, 256, NC2,
        (long)ZZ*256, (long)128*256, (long)ZZ*NC2, 2, 8);
  } else if (bid < N2){
    d_z2ncue(bid - N1, t, relb, cz_aw, cz_ab, zavg, zmax, dr_w, dr_b, cues);
  } else {
    d_scfin(bid - N2, t, part, cbuf, scb);
  }
}

// ================= role: outconv =================
__device__ void d_outconv(int bid, int t, const u16* __restrict__ outwb,
    const u16* __restrict__ Ybb,
    const float* __restrict__ bng, const float* __restrict__ bnb,
    const float* __restrict__ bnm, const float* __restrict__ bnv,
    const float* __restrict__ cues, const float* __restrict__ zf,
    float* __restrict__ dzfout, float* __restrict__ dzffull){
  int lb = bid >> 4; int tile = bid & 15; int l = lb/NB;
  const u16* A = outwb + (size_t)l*NC*NC2;
  const u16* B = Ybb + (size_t)lb*ZZ*NC2;
  int tm = tile >> 2, tn = tile & 3;
  int m0 = tm*64, n0 = tn*64;
  __shared__ u16 Asl[64][40];
  __shared__ u16 Bsl[64][40];
  int w = t>>6, l6 = t&63;
  int fr = l6&15, kg = (l6>>4)*8;
  int srow = t>>2, sseg = (t&3)*8;
  f4v ac0={0,0,0,0}, ac1={0,0,0,0}, ac2={0,0,0,0}, ac3={0,0,0,0};
  for (int kc=0; kc<NC2; kc+=32){
    us8 va = *(const us8*)&A[(size_t)(m0+srow)*NC2 + kc + sseg];
    *(us8*)&Asl[srow][sseg] = va;
    us8 vb = {0,0,0,0,0,0,0,0};
    int bn = n0 + srow;
    if (bn < ZZ) vb = *(const us8*)&B[(size_t)bn*NC2 + kc + sseg];
    *(us8*)&Bsl[srow][sseg] = vb;
    __syncthreads();
    bf8v af = *(const bf8v*)&Asl[w*16 + fr][kg];
    bf8v b0 = *(const bf8v*)&Bsl[fr][kg];
    bf8v b1 = *(const bf8v*)&Bsl[16+fr][kg];
    bf8v b2 = *(const bf8v*)&Bsl[32+fr][kg];
    bf8v b3 = *(const bf8v*)&Bsl[48+fr][kg];
    ac0 = __builtin_amdgcn_mfma_f32_16x16x32_bf16(af, b0, ac0, 0,0,0);
    ac1 = __builtin_amdgcn_mfma_f32_16x16x32_bf16(af, b1, ac1, 0,0,0);
    ac2 = __builtin_amdgcn_mfma_f32_16x16x32_bf16(af, b2, ac2, 0,0,0);
    ac3 = __builtin_amdgcn_mfma_f32_16x16x32_bf16(af, b3, ac3, 0,0,0);
    __syncthreads();
  }
  int mb = m0 + w*16 + ((l6>>4)<<2);
  #pragma unroll
  for (int j=0;j<4;j++){
    int z = n0 + j*16 + fr;
    if (z >= ZZ) continue;
    int h = z/15, wv2 = z%15;
    f4v a = (j==0)?ac0:(j==1)?ac1:(j==2)?ac2:ac3;
    #pragma unroll
    for (int r=0;r<4;r++){
      int c = mb + r;
      float scale = bng[l*NC+c] * rsqrtf(bnv[l*NC+c] + 1e-5f);
      float val = (a[r] - bnm[l*NC+c])*scale + bnb[l*NC+c];
      float cu = cues[(size_t)lb*NC + c];
      float zv = zf[((size_t)lb*NC + c)*ZZ + z];
      float rr = cu*zv + zv + val;
      dzffull[((size_t)lb*NC + c)*ZZ + z] = rr;
      if (h>=4 && h<11 && wv2>=4 && wv2<11)
        dzfout[((size_t)lb*NC + c)*49 + (h-4)*7 + (wv2-4)] = rr;
    }
  }
}

// ================= role: xfout (block per (lb,c), grid-stride x) =================
__device__ void d_xfout(int bc, int t, const float* __restrict__ xf,
    const float* __restrict__ scb, const float* __restrict__ cues,
    float* __restrict__ out){
  int lb = bc >> 8;
  float cu1 = 1.f + cues[bc];
  const float* xr = xf + (size_t)bc*XX;
  const float* sr = scb + (size_t)lb*XX;
  float* orow = out + (size_t)bc*XX;
  for (int x = t; x < XX; x += 256)
    orow[x] = cu1*xr[x] - sr[x];
}

__global__ __launch_bounds__(256) void sk_f(
    const u16* outwb, const u16* Ybb,
    const float* bn_g, const float* bn_b, const float* bn_m, const float* bn_v,
    const float* cues, const float* zf, float* o_zfout, float* o_zffull,
    const float* xf, const float* scb, float* o_xfout){
  int bid = blockIdx.x, t = threadIdx.x;
  const int N1 = 96*16;
  if (bid < N1){
    d_outconv(bid, t, outwb, Ybb, bn_g, bn_b, bn_m, bn_v, cues, zf, o_zfout, o_zffull);
  } else {
    d_xfout(bid - N1, t, xf, scb, cues, o_xfout);
  }
}

extern "C" void kernel_launch(void* const* d_in, const int* in_sizes, int n_in,
                              void* d_out, int out_size, void* d_ws, size_t ws_size,
                              hipStream_t stream){
  const float* zf      = (const float*)d_in[0];
  const float* xf      = (const float*)d_in[1];
  const float* maskp   = (const float*)d_in[2];
  const float* box     = (const float*)d_in[3];
  const float* nl_g_w  = (const float*)d_in[4];
  const float* nl_g_b  = (const float*)d_in[5];
  const float* nl_th_w = (const float*)d_in[6];
  const float* nl_th_b = (const float*)d_in[7];
  const float* nl_ph_w = (const float*)d_in[8];
  const float* nl_ph_b = (const float*)d_in[9];
  const float* nl_out_w= (const float*)d_in[10];
  const float* bn_g    = (const float*)d_in[11];
  const float* bn_b    = (const float*)d_in[12];
  const float* bn_m    = (const float*)d_in[13];
  const float* bn_v    = (const float*)d_in[14];
  const float* cz_th_w = (const float*)d_in[15];
  const float* cz_th_b = (const float*)d_in[16];
  const float* cz_ph_w = (const float*)d_in[17];
  const float* cz_ph_b = (const float*)d_in[18];
  const float* cz_gw   = (const float*)d_in[19];
  const float* cz_gb   = (const float*)d_in[20];
  const float* cz_aw   = (const float*)d_in[21];
  const float* cz_ab   = (const float*)d_in[22];
  const float* ap_w1   = (const float*)d_in[23];
  const float* ap_b1   = (const float*)d_in[24];
  const float* ap_w2   = (const float*)d_in[25];
  const float* ap_b2   = (const float*)d_in[26];
  const float* mp_w1   = (const float*)d_in[27];
  const float* mp_b1   = (const float*)d_in[28];
  const float* mp_w2   = (const float*)d_in[29];
  const float* mp_b2   = (const float*)d_in[30];
  const float* dr_w    = (const float*)d_in[31];
  const float* dr_b    = (const float*)d_in[32];
  const float* ac1_w   = (const float*)d_in[33];
  const float* ac1_b   = (const float*)d_in[34];
  const float* ac2_w   = (const float*)d_in[35];
  const float* ac2_b   = (const float*)d_in[36];
  const float* ac3_w   = (const float*)d_in[37];
  const float* ac3_b   = (const float*)d_in[38];
  const float* ac4_w   = (const float*)d_in[39];
  const float* ac4_b   = (const float*)d_in[40];
  const float* phi_w   = (const float*)d_in[41];
  const float* phi_b   = (const float*)d_in[42];
  const float* delta_w = (const float*)d_in[43];
  const float* delta_b = (const float*)d_in[44];
  (void)in_sizes; (void)n_in; (void)out_size; (void)ws_size;

  float* ws = (float*)d_ws;
  size_t off = 0;
  auto alloc = [&](size_t n){ size_t o = off; off += (n + 15) & ~(size_t)15; return o; };
  float* TH3f  = ws + alloc((size_t)NL*NB*ZZ*384/2);
  float* Sb    = ws + alloc((size_t)NL*NB*ZZ*ZZ);
  float* Fbuf  = ws + alloc((size_t)NL*NB*NC*NC);
  float* zfTf  = ws + alloc((size_t)NL*NB*ZZ*NC/2);
  float* Pbf   = ws + alloc((size_t)NL*NB*ZZ*256/2);
  float* GXTf  = ws + alloc((size_t)NL*NB*128*256/2);
  float* Ybbf  = ws + alloc((size_t)NL*NB*ZZ*NC2/2);
  float* CZ3Tf = ws + alloc((size_t)NL*NB*512*64/2);
  float* roisTf= ws + alloc((size_t)NL*NB*49*NC/2);
  float* Wcatf = ws + alloc((size_t)NL*384*256/2);
  float* Wczf  = ws + alloc((size_t)NL*512*256/2);
  float* outwbf= ws + alloc((size_t)NL*NC*NC2/2);
  u16* TH3  = (u16*)TH3f;
  u16 *zfT=(u16*)zfTf, *Pb=(u16*)Pbf, *GXT=(u16*)GXTf, *Ybb=(u16*)Ybbf,
      *CZ3T=(u16*)CZ3Tf, *roisT=(u16*)roisTf, *Wcat=(u16*)Wcatf,
      *Wcz=(u16*)Wczf, *outwb=(u16*)outwbf;
  float* bcat = ws + alloc((size_t)NL*384);
  float* bcz  = ws + alloc((size_t)NL*512);
  float* m3   = ws + alloc((size_t)NL*NB*ZZ);
  float* pavg = ws + alloc((size_t)NL*NB*NC);
  float* pmax = ws + alloc((size_t)NL*NB*NC);
  float* zavg = ws + alloc((size_t)NL*NB*NC);
  float* zmax = ws + alloc((size_t)NL*NB*NC);
  float* cues = ws + alloc((size_t)NL*NB*NC);
  float* zm   = ws + alloc((size_t)NL*NB*NC);
  float* zphi = ws + alloc((size_t)NL*NB*NC);
  float* wvec = ws + alloc((size_t)NL*NB*NC);
  float* sm   = ws + alloc((size_t)NL*NB);
  float* cbuf = ws + alloc((size_t)NL*NB);
  float* part = ws + alloc((size_t)NL*NB*4*XX);
  float* scb  = ws + alloc((size_t)NL*NB*XX);
  float* hidb = ws + alloc((size_t)NL*NB*2*NC2);
  float* relb = ws + alloc((size_t)NL*NB*2*NC);

  float* outp    = (float*)d_out;
  float* o_zfout = outp;
  float* o_zffull= outp + (size_t)NL*NB*NC*49;
  float* o_xfout = o_zffull + (size_t)NL*NB*NC*ZZ;

  // L1: mask + packs
  sk_a<<<NL*NB + (NL*512*256+255)/256, 256, 0, stream>>>(
      maskp, ac1_w, ac1_b, ac2_w, ac2_b, ac3_w, ac3_b, ac4_w, ac4_b, m3,
      nl_th_w, nl_th_b, nl_ph_w, nl_ph_b, nl_g_w, nl_g_b,
      cz_th_w, cz_th_b, cz_ph_w, cz_ph_b, nl_out_w,
      Wcat, bcat, Wcz, bcz, outwb);
  // L2: fused zf pass
  k_zfall<<<dim3(NL*NB, 8), 256, 0, stream>>>(zf, box, m3, zfT, pavg, pmax,
                                               roisT, zm, sm);
  // L3: projcat + mlp1 + CZ + zphi
  sk_b<<<96*24 + 96*64 + 96*8 + 96*64, 256, 0, stream>>>(
      zfT, Wcat, bcat, TH3, pavg, pmax, ap_w1, ap_b1, mp_w1, mp_b1, hidb,
      roisT, Wcz, bcz, CZ3T, zm, sm, phi_w, phi_b, zphi);
  // L4: S + gxt + mlp2 + F + wvec
  sk_c<<<96*16 + 96*8 + 96*128 + 96*16 + 96, 256, 0, stream>>>(
      TH3, Sb, GXT, hidb, ap_w2, ap_b2, mp_w2, mp_b2, zavg, zmax,
      CZ3T, Fbuf, zphi, delta_w, delta_b, wvec, cbuf);
  // L5: sc_part + softmax + relw
  sk_d<<<96*16 + 5400 + 96*128, 256, 0, stream>>>(
      xf, wvec, part, Sb, Pb, Fbuf, cz_gw, cz_gb, relb);
  // L6: PV + z2ncue + scfin
  sk_e<<<96*8 + 96*64 + 96, 256, 0, stream>>>(
      Pb, GXT, Ybb, relb, cz_aw, cz_ab, zavg, zmax, dr_w, dr_b, cues,
      part, cbuf, scb);
  // L7: outconv + xfout
  sk_f<<<96*16 + NL*NB*NC, 256, 0, stream>>>(
      outwb, Ybb, bn_g, bn_b, bn_m, bn_v, cues, zf, o_zfout, o_zffull,
      xf, scb, o_xfout);
}

// Round 16
// 258.815 us; speedup vs baseline: 4.0767x; 1.0462x over previous
//
#include <hip/hip_runtime.h>
#include <math.h>

#define NL 3
#define NB 32
#define NC 256
#define NC2 128
#define HZ 15
#define ZZ 225
#define XX 961
#define HMD 127

typedef unsigned short u16;
typedef __attribute__((ext_vector_type(8))) unsigned short us8;
typedef __attribute__((ext_vector_type(8))) short bf8v;
typedef __attribute__((ext_vector_type(4))) float f4v;

__device__ __forceinline__ u16 f2bf(float f){
  unsigned int u = __float_as_uint(f);
  unsigned int r = (u + 0x7fffu + ((u>>16)&1u)) >> 16;
  return (u16)r;
}
__device__ __forceinline__ float hat_int(float u){
  if (u <= -1.f) return 0.f;
  if (u <= 0.f){ float t = u + 1.f; return 0.5f*t*t; }
  if (u <= 1.f){ float t = 1.f - u; return 1.f - 0.5f*t*t; }
  return 1.f;
}
__device__ __forceinline__ float dot4(float4 a, float4 b){
  return a.x*b.x + a.y*b.y + a.z*b.z + a.w*b.w;
}
__device__ __forceinline__ float wave_red(float s){
  #pragma unroll
  for (int off=32; off>0; off>>=1) s += __shfl_xor(s, off);
  return s;
}

// ================= role: fused mask branch (bid in [0,96)) =================
__device__ void d_mask(int lb, int t, const float* __restrict__ mask,
    const float* __restrict__ w1, const float* __restrict__ b1,
    const float* __restrict__ w2, const float* __restrict__ b2,
    const float* __restrict__ w3, const float* __restrict__ b3,
    const float* __restrict__ w4, const float* __restrict__ b4,
    float* __restrict__ m3out){
  int l = lb/NB, b = lb%NB;
  __shared__ float c1s[4][56][56];
  __shared__ float c2s[8][28][28];
  __shared__ float r1s[8][14][14];
  __shared__ float c3s[4][14][14];
  __shared__ float r2s[4][15][15];
  __shared__ int   y0t[14];
  __shared__ float wyt[14];
  __shared__ int   y0t15[15];
  __shared__ float wyt15[15];
  if (t < 14){
    float sy = 122.0f/13.0f;
    float yf = (float)t * sy;
    int y0 = (int)floorf(yf); y0 = min(max(y0,0), 121);
    y0t[t] = y0; wyt[t] = yf - (float)y0;
  } else if (t < 29){
    int q = t-14;
    float sy = 13.0f/14.0f;
    float yf = (float)q * sy;
    int y0 = (int)floorf(yf); y0 = min(max(y0,0), 12);
    y0t15[q] = y0; wyt15[q] = yf - (float)y0;
  }
  __syncthreads();
  const float* mb = mask + (size_t)b*HMD*HMD;
  const float* wc1 = w1 + (size_t)l*4*2*9;
  for (int e=t; e<4*56*56; e+=256){
    int ci = e % 56, ri = (e/56) % 56, oc = e/(56*56);
    int row = y0t[ri>>2] + (ri&3);
    int col = y0t[ci>>2] + (ci&3);
    float acc = b1[l*4+oc];
    #pragma unroll
    for (int ky=0;ky<3;ky++)
      #pragma unroll
      for (int kx=0;kx<3;kx++){
        float mv = mb[(row+ky)*HMD + (col+kx)];
        acc += wc1[((oc*2+0)*3+ky)*3+kx]*mv;
        acc += wc1[((oc*2+1)*3+ky)*3+kx]*(1.f-mv);
      }
    c1s[oc][ri][ci] = fmaxf(acc, 0.f);
  }
  __syncthreads();
  const float* wc2 = w2 + (size_t)l*8*4*9;
  for (int e=t; e<8*28*28; e+=256){
    int j = e % 28, i = (e/28) % 28, oc = e/(28*28);
    int g = i>>1, dy = i&1, gc = j>>1, dx = j&1;
    float acc = b2[l*8+oc];
    #pragma unroll
    for (int ic=0; ic<4; ic++)
      #pragma unroll
      for (int ky=0;ky<3;ky++)
        #pragma unroll
        for (int kx=0;kx<3;kx++)
          acc += wc2[((oc*4+ic)*3+ky)*3+kx]*c1s[ic][g*4+dy+ky][gc*4+dx+kx];
    c2s[oc][i][j] = fmaxf(acc, 0.f);
  }
  __syncthreads();
  for (int e=t; e<8*14*14; e+=256){
    int ox = e % 14, oy = (e/14) % 14, oc = e/(14*14);
    float wy = wyt[oy], wx = wyt[ox];
    float v00 = c2s[oc][2*oy][2*ox],   v01 = c2s[oc][2*oy][2*ox+1];
    float v10 = c2s[oc][2*oy+1][2*ox], v11 = c2s[oc][2*oy+1][2*ox+1];
    r1s[oc][oy][ox] = (v00*(1.f-wy)+v10*wy)*(1.f-wx) + (v01*(1.f-wy)+v11*wy)*wx;
  }
  __syncthreads();
  const float* wc3 = w3 + (size_t)l*4*8*9;
  for (int e=t; e<4*14*14; e+=256){
    int x = e % 14, y = (e/14) % 14, oc = e/(14*14);
    float acc = b3[l*4+oc];
    for (int ic=0; ic<8; ic++)
      #pragma unroll
      for (int ky=-1;ky<=1;ky++){
        int yy = y+ky; if (yy<0||yy>=14) continue;
        #pragma unroll
        for (int kx=-1;kx<=1;kx++){
          int xx = x+kx; if (xx<0||xx>=14) continue;
          acc += wc3[((oc*8+ic)*3+(ky+1))*3+(kx+1)]*r1s[ic][yy][xx];
        }
      }
    c3s[oc][y][x] = acc;
  }
  __syncthreads();
  for (int e=t; e<4*15*15; e+=256){
    int ox = e % 15, oy = (e/15) % 15, oc = e/(15*15);
    int y0 = y0t15[oy], x0 = y0t15[ox];
    float wy = wyt15[oy], wx = wyt15[ox];
    float v00 = c3s[oc][y0][x0],   v01 = c3s[oc][y0][x0+1];
    float v10 = c3s[oc][y0+1][x0], v11 = c3s[oc][y0+1][x0+1];
    r2s[oc][oy][ox] = (v00*(1.f-wy)+v10*wy)*(1.f-wx) + (v01*(1.f-wy)+v11*wy)*wx;
  }
  __syncthreads();
  const float* wc4 = w4 + (size_t)l*1*4*9;
  for (int e=t; e<15*15; e+=256){
    int x = e % 15, y = e/15;
    float acc = b4[l];
    #pragma unroll
    for (int ic=0; ic<4; ic++)
      #pragma unroll
      for (int ky=-1;ky<=1;ky++){
        int yy = y+ky; if (yy<0||yy>=15) continue;
        #pragma unroll
        for (int kx=-1;kx<=1;kx++){
          int xx = x+kx; if (xx<0||xx>=15) continue;
          acc += wc4[(ic*3+(ky+1))*3+(kx+1)]*r2s[ic][yy][xx];
        }
      }
    m3out[(size_t)lb*ZZ + y*15 + x] = acc;
  }
}

// ================= role: weight packs =================
__device__ void d_packs(int idx,
    const float* __restrict__ thw, const float* __restrict__ thb,
    const float* __restrict__ phw, const float* __restrict__ phb,
    const float* __restrict__ gw,  const float* __restrict__ gb,
    const float* __restrict__ czthw, const float* __restrict__ czthb,
    const float* __restrict__ czphw, const float* __restrict__ czphb,
    const float* __restrict__ outw,
    u16* __restrict__ Wcat, float* __restrict__ bcat,
    u16* __restrict__ Wcz, float* __restrict__ bcz,
    u16* __restrict__ outwb){
  if (idx < NL*384*256){
    int k = idx & 255; int r = (idx >> 8) % 384; int l = idx/(384*256);
    float v;
    if (r < 128)      v = thw[((size_t)l*128 + r)*256 + k];
    else if (r < 256) v = phw[((size_t)l*128 + (r-128))*256 + k];
    else              v = gw [((size_t)l*128 + (r-256))*256 + k];
    Wcat[idx] = f2bf(v);
  }
  if (idx < NL*512*256){
    int k = idx & 255; int r = (idx >> 8) % 512; int l = idx/(512*256);
    float v;
    if (r < 256) v = czthw[((size_t)l*256 + r)*256 + k];
    else         v = czphw[((size_t)l*256 + (r-256))*256 + k];
    Wcz[idx] = f2bf(v);
  }
  if (idx < NL*NC*NC2) outwb[idx] = f2bf(outw[idx]);
  if (idx < NL*384){
    int r = idx % 384, l = idx/384;
    bcat[idx] = (r<128) ? thb[l*128+r] : (r<256) ? phb[l*128+r-128] : gb[l*128+r-256];
  }
  if (idx < NL*512){
    int r = idx % 512, l = idx/512;
    bcz[idx] = (r<256) ? czthb[l*256+r] : czphb[l*256+r-256];
  }
}

__global__ __launch_bounds__(256) void sk_a(const float* __restrict__ mask,
    const float* w1, const float* b1, const float* w2, const float* b2,
    const float* w3, const float* b3, const float* w4, const float* b4,
    float* m3out,
    const float* thw, const float* thb, const float* phw, const float* phb,
    const float* gw, const float* gb,
    const float* czthw, const float* czthb, const float* czphw, const float* czphb,
    const float* outw, u16* Wcat, float* bcat, u16* Wcz, float* bcz, u16* outwb){
  int bid = blockIdx.x, t = threadIdx.x;
  if (bid < NL*NB){
    d_mask(bid, t, mask, w1, b1, w2, b2, w3, b3, w4, b4, m3out);
  } else {
    d_packs((bid - NL*NB)*256 + t, thw, thb, phw, phb, gw, gb,
            czthw, czthb, czphw, czphb, outw, Wcat, bcat, Wcz, bcz, outwb);
  }
}

// ============ fused zf pass (own launch, grid (96,8)) ============
__global__ __launch_bounds__(256) void k_zfall(const float* __restrict__ zf,
    const float* __restrict__ box, const float* __restrict__ m3,
    u16* __restrict__ zfT, float* __restrict__ pavg, float* __restrict__ pmax,
    u16* __restrict__ roisT, float* __restrict__ zm, float* __restrict__ sm){
  int lb = blockIdx.x; int b = lb % NB; int c0 = blockIdx.y*32;
  __shared__ float fld[32*ZZ];
  __shared__ float Wy[7][15], Wx[7][15];
  __shared__ float tmp[32][7][16];
  __shared__ float roi[32][49];
  __shared__ float ms[ZZ];
  __shared__ float area_s;
  int t = threadIdx.x;
  const float* bx = box + b*4;
  const float SC = 15.0f/127.0f;
  float x1 = bx[0]*SC, y1 = bx[1]*SC, x2 = bx[2]*SC, y2 = bx[3]*SC;
  float bh = (y2-y1)/7.f, bw = (x2-x1)/7.f;
  if (t < 105){ int p=t/15, i=t%15;
    Wy[p][i] = hat_int(y1+(float)(p+1)*bh - (float)i) - hat_int(y1+(float)p*bh - (float)i); }
  else if (t < 210){ int q=(t-105)/15, i=(t-105)%15;
    Wx[q][i] = hat_int(x1+(float)(q+1)*bw - (float)i) - hat_int(x1+(float)q*bw - (float)i); }
  if (t == 255) area_s = fmaxf(bh*bw, 1e-6f);
  if (t < ZZ) ms[t] = m3[(size_t)lb*ZZ + t];
  const float* src = zf + ((size_t)lb*NC + c0)*ZZ;
  for (int e=t; e<32*ZZ; e+=256) fld[e] = src[e];
  __syncthreads();
  u16* dstT = zfT + (size_t)lb*ZZ*NC + c0;
  for (int e=t; e<ZZ*32; e+=256){
    int ci = e & 31, z = e >> 5;
    dstT[(size_t)z*NC + ci] = f2bf(fld[ci*ZZ + z]);
  }
  float inv_area = 1.f/area_s;
  for (int e=t; e<32*105; e+=256){
    int w = e%15; int pc = e/15; int p = pc%7; int cc = pc/7;
    float s = 0.f;
    #pragma unroll
    for (int h=0;h<15;h++) s += Wy[p][h]*fld[cc*ZZ + h*15 + w];
    tmp[cc][p][w] = s;
  }
  {
    int cc = t>>3, sub = t&7;
    const float* fr = &fld[cc*ZZ];
    float s = 0.f;
    for (int z=sub; z<ZZ; z+=8) s += fr[z]*ms[z];
    s += __shfl_down(s, 4, 8);
    s += __shfl_down(s, 2, 8);
    s += __shfl_down(s, 1, 8);
    if (sub == 0) zm[(size_t)lb*NC + c0 + cc] = s;
  }
  if (blockIdx.y == 0 && t < 64){
    float ss = 0.f;
    for (int z=t; z<ZZ; z+=64) ss += ms[z];
    ss = wave_red(ss);
    if (t == 0) sm[lb] = ss;
  }
  __syncthreads();
  for (int e=t; e<32*49; e+=256){
    int q = e%7; int pc = e/7; int p = pc%7; int cc = pc/7;
    float s = 0.f;
    #pragma unroll
    for (int w=0;w<15;w++) s += tmp[cc][p][w]*Wx[q][w];
    roi[cc][p*7+q] = s*inv_area;
  }
  __syncthreads();
  u16* dR = roisT + (size_t)lb*49*NC + c0;
  for (int e=t; e<49*32; e+=256){
    int ci = e & 31, s = e >> 5;
    dR[(size_t)s*NC + ci] = f2bf(roi[ci][s]);
  }
  if (t < 32){
    float s = 0.f, m = -1e30f;
    #pragma unroll
    for (int i=0;i<49;i++){ float v = roi[t][i]; s += v; m = fmaxf(m,v); }
    pavg[(size_t)lb*NC + c0 + t] = s/49.f;
    pmax[(size_t)lb*NC + c0 + t] = m;
  }
}

// ================= role: bf16 MFMA GEMM (flattened bid) =================
template<bool BPERL, bool HASBIAS, bool OUTBF, bool TROUT>
__device__ void d_mg(int bid, int t,
    const u16* __restrict__ A0, const u16* __restrict__ B0,
    const float* __restrict__ bias0, void* __restrict__ O0,
    int M, int N, int K, int lda, int ldb, int ldo,
    long Ab, long Bb, long Ob, int ntn, int ntiles)
{
  int lb = bid / ntiles; int tile = bid % ntiles; int l = lb / NB;
  const u16* A = A0 + (size_t)lb*Ab;
  const u16* B = B0 + (BPERL ? (size_t)l : (size_t)lb)*Bb;
  int tm = tile / ntn, tn = tile % ntn;
  int m0 = tm*64, n0 = tn*64;
  __shared__ u16 Asl[64][40];
  __shared__ u16 Bsl[64][40];
  int w = t>>6, l6 = t&63;
  int fr = l6&15, kg = (l6>>4)*8;
  int srow = t>>2, sseg = (t&3)*8;
  f4v ac0={0,0,0,0}, ac1={0,0,0,0}, ac2={0,0,0,0}, ac3={0,0,0,0};
  for (int kc=0; kc<K; kc+=32){
    us8 va = {0,0,0,0,0,0,0,0};
    int am = m0 + srow;
    if (am < M) va = *(const us8*)&A[(size_t)am*lda + kc + sseg];
    *(us8*)&Asl[srow][sseg] = va;
    us8 vb = {0,0,0,0,0,0,0,0};
    int bn = n0 + srow;
    if (bn < N) vb = *(const us8*)&B[(size_t)bn*ldb + kc + sseg];
    *(us8*)&Bsl[srow][sseg] = vb;
    __syncthreads();
    bf8v af = *(const bf8v*)&Asl[w*16 + fr][kg];
    bf8v b0 = *(const bf8v*)&Bsl[fr][kg];
    bf8v b1 = *(const bf8v*)&Bsl[16+fr][kg];
    bf8v b2 = *(const bf8v*)&Bsl[32+fr][kg];
    bf8v b3 = *(const bf8v*)&Bsl[48+fr][kg];
    ac0 = __builtin_amdgcn_mfma_f32_16x16x32_bf16(af, b0, ac0, 0,0,0);
    ac1 = __builtin_amdgcn_mfma_f32_16x16x32_bf16(af, b1, ac1, 0,0,0);
    ac2 = __builtin_amdgcn_mfma_f32_16x16x32_bf16(af, b2, ac2, 0,0,0);
    ac3 = __builtin_amdgcn_mfma_f32_16x16x32_bf16(af, b3, ac3, 0,0,0);
    __syncthreads();
  }
  int mb = m0 + w*16 + ((l6>>4)<<2);
  #pragma unroll
  for (int j=0;j<4;j++){
    int n = n0 + j*16 + fr;
    if (n >= N) continue;
    float bv = HASBIAS ? bias0[(size_t)l*N + n] : 0.f;
    f4v a = (j==0)?ac0:(j==1)?ac1:(j==2)?ac2:ac3;
    #pragma unroll
    for (int r=0;r<4;r++){
      int m = mb + r;
      if (TROUT){
        u16* out = (u16*)O0 + (size_t)lb*Ob;
        out[(size_t)n*ldo + m] = f2bf((m<M) ? (a[r]+bv) : 0.f);
      } else if (m < M){
        if (OUTBF){
          u16* out = (u16*)O0 + (size_t)lb*Ob;
          out[(size_t)m*ldo + n] = f2bf(a[r]+bv);
        } else {
          float* out = (float*)O0 + (size_t)lb*Ob;
          out[(size_t)m*ldo + n] = a[r]+bv;
        }
      }
    }
  }
}

// ================= role: mlp1 =================
__device__ void d_mlp1(int bid, int t, const float* __restrict__ pavg, const float* __restrict__ pmax,
    const float* __restrict__ aw1, const float* __restrict__ ab1,
    const float* __restrict__ mw1, const float* __restrict__ mb1,
    float* __restrict__ hid){
  int lb = bid >> 6; int rem = bid & 63; int pass = rem >> 5; int zb = rem & 31;
  int l = lb/NB;
  int wid = t>>6, lane = t&63;
  int r = zb*4 + wid;
  const float* pv = pass ? pmax : pavg;
  const float* w1 = pass ? mw1 : aw1;
  const float* b1 = pass ? mb1 : ab1;
  const float* wr = w1 + (size_t)(l*NC2+r)*NC;
  const float* pr = pv + (size_t)lb*NC;
  float s = dot4(((const float4*)wr)[lane], ((const float4*)pr)[lane]);
  s = wave_red(s);
  if (lane==0) hid[((size_t)lb*2 + pass)*NC2 + r] = fmaxf(s + b1[l*NC2+r], 0.f);
}

// ================= role: zphi =================
__device__ void d_zphi(int bid, int t, const float* __restrict__ zm, const float* __restrict__ sm,
    const float* __restrict__ phiw, const float* __restrict__ phib, float* __restrict__ zphi){
  int lb = bid >> 6; int rb = bid & 63; int l = lb/NB;
  int wid = t>>6, lane = t&63;
  int r = rb*4 + wid;
  const float* wr = phiw + (size_t)(l*NC + r)*NC;
  const float* zr = zm + (size_t)lb*NC;
  float s = dot4(((const float4*)wr)[lane], ((const float4*)zr)[lane]);
  s = wave_red(s);
  if (lane==0) zphi[(size_t)lb*NC + r] = s + phib[l*NC + r]*sm[lb];
}

__global__ __launch_bounds__(256) void sk_b(
    const u16* zfT, const u16* Wcat, const float* bcat, u16* TH3,
    const float* pavg, const float* pmax,
    const float* ap_w1, const float* ap_b1, const float* mp_w1, const float* mp_b1, float* hidb,
    const u16* roisT, const u16* Wcz, const float* bcz, u16* CZ3T,
    const float* zm, const float* sm, const float* phi_w, const float* phi_b, float* zphi){
  int bid = blockIdx.x, t = threadIdx.x;
  const int N1 = 96*24, N2 = N1 + 96*64, N3 = N2 + 96*8;
  if (bid < N1){
    d_mg<true,true,true,false>(bid, t, zfT, Wcat, bcat, TH3, ZZ, 384, NC, 256, 256, 384,
        (long)ZZ*256, (long)384*256, (long)ZZ*384, 6, 24);
  } else if (bid < N2){
    d_mlp1(bid - N1, t, pavg, pmax, ap_w1, ap_b1, mp_w1, mp_b1, hidb);
  } else if (bid < N3){
    d_mg<true,true,true,true>(bid - N2, t, roisT, Wcz, bcz, CZ3T, 49, 512, NC, 256, 256, 64,
        (long)49*256, (long)512*256, (long)512*64, 8, 8);
  } else {
    d_zphi(bid - N3, t, zm, sm, phi_w, phi_b, zphi);
  }
}

// ================= role: gxt =================
__device__ void d_gxt(int bid, int t, const u16* __restrict__ TH3, u16* __restrict__ GXT){
  int lb = bid >> 3; int z0 = (bid & 7)*32;
  __shared__ u16 lds[32][130];
  int n = t & 127, zi = t >> 7;
  const u16* src = TH3 + (size_t)lb*ZZ*384 + 256;
  #pragma unroll
  for (int p=0;p<16;p++){
    int z = z0 + zi + p*2;
    lds[zi+p*2][n] = (z < ZZ) ? src[(size_t)z*384 + n] : (u16)0;
  }
  __syncthreads();
  u16* dst = GXT + (size_t)lb*128*256;
  int zi2 = t & 31, ni = t >> 5;
  #pragma unroll
  for (int p=0;p<16;p++){
    int nn = ni + p*8;
    dst[(size_t)nn*256 + z0 + zi2] = lds[zi2][nn];
  }
}

// ================= role: mlp2 =================
__device__ void d_mlp2(int bid, int t, const float* __restrict__ hid,
    const float* __restrict__ aw2, const float* __restrict__ ab2,
    const float* __restrict__ mw2, const float* __restrict__ mb2,
    float* __restrict__ zavg, float* __restrict__ zmax){
  int lb = bid >> 7; int rem = bid & 127; int pass = rem >> 6; int cb = rem & 63;
  int l = lb/NB;
  int wid = t>>6, lane = t&63;
  int c = cb*4 + wid;
  const float* w2 = pass ? mw2 : aw2;
  const float* b2 = pass ? mb2 : ab2;
  const float* wr = w2 + (size_t)(l*NC+c)*NC2;
  const float* hr = hid + ((size_t)lb*2 + pass)*NC2;
  float2 wv = ((const float2*)wr)[lane];
  float2 hv = ((const float2*)hr)[lane];
  float s = wave_red(wv.x*hv.x + wv.y*hv.y);
  if (lane==0){
    float* zo = pass ? zmax : zavg;
    zo[(size_t)lb*NC + c] = s + b2[l*NC+c];
  }
}

// ================= role: wvec =================
__device__ void d_wvec(int lb, int t, const float* __restrict__ zphi, const float* __restrict__ dw,
    const float* __restrict__ db, float* __restrict__ wvec, float* __restrict__ cb){
  int l = lb/NB;
  __shared__ float zp[NC];
  __shared__ float red[NC];
  zp[t] = zphi[(size_t)lb*NC + t];
  __syncthreads();
  float s = 0.f;
  const float* dwl = dw + (size_t)l*NC*NC;
  for (int c=0;c<NC;c++) s += zp[c]*dwl[(size_t)c*NC + t];
  wvec[(size_t)lb*NC + t] = s;
  red[t] = zp[t]*db[l*NC + t];
  __syncthreads();
  for (int off2=128; off2>0; off2>>=1){
    if (t < off2) red[t] += red[t+off2];
    __syncthreads();
  }
  if (t==0) cb[lb] = red[0];
}

__global__ __launch_bounds__(256) void sk_c(
    const u16* TH3, float* Sb,
    u16* GXT,
    const float* hidb, const float* ap_w2, const float* ap_b2,
    const float* mp_w2, const float* mp_b2, float* zavg, float* zmax,
    const u16* CZ3T, float* Fbuf,
    const float* zphi, const float* delta_w, const float* delta_b, float* wvec, float* cbuf){
  int bid = blockIdx.x, t = threadIdx.x;
  const int N1 = 96*16, N2 = N1 + 96*8, N3 = N2 + 96*128, N4 = N3 + 96*16;
  if (bid < N1){
    d_mg<false,false,false,false>(bid, t, TH3, TH3+128, nullptr, Sb, ZZ, ZZ, NC2, 384, 384, ZZ,
        (long)ZZ*384, (long)ZZ*384, (long)ZZ*ZZ, 4, 16);
  } else if (bid < N2){
    d_gxt(bid - N1, t, TH3, GXT);
  } else if (bid < N3){
    d_mlp2(bid - N2, t, hidb, ap_w2, ap_b2, mp_w2, mp_b2, zavg, zmax);
  } else if (bid < N4){
    d_mg<false,false,false,false>(bid - N3, t, CZ3T, CZ3T+256*64, nullptr, Fbuf, NC, NC, 64, 64, 64, NC,
        (long)512*64, (long)512*64, (long)NC*NC, 4, 16);
  } else {
    d_wvec(bid - N4, t, zphi, delta_w, delta_b, wvec, cbuf);
  }
}

// ================= role: sc partial =================
__device__ void d_sc_part(int bid, int t, const float* __restrict__ xf,
    const float* __restrict__ wvec, float* __restrict__ part){
  int lb = bid >> 4; int rem = bid & 15; int xt = rem >> 2, cs = rem & 3;
  __shared__ float wv[64];
  if (t < 64) wv[t] = wvec[(size_t)lb*NC + cs*64 + t];
  __syncthreads();
  int x = xt*256 + t;
  if (x >= XX) return;
  const float* xb = xf + ((size_t)lb*NC + cs*64)*XX + x;
  float s = 0.f;
  #pragma unroll 8
  for (int c=0;c<64;c++) s += wv[c]*xb[(size_t)c*XX];
  part[((size_t)lb*4 + cs)*XX + x] = s;
}

// ================= role: softmax =================
__device__ void d_softmax(int bid, int t, const float* __restrict__ S, u16* __restrict__ P){
  int row = bid*4 + (t >> 6);
  int lane = t & 63;
  const float* r = S + (size_t)row*ZZ;
  float v[4]; float mx = -1e30f;
  #pragma unroll
  for (int q=0;q<4;q++){
    int j = lane + q*64;
    v[q] = (j<ZZ) ? r[j] : -1e30f;
    mx = fmaxf(mx, v[q]);
  }
  #pragma unroll
  for (int off=32; off>0; off>>=1) mx = fmaxf(mx, __shfl_xor(mx, off));
  float sum = 0.f;
  #pragma unroll
  for (int q=0;q<4;q++){
    v[q] = __expf(v[q]-mx);
    if (lane + q*64 < ZZ) sum += v[q];
  }
  #pragma unroll
  for (int off=32; off>0; off>>=1) sum += __shfl_xor(sum, off);
  float inv = 1.f/(16.f*sum);
  u16* pr = P + (size_t)row*256;
  #pragma unroll
  for (int q=0;q<4;q++){
    int j = lane + q*64;
    pr[j] = (j<ZZ) ? f2bf(v[q]*inv) : (u16)0;
  }
}

// ================= role: relw =================
__device__ void d_relw(int bid, int t, const float* __restrict__ F,
    const float* __restrict__ gw, const float* __restrict__ gb,
    float* __restrict__ rel){
  int lb = bid >> 7; int rb = bid & 127; int l = lb/NB;
  int wid = t>>6, lane = t&63;
  int r = rb*4 + wid;
  const float* wrow = gw + ((size_t)l*2*NC + r)*NC;
  const float* frow = F + (size_t)lb*NC*NC + (size_t)(r>>1)*NC;
  float s = dot4(((const float4*)wrow)[lane], ((const float4*)frow)[lane]);
  s = wave_red(s);
  if (lane==0) rel[(size_t)lb*2*NC + r] = fmaxf(s + gb[l*2*NC+r], 0.f);
}

__global__ __launch_bounds__(256) void sk_d(
    const float* xf, const float* wvec, float* part,
    const float* Sb, u16* Pb,
    const float* Fbuf, const float* cz_gw, const float* cz_gb, float* relb){
  int bid = blockIdx.x, t = threadIdx.x;
  const int N1 = 96*16, N2 = N1 + 5400;
  if (bid < N1){
    d_sc_part(bid, t, xf, wvec, part);
  } else if (bid < N2){
    d_softmax(bid - N1, t, Sb, Pb);
  } else {
    d_relw(bid - N2, t, Fbuf, cz_gw, cz_gb, relb);
  }
}

// ================= role: z2n+cues =================
__device__ void d_z2ncue(int bid, int t, const float* __restrict__ rel,
    const float* __restrict__ aw, const float* __restrict__ ab,
    const float* __restrict__ zavg, const float* __restrict__ zmax,
    const float* __restrict__ drw, const float* __restrict__ drb,
    float* __restrict__ cues){
  int lb = bid >> 6; int cb = bid & 63; int l = lb/NB;
  int wid = t>>6, lane = t&63;
  int c = cb*4 + wid;
  const float* arow = aw + ((size_t)l*NC + c)*2*NC;
  const float* rrow = rel + (size_t)lb*2*NC;
  float s = dot4(((const float4*)arow)[lane],    ((const float4*)rrow)[lane])
          + dot4(((const float4*)arow)[lane+64], ((const float4*)rrow)[lane+64]);
  s = wave_red(s);
  if (lane==0){
    float z2 = s + ab[l*NC+c];
    size_t idx = (size_t)lb*NC + c;
    const float* dw = drw + (size_t)(l*NC + c)*3;
    float x = dw[0]*zavg[idx] + dw[1]*zmax[idx] + dw[2]*z2 + drb[l*NC+c];
    cues[idx] = 1.f/(1.f + __expf(-x));
  }
}

// ================= role: sc finalize =================
__device__ void d_scfin(int lb, int t, const float* __restrict__ part,
    const float* __restrict__ cb, float* __restrict__ scb){
  float cbv = cb[lb];
  const float* pp = part + (size_t)lb*4*XX;
  for (int x = t; x < XX; x += 256){
    float s = pp[x] + pp[XX + x] + pp[2*XX + x] + pp[3*XX + x];
    scb[(size_t)lb*XX + x] = fminf(fmaxf((s + cbv)*0.0625f, 0.f), 1.f);
  }
}

__global__ __launch_bounds__(256) void sk_e(
    const u16* Pb, const u16* GXT, u16* Ybb,
    const float* relb, const float* cz_aw, const float* cz_ab,
    const float* zavg, const float* zmax, const float* dr_w, const float* dr_b, float* cues,
    const float* part, const float* cbuf, float* scb){
  int bid = blockIdx.x, t = threadIdx.x;
  const int N1 = 96*8, N2 = N1 + 96*64;
  if (bid < N1){
    d_mg<false,false,true,false>(bid, t, Pb, GXT, nullptr, Ybb, ZZ, NC2, 256, 256, 256, NC2,
        (long)ZZ*256, (long)128*256, (long)ZZ*NC2, 2, 8);
  } else if (bid < N2){
    d_z2ncue(bid - N1, t, relb, cz_aw, cz_ab, zavg, zmax, dr_w, dr_b, cues);
  } else {
    d_scfin(bid - N2, t, part, cbuf, scb);
  }
}

// ================= role: outconv (LDS-staged coalesced epilogue) =================
__device__ void d_outconv(int bid, int t, const u16* __restrict__ outwb,
    const u16* __restrict__ Ybb,
    const float* __restrict__ bng, const float* __restrict__ bnb,
    const float* __restrict__ bnm, const float* __restrict__ bnv,
    const float* __restrict__ cues, const float* __restrict__ zf,
    float* __restrict__ dzfout, float* __restrict__ dzffull){
  int lb = bid >> 4; int tile = bid & 15; int l = lb/NB;
  const u16* A = outwb + (size_t)l*NC*NC2;
  const u16* B = Ybb + (size_t)lb*ZZ*NC2;
  int tm = tile >> 2, tn = tile & 3;
  int m0 = tm*64, n0 = tn*64;
  __shared__ u16 Asl[64][40];
  __shared__ u16 Bsl[64][40];
  __shared__ float ob[64][65];
  int w = t>>6, l6 = t&63;
  int fr = l6&15, kg = (l6>>4)*8;
  int srow = t>>2, sseg = (t&3)*8;
  f4v ac0={0,0,0,0}, ac1={0,0,0,0}, ac2={0,0,0,0}, ac3={0,0,0,0};
  for (int kc=0; kc<NC2; kc+=32){
    us8 va = *(const us8*)&A[(size_t)(m0+srow)*NC2 + kc + sseg];
    *(us8*)&Asl[srow][sseg] = va;
    us8 vb = {0,0,0,0,0,0,0,0};
    int bn = n0 + srow;
    if (bn < ZZ) vb = *(const us8*)&B[(size_t)bn*NC2 + kc + sseg];
    *(us8*)&Bsl[srow][sseg] = vb;
    __syncthreads();
    bf8v af = *(const bf8v*)&Asl[w*16 + fr][kg];
    bf8v b0 = *(const bf8v*)&Bsl[fr][kg];
    bf8v b1 = *(const bf8v*)&Bsl[16+fr][kg];
    bf8v b2 = *(const bf8v*)&Bsl[32+fr][kg];
    bf8v b3 = *(const bf8v*)&Bsl[48+fr][kg];
    ac0 = __builtin_amdgcn_mfma_f32_16x16x32_bf16(af, b0, ac0, 0,0,0);
    ac1 = __builtin_amdgcn_mfma_f32_16x16x32_bf16(af, b1, ac1, 0,0,0);
    ac2 = __builtin_amdgcn_mfma_f32_16x16x32_bf16(af, b2, ac2, 0,0,0);
    ac3 = __builtin_amdgcn_mfma_f32_16x16x32_bf16(af, b3, ac3, 0,0,0);
    __syncthreads();
  }
  // load zf tile [64 c-rows][64 z-cols] coalesced
  #pragma unroll
  for (int it=0; it<16; ++it){
    int rr = (t>>6) + it*4;
    int zz = t & 63;
    int z = n0 + zz;
    ob[rr][zz] = (z < ZZ) ? zf[((size_t)lb*NC + m0 + rr)*ZZ + z] : 0.f;
  }
  __syncthreads();
  // apply BN/cues/residual in LDS
  int mbr = w*16 + ((l6>>4)<<2);
  #pragma unroll
  for (int j=0;j<4;j++){
    int zrel = j*16 + fr;
    int z = n0 + zrel;
    if (z >= ZZ) continue;
    f4v a = (j==0)?ac0:(j==1)?ac1:(j==2)?ac2:ac3;
    #pragma unroll
    for (int r=0;r<4;r++){
      int crel = mbr + r; int c = m0 + crel;
      float scale = bng[l*NC+c] * rsqrtf(bnv[l*NC+c] + 1e-5f);
      float val = (a[r] - bnm[l*NC+c])*scale + bnb[l*NC+c];
      float cu = cues[(size_t)lb*NC + c];
      float zv = ob[crel][zrel];
      ob[crel][zrel] = cu*zv + zv + val;
    }
  }
  __syncthreads();
  // coalesced zffull writes
  #pragma unroll
  for (int it=0; it<16; ++it){
    int rr = (t>>6) + it*4;
    int zz = t & 63;
    int z = n0 + zz;
    if (z < ZZ) dzffull[((size_t)lb*NC + m0 + rr)*ZZ + z] = ob[rr][zz];
  }
  // zfout 7x7 slice (z in [64,160])
  for (int e=t; e<64*49; e+=256){
    int cc = e / 49; int idx = e % 49; int p = idx/7, q = idx%7;
    int z = (p+4)*15 + (q+4);
    if (z >= n0 && z < n0+64)
      dzfout[((size_t)lb*NC + m0 + cc)*49 + p*7 + q] = ob[cc][z - n0];
  }
}

// ================= role: xfout (block per (lb, 8-ch group), float4) =================
__device__ void d_xfout(int bid, int t, const float* __restrict__ xf,
    const float* __restrict__ scb, const float* __restrict__ cues,
    float* __restrict__ out){
  int lb = bid >> 5; int cg = bid & 31;
  int cbase = cg*8;
  __shared__ float cu1s[8];
  if (t < 8) cu1s[t] = 1.f + cues[(size_t)lb*NC + cbase + t];
  __syncthreads();
  const float4* xr = (const float4*)(xf + ((size_t)lb*NC + cbase)*XX);
  float4* orow = (float4*)(out + ((size_t)lb*NC + cbase)*XX);
  const float* sr = scb + (size_t)lb*XX;
  const int NV = 8*XX/4;  // 1922
  for (int idx = t; idx < NV; idx += 256){
    float4 v = xr[idx];
    int rel = idx*4;
    float4 o;
    #pragma unroll
    for (int k=0;k<4;k++){
      int e = rel + k;
      int cl = e / XX;
      int x  = e - cl*XX;
      ((float*)&o)[k] = cu1s[cl]*((const float*)&v)[k] - sr[x];
    }
    orow[idx] = o;
  }
}

__global__ __launch_bounds__(256) void sk_f(
    const u16* outwb, const u16* Ybb,
    const float* bn_g, const float* bn_b, const float* bn_m, const float* bn_v,
    const float* cues, const float* zf, float* o_zfout, float* o_zffull,
    const float* xf, const float* scb, float* o_xfout){
  int bid = blockIdx.x, t = threadIdx.x;
  const int N1 = 96*16;
  if (bid < N1){
    d_outconv(bid, t, outwb, Ybb, bn_g, bn_b, bn_m, bn_v, cues, zf, o_zfout, o_zffull);
  } else {
    d_xfout(bid - N1, t, xf, scb, cues, o_xfout);
  }
}

extern "C" void kernel_launch(void* const* d_in, const int* in_sizes, int n_in,
                              void* d_out, int out_size, void* d_ws, size_t ws_size,
                              hipStream_t stream){
  const float* zf      = (const float*)d_in[0];
  const float* xf      = (const float*)d_in[1];
  const float* maskp   = (const float*)d_in[2];
  const float* box     = (const float*)d_in[3];
  const float* nl_g_w  = (const float*)d_in[4];
  const float* nl_g_b  = (const float*)d_in[5];
  const float* nl_th_w = (const float*)d_in[6];
  const float* nl_th_b = (const float*)d_in[7];
  const float* nl_ph_w = (const float*)d_in[8];
  const float* nl_ph_b = (const float*)d_in[9];
  const float* nl_out_w= (const float*)d_in[10];
  const float* bn_g    = (const float*)d_in[11];
  const float* bn_b    = (const float*)d_in[12];
  const float* bn_m    = (const float*)d_in[13];
  const float* bn_v    = (const float*)d_in[14];
  const float* cz_th_w = (const float*)d_in[15];
  const float* cz_th_b = (const float*)d_in[16];
  const float* cz_ph_w = (const float*)d_in[17];
  const float* cz_ph_b = (const float*)d_in[18];
  const float* cz_gw   = (const float*)d_in[19];
  const float* cz_gb   = (const float*)d_in[20];
  const float* cz_aw   = (const float*)d_in[21];
  const float* cz_ab   = (const float*)d_in[22];
  const float* ap_w1   = (const float*)d_in[23];
  const float* ap_b1   = (const float*)d_in[24];
  const float* ap_w2   = (const float*)d_in[25];
  const float* ap_b2   = (const float*)d_in[26];
  const float* mp_w1   = (const float*)d_in[27];
  const float* mp_b1   = (const float*)d_in[28];
  const float* mp_w2   = (const float*)d_in[29];
  const float* mp_b2   = (const float*)d_in[30];
  const float* dr_w    = (const float*)d_in[31];
  const float* dr_b    = (const float*)d_in[32];
  const float* ac1_w   = (const float*)d_in[33];
  const float* ac1_b   = (const float*)d_in[34];
  const float* ac2_w   = (const float*)d_in[35];
  const float* ac2_b   = (const float*)d_in[36];
  const float* ac3_w   = (const float*)d_in[37];
  const float* ac3_b   = (const float*)d_in[38];
  const float* ac4_w   = (const float*)d_in[39];
  const float* ac4_b   = (const float*)d_in[40];
  const float* phi_w   = (const float*)d_in[41];
  const float* phi_b   = (const float*)d_in[42];
  const float* delta_w = (const float*)d_in[43];
  const float* delta_b = (const float*)d_in[44];
  (void)in_sizes; (void)n_in; (void)out_size; (void)ws_size;

  float* ws = (float*)d_ws;
  size_t off = 0;
  auto alloc = [&](size_t n){ size_t o = off; off += (n + 15) & ~(size_t)15; return o; };
  float* TH3f  = ws + alloc((size_t)NL*NB*ZZ*384/2);
  float* Sb    = ws + alloc((size_t)NL*NB*ZZ*ZZ);
  float* Fbuf  = ws + alloc((size_t)NL*NB*NC*NC);
  float* zfTf  = ws + alloc((size_t)NL*NB*ZZ*NC/2);
  float* Pbf   = ws + alloc((size_t)NL*NB*ZZ*256/2);
  float* GXTf  = ws + alloc((size_t)NL*NB*128*256/2);
  float* Ybbf  = ws + alloc((size_t)NL*NB*ZZ*NC2/2);
  float* CZ3Tf = ws + alloc((size_t)NL*NB*512*64/2);
  float* roisTf= ws + alloc((size_t)NL*NB*49*NC/2);
  float* Wcatf = ws + alloc((size_t)NL*384*256/2);
  float* Wczf  = ws + alloc((size_t)NL*512*256/2);
  float* outwbf= ws + alloc((size_t)NL*NC*NC2/2);
  u16* TH3  = (u16*)TH3f;
  u16 *zfT=(u16*)zfTf, *Pb=(u16*)Pbf, *GXT=(u16*)GXTf, *Ybb=(u16*)Ybbf,
      *CZ3T=(u16*)CZ3Tf, *roisT=(u16*)roisTf, *Wcat=(u16*)Wcatf,
      *Wcz=(u16*)Wczf, *outwb=(u16*)outwbf;
  float* bcat = ws + alloc((size_t)NL*384);
  float* bcz  = ws + alloc((size_t)NL*512);
  float* m3   = ws + alloc((size_t)NL*NB*ZZ);
  float* pavg = ws + alloc((size_t)NL*NB*NC);
  float* pmax = ws + alloc((size_t)NL*NB*NC);
  float* zavg = ws + alloc((size_t)NL*NB*NC);
  float* zmax = ws + alloc((size_t)NL*NB*NC);
  float* cues = ws + alloc((size_t)NL*NB*NC);
  float* zm   = ws + alloc((size_t)NL*NB*NC);
  float* zphi = ws + alloc((size_t)NL*NB*NC);
  float* wvec = ws + alloc((size_t)NL*NB*NC);
  float* sm   = ws + alloc((size_t)NL*NB);
  float* cbuf = ws + alloc((size_t)NL*NB);
  float* part = ws + alloc((size_t)NL*NB*4*XX);
  float* scb  = ws + alloc((size_t)NL*NB*XX);
  float* hidb = ws + alloc((size_t)NL*NB*2*NC2);
  float* relb = ws + alloc((size_t)NL*NB*2*NC);

  float* outp    = (float*)d_out;
  float* o_zfout = outp;
  float* o_zffull= outp + (size_t)NL*NB*NC*49;
  float* o_xfout = o_zffull + (size_t)NL*NB*NC*ZZ;

  // L1: mask + packs
  sk_a<<<NL*NB + (NL*512*256+255)/256, 256, 0, stream>>>(
      maskp, ac1_w, ac1_b, ac2_w, ac2_b, ac3_w, ac3_b, ac4_w, ac4_b, m3,
      nl_th_w, nl_th_b, nl_ph_w, nl_ph_b, nl_g_w, nl_g_b,
      cz_th_w, cz_th_b, cz_ph_w, cz_ph_b, nl_out_w,
      Wcat, bcat, Wcz, bcz, outwb);
  // L2: fused zf pass
  k_zfall<<<dim3(NL*NB, 8), 256, 0, stream>>>(zf, box, m3, zfT, pavg, pmax,
                                               roisT, zm, sm);
  // L3: projcat + mlp1 + CZ + zphi
  sk_b<<<96*24 + 96*64 + 96*8 + 96*64, 256, 0, stream>>>(
      zfT, Wcat, bcat, TH3, pavg, pmax, ap_w1, ap_b1, mp_w1, mp_b1, hidb,
      roisT, Wcz, bcz, CZ3T, zm, sm, phi_w, phi_b, zphi);
  // L4: S + gxt + mlp2 + F + wvec
  sk_c<<<96*16 + 96*8 + 96*128 + 96*16 + 96, 256, 0, stream>>>(
      TH3, Sb, GXT, hidb, ap_w2, ap_b2, mp_w2, mp_b2, zavg, zmax,
      CZ3T, Fbuf, zphi, delta_w, delta_b, wvec, cbuf);
  // L5: sc_part + softmax + relw
  sk_d<<<96*16 + 5400 + 96*128, 256, 0, stream>>>(
      xf, wvec, part, Sb, Pb, Fbuf, cz_gw, cz_gb, relb);
  // L6: PV + z2ncue + scfin
  sk_e<<<96*8 + 96*64 + 96, 256, 0, stream>>>(
      Pb, GXT, Ybb, relb, cz_aw, cz_ab, zavg, zmax, dr_w, dr_b, cues,
      part, cbuf, scb);
  // L7: outconv + xfout
  sk_f<<<96*16 + 96*32, 256, 0, stream>>>(
      outwb, Ybb, bn_g, bn_b, bn_m, bn_v, cues, zf, o_zfout, o_zffull,
      xf, scb, o_xfout);
}

// Round 19
// 258.221 us; speedup vs baseline: 4.0861x; 1.0023x over previous
//
#include <hip/hip_runtime.h>
#include <math.h>

#define NL 3
#define NB 32
#define NC 256
#define NC2 128
#define HZ 15
#define ZZ 225
#define XX 961
#define HMD 127

typedef unsigned short u16;
typedef __attribute__((ext_vector_type(8))) unsigned short us8;
typedef __attribute__((ext_vector_type(8))) short bf8v;
typedef __attribute__((ext_vector_type(4))) float f4v;

__device__ __forceinline__ u16 f2bf(float f){
  unsigned int u = __float_as_uint(f);
  unsigned int r = (u + 0x7fffu + ((u>>16)&1u)) >> 16;
  return (u16)r;
}
__device__ __forceinline__ float hat_int(float u){
  if (u <= -1.f) return 0.f;
  if (u <= 0.f){ float t = u + 1.f; return 0.5f*t*t; }
  if (u <= 1.f){ float t = 1.f - u; return 1.f - 0.5f*t*t; }
  return 1.f;
}
__device__ __forceinline__ float dot4(float4 a, float4 b){
  return a.x*b.x + a.y*b.y + a.z*b.z + a.w*b.w;
}
__device__ __forceinline__ float wave_red(float s){
  #pragma unroll
  for (int off=32; off>0; off>>=1) s += __shfl_xor(s, off);
  return s;
}

// ================= role: fused mask branch (bid in [0,96)) =================
__device__ void d_mask(int lb, int t, const float* __restrict__ mask,
    const float* __restrict__ w1, const float* __restrict__ b1,
    const float* __restrict__ w2, const float* __restrict__ b2,
    const float* __restrict__ w3, const float* __restrict__ b3,
    const float* __restrict__ w4, const float* __restrict__ b4,
    float* __restrict__ m3out){
  int l = lb/NB, b = lb%NB;
  __shared__ float c1s[4][56][56];
  __shared__ float c2s[8][28][28];
  __shared__ float r1s[8][14][14];
  __shared__ float c3s[4][14][14];
  __shared__ float r2s[4][15][15];
  __shared__ int   y0t[14];
  __shared__ float wyt[14];
  __shared__ int   y0t15[15];
  __shared__ float wyt15[15];
  if (t < 14){
    float sy = 122.0f/13.0f;
    float yf = (float)t * sy;
    int y0 = (int)floorf(yf); y0 = min(max(y0,0), 121);
    y0t[t] = y0; wyt[t] = yf - (float)y0;
  } else if (t < 29){
    int q = t-14;
    float sy = 13.0f/14.0f;
    float yf = (float)q * sy;
    int y0 = (int)floorf(yf); y0 = min(max(y0,0), 12);
    y0t15[q] = y0; wyt15[q] = yf - (float)y0;
  }
  __syncthreads();
  const float* mb = mask + (size_t)b*HMD*HMD;
  const float* wc1 = w1 + (size_t)l*4*2*9;
  for (int e=t; e<4*56*56; e+=256){
    int ci = e % 56, ri = (e/56) % 56, oc = e/(56*56);
    int row = y0t[ri>>2] + (ri&3);
    int col = y0t[ci>>2] + (ci&3);
    float acc = b1[l*4+oc];
    #pragma unroll
    for (int ky=0;ky<3;ky++)
      #pragma unroll
      for (int kx=0;kx<3;kx++){
        float mv = mb[(row+ky)*HMD + (col+kx)];
        acc += wc1[((oc*2+0)*3+ky)*3+kx]*mv;
        acc += wc1[((oc*2+1)*3+ky)*3+kx]*(1.f-mv);
      }
    c1s[oc][ri][ci] = fmaxf(acc, 0.f);
  }
  __syncthreads();
  const float* wc2 = w2 + (size_t)l*8*4*9;
  for (int e=t; e<8*28*28; e+=256){
    int j = e % 28, i = (e/28) % 28, oc = e/(28*28);
    int g = i>>1, dy = i&1, gc = j>>1, dx = j&1;
    float acc = b2[l*8+oc];
    #pragma unroll
    for (int ic=0; ic<4; ic++)
      #pragma unroll
      for (int ky=0;ky<3;ky++)
        #pragma unroll
        for (int kx=0;kx<3;kx++)
          acc += wc2[((oc*4+ic)*3+ky)*3+kx]*c1s[ic][g*4+dy+ky][gc*4+dx+kx];
    c2s[oc][i][j] = fmaxf(acc, 0.f);
  }
  __syncthreads();
  for (int e=t; e<8*14*14; e+=256){
    int ox = e % 14, oy = (e/14) % 14, oc = e/(14*14);
    float wy = wyt[oy], wx = wyt[ox];
    float v00 = c2s[oc][2*oy][2*ox],   v01 = c2s[oc][2*oy][2*ox+1];
    float v10 = c2s[oc][2*oy+1][2*ox], v11 = c2s[oc][2*oy+1][2*ox+1];
    r1s[oc][oy][ox] = (v00*(1.f-wy)+v10*wy)*(1.f-wx) + (v01*(1.f-wy)+v11*wy)*wx;
  }
  __syncthreads();
  const float* wc3 = w3 + (size_t)l*4*8*9;
  for (int e=t; e<4*14*14; e+=256){
    int x = e % 14, y = (e/14) % 14, oc = e/(14*14);
    float acc = b3[l*4+oc];
    for (int ic=0; ic<8; ic++)
      #pragma unroll
      for (int ky=-1;ky<=1;ky++){
        int yy = y+ky; if (yy<0||yy>=14) continue;
        #pragma unroll
        for (int kx=-1;kx<=1;kx++){
          int xx = x+kx; if (xx<0||xx>=14) continue;
          acc += wc3[((oc*8+ic)*3+(ky+1))*3+(kx+1)]*r1s[ic][yy][xx];
        }
      }
    c3s[oc][y][x] = acc;
  }
  __syncthreads();
  for (int e=t; e<4*15*15; e+=256){
    int ox = e % 15, oy = (e/15) % 15, oc = e/(15*15);
    int y0 = y0t15[oy], x0 = y0t15[ox];
    float wy = wyt15[oy], wx = wyt15[ox];
    float v00 = c3s[oc][y0][x0],   v01 = c3s[oc][y0][x0+1];
    float v10 = c3s[oc][y0+1][x0], v11 = c3s[oc][y0+1][x0+1];
    r2s[oc][oy][ox] = (v00*(1.f-wy)+v10*wy)*(1.f-wx) + (v01*(1.f-wy)+v11*wy)*wx;
  }
  __syncthreads();
  const float* wc4 = w4 + (size_t)l*1*4*9;
  for (int e=t; e<15*15; e+=256){
    int x = e % 15, y = e/15;
    float acc = b4[l];
    #pragma unroll
    for (int ic=0; ic<4; ic++)
      #pragma unroll
      for (int ky=-1;ky<=1;ky++){
        int yy = y+ky; if (yy<0||yy>=15) continue;
        #pragma unroll
        for (int kx=-1;kx<=1;kx++){
          int xx = x+kx; if (xx<0||xx>=15) continue;
          acc += wc4[(ic*3+(ky+1))*3+(kx+1)]*r2s[ic][yy][xx];
        }
      }
    m3out[(size_t)lb*ZZ + y*15 + x] = acc;
  }
}

// ================= role: weight packs =================
__device__ void d_packs(int idx,
    const float* __restrict__ thw, const float* __restrict__ thb,
    const float* __restrict__ phw, const float* __restrict__ phb,
    const float* __restrict__ gw,  const float* __restrict__ gb,
    const float* __restrict__ czthw, const float* __restrict__ czthb,
    const float* __restrict__ czphw, const float* __restrict__ czphb,
    const float* __restrict__ outw,
    u16* __restrict__ Wcat, float* __restrict__ bcat,
    u16* __restrict__ Wcz, float* __restrict__ bcz,
    u16* __restrict__ outwb){
  if (idx < NL*384*256){
    int k = idx & 255; int r = (idx >> 8) % 384; int l = idx/(384*256);
    float v;
    if (r < 128)      v = thw[((size_t)l*128 + r)*256 + k];
    else if (r < 256) v = phw[((size_t)l*128 + (r-128))*256 + k];
    else              v = gw [((size_t)l*128 + (r-256))*256 + k];
    Wcat[idx] = f2bf(v);
  }
  if (idx < NL*512*256){
    int k = idx & 255; int r = (idx >> 8) % 512; int l = idx/(512*256);
    float v;
    if (r < 256) v = czthw[((size_t)l*256 + r)*256 + k];
    else         v = czphw[((size_t)l*256 + (r-256))*256 + k];
    Wcz[idx] = f2bf(v);
  }
  if (idx < NL*NC*NC2) outwb[idx] = f2bf(outw[idx]);
  if (idx < NL*384){
    int r = idx % 384, l = idx/384;
    bcat[idx] = (r<128) ? thb[l*128+r] : (r<256) ? phb[l*128+r-128] : gb[l*128+r-256];
  }
  if (idx < NL*512){
    int r = idx % 512, l = idx/512;
    bcz[idx] = (r<256) ? czthb[l*256+r] : czphb[l*256+r-256];
  }
}

__global__ __launch_bounds__(256) void sk_a(const float* __restrict__ mask,
    const float* w1, const float* b1, const float* w2, const float* b2,
    const float* w3, const float* b3, const float* w4, const float* b4,
    float* m3out,
    const float* thw, const float* thb, const float* phw, const float* phb,
    const float* gw, const float* gb,
    const float* czthw, const float* czthb, const float* czphw, const float* czphb,
    const float* outw, u16* Wcat, float* bcat, u16* Wcz, float* bcz, u16* outwb){
  int bid = blockIdx.x, t = threadIdx.x;
  if (bid < NL*NB){
    d_mask(bid, t, mask, w1, b1, w2, b2, w3, b3, w4, b4, m3out);
  } else {
    d_packs((bid - NL*NB)*256 + t, thw, thb, phw, phb, gw, gb,
            czthw, czthb, czphw, czphb, outw, Wcat, bcat, Wcz, bcz, outwb);
  }
}

// ============ fused zf pass (own launch, grid (96,8)) ============
__global__ __launch_bounds__(256) void k_zfall(const float* __restrict__ zf,
    const float* __restrict__ box, const float* __restrict__ m3,
    u16* __restrict__ zfT, float* __restrict__ pavg, float* __restrict__ pmax,
    u16* __restrict__ roisT, float* __restrict__ zm, float* __restrict__ sm){
  int lb = blockIdx.x; int b = lb % NB; int c0 = blockIdx.y*32;
  __shared__ float fld[32*ZZ];
  __shared__ float Wy[7][15], Wx[7][15];
  __shared__ float tmp[32][7][16];
  __shared__ float roi[32][49];
  __shared__ float ms[ZZ];
  __shared__ float area_s;
  int t = threadIdx.x;
  const float* bx = box + b*4;
  const float SC = 15.0f/127.0f;
  float x1 = bx[0]*SC, y1 = bx[1]*SC, x2 = bx[2]*SC, y2 = bx[3]*SC;
  float bh = (y2-y1)/7.f, bw = (x2-x1)/7.f;
  if (t < 105){ int p=t/15, i=t%15;
    Wy[p][i] = hat_int(y1+(float)(p+1)*bh - (float)i) - hat_int(y1+(float)p*bh - (float)i); }
  else if (t < 210){ int q=(t-105)/15, i=(t-105)%15;
    Wx[q][i] = hat_int(x1+(float)(q+1)*bw - (float)i) - hat_int(x1+(float)q*bw - (float)i); }
  if (t == 255) area_s = fmaxf(bh*bw, 1e-6f);
  if (t < ZZ) ms[t] = m3[(size_t)lb*ZZ + t];
  const float* src = zf + ((size_t)lb*NC + c0)*ZZ;
  for (int e=t; e<32*ZZ; e+=256) fld[e] = src[e];
  __syncthreads();
  u16* dstT = zfT + (size_t)lb*ZZ*NC + c0;
  for (int e=t; e<ZZ*32; e+=256){
    int ci = e & 31, z = e >> 5;
    dstT[(size_t)z*NC + ci] = f2bf(fld[ci*ZZ + z]);
  }
  float inv_area = 1.f/area_s;
  for (int e=t; e<32*105; e+=256){
    int w = e%15; int pc = e/15; int p = pc%7; int cc = pc/7;
    float s = 0.f;
    #pragma unroll
    for (int h=0;h<15;h++) s += Wy[p][h]*fld[cc*ZZ + h*15 + w];
    tmp[cc][p][w] = s;
  }
  {
    int cc = t>>3, sub = t&7;
    const float* fr = &fld[cc*ZZ];
    float s = 0.f;
    for (int z=sub; z<ZZ; z+=8) s += fr[z]*ms[z];
    s += __shfl_down(s, 4, 8);
    s += __shfl_down(s, 2, 8);
    s += __shfl_down(s, 1, 8);
    if (sub == 0) zm[(size_t)lb*NC + c0 + cc] = s;
  }
  if (blockIdx.y == 0 && t < 64){
    float ss = 0.f;
    for (int z=t; z<ZZ; z+=64) ss += ms[z];
    ss = wave_red(ss);
    if (t == 0) sm[lb] = ss;
  }
  __syncthreads();
  for (int e=t; e<32*49; e+=256){
    int q = e%7; int pc = e/7; int p = pc%7; int cc = pc/7;
    float s = 0.f;
    #pragma unroll
    for (int w=0;w<15;w++) s += tmp[cc][p][w]*Wx[q][w];
    roi[cc][p*7+q] = s*inv_area;
  }
  __syncthreads();
  u16* dR = roisT + (size_t)lb*49*NC + c0;
  for (int e=t; e<49*32; e+=256){
    int ci = e & 31, s = e >> 5;
    dR[(size_t)s*NC + ci] = f2bf(roi[ci][s]);
  }
  if (t < 32){
    float s = 0.f, m = -1e30f;
    #pragma unroll
    for (int i=0;i<49;i++){ float v = roi[t][i]; s += v; m = fmaxf(m,v); }
    pavg[(size_t)lb*NC + c0 + t] = s/49.f;
    pmax[(size_t)lb*NC + c0 + t] = m;
  }
}

// ================= role: bf16 MFMA GEMM (flattened bid) =================
template<bool BPERL, bool HASBIAS, bool OUTBF, bool TROUT>
__device__ void d_mg(int bid, int t,
    const u16* __restrict__ A0, const u16* __restrict__ B0,
    const float* __restrict__ bias0, void* __restrict__ O0,
    int M, int N, int K, int lda, int ldb, int ldo,
    long Ab, long Bb, long Ob, int ntn, int ntiles)
{
  int lb = bid / ntiles; int tile = bid % ntiles; int l = lb / NB;
  const u16* A = A0 + (size_t)lb*Ab;
  const u16* B = B0 + (BPERL ? (size_t)l : (size_t)lb)*Bb;
  int tm = tile / ntn, tn = tile % ntn;
  int m0 = tm*64, n0 = tn*64;
  __shared__ u16 Asl[64][40];
  __shared__ u16 Bsl[64][40];
  int w = t>>6, l6 = t&63;
  int fr = l6&15, kg = (l6>>4)*8;
  int srow = t>>2, sseg = (t&3)*8;
  f4v ac0={0,0,0,0}, ac1={0,0,0,0}, ac2={0,0,0,0}, ac3={0,0,0,0};
  for (int kc=0; kc<K; kc+=32){
    us8 va = {0,0,0,0,0,0,0,0};
    int am = m0 + srow;
    if (am < M) va = *(const us8*)&A[(size_t)am*lda + kc + sseg];
    *(us8*)&Asl[srow][sseg] = va;
    us8 vb = {0,0,0,0,0,0,0,0};
    int bn = n0 + srow;
    if (bn < N) vb = *(const us8*)&B[(size_t)bn*ldb + kc + sseg];
    *(us8*)&Bsl[srow][sseg] = vb;
    __syncthreads();
    bf8v af = *(const bf8v*)&Asl[w*16 + fr][kg];
    bf8v b0 = *(const bf8v*)&Bsl[fr][kg];
    bf8v b1 = *(const bf8v*)&Bsl[16+fr][kg];
    bf8v b2 = *(const bf8v*)&Bsl[32+fr][kg];
    bf8v b3 = *(const bf8v*)&Bsl[48+fr][kg];
    ac0 = __builtin_amdgcn_mfma_f32_16x16x32_bf16(af, b0, ac0, 0,0,0);
    ac1 = __builtin_amdgcn_mfma_f32_16x16x32_bf16(af, b1, ac1, 0,0,0);
    ac2 = __builtin_amdgcn_mfma_f32_16x16x32_bf16(af, b2, ac2, 0,0,0);
    ac3 = __builtin_amdgcn_mfma_f32_16x16x32_bf16(af, b3, ac3, 0,0,0);
    __syncthreads();
  }
  int mb = m0 + w*16 + ((l6>>4)<<2);
  #pragma unroll
  for (int j=0;j<4;j++){
    int n = n0 + j*16 + fr;
    if (n >= N) continue;
    float bv = HASBIAS ? bias0[(size_t)l*N + n] : 0.f;
    f4v a = (j==0)?ac0:(j==1)?ac1:(j==2)?ac2:ac3;
    #pragma unroll
    for (int r=0;r<4;r++){
      int m = mb + r;
      if (TROUT){
        u16* out = (u16*)O0 + (size_t)lb*Ob;
        out[(size_t)n*ldo + m] = f2bf((m<M) ? (a[r]+bv) : 0.f);
      } else if (m < M){
        if (OUTBF){
          u16* out = (u16*)O0 + (size_t)lb*Ob;
          out[(size_t)m*ldo + n] = f2bf(a[r]+bv);
        } else {
          float* out = (float*)O0 + (size_t)lb*Ob;
          out[(size_t)m*ldo + n] = a[r]+bv;
        }
      }
    }
  }
}

// ================= role: mlp1 =================
__device__ void d_mlp1(int bid, int t, const float* __restrict__ pavg, const float* __restrict__ pmax,
    const float* __restrict__ aw1, const float* __restrict__ ab1,
    const float* __restrict__ mw1, const float* __restrict__ mb1,
    float* __restrict__ hid){
  int lb = bid >> 6; int rem = bid & 63; int pass = rem >> 5; int zb = rem & 31;
  int l = lb/NB;
  int wid = t>>6, lane = t&63;
  int r = zb*4 + wid;
  const float* pv = pass ? pmax : pavg;
  const float* w1 = pass ? mw1 : aw1;
  const float* b1 = pass ? mb1 : ab1;
  const float* wr = w1 + (size_t)(l*NC2+r)*NC;
  const float* pr = pv + (size_t)lb*NC;
  float s = dot4(((const float4*)wr)[lane], ((const float4*)pr)[lane]);
  s = wave_red(s);
  if (lane==0) hid[((size_t)lb*2 + pass)*NC2 + r] = fmaxf(s + b1[l*NC2+r], 0.f);
}

// ================= role: zphi =================
__device__ void d_zphi(int bid, int t, const float* __restrict__ zm, const float* __restrict__ sm,
    const float* __restrict__ phiw, const float* __restrict__ phib, float* __restrict__ zphi){
  int lb = bid >> 6; int rb = bid & 63; int l = lb/NB;
  int wid = t>>6, lane = t&63;
  int r = rb*4 + wid;
  const float* wr = phiw + (size_t)(l*NC + r)*NC;
  const float* zr = zm + (size_t)lb*NC;
  float s = dot4(((const float4*)wr)[lane], ((const float4*)zr)[lane]);
  s = wave_red(s);
  if (lane==0) zphi[(size_t)lb*NC + r] = s + phib[l*NC + r]*sm[lb];
}

__global__ __launch_bounds__(256) void sk_b(
    const u16* zfT, const u16* Wcat, const float* bcat, u16* TH3,
    const float* pavg, const float* pmax,
    const float* ap_w1, const float* ap_b1, const float* mp_w1, const float* mp_b1, float* hidb,
    const u16* roisT, const u16* Wcz, const float* bcz, u16* CZ3T,
    const float* zm, const float* sm, const float* phi_w, const float* phi_b, float* zphi){
  int bid = blockIdx.x, t = threadIdx.x;
  const int N1 = 96*24, N2 = N1 + 96*64, N3 = N2 + 96*8;
  if (bid < N1){
    d_mg<true,true,true,false>(bid, t, zfT, Wcat, bcat, TH3, ZZ, 384, NC, 256, 256, 384,
        (long)ZZ*256, (long)384*256, (long)ZZ*384, 6, 24);
  } else if (bid < N2){
    d_mlp1(bid - N1, t, pavg, pmax, ap_w1, ap_b1, mp_w1, mp_b1, hidb);
  } else if (bid < N3){
    d_mg<true,true,true,true>(bid - N2, t, roisT, Wcz, bcz, CZ3T, 49, 512, NC, 256, 256, 64,
        (long)49*256, (long)512*256, (long)512*64, 8, 8);
  } else {
    d_zphi(bid - N3, t, zm, sm, phi_w, phi_b, zphi);
  }
}

// ================= role: gxt =================
__device__ void d_gxt(int bid, int t, const u16* __restrict__ TH3, u16* __restrict__ GXT){
  int lb = bid >> 3; int z0 = (bid & 7)*32;
  __shared__ u16 lds[32][130];
  int n = t & 127, zi = t >> 7;
  const u16* src = TH3 + (size_t)lb*ZZ*384 + 256;
  #pragma unroll
  for (int p=0;p<16;p++){
    int z = z0 + zi + p*2;
    lds[zi+p*2][n] = (z < ZZ) ? src[(size_t)z*384 + n] : (u16)0;
  }
  __syncthreads();
  u16* dst = GXT + (size_t)lb*128*256;
  int zi2 = t & 31, ni = t >> 5;
  #pragma unroll
  for (int p=0;p<16;p++){
    int nn = ni + p*8;
    dst[(size_t)nn*256 + z0 + zi2] = lds[zi2][nn];
  }
}

// ================= role: mlp2 =================
__device__ void d_mlp2(int bid, int t, const float* __restrict__ hid,
    const float* __restrict__ aw2, const float* __restrict__ ab2,
    const float* __restrict__ mw2, const float* __restrict__ mb2,
    float* __restrict__ zavg, float* __restrict__ zmax){
  int lb = bid >> 7; int rem = bid & 127; int pass = rem >> 6; int cb = rem & 63;
  int l = lb/NB;
  int wid = t>>6, lane = t&63;
  int c = cb*4 + wid;
  const float* w2 = pass ? mw2 : aw2;
  const float* b2 = pass ? mb2 : ab2;
  const float* wr = w2 + (size_t)(l*NC+c)*NC2;
  const float* hr = hid + ((size_t)lb*2 + pass)*NC2;
  float2 wv = ((const float2*)wr)[lane];
  float2 hv = ((const float2*)hr)[lane];
  float s = wave_red(wv.x*hv.x + wv.y*hv.y);
  if (lane==0){
    float* zo = pass ? zmax : zavg;
    zo[(size_t)lb*NC + c] = s + b2[l*NC+c];
  }
}

// ================= role: wvec =================
__device__ void d_wvec(int lb, int t, const float* __restrict__ zphi, const float* __restrict__ dw,
    const float* __restrict__ db, float* __restrict__ wvec, float* __restrict__ cb){
  int l = lb/NB;
  __shared__ float zp[NC];
  __shared__ float red[NC];
  zp[t] = zphi[(size_t)lb*NC + t];
  __syncthreads();
  float s = 0.f;
  const float* dwl = dw + (size_t)l*NC*NC;
  for (int c=0;c<NC;c++) s += zp[c]*dwl[(size_t)c*NC + t];
  wvec[(size_t)lb*NC + t] = s;
  red[t] = zp[t]*db[l*NC + t];
  __syncthreads();
  for (int off2=128; off2>0; off2>>=1){
    if (t < off2) red[t] += red[t+off2];
    __syncthreads();
  }
  if (t==0) cb[lb] = red[0];
}

__global__ __launch_bounds__(256) void sk_c(
    const u16* TH3, float* Sb,
    u16* GXT,
    const float* hidb, const float* ap_w2, const float* ap_b2,
    const float* mp_w2, const float* mp_b2, float* zavg, float* zmax,
    const u16* CZ3T, float* Fbuf,
    const float* zphi, const float* delta_w, const float* delta_b, float* wvec, float* cbuf){
  int bid = blockIdx.x, t = threadIdx.x;
  const int N1 = 96*16, N2 = N1 + 96*8, N3 = N2 + 96*128, N4 = N3 + 96*16;
  if (bid < N1){
    d_mg<false,false,false,false>(bid, t, TH3, TH3+128, nullptr, Sb, ZZ, ZZ, NC2, 384, 384, ZZ,
        (long)ZZ*384, (long)ZZ*384, (long)ZZ*ZZ, 4, 16);
  } else if (bid < N2){
    d_gxt(bid - N1, t, TH3, GXT);
  } else if (bid < N3){
    d_mlp2(bid - N2, t, hidb, ap_w2, ap_b2, mp_w2, mp_b2, zavg, zmax);
  } else if (bid < N4){
    d_mg<false,false,false,false>(bid - N3, t, CZ3T, CZ3T+256*64, nullptr, Fbuf, NC, NC, 64, 64, 64, NC,
        (long)512*64, (long)512*64, (long)NC*NC, 4, 16);
  } else {
    d_wvec(bid - N4, t, zphi, delta_w, delta_b, wvec, cbuf);
  }
}

// ================= role: sc partial =================
__device__ void d_sc_part(int bid, int t, const float* __restrict__ xf,
    const float* __restrict__ wvec, float* __restrict__ part){
  int lb = bid >> 4; int rem = bid & 15; int xt = rem >> 2, cs = rem & 3;
  __shared__ float wv[64];
  if (t < 64) wv[t] = wvec[(size_t)lb*NC + cs*64 + t];
  __syncthreads();
  int x = xt*256 + t;
  if (x >= XX) return;
  const float* xb = xf + ((size_t)lb*NC + cs*64)*XX + x;
  float s = 0.f;
  #pragma unroll 8
  for (int c=0;c<64;c++) s += wv[c]*xb[(size_t)c*XX];
  part[((size_t)lb*4 + cs)*XX + x] = s;
}

// ================= role: softmax =================
__device__ void d_softmax(int bid, int t, const float* __restrict__ S, u16* __restrict__ P){
  int row = bid*4 + (t >> 6);
  int lane = t & 63;
  const float* r = S + (size_t)row*ZZ;
  float v[4]; float mx = -1e30f;
  #pragma unroll
  for (int q=0;q<4;q++){
    int j = lane + q*64;
    v[q] = (j<ZZ) ? r[j] : -1e30f;
    mx = fmaxf(mx, v[q]);
  }
  #pragma unroll
  for (int off=32; off>0; off>>=1) mx = fmaxf(mx, __shfl_xor(mx, off));
  float sum = 0.f;
  #pragma unroll
  for (int q=0;q<4;q++){
    v[q] = __expf(v[q]-mx);
    if (lane + q*64 < ZZ) sum += v[q];
  }
  #pragma unroll
  for (int off=32; off>0; off>>=1) sum += __shfl_xor(sum, off);
  float inv = 1.f/(16.f*sum);
  u16* pr = P + (size_t)row*256;
  #pragma unroll
  for (int q=0;q<4;q++){
    int j = lane + q*64;
    pr[j] = (j<ZZ) ? f2bf(v[q]*inv) : (u16)0;
  }
}

// ================= role: relw =================
__device__ void d_relw(int bid, int t, const float* __restrict__ F,
    const float* __restrict__ gw, const float* __restrict__ gb,
    float* __restrict__ rel){
  int lb = bid >> 7; int rb = bid & 127; int l = lb/NB;
  int wid = t>>6, lane = t&63;
  int r = rb*4 + wid;
  const float* wrow = gw + ((size_t)l*2*NC + r)*NC;
  const float* frow = F + (size_t)lb*NC*NC + (size_t)(r>>1)*NC;
  float s = dot4(((const float4*)wrow)[lane], ((const float4*)frow)[lane]);
  s = wave_red(s);
  if (lane==0) rel[(size_t)lb*2*NC + r] = fmaxf(s + gb[l*2*NC+r], 0.f);
}

__global__ __launch_bounds__(256) void sk_d(
    const float* xf, const float* wvec, float* part,
    const float* Sb, u16* Pb,
    const float* Fbuf, const float* cz_gw, const float* cz_gb, float* relb){
  int bid = blockIdx.x, t = threadIdx.x;
  const int N1 = 96*16, N2 = N1 + 5400;
  if (bid < N1){
    d_sc_part(bid, t, xf, wvec, part);
  } else if (bid < N2){
    d_softmax(bid - N1, t, Sb, Pb);
  } else {
    d_relw(bid - N2, t, Fbuf, cz_gw, cz_gb, relb);
  }
}

// ================= role: z2n+cues =================
__device__ void d_z2ncue(int bid, int t, const float* __restrict__ rel,
    const float* __restrict__ aw, const float* __restrict__ ab,
    const float* __restrict__ zavg, const float* __restrict__ zmax,
    const float* __restrict__ drw, const float* __restrict__ drb,
    float* __restrict__ cues){
  int lb = bid >> 6; int cb = bid & 63; int l = lb/NB;
  int wid = t>>6, lane = t&63;
  int c = cb*4 + wid;
  const float* arow = aw + ((size_t)l*NC + c)*2*NC;
  const float* rrow = rel + (size_t)lb*2*NC;
  float s = dot4(((const float4*)arow)[lane],    ((const float4*)rrow)[lane])
          + dot4(((const float4*)arow)[lane+64], ((const float4*)rrow)[lane+64]);
  s = wave_red(s);
  if (lane==0){
    float z2 = s + ab[l*NC+c];
    size_t idx = (size_t)lb*NC + c;
    const float* dw = drw + (size_t)(l*NC + c)*3;
    float x = dw[0]*zavg[idx] + dw[1]*zmax[idx] + dw[2]*z2 + drb[l*NC+c];
    cues[idx] = 1.f/(1.f + __expf(-x));
  }
}

// ================= role: sc finalize =================
__device__ void d_scfin(int lb, int t, const float* __restrict__ part,
    const float* __restrict__ cb, float* __restrict__ scb){
  float cbv = cb[lb];
  const float* pp = part + (size_t)lb*4*XX;
  for (int x = t; x < XX; x += 256){
    float s = pp[x] + pp[XX + x] + pp[2*XX + x] + pp[3*XX + x];
    scb[(size_t)lb*XX + x] = fminf(fmaxf((s + cbv)*0.0625f, 0.f), 1.f);
  }
}

__global__ __launch_bounds__(256) void sk_e(
    const u16* Pb, const u16* GXT, u16* Ybb,
    const float* relb, const float* cz_aw, const float* cz_ab,
    const float* zavg, const float* zmax, const float* dr_w, const float* dr_b, float* cues,
    const float* part, const float* cbuf, float* scb){
  int bid = blockIdx.x, t = threadIdx.x;
  const int N1 = 96*8, N2 = N1 + 96*64;
  if (bid < N1){
    d_mg<false,false,true,false>(bid, t, Pb, GXT, nullptr, Ybb, ZZ, NC2, 256, 256, 256, NC2,
        (long)ZZ*256, (long)128*256, (long)ZZ*NC2, 2, 8);
  } else if (bid < N2){
    d_z2ncue(bid - N1, t, relb, cz_aw, cz_ab, zavg, zmax, dr_w, dr_b, cues);
  } else {
    d_scfin(bid - N2, t, part, cbuf, scb);
  }
}

// ================= role: outconv (LDS-staged coalesced epilogue) =================
__device__ void d_outconv(int bid, int t, const u16* __restrict__ outwb,
    const u16* __restrict__ Ybb,
    const float* __restrict__ bng, const float* __restrict__ bnb,
    const float* __restrict__ bnm, const float* __restrict__ bnv,
    const float* __restrict__ cues, const float* __restrict__ zf,
    float* __restrict__ dzfout, float* __restrict__ dzffull){
  int lb = bid >> 4; int tile = bid & 15; int l = lb/NB;
  const u16* A = outwb + (size_t)l*NC*NC2;
  const u16* B = Ybb + (size_t)lb*ZZ*NC2;
  int tm = tile >> 2, tn = tile & 3;
  int m0 = tm*64, n0 = tn*64;
  __shared__ u16 Asl[64][40];
  __shared__ u16 Bsl[64][40];
  __shared__ float ob[64][65];
  int w = t>>6, l6 = t&63;
  int fr = l6&15, kg = (l6>>4)*8;
  int srow = t>>2, sseg = (t&3)*8;
  f4v ac0={0,0,0,0}, ac1={0,0,0,0}, ac2={0,0,0,0}, ac3={0,0,0,0};
  for (int kc=0; kc<NC2; kc+=32){
    us8 va = *(const us8*)&A[(size_t)(m0+srow)*NC2 + kc + sseg];
    *(us8*)&Asl[srow][sseg] = va;
    us8 vb = {0,0,0,0,0,0,0,0};
    int bn = n0 + srow;
    if (bn < ZZ) vb = *(const us8*)&B[(size_t)bn*NC2 + kc + sseg];
    *(us8*)&Bsl[srow][sseg] = vb;
    __syncthreads();
    bf8v af = *(const bf8v*)&Asl[w*16 + fr][kg];
    bf8v b0 = *(const bf8v*)&Bsl[fr][kg];
    bf8v b1 = *(const bf8v*)&Bsl[16+fr][kg];
    bf8v b2 = *(const bf8v*)&Bsl[32+fr][kg];
    bf8v b3 = *(const bf8v*)&Bsl[48+fr][kg];
    ac0 = __builtin_amdgcn_mfma_f32_16x16x32_bf16(af, b0, ac0, 0,0,0);
    ac1 = __builtin_amdgcn_mfma_f32_16x16x32_bf16(af, b1, ac1, 0,0,0);
    ac2 = __builtin_amdgcn_mfma_f32_16x16x32_bf16(af, b2, ac2, 0,0,0);
    ac3 = __builtin_amdgcn_mfma_f32_16x16x32_bf16(af, b3, ac3, 0,0,0);
    __syncthreads();
  }
  #pragma unroll
  for (int it=0; it<16; ++it){
    int rr = (t>>6) + it*4;
    int zz = t & 63;
    int z = n0 + zz;
    ob[rr][zz] = (z < ZZ) ? zf[((size_t)lb*NC + m0 + rr)*ZZ + z] : 0.f;
  }
  __syncthreads();
  int mbr = w*16 + ((l6>>4)<<2);
  #pragma unroll
  for (int j=0;j<4;j++){
    int zrel = j*16 + fr;
    int z = n0 + zrel;
    if (z >= ZZ) continue;
    f4v a = (j==0)?ac0:(j==1)?ac1:(j==2)?ac2:ac3;
    #pragma unroll
    for (int r=0;r<4;r++){
      int crel = mbr + r; int c = m0 + crel;
      float scale = bng[l*NC+c] * rsqrtf(bnv[l*NC+c] + 1e-5f);
      float val = (a[r] - bnm[l*NC+c])*scale + bnb[l*NC+c];
      float cu = cues[(size_t)lb*NC + c];
      float zv = ob[crel][zrel];
      ob[crel][zrel] = cu*zv + zv + val;
    }
  }
  __syncthreads();
  #pragma unroll
  for (int it=0; it<16; ++it){
    int rr = (t>>6) + it*4;
    int zz = t & 63;
    int z = n0 + zz;
    if (z < ZZ) dzffull[((size_t)lb*NC + m0 + rr)*ZZ + z] = ob[rr][zz];
  }
  for (int e=t; e<64*49; e+=256){
    int cc = e / 49; int idx = e % 49; int p = idx/7, q = idx%7;
    int z = (p+4)*15 + (q+4);
    if (z >= n0 && z < n0+64)
      dzfout[((size_t)lb*NC + m0 + cc)*49 + p*7 + q] = ob[cc][z - n0];
  }
}

// ================= role: xfout (block per (lb, 8-ch group), float4) =================
__device__ void d_xfout(int bid, int t, const float* __restrict__ xf,
    const float* __restrict__ scb, const float* __restrict__ cues,
    float* __restrict__ out){
  int lb = bid >> 5; int cg = bid & 31;
  int cbase = cg*8;
  __shared__ float cu1s[8];
  if (t < 8) cu1s[t] = 1.f + cues[(size_t)lb*NC + cbase + t];
  __syncthreads();
  const float4* xr = (const float4*)(xf + ((size_t)lb*NC + cbase)*XX);
  float4* orow = (float4*)(out + ((size_t)lb*NC + cbase)*XX);
  const float* sr = scb + (size_t)lb*XX;
  const int NV = 8*XX/4;  // 1922
  for (int idx = t; idx < NV; idx += 256){
    float4 v = xr[idx];
    int rel = idx*4;
    float4 o;
    #pragma unroll
    for (int k=0;k<4;k++){
      int e = rel + k;
      int cl = e / XX;
      int x  = e - cl*XX;
      ((float*)&o)[k] = cu1s[cl]*((const float*)&v)[k] - sr[x];
    }
    orow[idx] = o;
  }
}

__global__ __launch_bounds__(256) void sk_f(
    const u16* outwb, const u16* Ybb,
    const float* bn_g, const float* bn_b, const float* bn_m, const float* bn_v,
    const float* cues, const float* zf, float* o_zfout, float* o_zffull,
    const float* xf, const float* scb, float* o_xfout){
  int bid = blockIdx.x, t = threadIdx.x;
  const int N1 = 96*16;
  if (bid < N1){
    d_outconv(bid, t, outwb, Ybb, bn_g, bn_b, bn_m, bn_v, cues, zf, o_zfout, o_zffull);
  } else {
    d_xfout(bid - N1, t, xf, scb, cues, o_xfout);
  }
}

extern "C" void kernel_launch(void* const* d_in, const int* in_sizes, int n_in,
                              void* d_out, int out_size, void* d_ws, size_t ws_size,
                              hipStream_t stream){
  const float* zf      = (const float*)d_in[0];
  const float* xf      = (const float*)d_in[1];
  const float* maskp   = (const float*)d_in[2];
  const float* box     = (const float*)d_in[3];
  const float* nl_g_w  = (const float*)d_in[4];
  const float* nl_g_b  = (const float*)d_in[5];
  const float* nl_th_w = (const float*)d_in[6];
  const float* nl_th_b = (const float*)d_in[7];
  const float* nl_ph_w = (const float*)d_in[8];
  const float* nl_ph_b = (const float*)d_in[9];
  const float* nl_out_w= (const float*)d_in[10];
  const float* bn_g    = (const float*)d_in[11];
  const float* bn_b    = (const float*)d_in[12];
  const float* bn_m    = (const float*)d_in[13];
  const float* bn_v    = (const float*)d_in[14];
  const float* cz_th_w = (const float*)d_in[15];
  const float* cz_th_b = (const float*)d_in[16];
  const float* cz_ph_w = (const float*)d_in[17];
  const float* cz_ph_b = (const float*)d_in[18];
  const float* cz_gw   = (const float*)d_in[19];
  const float* cz_gb   = (const float*)d_in[20];
  const float* cz_aw   = (const float*)d_in[21];
  const float* cz_ab   = (const float*)d_in[22];
  const float* ap_w1   = (const float*)d_in[23];
  const float* ap_b1   = (const float*)d_in[24];
  const float* ap_w2   = (const float*)d_in[25];
  const float* ap_b2   = (const float*)d_in[26];
  const float* mp_w1   = (const float*)d_in[27];
  const float* mp_b1   = (const float*)d_in[28];
  const float* mp_w2   = (const float*)d_in[29];
  const float* mp_b2   = (const float*)d_in[30];
  const float* dr_w    = (const float*)d_in[31];
  const float* dr_b    = (const float*)d_in[32];
  const float* ac1_w   = (const float*)d_in[33];
  const float* ac1_b   = (const float*)d_in[34];
  const float* ac2_w   = (const float*)d_in[35];
  const float* ac2_b   = (const float*)d_in[36];
  const float* ac3_w   = (const float*)d_in[37];
  const float* ac3_b   = (const float*)d_in[38];
  const float* ac4_w   = (const float*)d_in[39];
  const float* ac4_b   = (const float*)d_in[40];
  const float* phi_w   = (const float*)d_in[41];
  const float* phi_b   = (const float*)d_in[42];
  const float* delta_w = (const float*)d_in[43];
  const float* delta_b = (const float*)d_in[44];
  (void)in_sizes; (void)n_in; (void)out_size; (void)ws_size;

  float* ws = (float*)d_ws;
  size_t off = 0;
  auto alloc = [&](size_t n){ size_t o = off; off += (n + 15) & ~(size_t)15; return o; };
  float* TH3f  = ws + alloc((size_t)NL*NB*ZZ*384/2);
  float* Sb    = ws + alloc((size_t)NL*NB*ZZ*ZZ);
  float* Fbuf  = ws + alloc((size_t)NL*NB*NC*NC);
  float* zfTf  = ws + alloc((size_t)NL*NB*ZZ*NC/2);
  float* Pbf   = ws + alloc((size_t)NL*NB*ZZ*256/2);
  float* GXTf  = ws + alloc((size_t)NL*NB*128*256/2);
  float* Ybbf  = ws + alloc((size_t)NL*NB*ZZ*NC2/2);
  float* CZ3Tf = ws + alloc((size_t)NL*NB*512*64/2);
  float* roisTf= ws + alloc((size_t)NL*NB*49*NC/2);
  float* Wcatf = ws + alloc((size_t)NL*384*256/2);
  float* Wczf  = ws + alloc((size_t)NL*512*256/2);
  float* outwbf= ws + alloc((size_t)NL*NC*NC2/2);
  u16* TH3  = (u16*)TH3f;
  u16 *zfT=(u16*)zfTf, *Pb=(u16*)Pbf, *GXT=(u16*)GXTf, *Ybb=(u16*)Ybbf,
      *CZ3T=(u16*)CZ3Tf, *roisT=(u16*)roisTf, *Wcat=(u16*)Wcatf,
      *Wcz=(u16*)Wczf, *outwb=(u16*)outwbf;
  float* bcat = ws + alloc((size_t)NL*384);
  float* bcz  = ws + alloc((size_t)NL*512);
  float* m3   = ws + alloc((size_t)NL*NB*ZZ);
  float* pavg = ws + alloc((size_t)NL*NB*NC);
  float* pmax = ws + alloc((size_t)NL*NB*NC);
  float* zavg = ws + alloc((size_t)NL*NB*NC);
  float* zmax = ws + alloc((size_t)NL*NB*NC);
  float* cues = ws + alloc((size_t)NL*NB*NC);
  float* zm   = ws + alloc((size_t)NL*NB*NC);
  float* zphi = ws + alloc((size_t)NL*NB*NC);
  float* wvec = ws + alloc((size_t)NL*NB*NC);
  float* sm   = ws + alloc((size_t)NL*NB);
  float* cbuf = ws + alloc((size_t)NL*NB);
  float* part = ws + alloc((size_t)NL*NB*4*XX);
  float* scb  = ws + alloc((size_t)NL*NB*XX);
  float* hidb = ws + alloc((size_t)NL*NB*2*NC2);
  float* relb = ws + alloc((size_t)NL*NB*2*NC);

  float* outp    = (float*)d_out;
  float* o_zfout = outp;
  float* o_zffull= outp + (size_t)NL*NB*NC*49;
  float* o_xfout = o_zffull + (size_t)NL*NB*NC*ZZ;

  // L1: mask + packs
  sk_a<<<NL*NB + (NL*512*256+255)/256, 256, 0, stream>>>(
      maskp, ac1_w, ac1_b, ac2_w, ac2_b, ac3_w, ac3_b, ac4_w, ac4_b, m3,
      nl_th_w, nl_th_b, nl_ph_w, nl_ph_b, nl_g_w, nl_g_b,
      cz_th_w, cz_th_b, cz_ph_w, cz_ph_b, nl_out_w,
      Wcat, bcat, Wcz, bcz, outwb);
  // L2: fused zf pass
  k_zfall<<<dim3(NL*NB, 8), 256, 0, stream>>>(zf, box, m3, zfT, pavg, pmax,
                                               roisT, zm, sm);
  // L3: projcat + mlp1 + CZ + zphi
  sk_b<<<96*24 + 96*64 + 96*8 + 96*64, 256, 0, stream>>>(
      zfT, Wcat, bcat, TH3, pavg, pmax, ap_w1, ap_b1, mp_w1, mp_b1, hidb,
      roisT, Wcz, bcz, CZ3T, zm, sm, phi_w, phi_b, zphi);
  // L4: S + gxt + mlp2 + F + wvec
  sk_c<<<96*16 + 96*8 + 96*128 + 96*16 + 96, 256, 0, stream>>>(
      TH3, Sb, GXT, hidb, ap_w2, ap_b2, mp_w2, mp_b2, zavg, zmax,
      CZ3T, Fbuf, zphi, delta_w, delta_b, wvec, cbuf);
  // L5: sc_part + softmax + relw
  sk_d<<<96*16 + 5400 + 96*128, 256, 0, stream>>>(
      xf, wvec, part, Sb, Pb, Fbuf, cz_gw, cz_gb, relb);
  // L6: PV + z2ncue + scfin
  sk_e<<<96*8 + 96*64 + 96, 256, 0, stream>>>(
      Pb, GXT, Ybb, relb, cz_aw, cz_ab, zavg, zmax, dr_w, dr_b, cues,
      part, cbuf, scb);
  // L7: outconv + xfout
  sk_f<<<96*16 + 96*32, 256, 0, stream>>>(
      outwb, Ybb, bn_g, bn_b, bn_m, bn_v, cues, zf, o_zfout, o_zffull,
      xf, scb, o_xfout);
}